// Round 2
// baseline (41203.506 us; speedup 1.0000x reference)
//
#include <hip/hip_runtime.h>
#include <cstdint>
#include <cstddef>

// ParticleNet on MI355X — Round 2: fp32 pipeline + fp64-rescored kNN selection.
// B=1024 events, N=128 points, K=4 neighbors.
// knn: fp32 distances rank a top-6 shortlist; the 6 are rescored in fp64
// (exact for fp32 inputs) and the true top-4 picked with top_k tie semantics.
// This removes summation-order sensitivity in the neighbor SETS, which was
// the round-1 failure mode (absmax 0.0986 ~ a few flipped neighbors).

#define NB 1024
#define NPT 128

__device__ __forceinline__ float elu_f(float x) { return x > 0.0f ? x : expm1f(x); }

// ---------------------------------------------------------------- kNN ----
template<int C>
__global__ __launch_bounds__(128) void knn_kernel(const float* __restrict__ x,
                                                  int* __restrict__ idx) {
  __shared__ __align__(16) float xs[NPT][C + 4];
  __shared__ float x2s[NPT];
  __shared__ double x2d[NPT];
  const int b = blockIdx.x, t = threadIdx.x;
  const float* xb = x + (size_t)b * NPT * C;
  for (int e = t; e < NPT * C; e += 128) xs[e / C][e % C] = xb[e];
  __syncthreads();
  float xi[C];
  float s2 = 0.0f;
  double s2d = 0.0;
#pragma unroll
  for (int c = 0; c < C; ++c) {
    xi[c] = xs[t][c];
    s2 += xi[c] * xi[c];
    s2d += (double)xi[c] * (double)xi[c];
  }
  x2s[t] = s2;
  x2d[t] = s2d;
  __syncthreads();
  // ---- pass 1: fp32 top-6 shortlist (strict <, stable => lower index first)
  float bd0 = 1e30f, bd1 = 1e30f, bd2 = 1e30f, bd3 = 1e30f, bd4 = 1e30f, bd5 = 1e30f;
  int bi0 = 0, bi1 = 0, bi2 = 0, bi3 = 0, bi4 = 0, bi5 = 0;
  for (int j = 0; j < NPT; ++j) {
    if (j == t) continue;
    float dot = 0.0f;
    if constexpr (C >= 4) {
      const float4* xr = reinterpret_cast<const float4*>(&xs[j][0]);
#pragma unroll
      for (int c4 = 0; c4 < C / 4; ++c4) {
        float4 v = xr[c4];
        dot += xi[4 * c4 + 0] * v.x + xi[4 * c4 + 1] * v.y +
               xi[4 * c4 + 2] * v.z + xi[4 * c4 + 3] * v.w;
      }
    } else {
#pragma unroll
      for (int c = 0; c < C; ++c) dot += xi[c] * xs[j][c];
    }
    float d = s2 + x2s[j] - 2.0f * dot;
    if (d < bd5) {
      bd5 = d; bi5 = j;
      if (bd5 < bd4) {
        float td = bd4; bd4 = bd5; bd5 = td; int ti = bi4; bi4 = bi5; bi5 = ti;
        if (bd4 < bd3) {
          td = bd3; bd3 = bd4; bd4 = td; ti = bi3; bi3 = bi4; bi4 = ti;
          if (bd3 < bd2) {
            td = bd2; bd2 = bd3; bd3 = td; ti = bi2; bi2 = bi3; bi3 = ti;
            if (bd2 < bd1) {
              td = bd1; bd1 = bd2; bd2 = td; ti = bi1; bi1 = bi2; bi2 = ti;
              if (bd1 < bd0) {
                td = bd0; bd0 = bd1; bd1 = td; ti = bi0; bi0 = bi1; bi1 = ti;
              }
            }
          }
        }
      }
    }
  }
  // ---- pass 2: fp64 rescore of the 6 candidates (exact ordering) ----
  auto refine = [&](int j) -> double {
    double dot = 0.0;
#pragma unroll
    for (int c = 0; c < C; ++c) dot += (double)xi[c] * (double)xs[j][c];
    return s2d + x2d[j] - 2.0 * dot;
  };
  double e0 = refine(bi0), e1 = refine(bi1), e2 = refine(bi2);
  double e3 = refine(bi3), e4 = refine(bi4), e5 = refine(bi5);
  // full unrolled bubble sort of 6 by (d, idx) ascending — top_k tie semantics
#define CSWP(da, ia, db, ib)                                            \
  if ((da > db) || (da == db && ia > ib)) {                             \
    double _td = da; da = db; db = _td; int _ti = ia; ia = ib; ib = _ti; }
  CSWP(e0, bi0, e1, bi1) CSWP(e1, bi1, e2, bi2) CSWP(e2, bi2, e3, bi3)
  CSWP(e3, bi3, e4, bi4) CSWP(e4, bi4, e5, bi5)
  CSWP(e0, bi0, e1, bi1) CSWP(e1, bi1, e2, bi2) CSWP(e2, bi2, e3, bi3)
  CSWP(e3, bi3, e4, bi4)
  CSWP(e0, bi0, e1, bi1) CSWP(e1, bi1, e2, bi2) CSWP(e2, bi2, e3, bi3)
  CSWP(e0, bi0, e1, bi1) CSWP(e1, bi1, e2, bi2)
  CSWP(e0, bi0, e1, bi1)
#undef CSWP
  int* ib = idx + ((size_t)b * NPT + t) * 4;
  ib[0] = bi0; ib[1] = bi1; ib[2] = bi2; ib[3] = bi3;
}

// ---------------------------------------------------------------- ec1 ----
// 5 -> (concat 10) -> 32 -> 64, mean over 4 edges. Thread per point.
__global__ __launch_bounds__(128) void ec1_kernel(
    const float* __restrict__ feat, const int* __restrict__ idx,
    const float* __restrict__ w1, const float* __restrict__ b1,
    const float* __restrict__ w2, const float* __restrict__ b2,
    float* __restrict__ out) {
  __shared__ float fs[NPT][5];
  __shared__ float w1s[10][32];
  __shared__ float w2s[32][64];
  __shared__ float b1s[32], b2s[64];
  const int b = blockIdx.x, t = threadIdx.x;
  const float* fb = feat + (size_t)b * NPT * 5;
  for (int e = t; e < NPT * 5; e += 128) fs[e / 5][e % 5] = fb[e];
  for (int e = t; e < 320; e += 128) w1s[e / 32][e % 32] = w1[e];
  for (int e = t; e < 2048; e += 128) w2s[e >> 6][e & 63] = w2[e];
  if (t < 32) b1s[t] = b1[t];
  if (t < 64) b2s[t] = b2[t];
  __syncthreads();
  float xi[5];
#pragma unroll
  for (int c = 0; c < 5; ++c) xi[c] = fs[t][c];
  const int* ib = idx + ((size_t)b * NPT + t) * 4;
  float acc[64];
#pragma unroll
  for (int o = 0; o < 64; ++o) acc[o] = 0.0f;
  for (int e = 0; e < 4; ++e) {
    int j = ib[e];
    float in10[10];
#pragma unroll
    for (int c = 0; c < 5; ++c) {
      float xj = fs[j][c];
      in10[c] = xi[c];
      in10[5 + c] = xj - xi[c];
    }
    float t32[32];
#pragma unroll
    for (int o = 0; o < 32; ++o) {
      float s = b1s[o];
#pragma unroll
      for (int c = 0; c < 10; ++c) s += in10[c] * w1s[c][o];
      t32[o] = elu_f(s);
    }
#pragma unroll
    for (int o = 0; o < 64; ++o) {
      float s = b2s[o];
#pragma unroll
      for (int c = 0; c < 32; ++c) s += t32[c] * w2s[c][o];
      acc[o] += elu_f(s);
    }
  }
  float* ob = out + ((size_t)b * NPT + t) * 64;
#pragma unroll
  for (int o = 0; o < 64; ++o) ob[o] = 0.25f * acc[o];
}

// ---------------------------------------------------------------- ec2 ----
// 64 -> (concat 128) -> 96 -> 128, mean over 4 edges.
// Block = 1 event, 512 threads = 1 thread/edge; edge-mean via shfl_xor(1,2).
__global__ __launch_bounds__(512) void ec2_kernel(
    const float* __restrict__ x, const int* __restrict__ idx,
    const float* __restrict__ w1, const float* __restrict__ b1,
    const float* __restrict__ w2, const float* __restrict__ b2,
    float* __restrict__ out) {
  __shared__ __align__(16) float xs[NPT][68];     // 64 + pad (2-way max conflict)
  __shared__ __align__(16) float w1s[128][96];
  __shared__ __align__(16) float w2t[128][100];   // transposed w2, padded
  __shared__ float b1s[96], b2s[128];
  const int b = blockIdx.x, t = threadIdx.x;
  const float* xb = x + (size_t)b * NPT * 64;
  for (int e = t; e < NPT * 64; e += 512) xs[e >> 6][e & 63] = xb[e];
  for (int e = t; e < 128 * 96; e += 512) w1s[e / 96][e % 96] = w1[e];
  for (int e = t; e < 96 * 128; e += 512) w2t[e & 127][e >> 7] = w2[e];
  if (t < 96) b1s[t] = b1[t];
  if (t >= 384) b2s[t - 384] = b2[t - 384];
  __syncthreads();
  const int p = t >> 2, e4 = t & 3;
  const int j = idx[((size_t)b * NPT + p) * 4 + e4];
  float acc[96];
#pragma unroll
  for (int o = 0; o < 96; ++o) acc[o] = b1s[o];
  for (int c = 0; c < 64; ++c) {
    float xic = xs[p][c];
    float hd = xs[j][c] - xic;
    const float4* wr0 = reinterpret_cast<const float4*>(&w1s[c][0]);
    const float4* wr1 = reinterpret_cast<const float4*>(&w1s[64 + c][0]);
#pragma unroll
    for (int o4 = 0; o4 < 24; ++o4) {
      float4 a = wr0[o4];
      float4 d2 = wr1[o4];
      acc[4 * o4 + 0] += xic * a.x + hd * d2.x;
      acc[4 * o4 + 1] += xic * a.y + hd * d2.y;
      acc[4 * o4 + 2] += xic * a.z + hd * d2.z;
      acc[4 * o4 + 3] += xic * a.w + hd * d2.w;
    }
  }
#pragma unroll
  for (int o = 0; o < 96; ++o) acc[o] = elu_f(acc[o]);
  float* ob = out + ((size_t)b * NPT + p) * 128;
  for (int o4 = 0; o4 < 32; ++o4) {
    float s0 = b2s[4 * o4 + 0], s1 = b2s[4 * o4 + 1];
    float s2v = b2s[4 * o4 + 2], s3 = b2s[4 * o4 + 3];
    const float4* r0 = reinterpret_cast<const float4*>(&w2t[4 * o4 + 0][0]);
    const float4* r1 = reinterpret_cast<const float4*>(&w2t[4 * o4 + 1][0]);
    const float4* r2 = reinterpret_cast<const float4*>(&w2t[4 * o4 + 2][0]);
    const float4* r3 = reinterpret_cast<const float4*>(&w2t[4 * o4 + 3][0]);
#pragma unroll
    for (int k4 = 0; k4 < 24; ++k4) {
      float4 v0 = r0[k4], v1 = r1[k4], v2 = r2[k4], v3 = r3[k4];
      float t0 = acc[4 * k4 + 0], t1 = acc[4 * k4 + 1];
      float t2 = acc[4 * k4 + 2], t3 = acc[4 * k4 + 3];
      s0 += t0 * v0.x + t1 * v0.y + t2 * v0.z + t3 * v0.w;
      s1 += t0 * v1.x + t1 * v1.y + t2 * v1.z + t3 * v1.w;
      s2v += t0 * v2.x + t1 * v2.y + t2 * v2.z + t3 * v2.w;
      s3 += t0 * v3.x + t1 * v3.y + t2 * v3.z + t3 * v3.w;
    }
    s0 = elu_f(s0); s1 = elu_f(s1); s2v = elu_f(s2v); s3 = elu_f(s3);
    s0 += __shfl_xor(s0, 1); s0 += __shfl_xor(s0, 2);
    s1 += __shfl_xor(s1, 1); s1 += __shfl_xor(s1, 2);
    s2v += __shfl_xor(s2v, 1); s2v += __shfl_xor(s2v, 2);
    s3 += __shfl_xor(s3, 1); s3 += __shfl_xor(s3, 2);
    if ((o4 >> 3) == e4) {
      float4 v = {0.25f * s0, 0.25f * s1, 0.25f * s2v, 0.25f * s3};
      *reinterpret_cast<float4*>(&ob[4 * o4]) = v;
    }
  }
}

// ---------------------------------------------------------------- ec3 ----
// 128 -> (concat 256) -> 192 -> 256, mean over 4 edges. Thread per edge,
// hidden t[192] in registers, weights streamed through LDS in 64-row chunks.
__global__ __launch_bounds__(512) void ec3_kernel(
    const float* __restrict__ x, const int* __restrict__ idx,
    const float* __restrict__ w1, const float* __restrict__ b1,
    const float* __restrict__ w2, const float* __restrict__ b2,
    float* __restrict__ out) {
  __shared__ __align__(16) float xs[NPT][132];
  __shared__ __align__(16) float wbuf[64 * 196];  // 12544 floats, reused both layers
  __shared__ float b1s[192], b2s[256];
  const int b = blockIdx.x, t = threadIdx.x;
  const float* xb = x + (size_t)b * NPT * 128;
  for (int e = t; e < NPT * 128; e += 512) xs[e >> 7][e & 127] = xb[e];
  if (t < 192) b1s[t] = b1[t];
  if (t >= 256) b2s[t - 256] = b2[t - 256];
  const int p = t >> 2, e4 = t & 3;
  const int j = idx[((size_t)b * NPT + p) * 4 + e4];
  float tr[192];
  __syncthreads();
#pragma unroll
  for (int o = 0; o < 192; ++o) tr[o] = b1s[o];
  // layer 1: chunks cc=0,1 -> xi part (c 0..127); cc=2,3 -> (xj-xi) part.
  for (int cc = 0; cc < 4; ++cc) {
    __syncthreads();
    for (int e2 = t; e2 < 64 * 192; e2 += 512) wbuf[e2] = w1[(size_t)cc * 64 * 192 + e2];
    __syncthreads();
    const int fbase = (cc & 1) * 64;
    const bool diff = (cc >= 2);
    for (int cl = 0; cl < 64; ++cl) {
      const int f = fbase + cl;
      float xv = xs[p][f];
      float h = diff ? (xs[j][f] - xv) : xv;
      const float4* wr = reinterpret_cast<const float4*>(&wbuf[cl * 192]);
#pragma unroll
      for (int o4 = 0; o4 < 48; ++o4) {
        float4 w = wr[o4];
        tr[4 * o4 + 0] += h * w.x;
        tr[4 * o4 + 1] += h * w.y;
        tr[4 * o4 + 2] += h * w.z;
        tr[4 * o4 + 3] += h * w.w;
      }
    }
  }
#pragma unroll
  for (int o = 0; o < 192; ++o) tr[o] = elu_f(tr[o]);
  // layer 2: 4 output chunks of 64; w2 chunk transposed into LDS [ol][k].
  float* ob = out + ((size_t)b * NPT + p) * 256;
  for (int oc = 0; oc < 4; ++oc) {
    __syncthreads();
    for (int e2 = t; e2 < 192 * 64; e2 += 512) {
      int k = e2 >> 6, ol = e2 & 63;
      wbuf[ol * 196 + k] = w2[(size_t)k * 256 + oc * 64 + ol];
    }
    __syncthreads();
    for (int og = 0; og < 16; ++og) {
      float s0 = 0.f, s1 = 0.f, s2v = 0.f, s3 = 0.f;
      const float4* r0 = reinterpret_cast<const float4*>(&wbuf[(4 * og + 0) * 196]);
      const float4* r1 = reinterpret_cast<const float4*>(&wbuf[(4 * og + 1) * 196]);
      const float4* r2 = reinterpret_cast<const float4*>(&wbuf[(4 * og + 2) * 196]);
      const float4* r3 = reinterpret_cast<const float4*>(&wbuf[(4 * og + 3) * 196]);
#pragma unroll
      for (int k4 = 0; k4 < 48; ++k4) {
        float4 v0 = r0[k4], v1 = r1[k4], v2 = r2[k4], v3 = r3[k4];
        float t0 = tr[4 * k4 + 0], t1 = tr[4 * k4 + 1];
        float t2 = tr[4 * k4 + 2], t3 = tr[4 * k4 + 3];
        s0 += t0 * v0.x + t1 * v0.y + t2 * v0.z + t3 * v0.w;
        s1 += t0 * v1.x + t1 * v1.y + t2 * v1.z + t3 * v1.w;
        s2v += t0 * v2.x + t1 * v2.y + t2 * v2.z + t3 * v2.w;
        s3 += t0 * v3.x + t1 * v3.y + t2 * v3.z + t3 * v3.w;
      }
      int olb = 4 * og;
      s0 = elu_f(s0 + b2s[oc * 64 + olb + 0]);
      s1 = elu_f(s1 + b2s[oc * 64 + olb + 1]);
      s2v = elu_f(s2v + b2s[oc * 64 + olb + 2]);
      s3 = elu_f(s3 + b2s[oc * 64 + olb + 3]);
      s0 += __shfl_xor(s0, 1); s0 += __shfl_xor(s0, 2);
      s1 += __shfl_xor(s1, 1); s1 += __shfl_xor(s1, 2);
      s2v += __shfl_xor(s2v, 1); s2v += __shfl_xor(s2v, 2);
      s3 += __shfl_xor(s3, 1); s3 += __shfl_xor(s3, 2);
      if ((og >> 2) == e4) {
        float4 v = {0.25f * s0, 0.25f * s1, 0.25f * s2v, 0.25f * s3};
        *reinterpret_cast<float4*>(&ob[oc * 64 + olb]) = v;
      }
    }
  }
}

// --------------------------------------------------------------- head ----
// concat(5+64+128+256=453) -> 453 (ELU) -> 226 (ELU) -> 2.
// Block = 32 points, 512 threads = 16 pairs x 32 lanes; each lane owns a
// contiguous o-range for BOTH points of its pair (2x weight reuse per LDS read).
__global__ __launch_bounds__(512) void head_kernel(
    const float* __restrict__ feat, const float* __restrict__ o1,
    const float* __restrict__ o2, const float* __restrict__ o3,
    const float* __restrict__ w1, const float* __restrict__ b1,
    const float* __restrict__ w2, const float* __restrict__ b2,
    const float* __restrict__ w3, const float* __restrict__ b3,
    float* __restrict__ out) {
  __shared__ __align__(16) float bufA[32 * 456];       // X, later H2
  __shared__ __align__(16) float bufB[32 * 456];       // H1
  __shared__ __align__(16) float wch[16 * 456 + 64];   // weight k-chunk (+overread pad)
  const int t = threadIdx.x;
  const size_t pt0 = (size_t)blockIdx.x * 32;
  for (int e = t; e < 32 * 5; e += 512) bufA[(e / 5) * 456 + (e % 5)] = feat[pt0 * 5 + e];
  for (int e = t; e < 32 * 64; e += 512) bufA[(e >> 6) * 456 + 5 + (e & 63)] = o1[pt0 * 64 + e];
  for (int e = t; e < 32 * 128; e += 512) bufA[(e >> 7) * 456 + 69 + (e & 127)] = o2[pt0 * 128 + e];
  for (int e = t; e < 32 * 256; e += 512) bufA[(e >> 8) * 456 + 197 + (e & 255)] = o3[pt0 * 256 + e];
  const int g = t >> 5, s2 = t & 31;
  const int p0 = 2 * g, p1 = 2 * g + 1;
  // ---- layer 1: 453 -> 453, ELU ----
  {
    const int o0 = s2 * 16;
    const int cnt = max(0, min(16, 453 - o0));
    float acc0[16], acc1[16];
#pragma unroll
    for (int m = 0; m < 16; ++m) {
      int o = o0 + m;
      float bv = (o < 453) ? b1[o] : 0.0f;
      acc0[m] = bv; acc1[m] = bv;
    }
    for (int kc = 0; kc < 453; kc += 16) {
      const int kn = min(16, 453 - kc);
      __syncthreads();
      for (int e2 = t; e2 < kn * 453; e2 += 512)
        wch[(e2 / 453) * 456 + (e2 % 453)] = w1[(size_t)(kc + e2 / 453) * 453 + (e2 % 453)];
      __syncthreads();
      for (int kl = 0; kl < kn; ++kl) {
        float xv0 = bufA[p0 * 456 + kc + kl];
        float xv1 = bufA[p1 * 456 + kc + kl];
        const float4* wr = reinterpret_cast<const float4*>(&wch[kl * 456 + o0]);
#pragma unroll
        for (int m4 = 0; m4 < 4; ++m4) {
          float4 w = wr[m4];
          acc0[4 * m4 + 0] += xv0 * w.x; acc0[4 * m4 + 1] += xv0 * w.y;
          acc0[4 * m4 + 2] += xv0 * w.z; acc0[4 * m4 + 3] += xv0 * w.w;
          acc1[4 * m4 + 0] += xv1 * w.x; acc1[4 * m4 + 1] += xv1 * w.y;
          acc1[4 * m4 + 2] += xv1 * w.z; acc1[4 * m4 + 3] += xv1 * w.w;
        }
      }
    }
    __syncthreads();
#pragma unroll
    for (int m = 0; m < 16; ++m) {
      if (m < cnt) {
        bufB[p0 * 456 + o0 + m] = elu_f(acc0[m]);
        bufB[p1 * 456 + o0 + m] = elu_f(acc1[m]);
      }
    }
  }
  // ---- layer 2: 453 -> 226, ELU (H2 overwrites bufA) ----
  {
    const int o0 = s2 * 8;
    const int cnt = max(0, min(8, 226 - o0));
    float acc0[8], acc1[8];
#pragma unroll
    for (int m = 0; m < 8; ++m) {
      int o = o0 + m;
      float bv = (o < 226) ? b2[o] : 0.0f;
      acc0[m] = bv; acc1[m] = bv;
    }
    for (int kc = 0; kc < 453; kc += 16) {
      const int kn = min(16, 453 - kc);
      __syncthreads();
      for (int e2 = t; e2 < kn * 226; e2 += 512)
        wch[(e2 / 226) * 228 + (e2 % 226)] = w2[(size_t)(kc + e2 / 226) * 226 + (e2 % 226)];
      __syncthreads();
      for (int kl = 0; kl < kn; ++kl) {
        float xv0 = bufB[p0 * 456 + kc + kl];
        float xv1 = bufB[p1 * 456 + kc + kl];
        const float4* wr = reinterpret_cast<const float4*>(&wch[kl * 228 + o0]);
#pragma unroll
        for (int m4 = 0; m4 < 2; ++m4) {
          float4 w = wr[m4];
          acc0[4 * m4 + 0] += xv0 * w.x; acc0[4 * m4 + 1] += xv0 * w.y;
          acc0[4 * m4 + 2] += xv0 * w.z; acc0[4 * m4 + 3] += xv0 * w.w;
          acc1[4 * m4 + 0] += xv1 * w.x; acc1[4 * m4 + 1] += xv1 * w.y;
          acc1[4 * m4 + 2] += xv1 * w.z; acc1[4 * m4 + 3] += xv1 * w.w;
        }
      }
    }
    __syncthreads();
#pragma unroll
    for (int m = 0; m < 8; ++m) {
      if (m < cnt) {
        bufA[p0 * 456 + o0 + m] = elu_f(acc0[m]);
        bufA[p1 * 456 + o0 + m] = elu_f(acc1[m]);
      }
    }
  }
  __syncthreads();
  // ---- layer 3: 226 -> 2 (no ELU) ----
  {
    const int k0 = (s2 * 226) >> 5;
    const int k1 = ((s2 + 1) * 226) >> 5;
    float p00 = 0.f, p01 = 0.f, p10 = 0.f, p11 = 0.f;
    for (int k = k0; k < k1; ++k) {
      float wv0 = w3[2 * k + 0], wv1 = w3[2 * k + 1];
      float h0 = bufA[p0 * 456 + k], h1 = bufA[p1 * 456 + k];
      p00 += h0 * wv0; p01 += h0 * wv1;
      p10 += h1 * wv0; p11 += h1 * wv1;
    }
#pragma unroll
    for (int off = 1; off < 32; off <<= 1) {
      p00 += __shfl_xor(p00, off);
      p01 += __shfl_xor(p01, off);
      p10 += __shfl_xor(p10, off);
      p11 += __shfl_xor(p11, off);
    }
    if (s2 == 0) {
      float4 v = {p00 + b3[0], p01 + b3[1], p10 + b3[0], p11 + b3[1]};
      *reinterpret_cast<float4*>(&out[(pt0 + (size_t)p0) * 2]) = v;
    }
  }
}

// ------------------------------------------------------------- launch ----
extern "C" void kernel_launch(void* const* d_in, const int* in_sizes, int n_in,
                              void* d_out, int out_size, void* d_ws, size_t ws_size,
                              hipStream_t stream) {
  const float* coords = (const float*)d_in[0];
  const float* feat   = (const float*)d_in[1];
  const float* c1w1 = (const float*)d_in[2];  const float* c1b1 = (const float*)d_in[3];
  const float* c1w2 = (const float*)d_in[4];  const float* c1b2 = (const float*)d_in[5];
  const float* c2w1 = (const float*)d_in[6];  const float* c2b1 = (const float*)d_in[7];
  const float* c2w2 = (const float*)d_in[8];  const float* c2b2 = (const float*)d_in[9];
  const float* c3w1 = (const float*)d_in[10]; const float* c3b1 = (const float*)d_in[11];
  const float* c3w2 = (const float*)d_in[12]; const float* c3b2 = (const float*)d_in[13];
  const float* ow1  = (const float*)d_in[14]; const float* ob1  = (const float*)d_in[15];
  const float* ow2  = (const float*)d_in[16]; const float* ob2  = (const float*)d_in[17];
  const float* ow3  = (const float*)d_in[18]; const float* ob3  = (const float*)d_in[19];
  float* out = (float*)d_out;

  // ws layout (bytes): out1 [0,32M) | out2 [32M,96M) | out3 [96M,224M) | idx [224M,226M)
  char* ws = (char*)d_ws;
  float* out1 = (float*)(ws);
  float* out2 = (float*)(ws + 33554432UL);
  float* out3 = (float*)(ws + 100663296UL);
  int*   idx  = (int*)  (ws + 234881024UL);

  knn_kernel<2><<<NB, 128, 0, stream>>>(coords, idx);
  ec1_kernel<<<NB, 128, 0, stream>>>(feat, idx, c1w1, c1b1, c1w2, c1b2, out1);
  knn_kernel<64><<<NB, 128, 0, stream>>>(out1, idx);
  ec2_kernel<<<NB, 512, 0, stream>>>(out1, idx, c2w1, c2b1, c2w2, c2b2, out2);
  knn_kernel<128><<<NB, 128, 0, stream>>>(out2, idx);
  ec3_kernel<<<NB, 512, 0, stream>>>(out2, idx, c3w1, c3b1, c3w2, c3b2, out3);
  head_kernel<<<4096, 512, 0, stream>>>(feat, out1, out2, out3,
                                        ow1, ob1, ow2, ob2, ow3, ob3, out);
}

// Round 3
// 36131.763 us; speedup vs baseline: 1.1404x; 1.1404x over previous
//
#include <hip/hip_runtime.h>
#include <cstdint>
#include <cstddef>

// ParticleNet MI355X — Round 3.
// - kNN: fp32 shortlist + fp64 rescore (verified round 2).
// - ec1/ec2: fp32, thread-per-edge, register-tiled so nothing spills.
// - ec3: bf16 MFMA (16x16x32), split into ec3a (E->H1) and ec3b (H1->out3),
//   H1 staged bf16 in workspace (event-chunked to bound ws usage).
// - head: round-2 version, reads out3 as bf16.

#define NB 1024
#define NPT 128

typedef __attribute__((ext_vector_type(8))) short short8;
typedef __attribute__((ext_vector_type(4))) float floatx4;
typedef __attribute__((ext_vector_type(4))) unsigned int uint4v;

__device__ __forceinline__ float elu_f(float x) { return x > 0.0f ? x : expm1f(x); }

__device__ __forceinline__ unsigned short f2bf(float f) {
  unsigned u = __builtin_bit_cast(unsigned, f);
  unsigned r = u + 0x7FFFu + ((u >> 16) & 1u);
  return (unsigned short)(r >> 16);
}
__device__ __forceinline__ float bf2f(unsigned short h) {
  unsigned u = ((unsigned)h) << 16;
  return __builtin_bit_cast(float, u);
}

// ---------------------------------------------------------------- kNN ----
template<int C>
__global__ __launch_bounds__(128) void knn_kernel(const float* __restrict__ x,
                                                  int* __restrict__ idx) {
  __shared__ __align__(16) float xs[NPT][C + 4];
  __shared__ float x2s[NPT];
  __shared__ double x2d[NPT];
  const int b = blockIdx.x, t = threadIdx.x;
  const float* xb = x + (size_t)b * NPT * C;
  for (int e = t; e < NPT * C; e += 128) xs[e / C][e % C] = xb[e];
  __syncthreads();
  float xi[C];
  float s2 = 0.0f;
  double s2d = 0.0;
#pragma unroll
  for (int c = 0; c < C; ++c) {
    xi[c] = xs[t][c];
    s2 += xi[c] * xi[c];
    s2d += (double)xi[c] * (double)xi[c];
  }
  x2s[t] = s2;
  x2d[t] = s2d;
  __syncthreads();
  float bd0 = 1e30f, bd1 = 1e30f, bd2 = 1e30f, bd3 = 1e30f, bd4 = 1e30f, bd5 = 1e30f;
  int bi0 = 0, bi1 = 0, bi2 = 0, bi3 = 0, bi4 = 0, bi5 = 0;
  for (int j = 0; j < NPT; ++j) {
    if (j == t) continue;
    float dot = 0.0f;
    if constexpr (C >= 4) {
      const float4* xr = reinterpret_cast<const float4*>(&xs[j][0]);
#pragma unroll
      for (int c4 = 0; c4 < C / 4; ++c4) {
        float4 v = xr[c4];
        dot += xi[4 * c4 + 0] * v.x + xi[4 * c4 + 1] * v.y +
               xi[4 * c4 + 2] * v.z + xi[4 * c4 + 3] * v.w;
      }
    } else {
#pragma unroll
      for (int c = 0; c < C; ++c) dot += xi[c] * xs[j][c];
    }
    float d = s2 + x2s[j] - 2.0f * dot;
    if (d < bd5) {
      bd5 = d; bi5 = j;
      if (bd5 < bd4) {
        float td = bd4; bd4 = bd5; bd5 = td; int ti = bi4; bi4 = bi5; bi5 = ti;
        if (bd4 < bd3) {
          td = bd3; bd3 = bd4; bd4 = td; ti = bi3; bi3 = bi4; bi4 = ti;
          if (bd3 < bd2) {
            td = bd2; bd2 = bd3; bd3 = td; ti = bi2; bi2 = bi3; bi3 = ti;
            if (bd2 < bd1) {
              td = bd1; bd1 = bd2; bd2 = td; ti = bi1; bi1 = bi2; bi2 = ti;
              if (bd1 < bd0) {
                td = bd0; bd0 = bd1; bd1 = td; ti = bi0; bi0 = bi1; bi1 = ti;
              }
            }
          }
        }
      }
    }
  }
  auto refine = [&](int j) -> double {
    double dot = 0.0;
#pragma unroll
    for (int c = 0; c < C; ++c) dot += (double)xi[c] * (double)xs[j][c];
    return s2d + x2d[j] - 2.0 * dot;
  };
  double e0 = refine(bi0), e1 = refine(bi1), e2 = refine(bi2);
  double e3 = refine(bi3), e4 = refine(bi4), e5 = refine(bi5);
#define CSWP(da, ia, db, ib)                                            \
  if ((da > db) || (da == db && ia > ib)) {                             \
    double _td = da; da = db; db = _td; int _ti = ia; ia = ib; ib = _ti; }
  CSWP(e0, bi0, e1, bi1) CSWP(e1, bi1, e2, bi2) CSWP(e2, bi2, e3, bi3)
  CSWP(e3, bi3, e4, bi4) CSWP(e4, bi4, e5, bi5)
  CSWP(e0, bi0, e1, bi1) CSWP(e1, bi1, e2, bi2) CSWP(e2, bi2, e3, bi3)
  CSWP(e3, bi3, e4, bi4)
  CSWP(e0, bi0, e1, bi1) CSWP(e1, bi1, e2, bi2) CSWP(e2, bi2, e3, bi3)
  CSWP(e0, bi0, e1, bi1) CSWP(e1, bi1, e2, bi2)
  CSWP(e0, bi0, e1, bi1)
#undef CSWP
  int* ib = idx + ((size_t)b * NPT + t) * 4;
  ib[0] = bi0; ib[1] = bi1; ib[2] = bi2; ib[3] = bi3;
}

// ---------------------------------------------------------------- ec1 ----
// thread-per-edge, 512 threads/event. t32[32] + acc[32] live -> no spill.
__global__ __launch_bounds__(512, 2) void ec1_kernel(
    const float* __restrict__ feat, const int* __restrict__ idx,
    const float* __restrict__ w1, const float* __restrict__ b1,
    const float* __restrict__ w2, const float* __restrict__ b2,
    float* __restrict__ out) {
  __shared__ __align__(16) float fs[NPT][6];
  __shared__ __align__(16) float w1s[10][32];
  __shared__ __align__(16) float w2s[32][68];
  __shared__ float b1s[32], b2s[64];
  const int b = blockIdx.x, t = threadIdx.x;
  const float* fb = feat + (size_t)b * NPT * 5;
  for (int e = t; e < NPT * 5; e += 512) fs[e / 5][e % 5] = fb[e];
  if (t < 320) w1s[t / 32][t % 32] = w1[t];
  for (int e = t; e < 2048; e += 512) w2s[e >> 6][e & 63] = w2[e];
  if (t < 32) b1s[t] = b1[t];
  if (t >= 448) b2s[t - 448] = b2[t - 448];
  __syncthreads();
  const int p = t >> 2, e4 = t & 3;
  const int j = idx[(size_t)b * 512 + t];
  float t32[32];
#pragma unroll
  for (int o = 0; o < 32; ++o) t32[o] = b1s[o];
#pragma unroll
  for (int c = 0; c < 10; ++c) {
    float in_c = (c < 5) ? fs[p][c] : (fs[j][c - 5] - fs[p][c - 5]);
    const float4* wr = reinterpret_cast<const float4*>(&w1s[c][0]);
#pragma unroll
    for (int o4 = 0; o4 < 8; ++o4) {
      float4 w = wr[o4];
      t32[4 * o4 + 0] += in_c * w.x; t32[4 * o4 + 1] += in_c * w.y;
      t32[4 * o4 + 2] += in_c * w.z; t32[4 * o4 + 3] += in_c * w.w;
    }
  }
#pragma unroll
  for (int o = 0; o < 32; ++o) t32[o] = elu_f(t32[o]);
  for (int otile = 0; otile < 2; ++otile) {
    float acc[32];
#pragma unroll
    for (int o = 0; o < 32; ++o) acc[o] = b2s[otile * 32 + o];
#pragma unroll
    for (int k = 0; k < 32; ++k) {
      float hk = t32[k];
      const float4* wr = reinterpret_cast<const float4*>(&w2s[k][otile * 32]);
#pragma unroll
      for (int o4 = 0; o4 < 8; ++o4) {
        float4 w = wr[o4];
        acc[4 * o4 + 0] += hk * w.x; acc[4 * o4 + 1] += hk * w.y;
        acc[4 * o4 + 2] += hk * w.z; acc[4 * o4 + 3] += hk * w.w;
      }
    }
#pragma unroll
    for (int o = 0; o < 32; ++o) {
      float v = elu_f(acc[o]);
      v += __shfl_xor(v, 1);
      v += __shfl_xor(v, 2);
      acc[o] = v;
    }
    if (e4 == otile) {
      float* ob = out + ((size_t)b * NPT + p) * 64 + otile * 32;
#pragma unroll
      for (int o4 = 0; o4 < 8; ++o4) {
        float4 v = {0.25f * acc[4 * o4 + 0], 0.25f * acc[4 * o4 + 1],
                    0.25f * acc[4 * o4 + 2], 0.25f * acc[4 * o4 + 3]};
        *reinterpret_cast<float4*>(&ob[4 * o4]) = v;
      }
    }
  }
}

// ---------------------------------------------------------------- ec2 ----
// thread-per-edge; h[96] in registers across L1->L2; no spill (cap 256 VGPR).
__global__ __launch_bounds__(512, 2) void ec2_kernel(
    const float* __restrict__ x, const int* __restrict__ idx,
    const float* __restrict__ w1, const float* __restrict__ b1,
    const float* __restrict__ w2, const float* __restrict__ b2,
    float* __restrict__ out) {
  __shared__ __align__(16) float xs[NPT][68];
  __shared__ __align__(16) float w1s[128][100];
  __shared__ __align__(16) float w2s[96][132];
  __shared__ float b1s[96], b2s[128];
  const int b = blockIdx.x, t = threadIdx.x;
  const float* xb = x + (size_t)b * NPT * 64;
  for (int e = t; e < NPT * 64; e += 512) xs[e >> 6][e & 63] = xb[e];
  for (int e = t; e < 128 * 96; e += 512) w1s[e / 96][e % 96] = w1[e];
  for (int e = t; e < 96 * 128; e += 512) w2s[e >> 7][e & 127] = w2[e];
  if (t < 96) b1s[t] = b1[t];
  if (t >= 384) b2s[t - 384] = b2[t - 384];
  __syncthreads();
  const int p = t >> 2, e4 = t & 3;
  const int j = idx[(size_t)b * 512 + t];
  float h[96];
#pragma unroll
  for (int o = 0; o < 96; ++o) h[o] = b1s[o];
  for (int c = 0; c < 64; ++c) {
    float in_c = xs[p][c];
    const float4* wr = reinterpret_cast<const float4*>(&w1s[c][0]);
#pragma unroll
    for (int o4 = 0; o4 < 24; ++o4) {
      float4 w = wr[o4];
      h[4 * o4 + 0] += in_c * w.x; h[4 * o4 + 1] += in_c * w.y;
      h[4 * o4 + 2] += in_c * w.z; h[4 * o4 + 3] += in_c * w.w;
    }
  }
  for (int c = 0; c < 64; ++c) {
    float in_c = xs[j][c] - xs[p][c];
    const float4* wr = reinterpret_cast<const float4*>(&w1s[64 + c][0]);
#pragma unroll
    for (int o4 = 0; o4 < 24; ++o4) {
      float4 w = wr[o4];
      h[4 * o4 + 0] += in_c * w.x; h[4 * o4 + 1] += in_c * w.y;
      h[4 * o4 + 2] += in_c * w.z; h[4 * o4 + 3] += in_c * w.w;
    }
  }
#pragma unroll
  for (int o = 0; o < 96; ++o) h[o] = elu_f(h[o]);
  for (int otile = 0; otile < 4; ++otile) {
    float acc[32];
#pragma unroll
    for (int o = 0; o < 32; ++o) acc[o] = b2s[otile * 32 + o];
#pragma unroll
    for (int k = 0; k < 96; ++k) {
      float hk = h[k];
      const float4* wr = reinterpret_cast<const float4*>(&w2s[k][otile * 32]);
#pragma unroll
      for (int o4 = 0; o4 < 8; ++o4) {
        float4 w = wr[o4];
        acc[4 * o4 + 0] += hk * w.x; acc[4 * o4 + 1] += hk * w.y;
        acc[4 * o4 + 2] += hk * w.z; acc[4 * o4 + 3] += hk * w.w;
      }
    }
#pragma unroll
    for (int o = 0; o < 32; ++o) {
      float v = elu_f(acc[o]);
      v += __shfl_xor(v, 1);
      v += __shfl_xor(v, 2);
      acc[o] = v;
    }
    if (e4 == otile) {
      float* ob = out + ((size_t)b * NPT + p) * 128 + otile * 32;
#pragma unroll
      for (int o4 = 0; o4 < 8; ++o4) {
        float4 v = {0.25f * acc[4 * o4 + 0], 0.25f * acc[4 * o4 + 1],
                    0.25f * acc[4 * o4 + 2], 0.25f * acc[4 * o4 + 3]};
        *reinterpret_cast<float4*>(&ob[4 * o4]) = v;
      }
    }
  }
}

// ---------------------------------------------------------------- ec3a ----
// L1 of edgeconv3 as bf16 MFMA GEMM: E[512x256] x W1[256x192] -> H1 bf16.
// Block = 1 event, 8 waves, wave handles 4 m-tiles of 16 edges.
__global__ __launch_bounds__(512, 2) void ec3a_kernel(
    const float* __restrict__ x, const int* __restrict__ idx,
    const float* __restrict__ w1, const float* __restrict__ b1,
    unsigned short* __restrict__ h1) {
  __shared__ unsigned short Xb[128][136];    // bf16 of out2; row 272B
  __shared__ unsigned short W1t[192][264];   // [n][k] bf16; row 528B
  __shared__ float b1s[192];
  __shared__ unsigned short stg[8][16][40];  // per-wave D->A transpose stage
  const int b = blockIdx.x, t = threadIdx.x;
  const float* xb = x + (size_t)b * NPT * 128;
  for (int e = t; e < NPT * 128; e += 512) Xb[e >> 7][e & 127] = f2bf(xb[e]);
  for (int e = t; e < 256 * 192; e += 512) {
    int k = e / 192, n = e % 192;
    W1t[n][k] = f2bf(w1[e]);
  }
  if (t < 192) b1s[t] = b1[t];
  __syncthreads();
  const int w = t >> 6, l = t & 63;
  const int lr = l & 15, lq = l >> 4;
  for (int mt = 0; mt < 4; ++mt) {
    const int m = (w * 4 + mt) * 16;
    const int e = m + lr;
    const int p = e >> 2;
    const int jp = idx[(size_t)b * 512 + e];
    short8 A[8];
#pragma unroll
    for (int kk = 0; kk < 4; ++kk) {
      int k0 = kk * 32 + lq * 8;
      A[kk] = *reinterpret_cast<const short8*>(&Xb[p][k0]);
    }
#pragma unroll
    for (int kk = 0; kk < 4; ++kk) {
      int k0 = kk * 32 + lq * 8;
      short8 aj = *reinterpret_cast<const short8*>(&Xb[jp][k0]);
      short8 ai = *reinterpret_cast<const short8*>(&Xb[p][k0]);
      short8 d;
#pragma unroll
      for (int q = 0; q < 8; ++q)
        d[q] = (short)f2bf(bf2f((unsigned short)aj[q]) - bf2f((unsigned short)ai[q]));
      A[4 + kk] = d;
    }
    floatx4 acc[12];
#pragma unroll
    for (int n = 0; n < 12; ++n) acc[n] = (floatx4){0.f, 0.f, 0.f, 0.f};
#pragma unroll
    for (int n = 0; n < 12; ++n) {
#pragma unroll
      for (int kk = 0; kk < 8; ++kk) {
        short8 Bf = *reinterpret_cast<const short8*>(&W1t[n * 16 + lr][kk * 32 + lq * 8]);
        acc[n] = __builtin_amdgcn_mfma_f32_16x16x32_bf16(A[kk], Bf, acc[n], 0, 0, 0);
      }
    }
    // epilogue: bias+ELU -> bf16 -> stage (D layout -> row-major) -> global
#pragma unroll
    for (int pr = 0; pr < 6; ++pr) {
      float bv0 = b1s[pr * 32 + lr];
      float bv1 = b1s[pr * 32 + 16 + lr];
#pragma unroll
      for (int i = 0; i < 4; ++i) {
        stg[w][lq * 4 + i][lr]      = f2bf(elu_f(acc[2 * pr][i] + bv0));
        stg[w][lq * 4 + i][16 + lr] = f2bf(elu_f(acc[2 * pr + 1][i] + bv1));
      }
      asm volatile("s_waitcnt lgkmcnt(0)" ::: "memory");
      const unsigned short* src = &stg[w][l >> 2][(l & 3) * 8];
      uint4v vv = *reinterpret_cast<const uint4v*>(src);
      size_t dst = ((size_t)b * 512 + m + (l >> 2)) * 192 + pr * 32 + (l & 3) * 8;
      *reinterpret_cast<uint4v*>(&h1[dst]) = vv;
      asm volatile("s_waitcnt lgkmcnt(0)" ::: "memory");
    }
  }
}

// ---------------------------------------------------------------- ec3b ----
// L2: H1[512x192] x W2[192x256] -> ELU -> mean over 4 edges -> out3 bf16.
__global__ __launch_bounds__(512, 2) void ec3b_kernel(
    const unsigned short* __restrict__ h1,
    const float* __restrict__ w2, const float* __restrict__ b2,
    unsigned short* __restrict__ out3) {
  __shared__ unsigned short W2t[256][200];   // [n][k] bf16; row 400B
  __shared__ float b2s[256];
  const int b = blockIdx.x, t = threadIdx.x;
  for (int e = t; e < 192 * 256; e += 512) {
    int k = e >> 8, n = e & 255;
    W2t[n][k] = f2bf(w2[e]);
  }
  if (t < 256) b2s[t] = b2[t];
  __syncthreads();
  const int w = t >> 6, l = t & 63;
  const int lr = l & 15, lq = l >> 4;
  for (int mt = 0; mt < 4; ++mt) {
    const int m = (w * 4 + mt) * 16;
    floatx4 acc[16];
#pragma unroll
    for (int n = 0; n < 16; ++n) acc[n] = (floatx4){0.f, 0.f, 0.f, 0.f};
    const unsigned short* arow = h1 + ((size_t)b * 512 + m + lr) * 192;
#pragma unroll
    for (int kk = 0; kk < 6; ++kk) {
      short8 Af = *reinterpret_cast<const short8*>(&arow[kk * 32 + lq * 8]);
#pragma unroll
      for (int n = 0; n < 16; ++n) {
        short8 Bf = *reinterpret_cast<const short8*>(&W2t[n * 16 + lr][kk * 32 + lq * 8]);
        acc[n] = __builtin_amdgcn_mfma_f32_16x16x32_bf16(Af, Bf, acc[n], 0, 0, 0);
      }
    }
    // lane's 4 acc rows = the 4 edges of point p = m/4 + lq
    unsigned short* orow = out3 + ((size_t)b * NPT + (m >> 2) + lq) * 256;
#pragma unroll
    for (int n = 0; n < 16; ++n) {
      float bv = b2s[n * 16 + lr];
      float s = 0.f;
#pragma unroll
      for (int i = 0; i < 4; ++i) s += elu_f(acc[n][i] + bv);
      orow[n * 16 + lr] = f2bf(0.25f * s);
    }
  }
}

// --------------------------------------------------------------- head ----
__global__ __launch_bounds__(512) void head_kernel(
    const float* __restrict__ feat, const float* __restrict__ o1,
    const float* __restrict__ o2, const unsigned short* __restrict__ o3,
    const float* __restrict__ w1, const float* __restrict__ b1,
    const float* __restrict__ w2, const float* __restrict__ b2,
    const float* __restrict__ w3, const float* __restrict__ b3,
    float* __restrict__ out) {
  __shared__ __align__(16) float bufA[32 * 456];
  __shared__ __align__(16) float bufB[32 * 456];
  __shared__ __align__(16) float wch[16 * 456 + 64];
  const int t = threadIdx.x;
  const size_t pt0 = (size_t)blockIdx.x * 32;
  for (int e = t; e < 32 * 5; e += 512) bufA[(e / 5) * 456 + (e % 5)] = feat[pt0 * 5 + e];
  for (int e = t; e < 32 * 64; e += 512) bufA[(e >> 6) * 456 + 5 + (e & 63)] = o1[pt0 * 64 + e];
  for (int e = t; e < 32 * 128; e += 512) bufA[(e >> 7) * 456 + 69 + (e & 127)] = o2[pt0 * 128 + e];
  for (int e = t; e < 32 * 256; e += 512) bufA[(e >> 8) * 456 + 197 + (e & 255)] = bf2f(o3[pt0 * 256 + e]);
  const int g = t >> 5, s2 = t & 31;
  const int p0 = 2 * g, p1 = 2 * g + 1;
  {
    const int o0 = s2 * 16;
    const int cnt = max(0, min(16, 453 - o0));
    float acc0[16], acc1[16];
#pragma unroll
    for (int m = 0; m < 16; ++m) {
      int o = o0 + m;
      float bv = (o < 453) ? b1[o] : 0.0f;
      acc0[m] = bv; acc1[m] = bv;
    }
    for (int kc = 0; kc < 453; kc += 16) {
      const int kn = min(16, 453 - kc);
      __syncthreads();
      for (int e2 = t; e2 < kn * 453; e2 += 512)
        wch[(e2 / 453) * 456 + (e2 % 453)] = w1[(size_t)(kc + e2 / 453) * 453 + (e2 % 453)];
      __syncthreads();
      for (int kl = 0; kl < kn; ++kl) {
        float xv0 = bufA[p0 * 456 + kc + kl];
        float xv1 = bufA[p1 * 456 + kc + kl];
        const float4* wr = reinterpret_cast<const float4*>(&wch[kl * 456 + o0]);
#pragma unroll
        for (int m4 = 0; m4 < 4; ++m4) {
          float4 w = wr[m4];
          acc0[4 * m4 + 0] += xv0 * w.x; acc0[4 * m4 + 1] += xv0 * w.y;
          acc0[4 * m4 + 2] += xv0 * w.z; acc0[4 * m4 + 3] += xv0 * w.w;
          acc1[4 * m4 + 0] += xv1 * w.x; acc1[4 * m4 + 1] += xv1 * w.y;
          acc1[4 * m4 + 2] += xv1 * w.z; acc1[4 * m4 + 3] += xv1 * w.w;
        }
      }
    }
    __syncthreads();
#pragma unroll
    for (int m = 0; m < 16; ++m) {
      if (m < cnt) {
        bufB[p0 * 456 + o0 + m] = elu_f(acc0[m]);
        bufB[p1 * 456 + o0 + m] = elu_f(acc1[m]);
      }
    }
  }
  {
    const int o0 = s2 * 8;
    const int cnt = max(0, min(8, 226 - o0));
    float acc0[8], acc1[8];
#pragma unroll
    for (int m = 0; m < 8; ++m) {
      int o = o0 + m;
      float bv = (o < 226) ? b2[o] : 0.0f;
      acc0[m] = bv; acc1[m] = bv;
    }
    for (int kc = 0; kc < 453; kc += 16) {
      const int kn = min(16, 453 - kc);
      __syncthreads();
      for (int e2 = t; e2 < kn * 226; e2 += 512)
        wch[(e2 / 226) * 228 + (e2 % 226)] = w2[(size_t)(kc + e2 / 226) * 226 + (e2 % 226)];
      __syncthreads();
      for (int kl = 0; kl < kn; ++kl) {
        float xv0 = bufB[p0 * 456 + kc + kl];
        float xv1 = bufB[p1 * 456 + kc + kl];
        const float4* wr = reinterpret_cast<const float4*>(&wch[kl * 228 + o0]);
#pragma unroll
        for (int m4 = 0; m4 < 2; ++m4) {
          float4 w = wr[m4];
          acc0[4 * m4 + 0] += xv0 * w.x; acc0[4 * m4 + 1] += xv0 * w.y;
          acc0[4 * m4 + 2] += xv0 * w.z; acc0[4 * m4 + 3] += xv0 * w.w;
          acc1[4 * m4 + 0] += xv1 * w.x; acc1[4 * m4 + 1] += xv1 * w.y;
          acc1[4 * m4 + 2] += xv1 * w.z; acc1[4 * m4 + 3] += xv1 * w.w;
        }
      }
    }
    __syncthreads();
#pragma unroll
    for (int m = 0; m < 8; ++m) {
      if (m < cnt) {
        bufA[p0 * 456 + o0 + m] = elu_f(acc0[m]);
        bufA[p1 * 456 + o0 + m] = elu_f(acc1[m]);
      }
    }
  }
  __syncthreads();
  {
    const int k0 = (s2 * 226) >> 5;
    const int k1 = ((s2 + 1) * 226) >> 5;
    float p00 = 0.f, p01 = 0.f, p10 = 0.f, p11 = 0.f;
    for (int k = k0; k < k1; ++k) {
      float wv0 = w3[2 * k + 0], wv1 = w3[2 * k + 1];
      float h0 = bufA[p0 * 456 + k], h1 = bufA[p1 * 456 + k];
      p00 += h0 * wv0; p01 += h0 * wv1;
      p10 += h1 * wv0; p11 += h1 * wv1;
    }
#pragma unroll
    for (int off = 1; off < 32; off <<= 1) {
      p00 += __shfl_xor(p00, off);
      p01 += __shfl_xor(p01, off);
      p10 += __shfl_xor(p10, off);
      p11 += __shfl_xor(p11, off);
    }
    if (s2 == 0) {
      float4 v = {p00 + b3[0], p01 + b3[1], p10 + b3[0], p11 + b3[1]};
      *reinterpret_cast<float4*>(&out[(pt0 + (size_t)p0) * 2]) = v;
    }
  }
}

// ------------------------------------------------------------- launch ----
extern "C" void kernel_launch(void* const* d_in, const int* in_sizes, int n_in,
                              void* d_out, int out_size, void* d_ws, size_t ws_size,
                              hipStream_t stream) {
  const float* coords = (const float*)d_in[0];
  const float* feat   = (const float*)d_in[1];
  const float* c1w1 = (const float*)d_in[2];  const float* c1b1 = (const float*)d_in[3];
  const float* c1w2 = (const float*)d_in[4];  const float* c1b2 = (const float*)d_in[5];
  const float* c2w1 = (const float*)d_in[6];  const float* c2b1 = (const float*)d_in[7];
  const float* c2w2 = (const float*)d_in[8];  const float* c2b2 = (const float*)d_in[9];
  const float* c3w1 = (const float*)d_in[10]; const float* c3b1 = (const float*)d_in[11];
  const float* c3w2 = (const float*)d_in[12]; const float* c3b2 = (const float*)d_in[13];
  const float* ow1  = (const float*)d_in[14]; const float* ob1  = (const float*)d_in[15];
  const float* ow2  = (const float*)d_in[16]; const float* ob2  = (const float*)d_in[17];
  const float* ow3  = (const float*)d_in[18]; const float* ob3  = (const float*)d_in[19];
  float* out = (float*)d_out;

  // ws layout (MiB offsets): out1 f32 [0,32) | out2 f32 [32,96) |
  // out3 bf16 [96,160) | idx [160,162) | H1 bf16 chunk (256 events) [162,210)
  char* ws = (char*)d_ws;
  float* out1 = (float*)(ws);
  float* out2 = (float*)(ws + (32ull << 20));
  unsigned short* out3b = (unsigned short*)(ws + (96ull << 20));
  int* idx = (int*)(ws + (160ull << 20));
  unsigned short* h1 = (unsigned short*)(ws + (162ull << 20));

  knn_kernel<2><<<NB, 128, 0, stream>>>(coords, idx);
  ec1_kernel<<<NB, 512, 0, stream>>>(feat, idx, c1w1, c1b1, c1w2, c1b2, out1);
  knn_kernel<64><<<NB, 128, 0, stream>>>(out1, idx);
  ec2_kernel<<<NB, 512, 0, stream>>>(out1, idx, c2w1, c2b1, c2w2, c2b2, out2);
  knn_kernel<128><<<NB, 128, 0, stream>>>(out2, idx);
  for (int c = 0; c < 4; ++c) {
    ec3a_kernel<<<256, 512, 0, stream>>>(out2 + (size_t)c * 256 * NPT * 128,
                                         idx + (size_t)c * 256 * 512,
                                         c3w1, c3b1, h1);
    ec3b_kernel<<<256, 512, 0, stream>>>(h1, c3w2, c3b2,
                                         out3b + (size_t)c * 256 * NPT * 256);
  }
  head_kernel<<<4096, 512, 0, stream>>>(feat, out1, out2, out3b,
                                        ow1, ob1, ow2, ob2, ow3, ob3, out);
}

// Round 4
// 9000.357 us; speedup vs baseline: 4.5780x; 4.0145x over previous
//
#include <hip/hip_runtime.h>
#include <cstdint>
#include <cstddef>

// ParticleNet MI355X — Round 4.
// - kNN: fp32 shortlist + fp64 rescore (verified).
// - ec1: fp32 thread-per-edge (round 3).
// - ec2: SPLIT into ec2a/ec2b fp32 GEMMs with register tiling (round-3 version
//   spilled h[96] -> 70 GB of scratch HBM traffic, 27+ ms).
// - ec3: bf16 MFMA pair (verified round 3).
// - head: fp32 LDS-tiled (round 3).

#define NB 1024
#define NPT 128

typedef __attribute__((ext_vector_type(8))) short short8;
typedef __attribute__((ext_vector_type(4))) float floatx4;
typedef __attribute__((ext_vector_type(4))) unsigned int uint4v;

__device__ __forceinline__ float elu_f(float x) { return x > 0.0f ? x : expm1f(x); }

__device__ __forceinline__ unsigned short f2bf(float f) {
  unsigned u = __builtin_bit_cast(unsigned, f);
  unsigned r = u + 0x7FFFu + ((u >> 16) & 1u);
  return (unsigned short)(r >> 16);
}
__device__ __forceinline__ float bf2f(unsigned short h) {
  unsigned u = ((unsigned)h) << 16;
  return __builtin_bit_cast(float, u);
}

// ---------------------------------------------------------------- kNN ----
template<int C>
__global__ __launch_bounds__(128) void knn_kernel(const float* __restrict__ x,
                                                  int* __restrict__ idx) {
  __shared__ __align__(16) float xs[NPT][C + 4];
  __shared__ float x2s[NPT];
  __shared__ double x2d[NPT];
  const int b = blockIdx.x, t = threadIdx.x;
  const float* xb = x + (size_t)b * NPT * C;
  for (int e = t; e < NPT * C; e += 128) xs[e / C][e % C] = xb[e];
  __syncthreads();
  float xi[C];
  float s2 = 0.0f;
  double s2d = 0.0;
#pragma unroll
  for (int c = 0; c < C; ++c) {
    xi[c] = xs[t][c];
    s2 += xi[c] * xi[c];
    s2d += (double)xi[c] * (double)xi[c];
  }
  x2s[t] = s2;
  x2d[t] = s2d;
  __syncthreads();
  float bd0 = 1e30f, bd1 = 1e30f, bd2 = 1e30f, bd3 = 1e30f, bd4 = 1e30f, bd5 = 1e30f;
  int bi0 = 0, bi1 = 0, bi2 = 0, bi3 = 0, bi4 = 0, bi5 = 0;
  for (int j = 0; j < NPT; ++j) {
    if (j == t) continue;
    float dot = 0.0f;
    if constexpr (C >= 4) {
      const float4* xr = reinterpret_cast<const float4*>(&xs[j][0]);
#pragma unroll
      for (int c4 = 0; c4 < C / 4; ++c4) {
        float4 v = xr[c4];
        dot += xi[4 * c4 + 0] * v.x + xi[4 * c4 + 1] * v.y +
               xi[4 * c4 + 2] * v.z + xi[4 * c4 + 3] * v.w;
      }
    } else {
#pragma unroll
      for (int c = 0; c < C; ++c) dot += xi[c] * xs[j][c];
    }
    float d = s2 + x2s[j] - 2.0f * dot;
    if (d < bd5) {
      bd5 = d; bi5 = j;
      if (bd5 < bd4) {
        float td = bd4; bd4 = bd5; bd5 = td; int ti = bi4; bi4 = bi5; bi5 = ti;
        if (bd4 < bd3) {
          td = bd3; bd3 = bd4; bd4 = td; ti = bi3; bi3 = bi4; bi4 = ti;
          if (bd3 < bd2) {
            td = bd2; bd2 = bd3; bd3 = td; ti = bi2; bi2 = bi3; bi3 = ti;
            if (bd2 < bd1) {
              td = bd1; bd1 = bd2; bd2 = td; ti = bi1; bi1 = bi2; bi2 = ti;
              if (bd1 < bd0) {
                td = bd0; bd0 = bd1; bd1 = td; ti = bi0; bi0 = bi1; bi1 = ti;
              }
            }
          }
        }
      }
    }
  }
  auto refine = [&](int j) -> double {
    double dot = 0.0;
#pragma unroll
    for (int c = 0; c < C; ++c) dot += (double)xi[c] * (double)xs[j][c];
    return s2d + x2d[j] - 2.0 * dot;
  };
  double e0 = refine(bi0), e1 = refine(bi1), e2 = refine(bi2);
  double e3 = refine(bi3), e4 = refine(bi4), e5 = refine(bi5);
#define CSWP(da, ia, db, ib)                                            \
  if ((da > db) || (da == db && ia > ib)) {                             \
    double _td = da; da = db; db = _td; int _ti = ia; ia = ib; ib = _ti; }
  CSWP(e0, bi0, e1, bi1) CSWP(e1, bi1, e2, bi2) CSWP(e2, bi2, e3, bi3)
  CSWP(e3, bi3, e4, bi4) CSWP(e4, bi4, e5, bi5)
  CSWP(e0, bi0, e1, bi1) CSWP(e1, bi1, e2, bi2) CSWP(e2, bi2, e3, bi3)
  CSWP(e3, bi3, e4, bi4)
  CSWP(e0, bi0, e1, bi1) CSWP(e1, bi1, e2, bi2) CSWP(e2, bi2, e3, bi3)
  CSWP(e0, bi0, e1, bi1) CSWP(e1, bi1, e2, bi2)
  CSWP(e0, bi0, e1, bi1)
#undef CSWP
  int* ib = idx + ((size_t)b * NPT + t) * 4;
  ib[0] = bi0; ib[1] = bi1; ib[2] = bi2; ib[3] = bi3;
}

// ---------------------------------------------------------------- ec1 ----
__global__ __launch_bounds__(512, 2) void ec1_kernel(
    const float* __restrict__ feat, const int* __restrict__ idx,
    const float* __restrict__ w1, const float* __restrict__ b1,
    const float* __restrict__ w2, const float* __restrict__ b2,
    float* __restrict__ out) {
  __shared__ __align__(16) float fs[NPT][6];
  __shared__ __align__(16) float w1s[10][32];
  __shared__ __align__(16) float w2s[32][68];
  __shared__ float b1s[32], b2s[64];
  const int b = blockIdx.x, t = threadIdx.x;
  const float* fb = feat + (size_t)b * NPT * 5;
  for (int e = t; e < NPT * 5; e += 512) fs[e / 5][e % 5] = fb[e];
  if (t < 320) w1s[t / 32][t % 32] = w1[t];
  for (int e = t; e < 2048; e += 512) w2s[e >> 6][e & 63] = w2[e];
  if (t < 32) b1s[t] = b1[t];
  if (t >= 448) b2s[t - 448] = b2[t - 448];
  __syncthreads();
  const int p = t >> 2;
  const int e4 = t & 3;
  const int j = idx[(size_t)b * 512 + t];
  float t32[32];
#pragma unroll
  for (int o = 0; o < 32; ++o) t32[o] = b1s[o];
#pragma unroll
  for (int c = 0; c < 10; ++c) {
    float in_c = (c < 5) ? fs[p][c] : (fs[j][c - 5] - fs[p][c - 5]);
    const float4* wr = reinterpret_cast<const float4*>(&w1s[c][0]);
#pragma unroll
    for (int o4 = 0; o4 < 8; ++o4) {
      float4 w = wr[o4];
      t32[4 * o4 + 0] += in_c * w.x; t32[4 * o4 + 1] += in_c * w.y;
      t32[4 * o4 + 2] += in_c * w.z; t32[4 * o4 + 3] += in_c * w.w;
    }
  }
#pragma unroll
  for (int o = 0; o < 32; ++o) t32[o] = elu_f(t32[o]);
  for (int otile = 0; otile < 2; ++otile) {
    float acc[32];
#pragma unroll
    for (int o = 0; o < 32; ++o) acc[o] = b2s[otile * 32 + o];
#pragma unroll
    for (int k = 0; k < 32; ++k) {
      float hk = t32[k];
      const float4* wr = reinterpret_cast<const float4*>(&w2s[k][otile * 32]);
#pragma unroll
      for (int o4 = 0; o4 < 8; ++o4) {
        float4 w = wr[o4];
        acc[4 * o4 + 0] += hk * w.x; acc[4 * o4 + 1] += hk * w.y;
        acc[4 * o4 + 2] += hk * w.z; acc[4 * o4 + 3] += hk * w.w;
      }
    }
#pragma unroll
    for (int o = 0; o < 32; ++o) {
      float v = elu_f(acc[o]);
      v += __shfl_xor(v, 1);
      v += __shfl_xor(v, 2);
      acc[o] = v;
    }
    if (e4 == otile) {
      float* ob = out + ((size_t)b * NPT + p) * 64 + otile * 32;
#pragma unroll
      for (int o4 = 0; o4 < 8; ++o4) {
        float4 v = {0.25f * acc[4 * o4 + 0], 0.25f * acc[4 * o4 + 1],
                    0.25f * acc[4 * o4 + 2], 0.25f * acc[4 * o4 + 3]};
        *reinterpret_cast<float4*>(&ob[4 * o4]) = v;
      }
    }
  }
}

// ---------------------------------------------------------------- ec2a ----
// L1: E[512x128] x W1[128x96] -> ELU -> H fp32 (per 256-event chunk).
// Block = 1 event; thread = (point pb, quarter part): acc[4 edges][24 outs].
__global__ __launch_bounds__(512, 2) void ec2a_kernel(
    const float* __restrict__ x, const int* __restrict__ idx,
    const float* __restrict__ w1, const float* __restrict__ b1,
    float* __restrict__ H) {
  __shared__ __align__(16) float xs[NPT][68];
  __shared__ __align__(16) float w1s[128][100];
  __shared__ float b1s[96];
  const int b = blockIdx.x, t = threadIdx.x;
  const float* xb = x + (size_t)b * NPT * 64;
  for (int e = t; e < NPT * 64; e += 512) xs[e >> 6][e & 63] = xb[e];
  for (int e = t; e < 128 * 96; e += 512) w1s[e / 96][e % 96] = w1[e];
  if (t < 96) b1s[t] = b1[t];
  __syncthreads();
  const int pb = t >> 2, part = t & 3;
  const int n0 = part * 24;
  int jn[4];
#pragma unroll
  for (int i = 0; i < 4; ++i) jn[i] = idx[(size_t)b * 512 + pb * 4 + i];
  float acc[4][24];
#pragma unroll
  for (int m = 0; m < 24; ++m) {
    float bv = b1s[n0 + m];
#pragma unroll
    for (int i = 0; i < 4; ++i) acc[i][m] = bv;
  }
  // c in [0,64): xi part — input shared by all 4 edges of the point.
  for (int c = 0; c < 64; ++c) {
    float in_c = xs[pb][c];
    const float4* wr = reinterpret_cast<const float4*>(&w1s[c][n0]);
#pragma unroll
    for (int q4 = 0; q4 < 6; ++q4) {
      float4 wv = wr[q4];
#pragma unroll
      for (int i = 0; i < 4; ++i) {
        acc[i][4 * q4 + 0] += in_c * wv.x;
        acc[i][4 * q4 + 1] += in_c * wv.y;
        acc[i][4 * q4 + 2] += in_c * wv.z;
        acc[i][4 * q4 + 3] += in_c * wv.w;
      }
    }
  }
  // c in [64,128): (xj - xi) part — per-edge inputs, shared weights.
  for (int c = 0; c < 64; ++c) {
    float xic = xs[pb][c];
    float in0 = xs[jn[0]][c] - xic;
    float in1 = xs[jn[1]][c] - xic;
    float in2 = xs[jn[2]][c] - xic;
    float in3 = xs[jn[3]][c] - xic;
    const float4* wr = reinterpret_cast<const float4*>(&w1s[64 + c][n0]);
#pragma unroll
    for (int q4 = 0; q4 < 6; ++q4) {
      float4 wv = wr[q4];
      acc[0][4 * q4 + 0] += in0 * wv.x; acc[0][4 * q4 + 1] += in0 * wv.y;
      acc[0][4 * q4 + 2] += in0 * wv.z; acc[0][4 * q4 + 3] += in0 * wv.w;
      acc[1][4 * q4 + 0] += in1 * wv.x; acc[1][4 * q4 + 1] += in1 * wv.y;
      acc[1][4 * q4 + 2] += in1 * wv.z; acc[1][4 * q4 + 3] += in1 * wv.w;
      acc[2][4 * q4 + 0] += in2 * wv.x; acc[2][4 * q4 + 1] += in2 * wv.y;
      acc[2][4 * q4 + 2] += in2 * wv.z; acc[2][4 * q4 + 3] += in2 * wv.w;
      acc[3][4 * q4 + 0] += in3 * wv.x; acc[3][4 * q4 + 1] += in3 * wv.y;
      acc[3][4 * q4 + 2] += in3 * wv.z; acc[3][4 * q4 + 3] += in3 * wv.w;
    }
  }
#pragma unroll
  for (int i = 0; i < 4; ++i) {
    float* hrow = H + ((size_t)b * 512 + pb * 4 + i) * 96 + n0;
#pragma unroll
    for (int q4 = 0; q4 < 6; ++q4) {
      float4 v = {elu_f(acc[i][4 * q4 + 0]), elu_f(acc[i][4 * q4 + 1]),
                  elu_f(acc[i][4 * q4 + 2]), elu_f(acc[i][4 * q4 + 3])};
      *reinterpret_cast<float4*>(&hrow[4 * q4]) = v;
    }
  }
}

// ---------------------------------------------------------------- ec2b ----
// L2: H[512x96] x W2[96x128] -> ELU -> mean(4 edges) -> out2 fp32.
// Block = 64 points (256 edges); H staged TRANSPOSED so a thread's 4 edges
// are one float4; thread = (point g, stride-8 col set oq): acc[4][16].
__global__ __launch_bounds__(512, 2) void ec2b_kernel(
    const float* __restrict__ H, const float* __restrict__ w2,
    const float* __restrict__ b2, float* __restrict__ out) {
  __shared__ __align__(16) float hsT[96][260];
  __shared__ float w2s[96][132];
  __shared__ float b2s[128];
  const int z = blockIdx.x, t = threadIdx.x;
  const int bc = z >> 1, hh = z & 1;
  const float* Hb = H + ((size_t)bc * 512 + hh * 256) * 96;
  for (int i = t; i < 256 * 96; i += 512) hsT[i % 96][i / 96] = Hb[i];
  for (int i = t; i < 96 * 128; i += 512) w2s[i >> 7][i & 127] = w2[i];
  if (t < 128) b2s[t] = b2[t];
  __syncthreads();
  const int g = t >> 3, oq = t & 7;
  float acc[4][16];
#pragma unroll
  for (int m = 0; m < 16; ++m) {
    float bv = b2s[oq + 8 * m];
#pragma unroll
    for (int i = 0; i < 4; ++i) acc[i][m] = bv;
  }
  for (int k = 0; k < 96; ++k) {
    float4 hv = *reinterpret_cast<const float4*>(&hsT[k][4 * g]);
#pragma unroll
    for (int m = 0; m < 16; ++m) {
      float wv = w2s[k][oq + 8 * m];
      acc[0][m] += hv.x * wv;
      acc[1][m] += hv.y * wv;
      acc[2][m] += hv.z * wv;
      acc[3][m] += hv.w * wv;
    }
  }
  float* orow = out + ((size_t)bc * NPT + hh * 64 + g) * 128;
#pragma unroll
  for (int m = 0; m < 16; ++m) {
    float s = elu_f(acc[0][m]) + elu_f(acc[1][m]) +
              elu_f(acc[2][m]) + elu_f(acc[3][m]);
    orow[oq + 8 * m] = 0.25f * s;
  }
}

// ---------------------------------------------------------------- ec3a ----
__global__ __launch_bounds__(512, 2) void ec3a_kernel(
    const float* __restrict__ x, const int* __restrict__ idx,
    const float* __restrict__ w1, const float* __restrict__ b1,
    unsigned short* __restrict__ h1) {
  __shared__ unsigned short Xb[128][136];
  __shared__ unsigned short W1t[192][264];
  __shared__ float b1s[192];
  __shared__ unsigned short stg[8][16][40];
  const int b = blockIdx.x, t = threadIdx.x;
  const float* xb = x + (size_t)b * NPT * 128;
  for (int e = t; e < NPT * 128; e += 512) Xb[e >> 7][e & 127] = f2bf(xb[e]);
  for (int e = t; e < 256 * 192; e += 512) {
    int k = e / 192, n = e % 192;
    W1t[n][k] = f2bf(w1[e]);
  }
  if (t < 192) b1s[t] = b1[t];
  __syncthreads();
  const int w = t >> 6, l = t & 63;
  const int lr = l & 15, lq = l >> 4;
  for (int mt = 0; mt < 4; ++mt) {
    const int m = (w * 4 + mt) * 16;
    const int e = m + lr;
    const int p = e >> 2;
    const int jp = idx[(size_t)b * 512 + e];
    short8 A[8];
#pragma unroll
    for (int kk = 0; kk < 4; ++kk) {
      int k0 = kk * 32 + lq * 8;
      A[kk] = *reinterpret_cast<const short8*>(&Xb[p][k0]);
    }
#pragma unroll
    for (int kk = 0; kk < 4; ++kk) {
      int k0 = kk * 32 + lq * 8;
      short8 aj = *reinterpret_cast<const short8*>(&Xb[jp][k0]);
      short8 ai = *reinterpret_cast<const short8*>(&Xb[p][k0]);
      short8 d;
#pragma unroll
      for (int q = 0; q < 8; ++q)
        d[q] = (short)f2bf(bf2f((unsigned short)aj[q]) - bf2f((unsigned short)ai[q]));
      A[4 + kk] = d;
    }
    floatx4 acc[12];
#pragma unroll
    for (int n = 0; n < 12; ++n) acc[n] = (floatx4){0.f, 0.f, 0.f, 0.f};
#pragma unroll
    for (int n = 0; n < 12; ++n) {
#pragma unroll
      for (int kk = 0; kk < 8; ++kk) {
        short8 Bf = *reinterpret_cast<const short8*>(&W1t[n * 16 + lr][kk * 32 + lq * 8]);
        acc[n] = __builtin_amdgcn_mfma_f32_16x16x32_bf16(A[kk], Bf, acc[n], 0, 0, 0);
      }
    }
#pragma unroll
    for (int pr = 0; pr < 6; ++pr) {
      float bv0 = b1s[pr * 32 + lr];
      float bv1 = b1s[pr * 32 + 16 + lr];
#pragma unroll
      for (int i = 0; i < 4; ++i) {
        stg[w][lq * 4 + i][lr]      = f2bf(elu_f(acc[2 * pr][i] + bv0));
        stg[w][lq * 4 + i][16 + lr] = f2bf(elu_f(acc[2 * pr + 1][i] + bv1));
      }
      asm volatile("s_waitcnt lgkmcnt(0)" ::: "memory");
      const unsigned short* src = &stg[w][l >> 2][(l & 3) * 8];
      uint4v vv = *reinterpret_cast<const uint4v*>(src);
      size_t dst = ((size_t)b * 512 + m + (l >> 2)) * 192 + pr * 32 + (l & 3) * 8;
      *reinterpret_cast<uint4v*>(&h1[dst]) = vv;
      asm volatile("s_waitcnt lgkmcnt(0)" ::: "memory");
    }
  }
}

// ---------------------------------------------------------------- ec3b ----
__global__ __launch_bounds__(512, 2) void ec3b_kernel(
    const unsigned short* __restrict__ h1,
    const float* __restrict__ w2, const float* __restrict__ b2,
    unsigned short* __restrict__ out3) {
  __shared__ unsigned short W2t[256][200];
  __shared__ float b2s[256];
  const int b = blockIdx.x, t = threadIdx.x;
  for (int e = t; e < 192 * 256; e += 512) {
    int k = e >> 8, n = e & 255;
    W2t[n][k] = f2bf(w2[e]);
  }
  if (t < 256) b2s[t] = b2[t];
  __syncthreads();
  const int w = t >> 6, l = t & 63;
  const int lr = l & 15, lq = l >> 4;
  for (int mt = 0; mt < 4; ++mt) {
    const int m = (w * 4 + mt) * 16;
    floatx4 acc[16];
#pragma unroll
    for (int n = 0; n < 16; ++n) acc[n] = (floatx4){0.f, 0.f, 0.f, 0.f};
    const unsigned short* arow = h1 + ((size_t)b * 512 + m + lr) * 192;
#pragma unroll
    for (int kk = 0; kk < 6; ++kk) {
      short8 Af = *reinterpret_cast<const short8*>(&arow[kk * 32 + lq * 8]);
#pragma unroll
      for (int n = 0; n < 16; ++n) {
        short8 Bf = *reinterpret_cast<const short8*>(&W2t[n * 16 + lr][kk * 32 + lq * 8]);
        acc[n] = __builtin_amdgcn_mfma_f32_16x16x32_bf16(Af, Bf, acc[n], 0, 0, 0);
      }
    }
    unsigned short* orow = out3 + ((size_t)b * NPT + (m >> 2) + lq) * 256;
#pragma unroll
    for (int n = 0; n < 16; ++n) {
      float bv = b2s[n * 16 + lr];
      float s = 0.f;
#pragma unroll
      for (int i = 0; i < 4; ++i) s += elu_f(acc[n][i] + bv);
      orow[n * 16 + lr] = f2bf(0.25f * s);
    }
  }
}

// --------------------------------------------------------------- head ----
__global__ __launch_bounds__(512) void head_kernel(
    const float* __restrict__ feat, const float* __restrict__ o1,
    const float* __restrict__ o2, const unsigned short* __restrict__ o3,
    const float* __restrict__ w1, const float* __restrict__ b1,
    const float* __restrict__ w2, const float* __restrict__ b2,
    const float* __restrict__ w3, const float* __restrict__ b3,
    float* __restrict__ out) {
  __shared__ __align__(16) float bufA[32 * 456];
  __shared__ __align__(16) float bufB[32 * 456];
  __shared__ __align__(16) float wch[16 * 456 + 64];
  const int t = threadIdx.x;
  const size_t pt0 = (size_t)blockIdx.x * 32;
  for (int e = t; e < 32 * 5; e += 512) bufA[(e / 5) * 456 + (e % 5)] = feat[pt0 * 5 + e];
  for (int e = t; e < 32 * 64; e += 512) bufA[(e >> 6) * 456 + 5 + (e & 63)] = o1[pt0 * 64 + e];
  for (int e = t; e < 32 * 128; e += 512) bufA[(e >> 7) * 456 + 69 + (e & 127)] = o2[pt0 * 128 + e];
  for (int e = t; e < 32 * 256; e += 512) bufA[(e >> 8) * 456 + 197 + (e & 255)] = bf2f(o3[pt0 * 256 + e]);
  const int g = t >> 5, s2 = t & 31;
  const int p0 = 2 * g, p1 = 2 * g + 1;
  {
    const int o0 = s2 * 16;
    const int cnt = max(0, min(16, 453 - o0));
    float acc0[16], acc1[16];
#pragma unroll
    for (int m = 0; m < 16; ++m) {
      int o = o0 + m;
      float bv = (o < 453) ? b1[o] : 0.0f;
      acc0[m] = bv; acc1[m] = bv;
    }
    for (int kc = 0; kc < 453; kc += 16) {
      const int kn = min(16, 453 - kc);
      __syncthreads();
      for (int e2 = t; e2 < kn * 453; e2 += 512)
        wch[(e2 / 453) * 456 + (e2 % 453)] = w1[(size_t)(kc + e2 / 453) * 453 + (e2 % 453)];
      __syncthreads();
      for (int kl = 0; kl < kn; ++kl) {
        float xv0 = bufA[p0 * 456 + kc + kl];
        float xv1 = bufA[p1 * 456 + kc + kl];
        const float4* wr = reinterpret_cast<const float4*>(&wch[kl * 456 + o0]);
#pragma unroll
        for (int m4 = 0; m4 < 4; ++m4) {
          float4 w = wr[m4];
          acc0[4 * m4 + 0] += xv0 * w.x; acc0[4 * m4 + 1] += xv0 * w.y;
          acc0[4 * m4 + 2] += xv0 * w.z; acc0[4 * m4 + 3] += xv0 * w.w;
          acc1[4 * m4 + 0] += xv1 * w.x; acc1[4 * m4 + 1] += xv1 * w.y;
          acc1[4 * m4 + 2] += xv1 * w.z; acc1[4 * m4 + 3] += xv1 * w.w;
        }
      }
    }
    __syncthreads();
#pragma unroll
    for (int m = 0; m < 16; ++m) {
      if (m < cnt) {
        bufB[p0 * 456 + o0 + m] = elu_f(acc0[m]);
        bufB[p1 * 456 + o0 + m] = elu_f(acc1[m]);
      }
    }
  }
  {
    const int o0 = s2 * 8;
    const int cnt = max(0, min(8, 226 - o0));
    float acc0[8], acc1[8];
#pragma unroll
    for (int m = 0; m < 8; ++m) {
      int o = o0 + m;
      float bv = (o < 226) ? b2[o] : 0.0f;
      acc0[m] = bv; acc1[m] = bv;
    }
    for (int kc = 0; kc < 453; kc += 16) {
      const int kn = min(16, 453 - kc);
      __syncthreads();
      for (int e2 = t; e2 < kn * 226; e2 += 512)
        wch[(e2 / 226) * 228 + (e2 % 226)] = w2[(size_t)(kc + e2 / 226) * 226 + (e2 % 226)];
      __syncthreads();
      for (int kl = 0; kl < kn; ++kl) {
        float xv0 = bufB[p0 * 456 + kc + kl];
        float xv1 = bufB[p1 * 456 + kc + kl];
        const float4* wr = reinterpret_cast<const float4*>(&wch[kl * 228 + o0]);
#pragma unroll
        for (int m4 = 0; m4 < 2; ++m4) {
          float4 w = wr[m4];
          acc0[4 * m4 + 0] += xv0 * w.x; acc0[4 * m4 + 1] += xv0 * w.y;
          acc0[4 * m4 + 2] += xv0 * w.z; acc0[4 * m4 + 3] += xv0 * w.w;
          acc1[4 * m4 + 0] += xv1 * w.x; acc1[4 * m4 + 1] += xv1 * w.y;
          acc1[4 * m4 + 2] += xv1 * w.z; acc1[4 * m4 + 3] += xv1 * w.w;
        }
      }
    }
    __syncthreads();
#pragma unroll
    for (int m = 0; m < 8; ++m) {
      if (m < cnt) {
        bufA[p0 * 456 + o0 + m] = elu_f(acc0[m]);
        bufA[p1 * 456 + o0 + m] = elu_f(acc1[m]);
      }
    }
  }
  __syncthreads();
  {
    const int k0 = (s2 * 226) >> 5;
    const int k1 = ((s2 + 1) * 226) >> 5;
    float p00 = 0.f, p01 = 0.f, p10 = 0.f, p11 = 0.f;
    for (int k = k0; k < k1; ++k) {
      float wv0 = w3[2 * k + 0], wv1 = w3[2 * k + 1];
      float h0 = bufA[p0 * 456 + k], h1 = bufA[p1 * 456 + k];
      p00 += h0 * wv0; p01 += h0 * wv1;
      p10 += h1 * wv0; p11 += h1 * wv1;
    }
#pragma unroll
    for (int off = 1; off < 32; off <<= 1) {
      p00 += __shfl_xor(p00, off);
      p01 += __shfl_xor(p01, off);
      p10 += __shfl_xor(p10, off);
      p11 += __shfl_xor(p11, off);
    }
    if (s2 == 0) {
      float4 v = {p00 + b3[0], p01 + b3[1], p10 + b3[0], p11 + b3[1]};
      *reinterpret_cast<float4*>(&out[(pt0 + (size_t)p0) * 2]) = v;
    }
  }
}

// ------------------------------------------------------------- launch ----
extern "C" void kernel_launch(void* const* d_in, const int* in_sizes, int n_in,
                              void* d_out, int out_size, void* d_ws, size_t ws_size,
                              hipStream_t stream) {
  const float* coords = (const float*)d_in[0];
  const float* feat   = (const float*)d_in[1];
  const float* c1w1 = (const float*)d_in[2];  const float* c1b1 = (const float*)d_in[3];
  const float* c1w2 = (const float*)d_in[4];  const float* c1b2 = (const float*)d_in[5];
  const float* c2w1 = (const float*)d_in[6];  const float* c2b1 = (const float*)d_in[7];
  const float* c2w2 = (const float*)d_in[8];  const float* c2b2 = (const float*)d_in[9];
  const float* c3w1 = (const float*)d_in[10]; const float* c3b1 = (const float*)d_in[11];
  const float* c3w2 = (const float*)d_in[12]; const float* c3b2 = (const float*)d_in[13];
  const float* ow1  = (const float*)d_in[14]; const float* ob1  = (const float*)d_in[15];
  const float* ow2  = (const float*)d_in[16]; const float* ob2  = (const float*)d_in[17];
  const float* ow3  = (const float*)d_in[18]; const float* ob3  = (const float*)d_in[19];
  float* out = (float*)d_out;

  // ws layout (MiB): out1 f32 [0,32) | out2 f32 [32,96) | out3 bf16 [96,160)
  // | idx [160,162) | chunk buffer [162,212): ec2 H fp32 / ec3 H1 bf16
  // (both 256-event chunks of 50.3 MB, used sequentially).
  char* ws = (char*)d_ws;
  float* out1 = (float*)(ws);
  float* out2 = (float*)(ws + (32ull << 20));
  unsigned short* out3b = (unsigned short*)(ws + (96ull << 20));
  int* idx = (int*)(ws + (160ull << 20));
  float* Hbuf = (float*)(ws + (162ull << 20));
  unsigned short* h1 = (unsigned short*)(ws + (162ull << 20));

  knn_kernel<2><<<NB, 128, 0, stream>>>(coords, idx);
  ec1_kernel<<<NB, 512, 0, stream>>>(feat, idx, c1w1, c1b1, c1w2, c1b2, out1);
  knn_kernel<64><<<NB, 128, 0, stream>>>(out1, idx);
  for (int c = 0; c < 4; ++c) {
    ec2a_kernel<<<256, 512, 0, stream>>>(out1 + (size_t)c * 256 * NPT * 64,
                                         idx + (size_t)c * 256 * 512,
                                         c2w1, c2b1, Hbuf);
    ec2b_kernel<<<512, 512, 0, stream>>>(Hbuf, c2w2, c2b2,
                                         out2 + (size_t)c * 256 * NPT * 128);
  }
  knn_kernel<128><<<NB, 128, 0, stream>>>(out2, idx);
  for (int c = 0; c < 4; ++c) {
    ec3a_kernel<<<256, 512, 0, stream>>>(out2 + (size_t)c * 256 * NPT * 128,
                                         idx + (size_t)c * 256 * 512,
                                         c3w1, c3b1, h1);
    ec3b_kernel<<<256, 512, 0, stream>>>(h1, c3w2, c3b2,
                                         out3b + (size_t)c * 256 * NPT * 256);
  }
  head_kernel<<<4096, 512, 0, stream>>>(feat, out1, out2, out3b,
                                        ow1, ob1, ow2, ob2, ow3, ob3, out);
}

// Round 5
// 5685.427 us; speedup vs baseline: 7.2472x; 1.5831x over previous
//
#include <hip/hip_runtime.h>
#include <cstdint>
#include <cstddef>

// ParticleNet MI355X — Round 5.
// - kNN: fp32 shortlist + fp64 rescore (verified).
// - ec1: fp32 thread-per-edge (verified r4).
// - ec2: ec2a/ec2b fp32 register-tiled GEMMs (verified r4).
// - ec3: bf16 MFMA pair (verified r3/r4).
// - head: NEW fused bf16-MFMA kernel (r4's fp32 LDS version had 8.7e8 LDS
//   bank conflicts and ran 4.2 ms on the VALU).

#define NB 1024
#define NPT 128

typedef __attribute__((ext_vector_type(8))) short short8;
typedef __attribute__((ext_vector_type(4))) float floatx4;
typedef __attribute__((ext_vector_type(4))) unsigned int uint4v;

__device__ __forceinline__ float elu_f(float x) { return x > 0.0f ? x : expm1f(x); }

__device__ __forceinline__ unsigned short f2bf(float f) {
  unsigned u = __builtin_bit_cast(unsigned, f);
  unsigned r = u + 0x7FFFu + ((u >> 16) & 1u);
  return (unsigned short)(r >> 16);
}
__device__ __forceinline__ float bf2f(unsigned short h) {
  unsigned u = ((unsigned)h) << 16;
  return __builtin_bit_cast(float, u);
}

// ---------------------------------------------------------------- kNN ----
template<int C>
__global__ __launch_bounds__(128) void knn_kernel(const float* __restrict__ x,
                                                  int* __restrict__ idx) {
  __shared__ __align__(16) float xs[NPT][C + 4];
  __shared__ float x2s[NPT];
  __shared__ double x2d[NPT];
  const int b = blockIdx.x, t = threadIdx.x;
  const float* xb = x + (size_t)b * NPT * C;
  for (int e = t; e < NPT * C; e += 128) xs[e / C][e % C] = xb[e];
  __syncthreads();
  float xi[C];
  float s2 = 0.0f;
  double s2d = 0.0;
#pragma unroll
  for (int c = 0; c < C; ++c) {
    xi[c] = xs[t][c];
    s2 += xi[c] * xi[c];
    s2d += (double)xi[c] * (double)xi[c];
  }
  x2s[t] = s2;
  x2d[t] = s2d;
  __syncthreads();
  float bd0 = 1e30f, bd1 = 1e30f, bd2 = 1e30f, bd3 = 1e30f, bd4 = 1e30f, bd5 = 1e30f;
  int bi0 = 0, bi1 = 0, bi2 = 0, bi3 = 0, bi4 = 0, bi5 = 0;
  for (int j = 0; j < NPT; ++j) {
    if (j == t) continue;
    float dot = 0.0f;
    if constexpr (C >= 4) {
      const float4* xr = reinterpret_cast<const float4*>(&xs[j][0]);
#pragma unroll
      for (int c4 = 0; c4 < C / 4; ++c4) {
        float4 v = xr[c4];
        dot += xi[4 * c4 + 0] * v.x + xi[4 * c4 + 1] * v.y +
               xi[4 * c4 + 2] * v.z + xi[4 * c4 + 3] * v.w;
      }
    } else {
#pragma unroll
      for (int c = 0; c < C; ++c) dot += xi[c] * xs[j][c];
    }
    float d = s2 + x2s[j] - 2.0f * dot;
    if (d < bd5) {
      bd5 = d; bi5 = j;
      if (bd5 < bd4) {
        float td = bd4; bd4 = bd5; bd5 = td; int ti = bi4; bi4 = bi5; bi5 = ti;
        if (bd4 < bd3) {
          td = bd3; bd3 = bd4; bd4 = td; ti = bi3; bi3 = bi4; bi4 = ti;
          if (bd3 < bd2) {
            td = bd2; bd2 = bd3; bd3 = td; ti = bi2; bi2 = bi3; bi3 = ti;
            if (bd2 < bd1) {
              td = bd1; bd1 = bd2; bd2 = td; ti = bi1; bi1 = bi2; bi2 = ti;
              if (bd1 < bd0) {
                td = bd0; bd0 = bd1; bd1 = td; ti = bi0; bi0 = bi1; bi1 = ti;
              }
            }
          }
        }
      }
    }
  }
  auto refine = [&](int j) -> double {
    double dot = 0.0;
#pragma unroll
    for (int c = 0; c < C; ++c) dot += (double)xi[c] * (double)xs[j][c];
    return s2d + x2d[j] - 2.0 * dot;
  };
  double e0 = refine(bi0), e1 = refine(bi1), e2 = refine(bi2);
  double e3 = refine(bi3), e4 = refine(bi4), e5 = refine(bi5);
#define CSWP(da, ia, db, ib)                                            \
  if ((da > db) || (da == db && ia > ib)) {                             \
    double _td = da; da = db; db = _td; int _ti = ia; ia = ib; ib = _ti; }
  CSWP(e0, bi0, e1, bi1) CSWP(e1, bi1, e2, bi2) CSWP(e2, bi2, e3, bi3)
  CSWP(e3, bi3, e4, bi4) CSWP(e4, bi4, e5, bi5)
  CSWP(e0, bi0, e1, bi1) CSWP(e1, bi1, e2, bi2) CSWP(e2, bi2, e3, bi3)
  CSWP(e3, bi3, e4, bi4)
  CSWP(e0, bi0, e1, bi1) CSWP(e1, bi1, e2, bi2) CSWP(e2, bi2, e3, bi3)
  CSWP(e0, bi0, e1, bi1) CSWP(e1, bi1, e2, bi2)
  CSWP(e0, bi0, e1, bi1)
#undef CSWP
  int* ib = idx + ((size_t)b * NPT + t) * 4;
  ib[0] = bi0; ib[1] = bi1; ib[2] = bi2; ib[3] = bi3;
}

// ---------------------------------------------------------------- ec1 ----
__global__ __launch_bounds__(512, 2) void ec1_kernel(
    const float* __restrict__ feat, const int* __restrict__ idx,
    const float* __restrict__ w1, const float* __restrict__ b1,
    const float* __restrict__ w2, const float* __restrict__ b2,
    float* __restrict__ out) {
  __shared__ __align__(16) float fs[NPT][6];
  __shared__ __align__(16) float w1s[10][32];
  __shared__ __align__(16) float w2s[32][68];
  __shared__ float b1s[32], b2s[64];
  const int b = blockIdx.x, t = threadIdx.x;
  const float* fb = feat + (size_t)b * NPT * 5;
  for (int e = t; e < NPT * 5; e += 512) fs[e / 5][e % 5] = fb[e];
  if (t < 320) w1s[t / 32][t % 32] = w1[t];
  for (int e = t; e < 2048; e += 512) w2s[e >> 6][e & 63] = w2[e];
  if (t < 32) b1s[t] = b1[t];
  if (t >= 448) b2s[t - 448] = b2[t - 448];
  __syncthreads();
  const int p = t >> 2;
  const int e4 = t & 3;
  const int j = idx[(size_t)b * 512 + t];
  float t32[32];
#pragma unroll
  for (int o = 0; o < 32; ++o) t32[o] = b1s[o];
#pragma unroll
  for (int c = 0; c < 10; ++c) {
    float in_c = (c < 5) ? fs[p][c] : (fs[j][c - 5] - fs[p][c - 5]);
    const float4* wr = reinterpret_cast<const float4*>(&w1s[c][0]);
#pragma unroll
    for (int o4 = 0; o4 < 8; ++o4) {
      float4 w = wr[o4];
      t32[4 * o4 + 0] += in_c * w.x; t32[4 * o4 + 1] += in_c * w.y;
      t32[4 * o4 + 2] += in_c * w.z; t32[4 * o4 + 3] += in_c * w.w;
    }
  }
#pragma unroll
  for (int o = 0; o < 32; ++o) t32[o] = elu_f(t32[o]);
  for (int otile = 0; otile < 2; ++otile) {
    float acc[32];
#pragma unroll
    for (int o = 0; o < 32; ++o) acc[o] = b2s[otile * 32 + o];
#pragma unroll
    for (int k = 0; k < 32; ++k) {
      float hk = t32[k];
      const float4* wr = reinterpret_cast<const float4*>(&w2s[k][otile * 32]);
#pragma unroll
      for (int o4 = 0; o4 < 8; ++o4) {
        float4 w = wr[o4];
        acc[4 * o4 + 0] += hk * w.x; acc[4 * o4 + 1] += hk * w.y;
        acc[4 * o4 + 2] += hk * w.z; acc[4 * o4 + 3] += hk * w.w;
      }
    }
#pragma unroll
    for (int o = 0; o < 32; ++o) {
      float v = elu_f(acc[o]);
      v += __shfl_xor(v, 1);
      v += __shfl_xor(v, 2);
      acc[o] = v;
    }
    if (e4 == otile) {
      float* ob = out + ((size_t)b * NPT + p) * 64 + otile * 32;
#pragma unroll
      for (int o4 = 0; o4 < 8; ++o4) {
        float4 v = {0.25f * acc[4 * o4 + 0], 0.25f * acc[4 * o4 + 1],
                    0.25f * acc[4 * o4 + 2], 0.25f * acc[4 * o4 + 3]};
        *reinterpret_cast<float4*>(&ob[4 * o4]) = v;
      }
    }
  }
}

// ---------------------------------------------------------------- ec2a ----
__global__ __launch_bounds__(512, 2) void ec2a_kernel(
    const float* __restrict__ x, const int* __restrict__ idx,
    const float* __restrict__ w1, const float* __restrict__ b1,
    float* __restrict__ H) {
  __shared__ __align__(16) float xs[NPT][68];
  __shared__ __align__(16) float w1s[128][100];
  __shared__ float b1s[96];
  const int b = blockIdx.x, t = threadIdx.x;
  const float* xb = x + (size_t)b * NPT * 64;
  for (int e = t; e < NPT * 64; e += 512) xs[e >> 6][e & 63] = xb[e];
  for (int e = t; e < 128 * 96; e += 512) w1s[e / 96][e % 96] = w1[e];
  if (t < 96) b1s[t] = b1[t];
  __syncthreads();
  const int pb = t >> 2, part = t & 3;
  const int n0 = part * 24;
  int jn[4];
#pragma unroll
  for (int i = 0; i < 4; ++i) jn[i] = idx[(size_t)b * 512 + pb * 4 + i];
  float acc[4][24];
#pragma unroll
  for (int m = 0; m < 24; ++m) {
    float bv = b1s[n0 + m];
#pragma unroll
    for (int i = 0; i < 4; ++i) acc[i][m] = bv;
  }
  for (int c = 0; c < 64; ++c) {
    float in_c = xs[pb][c];
    const float4* wr = reinterpret_cast<const float4*>(&w1s[c][n0]);
#pragma unroll
    for (int q4 = 0; q4 < 6; ++q4) {
      float4 wv = wr[q4];
#pragma unroll
      for (int i = 0; i < 4; ++i) {
        acc[i][4 * q4 + 0] += in_c * wv.x;
        acc[i][4 * q4 + 1] += in_c * wv.y;
        acc[i][4 * q4 + 2] += in_c * wv.z;
        acc[i][4 * q4 + 3] += in_c * wv.w;
      }
    }
  }
  for (int c = 0; c < 64; ++c) {
    float xic = xs[pb][c];
    float in0 = xs[jn[0]][c] - xic;
    float in1 = xs[jn[1]][c] - xic;
    float in2 = xs[jn[2]][c] - xic;
    float in3 = xs[jn[3]][c] - xic;
    const float4* wr = reinterpret_cast<const float4*>(&w1s[64 + c][n0]);
#pragma unroll
    for (int q4 = 0; q4 < 6; ++q4) {
      float4 wv = wr[q4];
      acc[0][4 * q4 + 0] += in0 * wv.x; acc[0][4 * q4 + 1] += in0 * wv.y;
      acc[0][4 * q4 + 2] += in0 * wv.z; acc[0][4 * q4 + 3] += in0 * wv.w;
      acc[1][4 * q4 + 0] += in1 * wv.x; acc[1][4 * q4 + 1] += in1 * wv.y;
      acc[1][4 * q4 + 2] += in1 * wv.z; acc[1][4 * q4 + 3] += in1 * wv.w;
      acc[2][4 * q4 + 0] += in2 * wv.x; acc[2][4 * q4 + 1] += in2 * wv.y;
      acc[2][4 * q4 + 2] += in2 * wv.z; acc[2][4 * q4 + 3] += in2 * wv.w;
      acc[3][4 * q4 + 0] += in3 * wv.x; acc[3][4 * q4 + 1] += in3 * wv.y;
      acc[3][4 * q4 + 2] += in3 * wv.z; acc[3][4 * q4 + 3] += in3 * wv.w;
    }
  }
#pragma unroll
  for (int i = 0; i < 4; ++i) {
    float* hrow = H + ((size_t)b * 512 + pb * 4 + i) * 96 + n0;
#pragma unroll
    for (int q4 = 0; q4 < 6; ++q4) {
      float4 v = {elu_f(acc[i][4 * q4 + 0]), elu_f(acc[i][4 * q4 + 1]),
                  elu_f(acc[i][4 * q4 + 2]), elu_f(acc[i][4 * q4 + 3])};
      *reinterpret_cast<float4*>(&hrow[4 * q4]) = v;
    }
  }
}

// ---------------------------------------------------------------- ec2b ----
__global__ __launch_bounds__(512, 2) void ec2b_kernel(
    const float* __restrict__ H, const float* __restrict__ w2,
    const float* __restrict__ b2, float* __restrict__ out) {
  __shared__ __align__(16) float hsT[96][260];
  __shared__ float w2s[96][132];
  __shared__ float b2s[128];
  const int z = blockIdx.x, t = threadIdx.x;
  const int bc = z >> 1, hh = z & 1;
  const float* Hb = H + ((size_t)bc * 512 + hh * 256) * 96;
  for (int i = t; i < 256 * 96; i += 512) hsT[i % 96][i / 96] = Hb[i];
  for (int i = t; i < 96 * 128; i += 512) w2s[i >> 7][i & 127] = w2[i];
  if (t < 128) b2s[t] = b2[t];
  __syncthreads();
  const int g = t >> 3, oq = t & 7;
  float acc[4][16];
#pragma unroll
  for (int m = 0; m < 16; ++m) {
    float bv = b2s[oq + 8 * m];
#pragma unroll
    for (int i = 0; i < 4; ++i) acc[i][m] = bv;
  }
  for (int k = 0; k < 96; ++k) {
    float4 hv = *reinterpret_cast<const float4*>(&hsT[k][4 * g]);
#pragma unroll
    for (int m = 0; m < 16; ++m) {
      float wv = w2s[k][oq + 8 * m];
      acc[0][m] += hv.x * wv;
      acc[1][m] += hv.y * wv;
      acc[2][m] += hv.z * wv;
      acc[3][m] += hv.w * wv;
    }
  }
  float* orow = out + ((size_t)bc * NPT + hh * 64 + g) * 128;
#pragma unroll
  for (int m = 0; m < 16; ++m) {
    float s = elu_f(acc[0][m]) + elu_f(acc[1][m]) +
              elu_f(acc[2][m]) + elu_f(acc[3][m]);
    orow[oq + 8 * m] = 0.25f * s;
  }
}

// ---------------------------------------------------------------- ec3a ----
__global__ __launch_bounds__(512, 2) void ec3a_kernel(
    const float* __restrict__ x, const int* __restrict__ idx,
    const float* __restrict__ w1, const float* __restrict__ b1,
    unsigned short* __restrict__ h1) {
  __shared__ unsigned short Xb[128][136];
  __shared__ unsigned short W1t[192][264];
  __shared__ float b1s[192];
  __shared__ unsigned short stg[8][16][40];
  const int b = blockIdx.x, t = threadIdx.x;
  const float* xb = x + (size_t)b * NPT * 128;
  for (int e = t; e < NPT * 128; e += 512) Xb[e >> 7][e & 127] = f2bf(xb[e]);
  for (int e = t; e < 256 * 192; e += 512) {
    int k = e / 192, n = e % 192;
    W1t[n][k] = f2bf(w1[e]);
  }
  if (t < 192) b1s[t] = b1[t];
  __syncthreads();
  const int w = t >> 6, l = t & 63;
  const int lr = l & 15, lq = l >> 4;
  for (int mt = 0; mt < 4; ++mt) {
    const int m = (w * 4 + mt) * 16;
    const int e = m + lr;
    const int p = e >> 2;
    const int jp = idx[(size_t)b * 512 + e];
    short8 A[8];
#pragma unroll
    for (int kk = 0; kk < 4; ++kk) {
      int k0 = kk * 32 + lq * 8;
      A[kk] = *reinterpret_cast<const short8*>(&Xb[p][k0]);
    }
#pragma unroll
    for (int kk = 0; kk < 4; ++kk) {
      int k0 = kk * 32 + lq * 8;
      short8 aj = *reinterpret_cast<const short8*>(&Xb[jp][k0]);
      short8 ai = *reinterpret_cast<const short8*>(&Xb[p][k0]);
      short8 d;
#pragma unroll
      for (int q = 0; q < 8; ++q)
        d[q] = (short)f2bf(bf2f((unsigned short)aj[q]) - bf2f((unsigned short)ai[q]));
      A[4 + kk] = d;
    }
    floatx4 acc[12];
#pragma unroll
    for (int n = 0; n < 12; ++n) acc[n] = (floatx4){0.f, 0.f, 0.f, 0.f};
#pragma unroll
    for (int n = 0; n < 12; ++n) {
#pragma unroll
      for (int kk = 0; kk < 8; ++kk) {
        short8 Bf = *reinterpret_cast<const short8*>(&W1t[n * 16 + lr][kk * 32 + lq * 8]);
        acc[n] = __builtin_amdgcn_mfma_f32_16x16x32_bf16(A[kk], Bf, acc[n], 0, 0, 0);
      }
    }
#pragma unroll
    for (int pr = 0; pr < 6; ++pr) {
      float bv0 = b1s[pr * 32 + lr];
      float bv1 = b1s[pr * 32 + 16 + lr];
#pragma unroll
      for (int i = 0; i < 4; ++i) {
        stg[w][lq * 4 + i][lr]      = f2bf(elu_f(acc[2 * pr][i] + bv0));
        stg[w][lq * 4 + i][16 + lr] = f2bf(elu_f(acc[2 * pr + 1][i] + bv1));
      }
      asm volatile("s_waitcnt lgkmcnt(0)" ::: "memory");
      const unsigned short* src = &stg[w][l >> 2][(l & 3) * 8];
      uint4v vv = *reinterpret_cast<const uint4v*>(src);
      size_t dst = ((size_t)b * 512 + m + (l >> 2)) * 192 + pr * 32 + (l & 3) * 8;
      *reinterpret_cast<uint4v*>(&h1[dst]) = vv;
      asm volatile("s_waitcnt lgkmcnt(0)" ::: "memory");
    }
  }
}

// ---------------------------------------------------------------- ec3b ----
__global__ __launch_bounds__(512, 2) void ec3b_kernel(
    const unsigned short* __restrict__ h1,
    const float* __restrict__ w2, const float* __restrict__ b2,
    unsigned short* __restrict__ out3) {
  __shared__ unsigned short W2t[256][200];
  __shared__ float b2s[256];
  const int b = blockIdx.x, t = threadIdx.x;
  for (int e = t; e < 192 * 256; e += 512) {
    int k = e >> 8, n = e & 255;
    W2t[n][k] = f2bf(w2[e]);
  }
  if (t < 256) b2s[t] = b2[t];
  __syncthreads();
  const int w = t >> 6, l = t & 63;
  const int lr = l & 15, lq = l >> 4;
  for (int mt = 0; mt < 4; ++mt) {
    const int m = (w * 4 + mt) * 16;
    floatx4 acc[16];
#pragma unroll
    for (int n = 0; n < 16; ++n) acc[n] = (floatx4){0.f, 0.f, 0.f, 0.f};
    const unsigned short* arow = h1 + ((size_t)b * 512 + m + lr) * 192;
#pragma unroll
    for (int kk = 0; kk < 6; ++kk) {
      short8 Af = *reinterpret_cast<const short8*>(&arow[kk * 32 + lq * 8]);
#pragma unroll
      for (int n = 0; n < 16; ++n) {
        short8 Bf = *reinterpret_cast<const short8*>(&W2t[n * 16 + lr][kk * 32 + lq * 8]);
        acc[n] = __builtin_amdgcn_mfma_f32_16x16x32_bf16(Af, Bf, acc[n], 0, 0, 0);
      }
    }
    unsigned short* orow = out3 + ((size_t)b * NPT + (m >> 2) + lq) * 256;
#pragma unroll
    for (int n = 0; n < 16; ++n) {
      float bv = b2s[n * 16 + lr];
      float s = 0.f;
#pragma unroll
      for (int i = 0; i < 4; ++i) s += elu_f(acc[n][i] + bv);
      orow[n * 16 + lr] = f2bf(0.25f * s);
    }
  }
}

// ----------------------------------------------------------- head MFMA ----
// Fused 453->453->226->2 MLP, bf16 MFMA, fp32 accum; GEMM3 in fp32.
// Block = 64 points, 256 thr, 4 waves (1 wave-tile of 16 rows each).
// Concat-padded K layout: feat [0,8) | o1 [8,72) | o2 [72,200) | o3 [200,456)
// | zero [456,480). W1 rows permuted to match at staging time.
#define HSTR 488   // LDS row stride in shorts (976 B = 61*16 -> 2-way-free b128)
__global__ __launch_bounds__(256, 1) void head_mfma_kernel(
    const float* __restrict__ feat, const float* __restrict__ o1,
    const float* __restrict__ o2, const unsigned short* __restrict__ o3,
    const float* __restrict__ w1, const float* __restrict__ b1,
    const float* __restrict__ w2, const float* __restrict__ b2,
    const float* __restrict__ w3, const float* __restrict__ b3,
    float* __restrict__ out) {
  __shared__ unsigned short uA[64 * HSTR];  // Xls, then W dbuf (2 x 32 x HSTR)
  __shared__ unsigned short uH[64 * HSTR];  // H1 bf16
  __shared__ float b1s[480], b2s[256], w3s[512];
  const int t = threadIdx.x;
  const size_t base = (size_t)blockIdx.x * 64;

  // ---- stage concat -> Xls (bf16, padded layout) + biases ----
  for (int e = t; e < 64 * 8; e += 256) {
    int r = e >> 3, c = e & 7;
    uA[r * HSTR + c] = (c < 5) ? f2bf(feat[(base + r) * 5 + c]) : 0;
  }
  for (int e = t; e < 64 * 64; e += 256) {
    int r = e >> 6, c = e & 63;
    uA[r * HSTR + 8 + c] = f2bf(o1[(base + r) * 64 + c]);
  }
  for (int e = t; e < 64 * 128; e += 256) {
    int r = e >> 7, c = e & 127;
    uA[r * HSTR + 72 + c] = f2bf(o2[(base + r) * 128 + c]);
  }
  for (int e = t; e < 64 * 256; e += 256) {
    int r = e >> 8, c = e & 255;
    uA[r * HSTR + 200 + c] = o3[(base + r) * 256 + c];
  }
  for (int e = t; e < 64 * 32; e += 256) {
    int r = e >> 5, c = e & 31;
    uA[r * HSTR + 456 + c] = 0;
  }
  for (int i = t; i < 480; i += 256) b1s[i] = (i < 453) ? b1[i] : 0.f;
  if (t < 256) b2s[t] = (t < 226) ? b2[t] : 0.f;
  for (int i = t; i < 512; i += 256) w3s[i] = (i < 452) ? w3[i] : 0.f;
  __syncthreads();

  const int w = t >> 6, l = t & 63;
  const int lr = l & 15, lq = l >> 4;
  const int sn = t & 31, skq = t >> 5;   // staging: n-col, k-octant

  // ---- A1 fragments (held in registers across GEMM1) ----
  short8 Af[15];
#pragma unroll
  for (int kk = 0; kk < 15; ++kk)
    Af[kk] = *reinterpret_cast<const short8*>(
        &uA[(w * 16 + lr) * HSTR + kk * 32 + lq * 8]);
  __syncthreads();  // Xls dead -> uA becomes W double-buffer

  // W1 stage: Wbuf[d][n][k'] = w1[korig(k')*453 + (nt*32+n)], korig: pad-map.
#define STAGE_W1_LOAD(NTP)                                              \
  {                                                                     \
    _Pragma("unroll")                                                   \
    for (int q = 0; q < 60; ++q) {                                      \
      int kp = skq * 60 + q;                                            \
      int ko = (kp < 5) ? kp : kp - 3;                                  \
      bool ok = (kp < 5) || (kp >= 8 && kp < 456);                      \
      int no = (NTP) * 32 + sn;                                         \
      float x = 0.f;                                                    \
      if (ok && no < 453) x = w1[(size_t)ko * 453 + no];                \
      v[q] = x;                                                         \
    }                                                                   \
  }
#define STAGE_W2_LOAD(NTP)                                              \
  {                                                                     \
    _Pragma("unroll")                                                   \
    for (int q = 0; q < 60; ++q) {                                      \
      int kp = skq * 60 + q;                                            \
      int no = (NTP) * 32 + sn;                                         \
      float x = 0.f;                                                    \
      if (kp < 453 && no < 226) x = w2[(size_t)kp * 226 + no];          \
      v[q] = x;                                                         \
    }                                                                   \
  }
#define STAGE_WRITE(D)                                                  \
  {                                                                     \
    _Pragma("unroll")                                                   \
    for (int q = 0; q < 60; q += 2) {                                   \
      unsigned pk = (unsigned)f2bf(v[q]) | ((unsigned)f2bf(v[q + 1]) << 16); \
      *reinterpret_cast<unsigned*>(                                     \
          &uA[(D) * 15616 + sn * HSTR + skq * 60 + q]) = pk;            \
    }                                                                   \
  }

  {
    float v[60];
    STAGE_W1_LOAD(0)
    STAGE_WRITE(0)
  }
  __syncthreads();

  // ---- GEMM1: X[64x480] * W1t -> H1 (15 col-chunks of 32, dbuf) ----
  for (int nt = 0; nt < 15; ++nt) {
    const int d = nt & 1;
    float v[60];
    if (nt < 14) STAGE_W1_LOAD(nt + 1)
    floatx4 acc0 = {0.f, 0.f, 0.f, 0.f}, acc1 = {0.f, 0.f, 0.f, 0.f};
    const unsigned short* Wb = &uA[d * 15616];
#pragma unroll
    for (int kk = 0; kk < 15; ++kk) {
      short8 B0 = *reinterpret_cast<const short8*>(&Wb[lr * HSTR + kk * 32 + lq * 8]);
      short8 B1 = *reinterpret_cast<const short8*>(&Wb[(16 + lr) * HSTR + kk * 32 + lq * 8]);
      acc0 = __builtin_amdgcn_mfma_f32_16x16x32_bf16(Af[kk], B0, acc0, 0, 0, 0);
      acc1 = __builtin_amdgcn_mfma_f32_16x16x32_bf16(Af[kk], B1, acc1, 0, 0, 0);
    }
    {
      int c0 = nt * 32 + lr, c1 = nt * 32 + 16 + lr;
      float bb0 = b1s[c0], bb1 = b1s[c1];
#pragma unroll
      for (int i = 0; i < 4; ++i) {
        int row = w * 16 + lq * 4 + i;
        uH[row * HSTR + c0] = f2bf(elu_f(acc0[i] + bb0));
        uH[row * HSTR + c1] = f2bf(elu_f(acc1[i] + bb1));
      }
    }
    if (nt < 14) STAGE_WRITE(d ^ 1)
    __syncthreads();
  }

  // ---- A2 fragments from H1 ----
#pragma unroll
  for (int kk = 0; kk < 15; ++kk)
    Af[kk] = *reinterpret_cast<const short8*>(
        &uH[(w * 16 + lr) * HSTR + kk * 32 + lq * 8]);
  {
    float v[60];
    STAGE_W2_LOAD(0)
    STAGE_WRITE(0)
  }
  __syncthreads();

  // ---- GEMM2 (8 col-chunks of 32) + GEMM3 partial in fp32 ----
  float p0[4] = {0.f, 0.f, 0.f, 0.f}, p1[4] = {0.f, 0.f, 0.f, 0.f};
  for (int nt = 0; nt < 8; ++nt) {
    const int d = nt & 1;
    float v[60];
    if (nt < 7) STAGE_W2_LOAD(nt + 1)
    floatx4 acc0 = {0.f, 0.f, 0.f, 0.f}, acc1 = {0.f, 0.f, 0.f, 0.f};
    const unsigned short* Wb = &uA[d * 15616];
#pragma unroll
    for (int kk = 0; kk < 15; ++kk) {
      short8 B0 = *reinterpret_cast<const short8*>(&Wb[lr * HSTR + kk * 32 + lq * 8]);
      short8 B1 = *reinterpret_cast<const short8*>(&Wb[(16 + lr) * HSTR + kk * 32 + lq * 8]);
      acc0 = __builtin_amdgcn_mfma_f32_16x16x32_bf16(Af[kk], B0, acc0, 0, 0, 0);
      acc1 = __builtin_amdgcn_mfma_f32_16x16x32_bf16(Af[kk], B1, acc1, 0, 0, 0);
    }
    {
      int c0 = nt * 32 + lr, c1 = nt * 32 + 16 + lr;
      float bb0 = b2s[c0], bb1 = b2s[c1];
      float wa0 = w3s[c0 * 2], wb0 = w3s[c0 * 2 + 1];
      float wa1 = w3s[c1 * 2], wb1 = w3s[c1 * 2 + 1];
#pragma unroll
      for (int i = 0; i < 4; ++i) {
        float h0 = elu_f(acc0[i] + bb0);
        float h1v = elu_f(acc1[i] + bb1);
        p0[i] += h0 * wa0 + h1v * wa1;
        p1[i] += h0 * wb0 + h1v * wb1;
      }
    }
    if (nt < 7) STAGE_WRITE(d ^ 1)
    __syncthreads();
  }

  // ---- reduce GEMM3 partials over the 16 lr lanes and store ----
#pragma unroll
  for (int i = 0; i < 4; ++i) {
    float a = p0[i], bvv = p1[i];
#pragma unroll
    for (int m = 1; m < 16; m <<= 1) {
      a += __shfl_xor(a, m);
      bvv += __shfl_xor(bvv, m);
    }
    if (lr == 0) {
      size_t row = base + w * 16 + lq * 4 + i;
      float2 vv = {a + b3[0], bvv + b3[1]};
      *reinterpret_cast<float2*>(&out[row * 2]) = vv;
    }
  }
#undef STAGE_W1_LOAD
#undef STAGE_W2_LOAD
#undef STAGE_WRITE
}

// ------------------------------------------------------------- launch ----
extern "C" void kernel_launch(void* const* d_in, const int* in_sizes, int n_in,
                              void* d_out, int out_size, void* d_ws, size_t ws_size,
                              hipStream_t stream) {
  const float* coords = (const float*)d_in[0];
  const float* feat   = (const float*)d_in[1];
  const float* c1w1 = (const float*)d_in[2];  const float* c1b1 = (const float*)d_in[3];
  const float* c1w2 = (const float*)d_in[4];  const float* c1b2 = (const float*)d_in[5];
  const float* c2w1 = (const float*)d_in[6];  const float* c2b1 = (const float*)d_in[7];
  const float* c2w2 = (const float*)d_in[8];  const float* c2b2 = (const float*)d_in[9];
  const float* c3w1 = (const float*)d_in[10]; const float* c3b1 = (const float*)d_in[11];
  const float* c3w2 = (const float*)d_in[12]; const float* c3b2 = (const float*)d_in[13];
  const float* ow1  = (const float*)d_in[14]; const float* ob1  = (const float*)d_in[15];
  const float* ow2  = (const float*)d_in[16]; const float* ob2  = (const float*)d_in[17];
  const float* ow3  = (const float*)d_in[18]; const float* ob3  = (const float*)d_in[19];
  float* out = (float*)d_out;

  // ws layout (MiB): out1 f32 [0,32) | out2 f32 [32,96) | out3 bf16 [96,160)
  // | idx [160,162) | chunk buffer [162,212): ec2 H fp32 / ec3 H1 bf16.
  char* ws = (char*)d_ws;
  float* out1 = (float*)(ws);
  float* out2 = (float*)(ws + (32ull << 20));
  unsigned short* out3b = (unsigned short*)(ws + (96ull << 20));
  int* idx = (int*)(ws + (160ull << 20));
  float* Hbuf = (float*)(ws + (162ull << 20));
  unsigned short* h1 = (unsigned short*)(ws + (162ull << 20));

  knn_kernel<2><<<NB, 128, 0, stream>>>(coords, idx);
  ec1_kernel<<<NB, 512, 0, stream>>>(feat, idx, c1w1, c1b1, c1w2, c1b2, out1);
  knn_kernel<64><<<NB, 128, 0, stream>>>(out1, idx);
  for (int c = 0; c < 4; ++c) {
    ec2a_kernel<<<256, 512, 0, stream>>>(out1 + (size_t)c * 256 * NPT * 64,
                                         idx + (size_t)c * 256 * 512,
                                         c2w1, c2b1, Hbuf);
    ec2b_kernel<<<512, 512, 0, stream>>>(Hbuf, c2w2, c2b2,
                                         out2 + (size_t)c * 256 * NPT * 128);
  }
  knn_kernel<128><<<NB, 128, 0, stream>>>(out2, idx);
  for (int c = 0; c < 4; ++c) {
    ec3a_kernel<<<256, 512, 0, stream>>>(out2 + (size_t)c * 256 * NPT * 128,
                                         idx + (size_t)c * 256 * 512,
                                         c3w1, c3b1, h1);
    ec3b_kernel<<<256, 512, 0, stream>>>(h1, c3w2, c3b2,
                                         out3b + (size_t)c * 256 * NPT * 256);
  }
  head_mfma_kernel<<<2048, 256, 0, stream>>>(feat, out1, out2, out3b,
                                             ow1, ob1, ow2, ob2, ow3, ob3, out);
}

// Round 6
// 4099.634 us; speedup vs baseline: 10.0505x; 1.3868x over previous
//
#include <hip/hip_runtime.h>
#include <cstdint>
#include <cstddef>

// ParticleNet MI355X — Round 6.
// - kNN: fp32 shortlist + fp64 rescore (verified).
// - ec1: REWRITTEN layer2 — t32 parked in LDS, acc[16] tiles (r5 version
//   spilled under the 128-VGPR cap: 8.3 GB scratch traffic, 2.97 ms).
// - ec2: ec2a/ec2b fp32 register-tiled GEMMs (verified r4/r5).
// - ec3: bf16 MFMA pair (verified).
// - head: fused bf16 MFMA (verified r5).

#define NB 1024
#define NPT 128

typedef __attribute__((ext_vector_type(8))) short short8;
typedef __attribute__((ext_vector_type(4))) float floatx4;
typedef __attribute__((ext_vector_type(4))) unsigned int uint4v;

__device__ __forceinline__ float elu_f(float x) { return x > 0.0f ? x : expm1f(x); }

__device__ __forceinline__ unsigned short f2bf(float f) {
  unsigned u = __builtin_bit_cast(unsigned, f);
  unsigned r = u + 0x7FFFu + ((u >> 16) & 1u);
  return (unsigned short)(r >> 16);
}
__device__ __forceinline__ float bf2f(unsigned short h) {
  unsigned u = ((unsigned)h) << 16;
  return __builtin_bit_cast(float, u);
}

// ---------------------------------------------------------------- kNN ----
template<int C>
__global__ __launch_bounds__(128) void knn_kernel(const float* __restrict__ x,
                                                  int* __restrict__ idx) {
  __shared__ __align__(16) float xs[NPT][C + 4];
  __shared__ float x2s[NPT];
  __shared__ double x2d[NPT];
  const int b = blockIdx.x, t = threadIdx.x;
  const float* xb = x + (size_t)b * NPT * C;
  for (int e = t; e < NPT * C; e += 128) xs[e / C][e % C] = xb[e];
  __syncthreads();
  float xi[C];
  float s2 = 0.0f;
  double s2d = 0.0;
#pragma unroll
  for (int c = 0; c < C; ++c) {
    xi[c] = xs[t][c];
    s2 += xi[c] * xi[c];
    s2d += (double)xi[c] * (double)xi[c];
  }
  x2s[t] = s2;
  x2d[t] = s2d;
  __syncthreads();
  float bd0 = 1e30f, bd1 = 1e30f, bd2 = 1e30f, bd3 = 1e30f, bd4 = 1e30f, bd5 = 1e30f;
  int bi0 = 0, bi1 = 0, bi2 = 0, bi3 = 0, bi4 = 0, bi5 = 0;
  for (int j = 0; j < NPT; ++j) {
    if (j == t) continue;
    float dot = 0.0f;
    if constexpr (C >= 4) {
      const float4* xr = reinterpret_cast<const float4*>(&xs[j][0]);
#pragma unroll
      for (int c4 = 0; c4 < C / 4; ++c4) {
        float4 v = xr[c4];
        dot += xi[4 * c4 + 0] * v.x + xi[4 * c4 + 1] * v.y +
               xi[4 * c4 + 2] * v.z + xi[4 * c4 + 3] * v.w;
      }
    } else {
#pragma unroll
      for (int c = 0; c < C; ++c) dot += xi[c] * xs[j][c];
    }
    float d = s2 + x2s[j] - 2.0f * dot;
    if (d < bd5) {
      bd5 = d; bi5 = j;
      if (bd5 < bd4) {
        float td = bd4; bd4 = bd5; bd5 = td; int ti = bi4; bi4 = bi5; bi5 = ti;
        if (bd4 < bd3) {
          td = bd3; bd3 = bd4; bd4 = td; ti = bi3; bi3 = bi4; bi4 = ti;
          if (bd3 < bd2) {
            td = bd2; bd2 = bd3; bd3 = td; ti = bi2; bi2 = bi3; bi3 = ti;
            if (bd2 < bd1) {
              td = bd1; bd1 = bd2; bd2 = td; ti = bi1; bi1 = bi2; bi2 = ti;
              if (bd1 < bd0) {
                td = bd0; bd0 = bd1; bd1 = td; ti = bi0; bi0 = bi1; bi1 = ti;
              }
            }
          }
        }
      }
    }
  }
  auto refine = [&](int j) -> double {
    double dot = 0.0;
#pragma unroll
    for (int c = 0; c < C; ++c) dot += (double)xi[c] * (double)xs[j][c];
    return s2d + x2d[j] - 2.0 * dot;
  };
  double e0 = refine(bi0), e1 = refine(bi1), e2 = refine(bi2);
  double e3 = refine(bi3), e4 = refine(bi4), e5 = refine(bi5);
#define CSWP(da, ia, db, ib)                                            \
  if ((da > db) || (da == db && ia > ib)) {                             \
    double _td = da; da = db; db = _td; int _ti = ia; ia = ib; ib = _ti; }
  CSWP(e0, bi0, e1, bi1) CSWP(e1, bi1, e2, bi2) CSWP(e2, bi2, e3, bi3)
  CSWP(e3, bi3, e4, bi4) CSWP(e4, bi4, e5, bi5)
  CSWP(e0, bi0, e1, bi1) CSWP(e1, bi1, e2, bi2) CSWP(e2, bi2, e3, bi3)
  CSWP(e3, bi3, e4, bi4)
  CSWP(e0, bi0, e1, bi1) CSWP(e1, bi1, e2, bi2) CSWP(e2, bi2, e3, bi3)
  CSWP(e0, bi0, e1, bi1) CSWP(e1, bi1, e2, bi2)
  CSWP(e0, bi0, e1, bi1)
#undef CSWP
  int* ib = idx + ((size_t)b * NPT + t) * 4;
  ib[0] = bi0; ib[1] = bi1; ib[2] = bi2; ib[3] = bi3;
}

// ---------------------------------------------------------------- ec1 ----
// Thread-per-edge. Layer1 -> t32 regs -> ELU -> park in LDS (row/thread,
// stride 33 => conflict-free). Layer2 in 4 tiles of 16 outputs, acc[16]
// only -> no spill under the 128-VGPR cap.
__global__ __launch_bounds__(512, 2) void ec1_kernel(
    const float* __restrict__ feat, const int* __restrict__ idx,
    const float* __restrict__ w1, const float* __restrict__ b1,
    const float* __restrict__ w2, const float* __restrict__ b2,
    float* __restrict__ out) {
  __shared__ __align__(16) float fs[NPT][6];
  __shared__ __align__(16) float w1s[10][32];
  __shared__ __align__(16) float w2s[32][68];
  __shared__ float tls[512][33];
  __shared__ float b1s[32], b2s[64];
  const int b = blockIdx.x, t = threadIdx.x;
  const float* fb = feat + (size_t)b * NPT * 5;
  for (int e = t; e < NPT * 5; e += 512) fs[e / 5][e % 5] = fb[e];
  if (t < 320) w1s[t / 32][t % 32] = w1[t];
  for (int e = t; e < 2048; e += 512) w2s[e >> 6][e & 63] = w2[e];
  if (t < 32) b1s[t] = b1[t];
  if (t >= 448) b2s[t - 448] = b2[t - 448];
  __syncthreads();
  const int p = t >> 2;
  const int e4 = t & 3;
  const int j = idx[(size_t)b * 512 + t];
  {
    float t32[32];
#pragma unroll
    for (int o = 0; o < 32; ++o) t32[o] = b1s[o];
#pragma unroll
    for (int c = 0; c < 10; ++c) {
      float in_c = (c < 5) ? fs[p][c] : (fs[j][c - 5] - fs[p][c - 5]);
      const float4* wr = reinterpret_cast<const float4*>(&w1s[c][0]);
#pragma unroll
      for (int o4 = 0; o4 < 8; ++o4) {
        float4 w = wr[o4];
        t32[4 * o4 + 0] += in_c * w.x; t32[4 * o4 + 1] += in_c * w.y;
        t32[4 * o4 + 2] += in_c * w.z; t32[4 * o4 + 3] += in_c * w.w;
      }
    }
#pragma unroll
    for (int o = 0; o < 32; ++o) tls[t][o] = elu_f(t32[o]);
  }
  // layer 2: 4 tiles of 16 outputs; only acc[16] live.
  for (int otile = 0; otile < 4; ++otile) {
    float acc[16];
#pragma unroll
    for (int o = 0; o < 16; ++o) acc[o] = b2s[otile * 16 + o];
    for (int k = 0; k < 32; ++k) {
      float hk = tls[t][k];
      const float4* wr = reinterpret_cast<const float4*>(&w2s[k][otile * 16]);
#pragma unroll
      for (int o4 = 0; o4 < 4; ++o4) {
        float4 w = wr[o4];
        acc[4 * o4 + 0] += hk * w.x; acc[4 * o4 + 1] += hk * w.y;
        acc[4 * o4 + 2] += hk * w.z; acc[4 * o4 + 3] += hk * w.w;
      }
    }
#pragma unroll
    for (int o = 0; o < 16; ++o) {
      float v = elu_f(acc[o]);
      v += __shfl_xor(v, 1);
      v += __shfl_xor(v, 2);
      acc[o] = v;
    }
    if (e4 == otile) {
      float* ob = out + ((size_t)b * NPT + p) * 64 + otile * 16;
#pragma unroll
      for (int o4 = 0; o4 < 4; ++o4) {
        float4 v = {0.25f * acc[4 * o4 + 0], 0.25f * acc[4 * o4 + 1],
                    0.25f * acc[4 * o4 + 2], 0.25f * acc[4 * o4 + 3]};
        *reinterpret_cast<float4*>(&ob[4 * o4]) = v;
      }
    }
  }
}

// ---------------------------------------------------------------- ec2a ----
__global__ __launch_bounds__(512, 2) void ec2a_kernel(
    const float* __restrict__ x, const int* __restrict__ idx,
    const float* __restrict__ w1, const float* __restrict__ b1,
    float* __restrict__ H) {
  __shared__ __align__(16) float xs[NPT][68];
  __shared__ __align__(16) float w1s[128][100];
  __shared__ float b1s[96];
  const int b = blockIdx.x, t = threadIdx.x;
  const float* xb = x + (size_t)b * NPT * 64;
  for (int e = t; e < NPT * 64; e += 512) xs[e >> 6][e & 63] = xb[e];
  for (int e = t; e < 128 * 96; e += 512) w1s[e / 96][e % 96] = w1[e];
  if (t < 96) b1s[t] = b1[t];
  __syncthreads();
  const int pb = t >> 2, part = t & 3;
  const int n0 = part * 24;
  int jn[4];
#pragma unroll
  for (int i = 0; i < 4; ++i) jn[i] = idx[(size_t)b * 512 + pb * 4 + i];
  float acc[4][24];
#pragma unroll
  for (int m = 0; m < 24; ++m) {
    float bv = b1s[n0 + m];
#pragma unroll
    for (int i = 0; i < 4; ++i) acc[i][m] = bv;
  }
  for (int c = 0; c < 64; ++c) {
    float in_c = xs[pb][c];
    const float4* wr = reinterpret_cast<const float4*>(&w1s[c][n0]);
#pragma unroll
    for (int q4 = 0; q4 < 6; ++q4) {
      float4 wv = wr[q4];
#pragma unroll
      for (int i = 0; i < 4; ++i) {
        acc[i][4 * q4 + 0] += in_c * wv.x;
        acc[i][4 * q4 + 1] += in_c * wv.y;
        acc[i][4 * q4 + 2] += in_c * wv.z;
        acc[i][4 * q4 + 3] += in_c * wv.w;
      }
    }
  }
  for (int c = 0; c < 64; ++c) {
    float xic = xs[pb][c];
    float in0 = xs[jn[0]][c] - xic;
    float in1 = xs[jn[1]][c] - xic;
    float in2 = xs[jn[2]][c] - xic;
    float in3 = xs[jn[3]][c] - xic;
    const float4* wr = reinterpret_cast<const float4*>(&w1s[64 + c][n0]);
#pragma unroll
    for (int q4 = 0; q4 < 6; ++q4) {
      float4 wv = wr[q4];
      acc[0][4 * q4 + 0] += in0 * wv.x; acc[0][4 * q4 + 1] += in0 * wv.y;
      acc[0][4 * q4 + 2] += in0 * wv.z; acc[0][4 * q4 + 3] += in0 * wv.w;
      acc[1][4 * q4 + 0] += in1 * wv.x; acc[1][4 * q4 + 1] += in1 * wv.y;
      acc[1][4 * q4 + 2] += in1 * wv.z; acc[1][4 * q4 + 3] += in1 * wv.w;
      acc[2][4 * q4 + 0] += in2 * wv.x; acc[2][4 * q4 + 1] += in2 * wv.y;
      acc[2][4 * q4 + 2] += in2 * wv.z; acc[2][4 * q4 + 3] += in2 * wv.w;
      acc[3][4 * q4 + 0] += in3 * wv.x; acc[3][4 * q4 + 1] += in3 * wv.y;
      acc[3][4 * q4 + 2] += in3 * wv.z; acc[3][4 * q4 + 3] += in3 * wv.w;
    }
  }
#pragma unroll
  for (int i = 0; i < 4; ++i) {
    float* hrow = H + ((size_t)b * 512 + pb * 4 + i) * 96 + n0;
#pragma unroll
    for (int q4 = 0; q4 < 6; ++q4) {
      float4 v = {elu_f(acc[i][4 * q4 + 0]), elu_f(acc[i][4 * q4 + 1]),
                  elu_f(acc[i][4 * q4 + 2]), elu_f(acc[i][4 * q4 + 3])};
      *reinterpret_cast<float4*>(&hrow[4 * q4]) = v;
    }
  }
}

// ---------------------------------------------------------------- ec2b ----
__global__ __launch_bounds__(512, 2) void ec2b_kernel(
    const float* __restrict__ H, const float* __restrict__ w2,
    const float* __restrict__ b2, float* __restrict__ out) {
  __shared__ __align__(16) float hsT[96][260];
  __shared__ float w2s[96][132];
  __shared__ float b2s[128];
  const int z = blockIdx.x, t = threadIdx.x;
  const int bc = z >> 1, hh = z & 1;
  const float* Hb = H + ((size_t)bc * 512 + hh * 256) * 96;
  for (int i = t; i < 256 * 96; i += 512) hsT[i % 96][i / 96] = Hb[i];
  for (int i = t; i < 96 * 128; i += 512) w2s[i >> 7][i & 127] = w2[i];
  if (t < 128) b2s[t] = b2[t];
  __syncthreads();
  const int g = t >> 3, oq = t & 7;
  float acc[4][16];
#pragma unroll
  for (int m = 0; m < 16; ++m) {
    float bv = b2s[oq + 8 * m];
#pragma unroll
    for (int i = 0; i < 4; ++i) acc[i][m] = bv;
  }
  for (int k = 0; k < 96; ++k) {
    float4 hv = *reinterpret_cast<const float4*>(&hsT[k][4 * g]);
#pragma unroll
    for (int m = 0; m < 16; ++m) {
      float wv = w2s[k][oq + 8 * m];
      acc[0][m] += hv.x * wv;
      acc[1][m] += hv.y * wv;
      acc[2][m] += hv.z * wv;
      acc[3][m] += hv.w * wv;
    }
  }
  float* orow = out + ((size_t)bc * NPT + hh * 64 + g) * 128;
#pragma unroll
  for (int m = 0; m < 16; ++m) {
    float s = elu_f(acc[0][m]) + elu_f(acc[1][m]) +
              elu_f(acc[2][m]) + elu_f(acc[3][m]);
    orow[oq + 8 * m] = 0.25f * s;
  }
}

// ---------------------------------------------------------------- ec3a ----
__global__ __launch_bounds__(512, 2) void ec3a_kernel(
    const float* __restrict__ x, const int* __restrict__ idx,
    const float* __restrict__ w1, const float* __restrict__ b1,
    unsigned short* __restrict__ h1) {
  __shared__ unsigned short Xb[128][136];
  __shared__ unsigned short W1t[192][264];
  __shared__ float b1s[192];
  __shared__ unsigned short stg[8][16][40];
  const int b = blockIdx.x, t = threadIdx.x;
  const float* xb = x + (size_t)b * NPT * 128;
  for (int e = t; e < NPT * 128; e += 512) Xb[e >> 7][e & 127] = f2bf(xb[e]);
  for (int e = t; e < 256 * 192; e += 512) {
    int k = e / 192, n = e % 192;
    W1t[n][k] = f2bf(w1[e]);
  }
  if (t < 192) b1s[t] = b1[t];
  __syncthreads();
  const int w = t >> 6, l = t & 63;
  const int lr = l & 15, lq = l >> 4;
  for (int mt = 0; mt < 4; ++mt) {
    const int m = (w * 4 + mt) * 16;
    const int e = m + lr;
    const int p = e >> 2;
    const int jp = idx[(size_t)b * 512 + e];
    short8 A[8];
#pragma unroll
    for (int kk = 0; kk < 4; ++kk) {
      int k0 = kk * 32 + lq * 8;
      A[kk] = *reinterpret_cast<const short8*>(&Xb[p][k0]);
    }
#pragma unroll
    for (int kk = 0; kk < 4; ++kk) {
      int k0 = kk * 32 + lq * 8;
      short8 aj = *reinterpret_cast<const short8*>(&Xb[jp][k0]);
      short8 ai = *reinterpret_cast<const short8*>(&Xb[p][k0]);
      short8 d;
#pragma unroll
      for (int q = 0; q < 8; ++q)
        d[q] = (short)f2bf(bf2f((unsigned short)aj[q]) - bf2f((unsigned short)ai[q]));
      A[4 + kk] = d;
    }
    floatx4 acc[12];
#pragma unroll
    for (int n = 0; n < 12; ++n) acc[n] = (floatx4){0.f, 0.f, 0.f, 0.f};
#pragma unroll
    for (int n = 0; n < 12; ++n) {
#pragma unroll
      for (int kk = 0; kk < 8; ++kk) {
        short8 Bf = *reinterpret_cast<const short8*>(&W1t[n * 16 + lr][kk * 32 + lq * 8]);
        acc[n] = __builtin_amdgcn_mfma_f32_16x16x32_bf16(A[kk], Bf, acc[n], 0, 0, 0);
      }
    }
#pragma unroll
    for (int pr = 0; pr < 6; ++pr) {
      float bv0 = b1s[pr * 32 + lr];
      float bv1 = b1s[pr * 32 + 16 + lr];
#pragma unroll
      for (int i = 0; i < 4; ++i) {
        stg[w][lq * 4 + i][lr]      = f2bf(elu_f(acc[2 * pr][i] + bv0));
        stg[w][lq * 4 + i][16 + lr] = f2bf(elu_f(acc[2 * pr + 1][i] + bv1));
      }
      asm volatile("s_waitcnt lgkmcnt(0)" ::: "memory");
      const unsigned short* src = &stg[w][l >> 2][(l & 3) * 8];
      uint4v vv = *reinterpret_cast<const uint4v*>(src);
      size_t dst = ((size_t)b * 512 + m + (l >> 2)) * 192 + pr * 32 + (l & 3) * 8;
      *reinterpret_cast<uint4v*>(&h1[dst]) = vv;
      asm volatile("s_waitcnt lgkmcnt(0)" ::: "memory");
    }
  }
}

// ---------------------------------------------------------------- ec3b ----
__global__ __launch_bounds__(512, 2) void ec3b_kernel(
    const unsigned short* __restrict__ h1,
    const float* __restrict__ w2, const float* __restrict__ b2,
    unsigned short* __restrict__ out3) {
  __shared__ unsigned short W2t[256][200];
  __shared__ float b2s[256];
  const int b = blockIdx.x, t = threadIdx.x;
  for (int e = t; e < 192 * 256; e += 512) {
    int k = e >> 8, n = e & 255;
    W2t[n][k] = f2bf(w2[e]);
  }
  if (t < 256) b2s[t] = b2[t];
  __syncthreads();
  const int w = t >> 6, l = t & 63;
  const int lr = l & 15, lq = l >> 4;
  for (int mt = 0; mt < 4; ++mt) {
    const int m = (w * 4 + mt) * 16;
    floatx4 acc[16];
#pragma unroll
    for (int n = 0; n < 16; ++n) acc[n] = (floatx4){0.f, 0.f, 0.f, 0.f};
    const unsigned short* arow = h1 + ((size_t)b * 512 + m + lr) * 192;
#pragma unroll
    for (int kk = 0; kk < 6; ++kk) {
      short8 Af = *reinterpret_cast<const short8*>(&arow[kk * 32 + lq * 8]);
#pragma unroll
      for (int n = 0; n < 16; ++n) {
        short8 Bf = *reinterpret_cast<const short8*>(&W2t[n * 16 + lr][kk * 32 + lq * 8]);
        acc[n] = __builtin_amdgcn_mfma_f32_16x16x32_bf16(Af, Bf, acc[n], 0, 0, 0);
      }
    }
    unsigned short* orow = out3 + ((size_t)b * NPT + (m >> 2) + lq) * 256;
#pragma unroll
    for (int n = 0; n < 16; ++n) {
      float bv = b2s[n * 16 + lr];
      float s = 0.f;
#pragma unroll
      for (int i = 0; i < 4; ++i) s += elu_f(acc[n][i] + bv);
      orow[n * 16 + lr] = f2bf(0.25f * s);
    }
  }
}

// ----------------------------------------------------------- head MFMA ----
#define HSTR 488
__global__ __launch_bounds__(256, 1) void head_mfma_kernel(
    const float* __restrict__ feat, const float* __restrict__ o1,
    const float* __restrict__ o2, const unsigned short* __restrict__ o3,
    const float* __restrict__ w1, const float* __restrict__ b1,
    const float* __restrict__ w2, const float* __restrict__ b2,
    const float* __restrict__ w3, const float* __restrict__ b3,
    float* __restrict__ out) {
  __shared__ unsigned short uA[64 * HSTR];
  __shared__ unsigned short uH[64 * HSTR];
  __shared__ float b1s[480], b2s[256], w3s[512];
  const int t = threadIdx.x;
  const size_t base = (size_t)blockIdx.x * 64;

  for (int e = t; e < 64 * 8; e += 256) {
    int r = e >> 3, c = e & 7;
    uA[r * HSTR + c] = (c < 5) ? f2bf(feat[(base + r) * 5 + c]) : 0;
  }
  for (int e = t; e < 64 * 64; e += 256) {
    int r = e >> 6, c = e & 63;
    uA[r * HSTR + 8 + c] = f2bf(o1[(base + r) * 64 + c]);
  }
  for (int e = t; e < 64 * 128; e += 256) {
    int r = e >> 7, c = e & 127;
    uA[r * HSTR + 72 + c] = f2bf(o2[(base + r) * 128 + c]);
  }
  for (int e = t; e < 64 * 256; e += 256) {
    int r = e >> 8, c = e & 255;
    uA[r * HSTR + 200 + c] = o3[(base + r) * 256 + c];
  }
  for (int e = t; e < 64 * 32; e += 256) {
    int r = e >> 5, c = e & 31;
    uA[r * HSTR + 456 + c] = 0;
  }
  for (int i = t; i < 480; i += 256) b1s[i] = (i < 453) ? b1[i] : 0.f;
  if (t < 256) b2s[t] = (t < 226) ? b2[t] : 0.f;
  for (int i = t; i < 512; i += 256) w3s[i] = (i < 452) ? w3[i] : 0.f;
  __syncthreads();

  const int w = t >> 6, l = t & 63;
  const int lr = l & 15, lq = l >> 4;
  const int sn = t & 31, skq = t >> 5;

  short8 Af[15];
#pragma unroll
  for (int kk = 0; kk < 15; ++kk)
    Af[kk] = *reinterpret_cast<const short8*>(
        &uA[(w * 16 + lr) * HSTR + kk * 32 + lq * 8]);
  __syncthreads();

#define STAGE_W1_LOAD(NTP)                                              \
  {                                                                     \
    _Pragma("unroll")                                                   \
    for (int q = 0; q < 60; ++q) {                                      \
      int kp = skq * 60 + q;                                            \
      int ko = (kp < 5) ? kp : kp - 3;                                  \
      bool ok = (kp < 5) || (kp >= 8 && kp < 456);                      \
      int no = (NTP) * 32 + sn;                                         \
      float x = 0.f;                                                    \
      if (ok && no < 453) x = w1[(size_t)ko * 453 + no];                \
      v[q] = x;                                                         \
    }                                                                   \
  }
#define STAGE_W2_LOAD(NTP)                                              \
  {                                                                     \
    _Pragma("unroll")                                                   \
    for (int q = 0; q < 60; ++q) {                                      \
      int kp = skq * 60 + q;                                            \
      int no = (NTP) * 32 + sn;                                         \
      float x = 0.f;                                                    \
      if (kp < 453 && no < 226) x = w2[(size_t)kp * 226 + no];          \
      v[q] = x;                                                         \
    }                                                                   \
  }
#define STAGE_WRITE(D)                                                  \
  {                                                                     \
    _Pragma("unroll")                                                   \
    for (int q = 0; q < 60; q += 2) {                                   \
      unsigned pk = (unsigned)f2bf(v[q]) | ((unsigned)f2bf(v[q + 1]) << 16); \
      *reinterpret_cast<unsigned*>(                                     \
          &uA[(D) * 15616 + sn * HSTR + skq * 60 + q]) = pk;            \
    }                                                                   \
  }

  {
    float v[60];
    STAGE_W1_LOAD(0)
    STAGE_WRITE(0)
  }
  __syncthreads();

  for (int nt = 0; nt < 15; ++nt) {
    const int d = nt & 1;
    float v[60];
    if (nt < 14) STAGE_W1_LOAD(nt + 1)
    floatx4 acc0 = {0.f, 0.f, 0.f, 0.f}, acc1 = {0.f, 0.f, 0.f, 0.f};
    const unsigned short* Wb = &uA[d * 15616];
#pragma unroll
    for (int kk = 0; kk < 15; ++kk) {
      short8 B0 = *reinterpret_cast<const short8*>(&Wb[lr * HSTR + kk * 32 + lq * 8]);
      short8 B1 = *reinterpret_cast<const short8*>(&Wb[(16 + lr) * HSTR + kk * 32 + lq * 8]);
      acc0 = __builtin_amdgcn_mfma_f32_16x16x32_bf16(Af[kk], B0, acc0, 0, 0, 0);
      acc1 = __builtin_amdgcn_mfma_f32_16x16x32_bf16(Af[kk], B1, acc1, 0, 0, 0);
    }
    {
      int c0 = nt * 32 + lr, c1 = nt * 32 + 16 + lr;
      float bb0 = b1s[c0], bb1 = b1s[c1];
#pragma unroll
      for (int i = 0; i < 4; ++i) {
        int row = w * 16 + lq * 4 + i;
        uH[row * HSTR + c0] = f2bf(elu_f(acc0[i] + bb0));
        uH[row * HSTR + c1] = f2bf(elu_f(acc1[i] + bb1));
      }
    }
    if (nt < 14) STAGE_WRITE(d ^ 1)
    __syncthreads();
  }

#pragma unroll
  for (int kk = 0; kk < 15; ++kk)
    Af[kk] = *reinterpret_cast<const short8*>(
        &uH[(w * 16 + lr) * HSTR + kk * 32 + lq * 8]);
  {
    float v[60];
    STAGE_W2_LOAD(0)
    STAGE_WRITE(0)
  }
  __syncthreads();

  float p0[4] = {0.f, 0.f, 0.f, 0.f}, p1[4] = {0.f, 0.f, 0.f, 0.f};
  for (int nt = 0; nt < 8; ++nt) {
    const int d = nt & 1;
    float v[60];
    if (nt < 7) STAGE_W2_LOAD(nt + 1)
    floatx4 acc0 = {0.f, 0.f, 0.f, 0.f}, acc1 = {0.f, 0.f, 0.f, 0.f};
    const unsigned short* Wb = &uA[d * 15616];
#pragma unroll
    for (int kk = 0; kk < 15; ++kk) {
      short8 B0 = *reinterpret_cast<const short8*>(&Wb[lr * HSTR + kk * 32 + lq * 8]);
      short8 B1 = *reinterpret_cast<const short8*>(&Wb[(16 + lr) * HSTR + kk * 32 + lq * 8]);
      acc0 = __builtin_amdgcn_mfma_f32_16x16x32_bf16(Af[kk], B0, acc0, 0, 0, 0);
      acc1 = __builtin_amdgcn_mfma_f32_16x16x32_bf16(Af[kk], B1, acc1, 0, 0, 0);
    }
    {
      int c0 = nt * 32 + lr, c1 = nt * 32 + 16 + lr;
      float bb0 = b2s[c0], bb1 = b2s[c1];
      float wa0 = w3s[c0 * 2], wb0 = w3s[c0 * 2 + 1];
      float wa1 = w3s[c1 * 2], wb1 = w3s[c1 * 2 + 1];
#pragma unroll
      for (int i = 0; i < 4; ++i) {
        float h0 = elu_f(acc0[i] + bb0);
        float h1v = elu_f(acc1[i] + bb1);
        p0[i] += h0 * wa0 + h1v * wa1;
        p1[i] += h0 * wb0 + h1v * wb1;
      }
    }
    if (nt < 7) STAGE_WRITE(d ^ 1)
    __syncthreads();
  }

#pragma unroll
  for (int i = 0; i < 4; ++i) {
    float a = p0[i], bvv = p1[i];
#pragma unroll
    for (int m = 1; m < 16; m <<= 1) {
      a += __shfl_xor(a, m);
      bvv += __shfl_xor(bvv, m);
    }
    if (lr == 0) {
      size_t row = base + w * 16 + lq * 4 + i;
      float2 vv = {a + b3[0], bvv + b3[1]};
      *reinterpret_cast<float2*>(&out[row * 2]) = vv;
    }
  }
#undef STAGE_W1_LOAD
#undef STAGE_W2_LOAD
#undef STAGE_WRITE
}

// ------------------------------------------------------------- launch ----
extern "C" void kernel_launch(void* const* d_in, const int* in_sizes, int n_in,
                              void* d_out, int out_size, void* d_ws, size_t ws_size,
                              hipStream_t stream) {
  const float* coords = (const float*)d_in[0];
  const float* feat   = (const float*)d_in[1];
  const float* c1w1 = (const float*)d_in[2];  const float* c1b1 = (const float*)d_in[3];
  const float* c1w2 = (const float*)d_in[4];  const float* c1b2 = (const float*)d_in[5];
  const float* c2w1 = (const float*)d_in[6];  const float* c2b1 = (const float*)d_in[7];
  const float* c2w2 = (const float*)d_in[8];  const float* c2b2 = (const float*)d_in[9];
  const float* c3w1 = (const float*)d_in[10]; const float* c3b1 = (const float*)d_in[11];
  const float* c3w2 = (const float*)d_in[12]; const float* c3b2 = (const float*)d_in[13];
  const float* ow1  = (const float*)d_in[14]; const float* ob1  = (const float*)d_in[15];
  const float* ow2  = (const float*)d_in[16]; const float* ob2  = (const float*)d_in[17];
  const float* ow3  = (const float*)d_in[18]; const float* ob3  = (const float*)d_in[19];
  float* out = (float*)d_out;

  char* ws = (char*)d_ws;
  float* out1 = (float*)(ws);
  float* out2 = (float*)(ws + (32ull << 20));
  unsigned short* out3b = (unsigned short*)(ws + (96ull << 20));
  int* idx = (int*)(ws + (160ull << 20));
  float* Hbuf = (float*)(ws + (162ull << 20));
  unsigned short* h1 = (unsigned short*)(ws + (162ull << 20));

  knn_kernel<2><<<NB, 128, 0, stream>>>(coords, idx);
  ec1_kernel<<<NB, 512, 0, stream>>>(feat, idx, c1w1, c1b1, c1w2, c1b2, out1);
  knn_kernel<64><<<NB, 128, 0, stream>>>(out1, idx);
  for (int c = 0; c < 4; ++c) {
    ec2a_kernel<<<256, 512, 0, stream>>>(out1 + (size_t)c * 256 * NPT * 64,
                                         idx + (size_t)c * 256 * 512,
                                         c2w1, c2b1, Hbuf);
    ec2b_kernel<<<512, 512, 0, stream>>>(Hbuf, c2w2, c2b2,
                                         out2 + (size_t)c * 256 * NPT * 128);
  }
  knn_kernel<128><<<NB, 128, 0, stream>>>(out2, idx);
  for (int c = 0; c < 4; ++c) {
    ec3a_kernel<<<256, 512, 0, stream>>>(out2 + (size_t)c * 256 * NPT * 128,
                                         idx + (size_t)c * 256 * 512,
                                         c3w1, c3b1, h1);
    ec3b_kernel<<<256, 512, 0, stream>>>(h1, c3w2, c3b2,
                                         out3b + (size_t)c * 256 * NPT * 256);
  }
  head_mfma_kernel<<<2048, 256, 0, stream>>>(feat, out1, out2, out3b,
                                             ow1, ob1, ow2, ob2, ow3, ob3, out);
}

// Round 7
// 2692.084 us; speedup vs baseline: 15.3054x; 1.5228x over previous
//
#include <hip/hip_runtime.h>
#include <cstdint>
#include <cstddef>

// ParticleNet MI355X — Round 7.
// - kNN: fp32 shortlist + fp64 rescore (verified).
// - ec1: REWRITTEN in the ec2a register-tiling shape (r6 version still spilled
//   ~5.5 GB scratch under the 128-VGPR cap; this one peaks ~90 regs with a
//   256-VGPR budget). out1 summation order unchanged -> bit-identical.
// - ec2: ec2a/ec2b fp32 register-tiled GEMMs (verified).
// - ec3: bf16 MFMA pair (verified).
// - head: fused bf16 MFMA (verified).

#define NB 1024
#define NPT 128

typedef __attribute__((ext_vector_type(8))) short short8;
typedef __attribute__((ext_vector_type(4))) float floatx4;
typedef __attribute__((ext_vector_type(4))) unsigned int uint4v;

__device__ __forceinline__ float elu_f(float x) { return x > 0.0f ? x : expm1f(x); }

__device__ __forceinline__ unsigned short f2bf(float f) {
  unsigned u = __builtin_bit_cast(unsigned, f);
  unsigned r = u + 0x7FFFu + ((u >> 16) & 1u);
  return (unsigned short)(r >> 16);
}
__device__ __forceinline__ float bf2f(unsigned short h) {
  unsigned u = ((unsigned)h) << 16;
  return __builtin_bit_cast(float, u);
}

// ---------------------------------------------------------------- kNN ----
template<int C>
__global__ __launch_bounds__(128) void knn_kernel(const float* __restrict__ x,
                                                  int* __restrict__ idx) {
  __shared__ __align__(16) float xs[NPT][C + 4];
  __shared__ float x2s[NPT];
  __shared__ double x2d[NPT];
  const int b = blockIdx.x, t = threadIdx.x;
  const float* xb = x + (size_t)b * NPT * C;
  for (int e = t; e < NPT * C; e += 128) xs[e / C][e % C] = xb[e];
  __syncthreads();
  float xi[C];
  float s2 = 0.0f;
  double s2d = 0.0;
#pragma unroll
  for (int c = 0; c < C; ++c) {
    xi[c] = xs[t][c];
    s2 += xi[c] * xi[c];
    s2d += (double)xi[c] * (double)xi[c];
  }
  x2s[t] = s2;
  x2d[t] = s2d;
  __syncthreads();
  float bd0 = 1e30f, bd1 = 1e30f, bd2 = 1e30f, bd3 = 1e30f, bd4 = 1e30f, bd5 = 1e30f;
  int bi0 = 0, bi1 = 0, bi2 = 0, bi3 = 0, bi4 = 0, bi5 = 0;
  for (int j = 0; j < NPT; ++j) {
    if (j == t) continue;
    float dot = 0.0f;
    if constexpr (C >= 4) {
      const float4* xr = reinterpret_cast<const float4*>(&xs[j][0]);
#pragma unroll
      for (int c4 = 0; c4 < C / 4; ++c4) {
        float4 v = xr[c4];
        dot += xi[4 * c4 + 0] * v.x + xi[4 * c4 + 1] * v.y +
               xi[4 * c4 + 2] * v.z + xi[4 * c4 + 3] * v.w;
      }
    } else {
#pragma unroll
      for (int c = 0; c < C; ++c) dot += xi[c] * xs[j][c];
    }
    float d = s2 + x2s[j] - 2.0f * dot;
    if (d < bd5) {
      bd5 = d; bi5 = j;
      if (bd5 < bd4) {
        float td = bd4; bd4 = bd5; bd5 = td; int ti = bi4; bi4 = bi5; bi5 = ti;
        if (bd4 < bd3) {
          td = bd3; bd3 = bd4; bd4 = td; ti = bi3; bi3 = bi4; bi4 = ti;
          if (bd3 < bd2) {
            td = bd2; bd2 = bd3; bd3 = td; ti = bi2; bi2 = bi3; bi3 = ti;
            if (bd2 < bd1) {
              td = bd1; bd1 = bd2; bd2 = td; ti = bi1; bi1 = bi2; bi2 = ti;
              if (bd1 < bd0) {
                td = bd0; bd0 = bd1; bd1 = td; ti = bi0; bi0 = bi1; bi1 = ti;
              }
            }
          }
        }
      }
    }
  }
  auto refine = [&](int j) -> double {
    double dot = 0.0;
#pragma unroll
    for (int c = 0; c < C; ++c) dot += (double)xi[c] * (double)xs[j][c];
    return s2d + x2d[j] - 2.0 * dot;
  };
  double e0 = refine(bi0), e1 = refine(bi1), e2 = refine(bi2);
  double e3 = refine(bi3), e4 = refine(bi4), e5 = refine(bi5);
#define CSWP(da, ia, db, ib)                                            \
  if ((da > db) || (da == db && ia > ib)) {                             \
    double _td = da; da = db; db = _td; int _ti = ia; ia = ib; ib = _ti; }
  CSWP(e0, bi0, e1, bi1) CSWP(e1, bi1, e2, bi2) CSWP(e2, bi2, e3, bi3)
  CSWP(e3, bi3, e4, bi4) CSWP(e4, bi4, e5, bi5)
  CSWP(e0, bi0, e1, bi1) CSWP(e1, bi1, e2, bi2) CSWP(e2, bi2, e3, bi3)
  CSWP(e3, bi3, e4, bi4)
  CSWP(e0, bi0, e1, bi1) CSWP(e1, bi1, e2, bi2) CSWP(e2, bi2, e3, bi3)
  CSWP(e0, bi0, e1, bi1) CSWP(e1, bi1, e2, bi2)
  CSWP(e0, bi0, e1, bi1)
#undef CSWP
  int* ib = idx + ((size_t)b * NPT + t) * 4;
  ib[0] = bi0; ib[1] = bi1; ib[2] = bi2; ib[3] = bi3;
}

// ---------------------------------------------------------------- ec1 ----
// Block = (event, half): 64 points / 256 edges, 256 threads, 256-VGPR budget.
// Phase A: thread-per-edge -> h[32] regs -> ELU -> hs[256][33] LDS.
// Phase B: thread = (point g, quarter q): acc[4 edges][16 outs] = 64 regs,
// per-edge ELU + thread-local mean, coalesced float4 stores.
__global__ __launch_bounds__(256) void ec1_kernel(
    const float* __restrict__ feat, const int* __restrict__ idx,
    const float* __restrict__ w1, const float* __restrict__ b1,
    const float* __restrict__ w2, const float* __restrict__ b2,
    float* __restrict__ out) {
  __shared__ __align__(16) float fs[NPT][6];
  __shared__ __align__(16) float w1s[10][32];
  __shared__ __align__(16) float w2s[32][68];
  __shared__ float hs[256][33];
  __shared__ float b1s[32], b2s[64];
  const int z = blockIdx.x, t = threadIdx.x;
  const int b = z >> 1, hh = z & 1;
  const float* fb = feat + (size_t)b * NPT * 5;
  for (int e = t; e < NPT * 5; e += 256) fs[e / 5][e % 5] = fb[e];
  for (int e = t; e < 320; e += 256) w1s[e / 32][e % 32] = w1[e];
  for (int e = t; e < 2048; e += 256) w2s[e >> 6][e & 63] = w2[e];
  if (t < 32) b1s[t] = b1[t];
  if (t >= 192) b2s[t - 192] = b2[t - 192];
  __syncthreads();
  // ---- Phase A: local edge t -> (local point t>>2, edge slot t&3) ----
  {
    const int p = hh * 64 + (t >> 2);
    const int j = idx[(size_t)b * 512 + p * 4 + (t & 3)];
    float h[32];
#pragma unroll
    for (int o = 0; o < 32; ++o) h[o] = b1s[o];
#pragma unroll
    for (int c = 0; c < 10; ++c) {
      float in_c = (c < 5) ? fs[p][c] : (fs[j][c - 5] - fs[p][c - 5]);
      const float4* wr = reinterpret_cast<const float4*>(&w1s[c][0]);
#pragma unroll
      for (int o4 = 0; o4 < 8; ++o4) {
        float4 w = wr[o4];
        h[4 * o4 + 0] += in_c * w.x; h[4 * o4 + 1] += in_c * w.y;
        h[4 * o4 + 2] += in_c * w.z; h[4 * o4 + 3] += in_c * w.w;
      }
    }
#pragma unroll
    for (int o = 0; o < 32; ++o) hs[t][o] = elu_f(h[o]);
  }
  __syncthreads();
  // ---- Phase B: thread = (point g, output quarter q) ----
  {
    const int g = t >> 2, q = t & 3;
    const int o0 = q * 16;
    float acc[4][16];
#pragma unroll
    for (int m = 0; m < 16; ++m) {
      float bv = b2s[o0 + m];
#pragma unroll
      for (int i = 0; i < 4; ++i) acc[i][m] = bv;
    }
    for (int k = 0; k < 32; ++k) {
      float hk0 = hs[g * 4 + 0][k];
      float hk1 = hs[g * 4 + 1][k];
      float hk2 = hs[g * 4 + 2][k];
      float hk3 = hs[g * 4 + 3][k];
      const float4* wr = reinterpret_cast<const float4*>(&w2s[k][o0]);
#pragma unroll
      for (int m4 = 0; m4 < 4; ++m4) {
        float4 w = wr[m4];
        acc[0][4 * m4 + 0] += hk0 * w.x; acc[0][4 * m4 + 1] += hk0 * w.y;
        acc[0][4 * m4 + 2] += hk0 * w.z; acc[0][4 * m4 + 3] += hk0 * w.w;
        acc[1][4 * m4 + 0] += hk1 * w.x; acc[1][4 * m4 + 1] += hk1 * w.y;
        acc[1][4 * m4 + 2] += hk1 * w.z; acc[1][4 * m4 + 3] += hk1 * w.w;
        acc[2][4 * m4 + 0] += hk2 * w.x; acc[2][4 * m4 + 1] += hk2 * w.y;
        acc[2][4 * m4 + 2] += hk2 * w.z; acc[2][4 * m4 + 3] += hk2 * w.w;
        acc[3][4 * m4 + 0] += hk3 * w.x; acc[3][4 * m4 + 1] += hk3 * w.y;
        acc[3][4 * m4 + 2] += hk3 * w.z; acc[3][4 * m4 + 3] += hk3 * w.w;
      }
    }
    float* ob = out + ((size_t)b * NPT + hh * 64 + g) * 64 + o0;
#pragma unroll
    for (int m4 = 0; m4 < 4; ++m4) {
      float4 v;
      float* vp = &v.x;
#pragma unroll
      for (int s = 0; s < 4; ++s) {
        int m = 4 * m4 + s;
        vp[s] = 0.25f * (elu_f(acc[0][m]) + elu_f(acc[1][m]) +
                         elu_f(acc[2][m]) + elu_f(acc[3][m]));
      }
      *reinterpret_cast<float4*>(&ob[4 * m4]) = v;
    }
  }
}

// ---------------------------------------------------------------- ec2a ----
__global__ __launch_bounds__(512, 2) void ec2a_kernel(
    const float* __restrict__ x, const int* __restrict__ idx,
    const float* __restrict__ w1, const float* __restrict__ b1,
    float* __restrict__ H) {
  __shared__ __align__(16) float xs[NPT][68];
  __shared__ __align__(16) float w1s[128][100];
  __shared__ float b1s[96];
  const int b = blockIdx.x, t = threadIdx.x;
  const float* xb = x + (size_t)b * NPT * 64;
  for (int e = t; e < NPT * 64; e += 512) xs[e >> 6][e & 63] = xb[e];
  for (int e = t; e < 128 * 96; e += 512) w1s[e / 96][e % 96] = w1[e];
  if (t < 96) b1s[t] = b1[t];
  __syncthreads();
  const int pb = t >> 2, part = t & 3;
  const int n0 = part * 24;
  int jn[4];
#pragma unroll
  for (int i = 0; i < 4; ++i) jn[i] = idx[(size_t)b * 512 + pb * 4 + i];
  float acc[4][24];
#pragma unroll
  for (int m = 0; m < 24; ++m) {
    float bv = b1s[n0 + m];
#pragma unroll
    for (int i = 0; i < 4; ++i) acc[i][m] = bv;
  }
  for (int c = 0; c < 64; ++c) {
    float in_c = xs[pb][c];
    const float4* wr = reinterpret_cast<const float4*>(&w1s[c][n0]);
#pragma unroll
    for (int q4 = 0; q4 < 6; ++q4) {
      float4 wv = wr[q4];
#pragma unroll
      for (int i = 0; i < 4; ++i) {
        acc[i][4 * q4 + 0] += in_c * wv.x;
        acc[i][4 * q4 + 1] += in_c * wv.y;
        acc[i][4 * q4 + 2] += in_c * wv.z;
        acc[i][4 * q4 + 3] += in_c * wv.w;
      }
    }
  }
  for (int c = 0; c < 64; ++c) {
    float xic = xs[pb][c];
    float in0 = xs[jn[0]][c] - xic;
    float in1 = xs[jn[1]][c] - xic;
    float in2 = xs[jn[2]][c] - xic;
    float in3 = xs[jn[3]][c] - xic;
    const float4* wr = reinterpret_cast<const float4*>(&w1s[64 + c][n0]);
#pragma unroll
    for (int q4 = 0; q4 < 6; ++q4) {
      float4 wv = wr[q4];
      acc[0][4 * q4 + 0] += in0 * wv.x; acc[0][4 * q4 + 1] += in0 * wv.y;
      acc[0][4 * q4 + 2] += in0 * wv.z; acc[0][4 * q4 + 3] += in0 * wv.w;
      acc[1][4 * q4 + 0] += in1 * wv.x; acc[1][4 * q4 + 1] += in1 * wv.y;
      acc[1][4 * q4 + 2] += in1 * wv.z; acc[1][4 * q4 + 3] += in1 * wv.w;
      acc[2][4 * q4 + 0] += in2 * wv.x; acc[2][4 * q4 + 1] += in2 * wv.y;
      acc[2][4 * q4 + 2] += in2 * wv.z; acc[2][4 * q4 + 3] += in2 * wv.w;
      acc[3][4 * q4 + 0] += in3 * wv.x; acc[3][4 * q4 + 1] += in3 * wv.y;
      acc[3][4 * q4 + 2] += in3 * wv.z; acc[3][4 * q4 + 3] += in3 * wv.w;
    }
  }
#pragma unroll
  for (int i = 0; i < 4; ++i) {
    float* hrow = H + ((size_t)b * 512 + pb * 4 + i) * 96 + n0;
#pragma unroll
    for (int q4 = 0; q4 < 6; ++q4) {
      float4 v = {elu_f(acc[i][4 * q4 + 0]), elu_f(acc[i][4 * q4 + 1]),
                  elu_f(acc[i][4 * q4 + 2]), elu_f(acc[i][4 * q4 + 3])};
      *reinterpret_cast<float4*>(&hrow[4 * q4]) = v;
    }
  }
}

// ---------------------------------------------------------------- ec2b ----
__global__ __launch_bounds__(512, 2) void ec2b_kernel(
    const float* __restrict__ H, const float* __restrict__ w2,
    const float* __restrict__ b2, float* __restrict__ out) {
  __shared__ __align__(16) float hsT[96][260];
  __shared__ float w2s[96][132];
  __shared__ float b2s[128];
  const int z = blockIdx.x, t = threadIdx.x;
  const int bc = z >> 1, hh = z & 1;
  const float* Hb = H + ((size_t)bc * 512 + hh * 256) * 96;
  for (int i = t; i < 256 * 96; i += 512) hsT[i % 96][i / 96] = Hb[i];
  for (int i = t; i < 96 * 128; i += 512) w2s[i >> 7][i & 127] = w2[i];
  if (t < 128) b2s[t] = b2[t];
  __syncthreads();
  const int g = t >> 3, oq = t & 7;
  float acc[4][16];
#pragma unroll
  for (int m = 0; m < 16; ++m) {
    float bv = b2s[oq + 8 * m];
#pragma unroll
    for (int i = 0; i < 4; ++i) acc[i][m] = bv;
  }
  for (int k = 0; k < 96; ++k) {
    float4 hv = *reinterpret_cast<const float4*>(&hsT[k][4 * g]);
#pragma unroll
    for (int m = 0; m < 16; ++m) {
      float wv = w2s[k][oq + 8 * m];
      acc[0][m] += hv.x * wv;
      acc[1][m] += hv.y * wv;
      acc[2][m] += hv.z * wv;
      acc[3][m] += hv.w * wv;
    }
  }
  float* orow = out + ((size_t)bc * NPT + hh * 64 + g) * 128;
#pragma unroll
  for (int m = 0; m < 16; ++m) {
    float s = elu_f(acc[0][m]) + elu_f(acc[1][m]) +
              elu_f(acc[2][m]) + elu_f(acc[3][m]);
    orow[oq + 8 * m] = 0.25f * s;
  }
}

// ---------------------------------------------------------------- ec3a ----
__global__ __launch_bounds__(512, 2) void ec3a_kernel(
    const float* __restrict__ x, const int* __restrict__ idx,
    const float* __restrict__ w1, const float* __restrict__ b1,
    unsigned short* __restrict__ h1) {
  __shared__ unsigned short Xb[128][136];
  __shared__ unsigned short W1t[192][264];
  __shared__ float b1s[192];
  __shared__ unsigned short stg[8][16][40];
  const int b = blockIdx.x, t = threadIdx.x;
  const float* xb = x + (size_t)b * NPT * 128;
  for (int e = t; e < NPT * 128; e += 512) Xb[e >> 7][e & 127] = f2bf(xb[e]);
  for (int e = t; e < 256 * 192; e += 512) {
    int k = e / 192, n = e % 192;
    W1t[n][k] = f2bf(w1[e]);
  }
  if (t < 192) b1s[t] = b1[t];
  __syncthreads();
  const int w = t >> 6, l = t & 63;
  const int lr = l & 15, lq = l >> 4;
  for (int mt = 0; mt < 4; ++mt) {
    const int m = (w * 4 + mt) * 16;
    const int e = m + lr;
    const int p = e >> 2;
    const int jp = idx[(size_t)b * 512 + e];
    short8 A[8];
#pragma unroll
    for (int kk = 0; kk < 4; ++kk) {
      int k0 = kk * 32 + lq * 8;
      A[kk] = *reinterpret_cast<const short8*>(&Xb[p][k0]);
    }
#pragma unroll
    for (int kk = 0; kk < 4; ++kk) {
      int k0 = kk * 32 + lq * 8;
      short8 aj = *reinterpret_cast<const short8*>(&Xb[jp][k0]);
      short8 ai = *reinterpret_cast<const short8*>(&Xb[p][k0]);
      short8 d;
#pragma unroll
      for (int q = 0; q < 8; ++q)
        d[q] = (short)f2bf(bf2f((unsigned short)aj[q]) - bf2f((unsigned short)ai[q]));
      A[4 + kk] = d;
    }
    floatx4 acc[12];
#pragma unroll
    for (int n = 0; n < 12; ++n) acc[n] = (floatx4){0.f, 0.f, 0.f, 0.f};
#pragma unroll
    for (int n = 0; n < 12; ++n) {
#pragma unroll
      for (int kk = 0; kk < 8; ++kk) {
        short8 Bf = *reinterpret_cast<const short8*>(&W1t[n * 16 + lr][kk * 32 + lq * 8]);
        acc[n] = __builtin_amdgcn_mfma_f32_16x16x32_bf16(A[kk], Bf, acc[n], 0, 0, 0);
      }
    }
#pragma unroll
    for (int pr = 0; pr < 6; ++pr) {
      float bv0 = b1s[pr * 32 + lr];
      float bv1 = b1s[pr * 32 + 16 + lr];
#pragma unroll
      for (int i = 0; i < 4; ++i) {
        stg[w][lq * 4 + i][lr]      = f2bf(elu_f(acc[2 * pr][i] + bv0));
        stg[w][lq * 4 + i][16 + lr] = f2bf(elu_f(acc[2 * pr + 1][i] + bv1));
      }
      asm volatile("s_waitcnt lgkmcnt(0)" ::: "memory");
      const unsigned short* src = &stg[w][l >> 2][(l & 3) * 8];
      uint4v vv = *reinterpret_cast<const uint4v*>(src);
      size_t dst = ((size_t)b * 512 + m + (l >> 2)) * 192 + pr * 32 + (l & 3) * 8;
      *reinterpret_cast<uint4v*>(&h1[dst]) = vv;
      asm volatile("s_waitcnt lgkmcnt(0)" ::: "memory");
    }
  }
}

// ---------------------------------------------------------------- ec3b ----
__global__ __launch_bounds__(512, 2) void ec3b_kernel(
    const unsigned short* __restrict__ h1,
    const float* __restrict__ w2, const float* __restrict__ b2,
    unsigned short* __restrict__ out3) {
  __shared__ unsigned short W2t[256][200];
  __shared__ float b2s[256];
  const int b = blockIdx.x, t = threadIdx.x;
  for (int e = t; e < 192 * 256; e += 512) {
    int k = e >> 8, n = e & 255;
    W2t[n][k] = f2bf(w2[e]);
  }
  if (t < 256) b2s[t] = b2[t];
  __syncthreads();
  const int w = t >> 6, l = t & 63;
  const int lr = l & 15, lq = l >> 4;
  for (int mt = 0; mt < 4; ++mt) {
    const int m = (w * 4 + mt) * 16;
    floatx4 acc[16];
#pragma unroll
    for (int n = 0; n < 16; ++n) acc[n] = (floatx4){0.f, 0.f, 0.f, 0.f};
    const unsigned short* arow = h1 + ((size_t)b * 512 + m + lr) * 192;
#pragma unroll
    for (int kk = 0; kk < 6; ++kk) {
      short8 Af = *reinterpret_cast<const short8*>(&arow[kk * 32 + lq * 8]);
#pragma unroll
      for (int n = 0; n < 16; ++n) {
        short8 Bf = *reinterpret_cast<const short8*>(&W2t[n * 16 + lr][kk * 32 + lq * 8]);
        acc[n] = __builtin_amdgcn_mfma_f32_16x16x32_bf16(Af, Bf, acc[n], 0, 0, 0);
      }
    }
    unsigned short* orow = out3 + ((size_t)b * NPT + (m >> 2) + lq) * 256;
#pragma unroll
    for (int n = 0; n < 16; ++n) {
      float bv = b2s[n * 16 + lr];
      float s = 0.f;
#pragma unroll
      for (int i = 0; i < 4; ++i) s += elu_f(acc[n][i] + bv);
      orow[n * 16 + lr] = f2bf(0.25f * s);
    }
  }
}

// ----------------------------------------------------------- head MFMA ----
#define HSTR 488
__global__ __launch_bounds__(256, 1) void head_mfma_kernel(
    const float* __restrict__ feat, const float* __restrict__ o1,
    const float* __restrict__ o2, const unsigned short* __restrict__ o3,
    const float* __restrict__ w1, const float* __restrict__ b1,
    const float* __restrict__ w2, const float* __restrict__ b2,
    const float* __restrict__ w3, const float* __restrict__ b3,
    float* __restrict__ out) {
  __shared__ unsigned short uA[64 * HSTR];
  __shared__ unsigned short uH[64 * HSTR];
  __shared__ float b1s[480], b2s[256], w3s[512];
  const int t = threadIdx.x;
  const size_t base = (size_t)blockIdx.x * 64;

  for (int e = t; e < 64 * 8; e += 256) {
    int r = e >> 3, c = e & 7;
    uA[r * HSTR + c] = (c < 5) ? f2bf(feat[(base + r) * 5 + c]) : 0;
  }
  for (int e = t; e < 64 * 64; e += 256) {
    int r = e >> 6, c = e & 63;
    uA[r * HSTR + 8 + c] = f2bf(o1[(base + r) * 64 + c]);
  }
  for (int e = t; e < 64 * 128; e += 256) {
    int r = e >> 7, c = e & 127;
    uA[r * HSTR + 72 + c] = f2bf(o2[(base + r) * 128 + c]);
  }
  for (int e = t; e < 64 * 256; e += 256) {
    int r = e >> 8, c = e & 255;
    uA[r * HSTR + 200 + c] = o3[(base + r) * 256 + c];
  }
  for (int e = t; e < 64 * 32; e += 256) {
    int r = e >> 5, c = e & 31;
    uA[r * HSTR + 456 + c] = 0;
  }
  for (int i = t; i < 480; i += 256) b1s[i] = (i < 453) ? b1[i] : 0.f;
  if (t < 256) b2s[t] = (t < 226) ? b2[t] : 0.f;
  for (int i = t; i < 512; i += 256) w3s[i] = (i < 452) ? w3[i] : 0.f;
  __syncthreads();

  const int w = t >> 6, l = t & 63;
  const int lr = l & 15, lq = l >> 4;
  const int sn = t & 31, skq = t >> 5;

  short8 Af[15];
#pragma unroll
  for (int kk = 0; kk < 15; ++kk)
    Af[kk] = *reinterpret_cast<const short8*>(
        &uA[(w * 16 + lr) * HSTR + kk * 32 + lq * 8]);
  __syncthreads();

#define STAGE_W1_LOAD(NTP)                                              \
  {                                                                     \
    _Pragma("unroll")                                                   \
    for (int q = 0; q < 60; ++q) {                                      \
      int kp = skq * 60 + q;                                            \
      int ko = (kp < 5) ? kp : kp - 3;                                  \
      bool ok = (kp < 5) || (kp >= 8 && kp < 456);                      \
      int no = (NTP) * 32 + sn;                                         \
      float x = 0.f;                                                    \
      if (ok && no < 453) x = w1[(size_t)ko * 453 + no];                \
      v[q] = x;                                                         \
    }                                                                   \
  }
#define STAGE_W2_LOAD(NTP)                                              \
  {                                                                     \
    _Pragma("unroll")                                                   \
    for (int q = 0; q < 60; ++q) {                                      \
      int kp = skq * 60 + q;                                            \
      int no = (NTP) * 32 + sn;                                         \
      float x = 0.f;                                                    \
      if (kp < 453 && no < 226) x = w2[(size_t)kp * 226 + no];          \
      v[q] = x;                                                         \
    }                                                                   \
  }
#define STAGE_WRITE(D)                                                  \
  {                                                                     \
    _Pragma("unroll")                                                   \
    for (int q = 0; q < 60; q += 2) {                                   \
      unsigned pk = (unsigned)f2bf(v[q]) | ((unsigned)f2bf(v[q + 1]) << 16); \
      *reinterpret_cast<unsigned*>(                                     \
          &uA[(D) * 15616 + sn * HSTR + skq * 60 + q]) = pk;            \
    }                                                                   \
  }

  {
    float v[60];
    STAGE_W1_LOAD(0)
    STAGE_WRITE(0)
  }
  __syncthreads();

  for (int nt = 0; nt < 15; ++nt) {
    const int d = nt & 1;
    float v[60];
    if (nt < 14) STAGE_W1_LOAD(nt + 1)
    floatx4 acc0 = {0.f, 0.f, 0.f, 0.f}, acc1 = {0.f, 0.f, 0.f, 0.f};
    const unsigned short* Wb = &uA[d * 15616];
#pragma unroll
    for (int kk = 0; kk < 15; ++kk) {
      short8 B0 = *reinterpret_cast<const short8*>(&Wb[lr * HSTR + kk * 32 + lq * 8]);
      short8 B1 = *reinterpret_cast<const short8*>(&Wb[(16 + lr) * HSTR + kk * 32 + lq * 8]);
      acc0 = __builtin_amdgcn_mfma_f32_16x16x32_bf16(Af[kk], B0, acc0, 0, 0, 0);
      acc1 = __builtin_amdgcn_mfma_f32_16x16x32_bf16(Af[kk], B1, acc1, 0, 0, 0);
    }
    {
      int c0 = nt * 32 + lr, c1 = nt * 32 + 16 + lr;
      float bb0 = b1s[c0], bb1 = b1s[c1];
#pragma unroll
      for (int i = 0; i < 4; ++i) {
        int row = w * 16 + lq * 4 + i;
        uH[row * HSTR + c0] = f2bf(elu_f(acc0[i] + bb0));
        uH[row * HSTR + c1] = f2bf(elu_f(acc1[i] + bb1));
      }
    }
    if (nt < 14) STAGE_WRITE(d ^ 1)
    __syncthreads();
  }

#pragma unroll
  for (int kk = 0; kk < 15; ++kk)
    Af[kk] = *reinterpret_cast<const short8*>(
        &uH[(w * 16 + lr) * HSTR + kk * 32 + lq * 8]);
  {
    float v[60];
    STAGE_W2_LOAD(0)
    STAGE_WRITE(0)
  }
  __syncthreads();

  float p0[4] = {0.f, 0.f, 0.f, 0.f}, p1[4] = {0.f, 0.f, 0.f, 0.f};
  for (int nt = 0; nt < 8; ++nt) {
    const int d = nt & 1;
    float v[60];
    if (nt < 7) STAGE_W2_LOAD(nt + 1)
    floatx4 acc0 = {0.f, 0.f, 0.f, 0.f}, acc1 = {0.f, 0.f, 0.f, 0.f};
    const unsigned short* Wb = &uA[d * 15616];
#pragma unroll
    for (int kk = 0; kk < 15; ++kk) {
      short8 B0 = *reinterpret_cast<const short8*>(&Wb[lr * HSTR + kk * 32 + lq * 8]);
      short8 B1 = *reinterpret_cast<const short8*>(&Wb[(16 + lr) * HSTR + kk * 32 + lq * 8]);
      acc0 = __builtin_amdgcn_mfma_f32_16x16x32_bf16(Af[kk], B0, acc0, 0, 0, 0);
      acc1 = __builtin_amdgcn_mfma_f32_16x16x32_bf16(Af[kk], B1, acc1, 0, 0, 0);
    }
    {
      int c0 = nt * 32 + lr, c1 = nt * 32 + 16 + lr;
      float bb0 = b2s[c0], bb1 = b2s[c1];
      float wa0 = w3s[c0 * 2], wb0 = w3s[c0 * 2 + 1];
      float wa1 = w3s[c1 * 2], wb1 = w3s[c1 * 2 + 1];
#pragma unroll
      for (int i = 0; i < 4; ++i) {
        float h0 = elu_f(acc0[i] + bb0);
        float h1v = elu_f(acc1[i] + bb1);
        p0[i] += h0 * wa0 + h1v * wa1;
        p1[i] += h0 * wb0 + h1v * wb1;
      }
    }
    if (nt < 7) STAGE_WRITE(d ^ 1)
    __syncthreads();
  }

#pragma unroll
  for (int i = 0; i < 4; ++i) {
    float a = p0[i], bvv = p1[i];
#pragma unroll
    for (int m = 1; m < 16; m <<= 1) {
      a += __shfl_xor(a, m);
      bvv += __shfl_xor(bvv, m);
    }
    if (lr == 0) {
      size_t row = base + w * 16 + lq * 4 + i;
      float2 vv = {a + b3[0], bvv + b3[1]};
      *reinterpret_cast<float2*>(&out[row * 2]) = vv;
    }
  }
#undef STAGE_W1_LOAD
#undef STAGE_W2_LOAD
#undef STAGE_WRITE
}

// ------------------------------------------------------------- launch ----
extern "C" void kernel_launch(void* const* d_in, const int* in_sizes, int n_in,
                              void* d_out, int out_size, void* d_ws, size_t ws_size,
                              hipStream_t stream) {
  const float* coords = (const float*)d_in[0];
  const float* feat   = (const float*)d_in[1];
  const float* c1w1 = (const float*)d_in[2];  const float* c1b1 = (const float*)d_in[3];
  const float* c1w2 = (const float*)d_in[4];  const float* c1b2 = (const float*)d_in[5];
  const float* c2w1 = (const float*)d_in[6];  const float* c2b1 = (const float*)d_in[7];
  const float* c2w2 = (const float*)d_in[8];  const float* c2b2 = (const float*)d_in[9];
  const float* c3w1 = (const float*)d_in[10]; const float* c3b1 = (const float*)d_in[11];
  const float* c3w2 = (const float*)d_in[12]; const float* c3b2 = (const float*)d_in[13];
  const float* ow1  = (const float*)d_in[14]; const float* ob1  = (const float*)d_in[15];
  const float* ow2  = (const float*)d_in[16]; const float* ob2  = (const float*)d_in[17];
  const float* ow3  = (const float*)d_in[18]; const float* ob3  = (const float*)d_in[19];
  float* out = (float*)d_out;

  char* ws = (char*)d_ws;
  float* out1 = (float*)(ws);
  float* out2 = (float*)(ws + (32ull << 20));
  unsigned short* out3b = (unsigned short*)(ws + (96ull << 20));
  int* idx = (int*)(ws + (160ull << 20));
  float* Hbuf = (float*)(ws + (162ull << 20));
  unsigned short* h1 = (unsigned short*)(ws + (162ull << 20));

  knn_kernel<2><<<NB, 128, 0, stream>>>(coords, idx);
  ec1_kernel<<<2 * NB, 256, 0, stream>>>(feat, idx, c1w1, c1b1, c1w2, c1b2, out1);
  knn_kernel<64><<<NB, 128, 0, stream>>>(out1, idx);
  for (int c = 0; c < 4; ++c) {
    ec2a_kernel<<<256, 512, 0, stream>>>(out1 + (size_t)c * 256 * NPT * 64,
                                         idx + (size_t)c * 256 * 512,
                                         c2w1, c2b1, Hbuf);
    ec2b_kernel<<<512, 512, 0, stream>>>(Hbuf, c2w2, c2b2,
                                         out2 + (size_t)c * 256 * NPT * 128);
  }
  knn_kernel<128><<<NB, 128, 0, stream>>>(out2, idx);
  for (int c = 0; c < 4; ++c) {
    ec3a_kernel<<<256, 512, 0, stream>>>(out2 + (size_t)c * 256 * NPT * 128,
                                         idx + (size_t)c * 256 * 512,
                                         c3w1, c3b1, h1);
    ec3b_kernel<<<256, 512, 0, stream>>>(h1, c3w2, c3b2,
                                         out3b + (size_t)c * 256 * NPT * 256);
  }
  head_mfma_kernel<<<2048, 256, 0, stream>>>(feat, out1, out2, out3b,
                                             ow1, ob1, ow2, ob2, ow3, ob3, out);
}

// Round 8
// 2407.804 us; speedup vs baseline: 17.1125x; 1.1181x over previous
//
#include <hip/hip_runtime.h>
#include <cstdint>
#include <cstddef>

// ParticleNet MI355X — Round 8.
// - kNN: fp32 shortlist + fp64 rescore (verified).
// - ec1: ec2a-shaped register tiling (verified r7).
// - ec2: ec2a/ec2b fp32 register-tiled GEMMs (verified).
// - ec3: bf16 MFMA pair (verified).
// - head: v2 — weights pre-converted to padded bf16 (prep kernel) so staging
//   is coalesced 16B copies (r7 version did scattered 4B loads: ~45 GB of L2
//   line traffic, 710 us). 64-col chunks -> 4 independent MFMA chains.

#define NB 1024
#define NPT 128

typedef __attribute__((ext_vector_type(8))) short short8;
typedef __attribute__((ext_vector_type(4))) float floatx4;
typedef __attribute__((ext_vector_type(4))) unsigned int uint4v;

__device__ __forceinline__ float elu_f(float x) { return x > 0.0f ? x : expm1f(x); }

__device__ __forceinline__ unsigned short f2bf(float f) {
  unsigned u = __builtin_bit_cast(unsigned, f);
  unsigned r = u + 0x7FFFu + ((u >> 16) & 1u);
  return (unsigned short)(r >> 16);
}
__device__ __forceinline__ float bf2f(unsigned short h) {
  unsigned u = ((unsigned)h) << 16;
  return __builtin_bit_cast(float, u);
}

// ---------------------------------------------------------------- kNN ----
template<int C>
__global__ __launch_bounds__(128) void knn_kernel(const float* __restrict__ x,
                                                  int* __restrict__ idx) {
  __shared__ __align__(16) float xs[NPT][C + 4];
  __shared__ float x2s[NPT];
  __shared__ double x2d[NPT];
  const int b = blockIdx.x, t = threadIdx.x;
  const float* xb = x + (size_t)b * NPT * C;
  for (int e = t; e < NPT * C; e += 128) xs[e / C][e % C] = xb[e];
  __syncthreads();
  float xi[C];
  float s2 = 0.0f;
  double s2d = 0.0;
#pragma unroll
  for (int c = 0; c < C; ++c) {
    xi[c] = xs[t][c];
    s2 += xi[c] * xi[c];
    s2d += (double)xi[c] * (double)xi[c];
  }
  x2s[t] = s2;
  x2d[t] = s2d;
  __syncthreads();
  float bd0 = 1e30f, bd1 = 1e30f, bd2 = 1e30f, bd3 = 1e30f, bd4 = 1e30f, bd5 = 1e30f;
  int bi0 = 0, bi1 = 0, bi2 = 0, bi3 = 0, bi4 = 0, bi5 = 0;
  for (int j = 0; j < NPT; ++j) {
    if (j == t) continue;
    float dot = 0.0f;
    if constexpr (C >= 4) {
      const float4* xr = reinterpret_cast<const float4*>(&xs[j][0]);
#pragma unroll
      for (int c4 = 0; c4 < C / 4; ++c4) {
        float4 v = xr[c4];
        dot += xi[4 * c4 + 0] * v.x + xi[4 * c4 + 1] * v.y +
               xi[4 * c4 + 2] * v.z + xi[4 * c4 + 3] * v.w;
      }
    } else {
#pragma unroll
      for (int c = 0; c < C; ++c) dot += xi[c] * xs[j][c];
    }
    float d = s2 + x2s[j] - 2.0f * dot;
    if (d < bd5) {
      bd5 = d; bi5 = j;
      if (bd5 < bd4) {
        float td = bd4; bd4 = bd5; bd5 = td; int ti = bi4; bi4 = bi5; bi5 = ti;
        if (bd4 < bd3) {
          td = bd3; bd3 = bd4; bd4 = td; ti = bi3; bi3 = bi4; bi4 = ti;
          if (bd3 < bd2) {
            td = bd2; bd2 = bd3; bd3 = td; ti = bi2; bi2 = bi3; bi3 = ti;
            if (bd2 < bd1) {
              td = bd1; bd1 = bd2; bd2 = td; ti = bi1; bi1 = bi2; bi2 = ti;
              if (bd1 < bd0) {
                td = bd0; bd0 = bd1; bd1 = td; ti = bi0; bi0 = bi1; bi1 = ti;
              }
            }
          }
        }
      }
    }
  }
  auto refine = [&](int j) -> double {
    double dot = 0.0;
#pragma unroll
    for (int c = 0; c < C; ++c) dot += (double)xi[c] * (double)xs[j][c];
    return s2d + x2d[j] - 2.0 * dot;
  };
  double e0 = refine(bi0), e1 = refine(bi1), e2 = refine(bi2);
  double e3 = refine(bi3), e4 = refine(bi4), e5 = refine(bi5);
#define CSWP(da, ia, db, ib)                                            \
  if ((da > db) || (da == db && ia > ib)) {                             \
    double _td = da; da = db; db = _td; int _ti = ia; ia = ib; ib = _ti; }
  CSWP(e0, bi0, e1, bi1) CSWP(e1, bi1, e2, bi2) CSWP(e2, bi2, e3, bi3)
  CSWP(e3, bi3, e4, bi4) CSWP(e4, bi4, e5, bi5)
  CSWP(e0, bi0, e1, bi1) CSWP(e1, bi1, e2, bi2) CSWP(e2, bi2, e3, bi3)
  CSWP(e3, bi3, e4, bi4)
  CSWP(e0, bi0, e1, bi1) CSWP(e1, bi1, e2, bi2) CSWP(e2, bi2, e3, bi3)
  CSWP(e0, bi0, e1, bi1) CSWP(e1, bi1, e2, bi2)
  CSWP(e0, bi0, e1, bi1)
#undef CSWP
  int* ib = idx + ((size_t)b * NPT + t) * 4;
  ib[0] = bi0; ib[1] = bi1; ib[2] = bi2; ib[3] = bi3;
}

// ---------------------------------------------------------------- ec1 ----
__global__ __launch_bounds__(256) void ec1_kernel(
    const float* __restrict__ feat, const int* __restrict__ idx,
    const float* __restrict__ w1, const float* __restrict__ b1,
    const float* __restrict__ w2, const float* __restrict__ b2,
    float* __restrict__ out) {
  __shared__ __align__(16) float fs[NPT][6];
  __shared__ __align__(16) float w1s[10][32];
  __shared__ __align__(16) float w2s[32][68];
  __shared__ float hs[256][33];
  __shared__ float b1s[32], b2s[64];
  const int z = blockIdx.x, t = threadIdx.x;
  const int b = z >> 1, hh = z & 1;
  const float* fb = feat + (size_t)b * NPT * 5;
  for (int e = t; e < NPT * 5; e += 256) fs[e / 5][e % 5] = fb[e];
  for (int e = t; e < 320; e += 256) w1s[e / 32][e % 32] = w1[e];
  for (int e = t; e < 2048; e += 256) w2s[e >> 6][e & 63] = w2[e];
  if (t < 32) b1s[t] = b1[t];
  if (t >= 192) b2s[t - 192] = b2[t - 192];
  __syncthreads();
  {
    const int p = hh * 64 + (t >> 2);
    const int j = idx[(size_t)b * 512 + p * 4 + (t & 3)];
    float h[32];
#pragma unroll
    for (int o = 0; o < 32; ++o) h[o] = b1s[o];
#pragma unroll
    for (int c = 0; c < 10; ++c) {
      float in_c = (c < 5) ? fs[p][c] : (fs[j][c - 5] - fs[p][c - 5]);
      const float4* wr = reinterpret_cast<const float4*>(&w1s[c][0]);
#pragma unroll
      for (int o4 = 0; o4 < 8; ++o4) {
        float4 w = wr[o4];
        h[4 * o4 + 0] += in_c * w.x; h[4 * o4 + 1] += in_c * w.y;
        h[4 * o4 + 2] += in_c * w.z; h[4 * o4 + 3] += in_c * w.w;
      }
    }
#pragma unroll
    for (int o = 0; o < 32; ++o) hs[t][o] = elu_f(h[o]);
  }
  __syncthreads();
  {
    const int g = t >> 2, q = t & 3;
    const int o0 = q * 16;
    float acc[4][16];
#pragma unroll
    for (int m = 0; m < 16; ++m) {
      float bv = b2s[o0 + m];
#pragma unroll
      for (int i = 0; i < 4; ++i) acc[i][m] = bv;
    }
    for (int k = 0; k < 32; ++k) {
      float hk0 = hs[g * 4 + 0][k];
      float hk1 = hs[g * 4 + 1][k];
      float hk2 = hs[g * 4 + 2][k];
      float hk3 = hs[g * 4 + 3][k];
      const float4* wr = reinterpret_cast<const float4*>(&w2s[k][o0]);
#pragma unroll
      for (int m4 = 0; m4 < 4; ++m4) {
        float4 w = wr[m4];
        acc[0][4 * m4 + 0] += hk0 * w.x; acc[0][4 * m4 + 1] += hk0 * w.y;
        acc[0][4 * m4 + 2] += hk0 * w.z; acc[0][4 * m4 + 3] += hk0 * w.w;
        acc[1][4 * m4 + 0] += hk1 * w.x; acc[1][4 * m4 + 1] += hk1 * w.y;
        acc[1][4 * m4 + 2] += hk1 * w.z; acc[1][4 * m4 + 3] += hk1 * w.w;
        acc[2][4 * m4 + 0] += hk2 * w.x; acc[2][4 * m4 + 1] += hk2 * w.y;
        acc[2][4 * m4 + 2] += hk2 * w.z; acc[2][4 * m4 + 3] += hk2 * w.w;
        acc[3][4 * m4 + 0] += hk3 * w.x; acc[3][4 * m4 + 1] += hk3 * w.y;
        acc[3][4 * m4 + 2] += hk3 * w.z; acc[3][4 * m4 + 3] += hk3 * w.w;
      }
    }
    float* ob = out + ((size_t)b * NPT + hh * 64 + g) * 64 + o0;
#pragma unroll
    for (int m4 = 0; m4 < 4; ++m4) {
      float4 v;
      float* vp = &v.x;
#pragma unroll
      for (int s = 0; s < 4; ++s) {
        int m = 4 * m4 + s;
        vp[s] = 0.25f * (elu_f(acc[0][m]) + elu_f(acc[1][m]) +
                         elu_f(acc[2][m]) + elu_f(acc[3][m]));
      }
      *reinterpret_cast<float4*>(&ob[4 * m4]) = v;
    }
  }
}

// ---------------------------------------------------------------- ec2a ----
__global__ __launch_bounds__(512, 2) void ec2a_kernel(
    const float* __restrict__ x, const int* __restrict__ idx,
    const float* __restrict__ w1, const float* __restrict__ b1,
    float* __restrict__ H) {
  __shared__ __align__(16) float xs[NPT][68];
  __shared__ __align__(16) float w1s[128][100];
  __shared__ float b1s[96];
  const int b = blockIdx.x, t = threadIdx.x;
  const float* xb = x + (size_t)b * NPT * 64;
  for (int e = t; e < NPT * 64; e += 512) xs[e >> 6][e & 63] = xb[e];
  for (int e = t; e < 128 * 96; e += 512) w1s[e / 96][e % 96] = w1[e];
  if (t < 96) b1s[t] = b1[t];
  __syncthreads();
  const int pb = t >> 2, part = t & 3;
  const int n0 = part * 24;
  int jn[4];
#pragma unroll
  for (int i = 0; i < 4; ++i) jn[i] = idx[(size_t)b * 512 + pb * 4 + i];
  float acc[4][24];
#pragma unroll
  for (int m = 0; m < 24; ++m) {
    float bv = b1s[n0 + m];
#pragma unroll
    for (int i = 0; i < 4; ++i) acc[i][m] = bv;
  }
  for (int c = 0; c < 64; ++c) {
    float in_c = xs[pb][c];
    const float4* wr = reinterpret_cast<const float4*>(&w1s[c][n0]);
#pragma unroll
    for (int q4 = 0; q4 < 6; ++q4) {
      float4 wv = wr[q4];
#pragma unroll
      for (int i = 0; i < 4; ++i) {
        acc[i][4 * q4 + 0] += in_c * wv.x;
        acc[i][4 * q4 + 1] += in_c * wv.y;
        acc[i][4 * q4 + 2] += in_c * wv.z;
        acc[i][4 * q4 + 3] += in_c * wv.w;
      }
    }
  }
  for (int c = 0; c < 64; ++c) {
    float xic = xs[pb][c];
    float in0 = xs[jn[0]][c] - xic;
    float in1 = xs[jn[1]][c] - xic;
    float in2 = xs[jn[2]][c] - xic;
    float in3 = xs[jn[3]][c] - xic;
    const float4* wr = reinterpret_cast<const float4*>(&w1s[64 + c][n0]);
#pragma unroll
    for (int q4 = 0; q4 < 6; ++q4) {
      float4 wv = wr[q4];
      acc[0][4 * q4 + 0] += in0 * wv.x; acc[0][4 * q4 + 1] += in0 * wv.y;
      acc[0][4 * q4 + 2] += in0 * wv.z; acc[0][4 * q4 + 3] += in0 * wv.w;
      acc[1][4 * q4 + 0] += in1 * wv.x; acc[1][4 * q4 + 1] += in1 * wv.y;
      acc[1][4 * q4 + 2] += in1 * wv.z; acc[1][4 * q4 + 3] += in1 * wv.w;
      acc[2][4 * q4 + 0] += in2 * wv.x; acc[2][4 * q4 + 1] += in2 * wv.y;
      acc[2][4 * q4 + 2] += in2 * wv.z; acc[2][4 * q4 + 3] += in2 * wv.w;
      acc[3][4 * q4 + 0] += in3 * wv.x; acc[3][4 * q4 + 1] += in3 * wv.y;
      acc[3][4 * q4 + 2] += in3 * wv.z; acc[3][4 * q4 + 3] += in3 * wv.w;
    }
  }
#pragma unroll
  for (int i = 0; i < 4; ++i) {
    float* hrow = H + ((size_t)b * 512 + pb * 4 + i) * 96 + n0;
#pragma unroll
    for (int q4 = 0; q4 < 6; ++q4) {
      float4 v = {elu_f(acc[i][4 * q4 + 0]), elu_f(acc[i][4 * q4 + 1]),
                  elu_f(acc[i][4 * q4 + 2]), elu_f(acc[i][4 * q4 + 3])};
      *reinterpret_cast<float4*>(&hrow[4 * q4]) = v;
    }
  }
}

// ---------------------------------------------------------------- ec2b ----
__global__ __launch_bounds__(512, 2) void ec2b_kernel(
    const float* __restrict__ H, const float* __restrict__ w2,
    const float* __restrict__ b2, float* __restrict__ out) {
  __shared__ __align__(16) float hsT[96][260];
  __shared__ float w2s[96][132];
  __shared__ float b2s[128];
  const int z = blockIdx.x, t = threadIdx.x;
  const int bc = z >> 1, hh = z & 1;
  const float* Hb = H + ((size_t)bc * 512 + hh * 256) * 96;
  for (int i = t; i < 256 * 96; i += 512) hsT[i % 96][i / 96] = Hb[i];
  for (int i = t; i < 96 * 128; i += 512) w2s[i >> 7][i & 127] = w2[i];
  if (t < 128) b2s[t] = b2[t];
  __syncthreads();
  const int g = t >> 3, oq = t & 7;
  float acc[4][16];
#pragma unroll
  for (int m = 0; m < 16; ++m) {
    float bv = b2s[oq + 8 * m];
#pragma unroll
    for (int i = 0; i < 4; ++i) acc[i][m] = bv;
  }
  for (int k = 0; k < 96; ++k) {
    float4 hv = *reinterpret_cast<const float4*>(&hsT[k][4 * g]);
#pragma unroll
    for (int m = 0; m < 16; ++m) {
      float wv = w2s[k][oq + 8 * m];
      acc[0][m] += hv.x * wv;
      acc[1][m] += hv.y * wv;
      acc[2][m] += hv.z * wv;
      acc[3][m] += hv.w * wv;
    }
  }
  float* orow = out + ((size_t)bc * NPT + hh * 64 + g) * 128;
#pragma unroll
  for (int m = 0; m < 16; ++m) {
    float s = elu_f(acc[0][m]) + elu_f(acc[1][m]) +
              elu_f(acc[2][m]) + elu_f(acc[3][m]);
    orow[oq + 8 * m] = 0.25f * s;
  }
}

// ---------------------------------------------------------------- ec3a ----
__global__ __launch_bounds__(512, 2) void ec3a_kernel(
    const float* __restrict__ x, const int* __restrict__ idx,
    const float* __restrict__ w1, const float* __restrict__ b1,
    unsigned short* __restrict__ h1) {
  __shared__ unsigned short Xb[128][136];
  __shared__ unsigned short W1t[192][264];
  __shared__ float b1s[192];
  __shared__ unsigned short stg[8][16][40];
  const int b = blockIdx.x, t = threadIdx.x;
  const float* xb = x + (size_t)b * NPT * 128;
  for (int e = t; e < NPT * 128; e += 512) Xb[e >> 7][e & 127] = f2bf(xb[e]);
  for (int e = t; e < 256 * 192; e += 512) {
    int k = e / 192, n = e % 192;
    W1t[n][k] = f2bf(w1[e]);
  }
  if (t < 192) b1s[t] = b1[t];
  __syncthreads();
  const int w = t >> 6, l = t & 63;
  const int lr = l & 15, lq = l >> 4;
  for (int mt = 0; mt < 4; ++mt) {
    const int m = (w * 4 + mt) * 16;
    const int e = m + lr;
    const int p = e >> 2;
    const int jp = idx[(size_t)b * 512 + e];
    short8 A[8];
#pragma unroll
    for (int kk = 0; kk < 4; ++kk) {
      int k0 = kk * 32 + lq * 8;
      A[kk] = *reinterpret_cast<const short8*>(&Xb[p][k0]);
    }
#pragma unroll
    for (int kk = 0; kk < 4; ++kk) {
      int k0 = kk * 32 + lq * 8;
      short8 aj = *reinterpret_cast<const short8*>(&Xb[jp][k0]);
      short8 ai = *reinterpret_cast<const short8*>(&Xb[p][k0]);
      short8 d;
#pragma unroll
      for (int q = 0; q < 8; ++q)
        d[q] = (short)f2bf(bf2f((unsigned short)aj[q]) - bf2f((unsigned short)ai[q]));
      A[4 + kk] = d;
    }
    floatx4 acc[12];
#pragma unroll
    for (int n = 0; n < 12; ++n) acc[n] = (floatx4){0.f, 0.f, 0.f, 0.f};
#pragma unroll
    for (int n = 0; n < 12; ++n) {
#pragma unroll
      for (int kk = 0; kk < 8; ++kk) {
        short8 Bf = *reinterpret_cast<const short8*>(&W1t[n * 16 + lr][kk * 32 + lq * 8]);
        acc[n] = __builtin_amdgcn_mfma_f32_16x16x32_bf16(A[kk], Bf, acc[n], 0, 0, 0);
      }
    }
#pragma unroll
    for (int pr = 0; pr < 6; ++pr) {
      float bv0 = b1s[pr * 32 + lr];
      float bv1 = b1s[pr * 32 + 16 + lr];
#pragma unroll
      for (int i = 0; i < 4; ++i) {
        stg[w][lq * 4 + i][lr]      = f2bf(elu_f(acc[2 * pr][i] + bv0));
        stg[w][lq * 4 + i][16 + lr] = f2bf(elu_f(acc[2 * pr + 1][i] + bv1));
      }
      asm volatile("s_waitcnt lgkmcnt(0)" ::: "memory");
      const unsigned short* src = &stg[w][l >> 2][(l & 3) * 8];
      uint4v vv = *reinterpret_cast<const uint4v*>(src);
      size_t dst = ((size_t)b * 512 + m + (l >> 2)) * 192 + pr * 32 + (l & 3) * 8;
      *reinterpret_cast<uint4v*>(&h1[dst]) = vv;
      asm volatile("s_waitcnt lgkmcnt(0)" ::: "memory");
    }
  }
}

// ---------------------------------------------------------------- ec3b ----
__global__ __launch_bounds__(512, 2) void ec3b_kernel(
    const unsigned short* __restrict__ h1,
    const float* __restrict__ w2, const float* __restrict__ b2,
    unsigned short* __restrict__ out3) {
  __shared__ unsigned short W2t[256][200];
  __shared__ float b2s[256];
  const int b = blockIdx.x, t = threadIdx.x;
  for (int e = t; e < 192 * 256; e += 512) {
    int k = e >> 8, n = e & 255;
    W2t[n][k] = f2bf(w2[e]);
  }
  if (t < 256) b2s[t] = b2[t];
  __syncthreads();
  const int w = t >> 6, l = t & 63;
  const int lr = l & 15, lq = l >> 4;
  for (int mt = 0; mt < 4; ++mt) {
    const int m = (w * 4 + mt) * 16;
    floatx4 acc[16];
#pragma unroll
    for (int n = 0; n < 16; ++n) acc[n] = (floatx4){0.f, 0.f, 0.f, 0.f};
    const unsigned short* arow = h1 + ((size_t)b * 512 + m + lr) * 192;
#pragma unroll
    for (int kk = 0; kk < 6; ++kk) {
      short8 Af = *reinterpret_cast<const short8*>(&arow[kk * 32 + lq * 8]);
#pragma unroll
      for (int n = 0; n < 16; ++n) {
        short8 Bf = *reinterpret_cast<const short8*>(&W2t[n * 16 + lr][kk * 32 + lq * 8]);
        acc[n] = __builtin_amdgcn_mfma_f32_16x16x32_bf16(Af, Bf, acc[n], 0, 0, 0);
      }
    }
    unsigned short* orow = out3 + ((size_t)b * NPT + (m >> 2) + lq) * 256;
#pragma unroll
    for (int n = 0; n < 16; ++n) {
      float bv = b2s[n * 16 + lr];
      float s = 0.f;
#pragma unroll
      for (int i = 0; i < 4; ++i) s += elu_f(acc[n][i] + bv);
      orow[n * 16 + lr] = f2bf(0.25f * s);
    }
  }
}

// ------------------------------------------------------------ head prep ----
// One-off: convert head weights to bf16 in MFMA-friendly padded layouts.
// w1p[512][480]: w1p[n][kp] = w1[ko(kp)*453+n]; kp pad-map per X layout.
// w2p[256][480]: w2p[n][kp] = w2[kp*226+n].
__global__ __launch_bounds__(256) void head_prep_kernel(
    const float* __restrict__ w1, const float* __restrict__ w2,
    unsigned short* __restrict__ w1p, unsigned short* __restrict__ w2p) {
  int i = blockIdx.x * 256 + threadIdx.x;
  if (i < 512 * 480) {
    int n = i / 480, kp = i % 480;
    int ko = (kp < 5) ? kp : kp - 3;
    bool ok = ((kp < 5) || (kp >= 8 && kp < 456)) && (n < 453);
    w1p[i] = ok ? f2bf(w1[(size_t)ko * 453 + n]) : (unsigned short)0;
  } else {
    int j = i - 512 * 480;
    if (j < 256 * 480) {
      int n = j / 480, kp = j % 480;
      bool ok = (kp < 453) && (n < 226);
      w2p[j] = ok ? f2bf(w2[(size_t)kp * 226 + n]) : (unsigned short)0;
    }
  }
}

// ----------------------------------------------------------- head MFMA ----
// Fused 453->453->226->2, bf16 MFMA. Block = 64 points, 256 thr, 4 waves.
// W chunks: 64 cols x 480 k bf16, staged as coalesced 16B copies from the
// pre-converted w1p/w2p; T14 issue-early/write-late; 4 indep acc chains.
#define HSTR 488   // LDS row stride in shorts (976 B)
__global__ __launch_bounds__(256) void head_mfma_kernel(
    const float* __restrict__ feat, const float* __restrict__ o1,
    const float* __restrict__ o2, const unsigned short* __restrict__ o3,
    const unsigned short* __restrict__ w1p, const float* __restrict__ b1,
    const unsigned short* __restrict__ w2p, const float* __restrict__ b2,
    const float* __restrict__ w3, const float* __restrict__ b3,
    float* __restrict__ out) {
  __shared__ unsigned short uA[64 * HSTR];  // X, then W chunk buffer
  __shared__ unsigned short uH[64 * HSTR];  // H1 bf16 (k-padded with zeros)
  __shared__ float b1s[512], b2s[256], w3s[512];
  const int t = threadIdx.x;
  const size_t base = (size_t)blockIdx.x * 64;

  // ---- stage concat X -> uA (bf16, padded k layout) ----
  for (int e = t; e < 64 * 8; e += 256) {
    int r = e >> 3, c = e & 7;
    uA[r * HSTR + c] = (c < 5) ? f2bf(feat[(base + r) * 5 + c]) : 0;
  }
  for (int e = t; e < 64 * 64; e += 256) {
    int r = e >> 6, c = e & 63;
    uA[r * HSTR + 8 + c] = f2bf(o1[(base + r) * 64 + c]);
  }
  for (int e = t; e < 64 * 128; e += 256) {
    int r = e >> 7, c = e & 127;
    uA[r * HSTR + 72 + c] = f2bf(o2[(base + r) * 128 + c]);
  }
  for (int e = t; e < 64 * 256; e += 256) {
    int r = e >> 8, c = e & 255;
    uA[r * HSTR + 200 + c] = o3[(base + r) * 256 + c];
  }
  for (int e = t; e < 64 * 32; e += 256) {
    int r = e >> 5, c = e & 31;
    uA[r * HSTR + 456 + c] = 0;
  }
  for (int i = t; i < 512; i += 256) b1s[i] = (i < 453) ? b1[i] : 0.f;
  if (t < 256) b2s[t] = (t < 226) ? b2[t] : 0.f;
  for (int i = t; i < 512; i += 256) w3s[i] = (i < 452) ? w3[i] : 0.f;
  __syncthreads();

  const int w = t >> 6, l = t & 63;
  const int lr = l & 15, lq = l >> 4;
  const int tr = t >> 2, tc = t & 3;   // staging: row (W col), 16B-quad

  short8 Af[15];
#pragma unroll
  for (int kk = 0; kk < 15; ++kk)
    Af[kk] = *reinterpret_cast<const short8*>(
        &uA[(w * 16 + lr) * HSTR + kk * 32 + lq * 8]);
  __syncthreads();  // X dead -> uA is the W chunk buffer

  uint4v v[15];
#define WLOAD(SRC, CH)                                                   \
  {                                                                      \
    _Pragma("unroll")                                                    \
    for (int i = 0; i < 15; ++i)                                         \
      v[i] = *reinterpret_cast<const uint4v*>(                           \
          &SRC[((size_t)((CH) * 64 + tr)) * 480 + (tc + 4 * i) * 8]);    \
  }
#define WWRITE()                                                         \
  {                                                                      \
    _Pragma("unroll")                                                    \
    for (int i = 0; i < 15; ++i)                                         \
      *reinterpret_cast<uint4v*>(&uA[tr * HSTR + (tc + 4 * i) * 8]) = v[i]; \
  }

  WLOAD(w1p, 0)
  WWRITE()
  __syncthreads();

  // ---- GEMM1: 8 chunks of 64 cols ----
  for (int ch = 0; ch < 8; ++ch) {
    if (ch < 7) WLOAD(w1p, ch + 1)
    floatx4 a0 = {0.f, 0.f, 0.f, 0.f}, a1 = {0.f, 0.f, 0.f, 0.f};
    floatx4 a2 = {0.f, 0.f, 0.f, 0.f}, a3 = {0.f, 0.f, 0.f, 0.f};
#pragma unroll
    for (int kk = 0; kk < 15; ++kk) {
      int ko = kk * 32 + lq * 8;
      short8 B0 = *reinterpret_cast<const short8*>(&uA[(lr)*HSTR + ko]);
      short8 B1 = *reinterpret_cast<const short8*>(&uA[(16 + lr) * HSTR + ko]);
      short8 B2 = *reinterpret_cast<const short8*>(&uA[(32 + lr) * HSTR + ko]);
      short8 B3 = *reinterpret_cast<const short8*>(&uA[(48 + lr) * HSTR + ko]);
      a0 = __builtin_amdgcn_mfma_f32_16x16x32_bf16(Af[kk], B0, a0, 0, 0, 0);
      a1 = __builtin_amdgcn_mfma_f32_16x16x32_bf16(Af[kk], B1, a1, 0, 0, 0);
      a2 = __builtin_amdgcn_mfma_f32_16x16x32_bf16(Af[kk], B2, a2, 0, 0, 0);
      a3 = __builtin_amdgcn_mfma_f32_16x16x32_bf16(Af[kk], B3, a3, 0, 0, 0);
    }
    {
      floatx4 aj[4] = {a0, a1, a2, a3};
#pragma unroll
      for (int jx = 0; jx < 4; ++jx) {
        int c = ch * 64 + jx * 16 + lr;
        if (c < 480) {
          float bb = b1s[c];
#pragma unroll
          for (int i = 0; i < 4; ++i) {
            int row = w * 16 + lq * 4 + i;
            uH[row * HSTR + c] =
                (c < 453) ? f2bf(elu_f(aj[jx][i] + bb)) : (unsigned short)0;
          }
        }
      }
    }
    __syncthreads();
    if (ch < 7) WWRITE()
    __syncthreads();
  }

  // ---- A2 fragments from H1; stage w2p chunk 0 ----
#pragma unroll
  for (int kk = 0; kk < 15; ++kk)
    Af[kk] = *reinterpret_cast<const short8*>(
        &uH[(w * 16 + lr) * HSTR + kk * 32 + lq * 8]);
  WLOAD(w2p, 0)
  WWRITE()
  __syncthreads();

  // ---- GEMM2: 4 chunks of 64 cols + fp32 GEMM3 partials ----
  float p0[4] = {0.f, 0.f, 0.f, 0.f}, p1[4] = {0.f, 0.f, 0.f, 0.f};
  for (int ch = 0; ch < 4; ++ch) {
    if (ch < 3) WLOAD(w2p, ch + 1)
    floatx4 a0 = {0.f, 0.f, 0.f, 0.f}, a1 = {0.f, 0.f, 0.f, 0.f};
    floatx4 a2 = {0.f, 0.f, 0.f, 0.f}, a3 = {0.f, 0.f, 0.f, 0.f};
#pragma unroll
    for (int kk = 0; kk < 15; ++kk) {
      int ko = kk * 32 + lq * 8;
      short8 B0 = *reinterpret_cast<const short8*>(&uA[(lr)*HSTR + ko]);
      short8 B1 = *reinterpret_cast<const short8*>(&uA[(16 + lr) * HSTR + ko]);
      short8 B2 = *reinterpret_cast<const short8*>(&uA[(32 + lr) * HSTR + ko]);
      short8 B3 = *reinterpret_cast<const short8*>(&uA[(48 + lr) * HSTR + ko]);
      a0 = __builtin_amdgcn_mfma_f32_16x16x32_bf16(Af[kk], B0, a0, 0, 0, 0);
      a1 = __builtin_amdgcn_mfma_f32_16x16x32_bf16(Af[kk], B1, a1, 0, 0, 0);
      a2 = __builtin_amdgcn_mfma_f32_16x16x32_bf16(Af[kk], B2, a2, 0, 0, 0);
      a3 = __builtin_amdgcn_mfma_f32_16x16x32_bf16(Af[kk], B3, a3, 0, 0, 0);
    }
    {
      floatx4 aj[4] = {a0, a1, a2, a3};
#pragma unroll
      for (int jx = 0; jx < 4; ++jx) {
        int c = ch * 64 + jx * 16 + lr;
        float bb = b2s[c];
        float wa = w3s[2 * c], wb = w3s[2 * c + 1];
#pragma unroll
        for (int i = 0; i < 4; ++i) {
          float h = (c < 226) ? elu_f(aj[jx][i] + bb) : 0.f;
          p0[i] += h * wa;
          p1[i] += h * wb;
        }
      }
    }
    __syncthreads();
    if (ch < 3) WWRITE()
    __syncthreads();
  }

  // ---- reduce over the 16 lr lanes and store ----
#pragma unroll
  for (int i = 0; i < 4; ++i) {
    float a = p0[i], bvv = p1[i];
#pragma unroll
    for (int m = 1; m < 16; m <<= 1) {
      a += __shfl_xor(a, m);
      bvv += __shfl_xor(bvv, m);
    }
    if (lr == 0) {
      size_t row = base + w * 16 + lq * 4 + i;
      float2 vv = {a + b3[0], bvv + b3[1]};
      *reinterpret_cast<float2*>(&out[row * 2]) = vv;
    }
  }
#undef WLOAD
#undef WWRITE
}

// ------------------------------------------------------------- launch ----
extern "C" void kernel_launch(void* const* d_in, const int* in_sizes, int n_in,
                              void* d_out, int out_size, void* d_ws, size_t ws_size,
                              hipStream_t stream) {
  const float* coords = (const float*)d_in[0];
  const float* feat   = (const float*)d_in[1];
  const float* c1w1 = (const float*)d_in[2];  const float* c1b1 = (const float*)d_in[3];
  const float* c1w2 = (const float*)d_in[4];  const float* c1b2 = (const float*)d_in[5];
  const float* c2w1 = (const float*)d_in[6];  const float* c2b1 = (const float*)d_in[7];
  const float* c2w2 = (const float*)d_in[8];  const float* c2b2 = (const float*)d_in[9];
  const float* c3w1 = (const float*)d_in[10]; const float* c3b1 = (const float*)d_in[11];
  const float* c3w2 = (const float*)d_in[12]; const float* c3b2 = (const float*)d_in[13];
  const float* ow1  = (const float*)d_in[14]; const float* ob1  = (const float*)d_in[15];
  const float* ow2  = (const float*)d_in[16]; const float* ob2  = (const float*)d_in[17];
  const float* ow3  = (const float*)d_in[18]; const float* ob3  = (const float*)d_in[19];
  float* out = (float*)d_out;

  // ws (MiB): out1 [0,32) | out2 [32,96) | out3 bf16 [96,160) | idx [160,162)
  // | chunk buf [162,212) | w1p bf16 [212,212.47) | w2p bf16 [213,213.24)
  char* ws = (char*)d_ws;
  float* out1 = (float*)(ws);
  float* out2 = (float*)(ws + (32ull << 20));
  unsigned short* out3b = (unsigned short*)(ws + (96ull << 20));
  int* idx = (int*)(ws + (160ull << 20));
  float* Hbuf = (float*)(ws + (162ull << 20));
  unsigned short* h1 = (unsigned short*)(ws + (162ull << 20));
  unsigned short* w1p = (unsigned short*)(ws + (212ull << 20));
  unsigned short* w2p = (unsigned short*)(ws + (213ull << 20));

  head_prep_kernel<<<1440, 256, 0, stream>>>(ow1, ow2, w1p, w2p);
  knn_kernel<2><<<NB, 128, 0, stream>>>(coords, idx);
  ec1_kernel<<<2 * NB, 256, 0, stream>>>(feat, idx, c1w1, c1b1, c1w2, c1b2, out1);
  knn_kernel<64><<<NB, 128, 0, stream>>>(out1, idx);
  for (int c = 0; c < 4; ++c) {
    ec2a_kernel<<<256, 512, 0, stream>>>(out1 + (size_t)c * 256 * NPT * 64,
                                         idx + (size_t)c * 256 * 512,
                                         c2w1, c2b1, Hbuf);
    ec2b_kernel<<<512, 512, 0, stream>>>(Hbuf, c2w2, c2b2,
                                         out2 + (size_t)c * 256 * NPT * 128);
  }
  knn_kernel<128><<<NB, 128, 0, stream>>>(out2, idx);
  for (int c = 0; c < 4; ++c) {
    ec3a_kernel<<<256, 512, 0, stream>>>(out2 + (size_t)c * 256 * NPT * 128,
                                         idx + (size_t)c * 256 * 512,
                                         c3w1, c3b1, h1);
    ec3b_kernel<<<256, 512, 0, stream>>>(h1, c3w2, c3b2,
                                         out3b + (size_t)c * 256 * NPT * 256);
  }
  head_mfma_kernel<<<2048, 256, 0, stream>>>(feat, out1, out2, out3b,
                                             w1p, ob1, w2p, ob2, ow3, ob3, out);
}

// Round 9
// 2138.648 us; speedup vs baseline: 19.2661x; 1.1259x over previous
//
#include <hip/hip_runtime.h>
#include <cstdint>
#include <cstddef>

// ParticleNet MI355X — Round 9.
// - kNN C=2: r2 kernel (verified). kNN C=64/128: NEW 512-thread quarter-split
//   (r8 version was latency-bound: 1 wave/SIMD, 32 serial b128 reads/j, 490us).
// - ec1: ec2a-shaped register tiling (verified r7/r8).
// - ec2: ec2a/ec2b fp32 register-tiled GEMMs (verified).
// - ec3: bf16 MFMA pair (verified).
// - head: prep-converted bf16 weights + fused MFMA (verified r8).

#define NB 1024
#define NPT 128

typedef __attribute__((ext_vector_type(8))) short short8;
typedef __attribute__((ext_vector_type(4))) float floatx4;
typedef __attribute__((ext_vector_type(4))) unsigned int uint4v;

__device__ __forceinline__ float elu_f(float x) { return x > 0.0f ? x : expm1f(x); }

__device__ __forceinline__ unsigned short f2bf(float f) {
  unsigned u = __builtin_bit_cast(unsigned, f);
  unsigned r = u + 0x7FFFu + ((u >> 16) & 1u);
  return (unsigned short)(r >> 16);
}
__device__ __forceinline__ float bf2f(unsigned short h) {
  unsigned u = ((unsigned)h) << 16;
  return __builtin_bit_cast(float, u);
}

// ------------------------------------------------------------- kNN C=2 ----
template<int C>
__global__ __launch_bounds__(128) void knn_kernel(const float* __restrict__ x,
                                                  int* __restrict__ idx) {
  __shared__ __align__(16) float xs[NPT][C + 4];
  __shared__ float x2s[NPT];
  __shared__ double x2d[NPT];
  const int b = blockIdx.x, t = threadIdx.x;
  const float* xb = x + (size_t)b * NPT * C;
  for (int e = t; e < NPT * C; e += 128) xs[e / C][e % C] = xb[e];
  __syncthreads();
  float xi[C];
  float s2 = 0.0f;
  double s2d = 0.0;
#pragma unroll
  for (int c = 0; c < C; ++c) {
    xi[c] = xs[t][c];
    s2 += xi[c] * xi[c];
    s2d += (double)xi[c] * (double)xi[c];
  }
  x2s[t] = s2;
  x2d[t] = s2d;
  __syncthreads();
  float bd0 = 1e30f, bd1 = 1e30f, bd2 = 1e30f, bd3 = 1e30f, bd4 = 1e30f, bd5 = 1e30f;
  int bi0 = 0, bi1 = 0, bi2 = 0, bi3 = 0, bi4 = 0, bi5 = 0;
  for (int j = 0; j < NPT; ++j) {
    if (j == t) continue;
    float dot = 0.0f;
#pragma unroll
    for (int c = 0; c < C; ++c) dot += xi[c] * xs[j][c];
    float d = s2 + x2s[j] - 2.0f * dot;
    if (d < bd5) {
      bd5 = d; bi5 = j;
      if (bd5 < bd4) {
        float td = bd4; bd4 = bd5; bd5 = td; int ti = bi4; bi4 = bi5; bi5 = ti;
        if (bd4 < bd3) {
          td = bd3; bd3 = bd4; bd4 = td; ti = bi3; bi3 = bi4; bi4 = ti;
          if (bd3 < bd2) {
            td = bd2; bd2 = bd3; bd3 = td; ti = bi2; bi2 = bi3; bi3 = ti;
            if (bd2 < bd1) {
              td = bd1; bd1 = bd2; bd2 = td; ti = bi1; bi1 = bi2; bi2 = ti;
              if (bd1 < bd0) {
                td = bd0; bd0 = bd1; bd1 = td; ti = bi0; bi0 = bi1; bi1 = ti;
              }
            }
          }
        }
      }
    }
  }
  auto refine = [&](int j) -> double {
    double dot = 0.0;
#pragma unroll
    for (int c = 0; c < C; ++c) dot += (double)xi[c] * (double)xs[j][c];
    return s2d + x2d[j] - 2.0 * dot;
  };
  double e0 = refine(bi0), e1 = refine(bi1), e2 = refine(bi2);
  double e3 = refine(bi3), e4 = refine(bi4), e5 = refine(bi5);
#define CSWP(da, ia, db, ib)                                            \
  if ((da > db) || (da == db && ia > ib)) {                             \
    double _td = da; da = db; db = _td; int _ti = ia; ia = ib; ib = _ti; }
  CSWP(e0, bi0, e1, bi1) CSWP(e1, bi1, e2, bi2) CSWP(e2, bi2, e3, bi3)
  CSWP(e3, bi3, e4, bi4) CSWP(e4, bi4, e5, bi5)
  CSWP(e0, bi0, e1, bi1) CSWP(e1, bi1, e2, bi2) CSWP(e2, bi2, e3, bi3)
  CSWP(e3, bi3, e4, bi4)
  CSWP(e0, bi0, e1, bi1) CSWP(e1, bi1, e2, bi2) CSWP(e2, bi2, e3, bi3)
  CSWP(e0, bi0, e1, bi1) CSWP(e1, bi1, e2, bi2)
  CSWP(e0, bi0, e1, bi1)
#undef CSWP
  int* ib = idx + ((size_t)b * NPT + t) * 4;
  ib[0] = bi0; ib[1] = bi1; ib[2] = bi2; ib[3] = bi3;
}

// ------------------------------------------------------- kNN C=64/128 ----
// 512 threads: thread = (point p = t>>2, channel-quarter q = t&3).
// Quarters stored at stride CQ+4 so the 4 per-wave read bases hit distinct
// banks (128B spacing would alias to bank 0). Quarter dots combined via
// 2 DPP shfl_xor; all 4 lanes of a point run the identical top-6 insertion.
// fp64 rescore: per-quarter fp64 partials + butterfly (exact ordering).
template<int C>
__global__ __launch_bounds__(512) void knn512_kernel(const float* __restrict__ x,
                                                     int* __restrict__ idx) {
  constexpr int CQ = C / 4;       // channels per quarter
  constexpr int QS = CQ + 4;      // quarter stride in floats
  __shared__ __align__(16) float xs[NPT][4 * QS];
  __shared__ float x2s[NPT];
  __shared__ double x2d[NPT];
  const int b = blockIdx.x, t = threadIdx.x;
  const float* xb = x + (size_t)b * NPT * C;
  for (int e = t; e < NPT * C; e += 512) {
    int r = e / C, c = e % C;
    xs[r][(c / CQ) * QS + (c % CQ)] = xb[e];
  }
  __syncthreads();
  const int p = t >> 2, q = t & 3;
  float xi[CQ];
  float s2 = 0.f;
  double s2d = 0.0;
#pragma unroll
  for (int c = 0; c < CQ; ++c) {
    xi[c] = xs[p][q * QS + c];
    s2 += xi[c] * xi[c];
    s2d += (double)xi[c] * (double)xi[c];
  }
  s2 += __shfl_xor(s2, 1);  s2 += __shfl_xor(s2, 2);
  s2d += __shfl_xor(s2d, 1); s2d += __shfl_xor(s2d, 2);
  if (q == 0) { x2s[p] = s2; x2d[p] = s2d; }
  __syncthreads();
  float bd0 = 1e30f, bd1 = 1e30f, bd2 = 1e30f, bd3 = 1e30f, bd4 = 1e30f, bd5 = 1e30f;
  int bi0 = 0, bi1 = 0, bi2 = 0, bi3 = 0, bi4 = 0, bi5 = 0;
  for (int j = 0; j < NPT; ++j) {
    if (j == p) continue;
    const float4* xr = reinterpret_cast<const float4*>(&xs[j][q * QS]);
    float part0 = 0.f, part1 = 0.f, part2 = 0.f, part3 = 0.f;
#pragma unroll
    for (int c4 = 0; c4 < CQ / 4; ++c4) {
      float4 v = xr[c4];
      float s = xi[4 * c4 + 0] * v.x + xi[4 * c4 + 1] * v.y +
                xi[4 * c4 + 2] * v.z + xi[4 * c4 + 3] * v.w;
      if ((c4 & 3) == 0) part0 += s;
      else if ((c4 & 3) == 1) part1 += s;
      else if ((c4 & 3) == 2) part2 += s;
      else part3 += s;
    }
    float dot = (part0 + part1) + (part2 + part3);
    dot += __shfl_xor(dot, 1);
    dot += __shfl_xor(dot, 2);
    float d = s2 + x2s[j] - 2.0f * dot;
    if (d < bd5) {
      bd5 = d; bi5 = j;
      if (bd5 < bd4) {
        float td = bd4; bd4 = bd5; bd5 = td; int ti = bi4; bi4 = bi5; bi5 = ti;
        if (bd4 < bd3) {
          td = bd3; bd3 = bd4; bd4 = td; ti = bi3; bi3 = bi4; bi4 = ti;
          if (bd3 < bd2) {
            td = bd2; bd2 = bd3; bd3 = td; ti = bi2; bi2 = bi3; bi3 = ti;
            if (bd2 < bd1) {
              td = bd1; bd1 = bd2; bd2 = td; ti = bi1; bi1 = bi2; bi2 = ti;
              if (bd1 < bd0) {
                td = bd0; bd0 = bd1; bd1 = td; ti = bi0; bi0 = bi1; bi1 = ti;
              }
            }
          }
        }
      }
    }
  }
  auto refine = [&](int j) -> double {
    double dot = 0.0;
#pragma unroll
    for (int c = 0; c < CQ; ++c) dot += (double)xi[c] * (double)xs[j][q * QS + c];
    dot += __shfl_xor(dot, 1);
    dot += __shfl_xor(dot, 2);
    return s2d + x2d[j] - 2.0 * dot;
  };
  double e0 = refine(bi0), e1 = refine(bi1), e2 = refine(bi2);
  double e3 = refine(bi3), e4 = refine(bi4), e5 = refine(bi5);
#define CSWP(da, ia, db, ib)                                            \
  if ((da > db) || (da == db && ia > ib)) {                             \
    double _td = da; da = db; db = _td; int _ti = ia; ia = ib; ib = _ti; }
  CSWP(e0, bi0, e1, bi1) CSWP(e1, bi1, e2, bi2) CSWP(e2, bi2, e3, bi3)
  CSWP(e3, bi3, e4, bi4) CSWP(e4, bi4, e5, bi5)
  CSWP(e0, bi0, e1, bi1) CSWP(e1, bi1, e2, bi2) CSWP(e2, bi2, e3, bi3)
  CSWP(e3, bi3, e4, bi4)
  CSWP(e0, bi0, e1, bi1) CSWP(e1, bi1, e2, bi2) CSWP(e2, bi2, e3, bi3)
  CSWP(e0, bi0, e1, bi1) CSWP(e1, bi1, e2, bi2)
  CSWP(e0, bi0, e1, bi1)
#undef CSWP
  if (q == 0) {
    int* ib = idx + ((size_t)b * NPT + p) * 4;
    ib[0] = bi0; ib[1] = bi1; ib[2] = bi2; ib[3] = bi3;
  }
}

// ---------------------------------------------------------------- ec1 ----
__global__ __launch_bounds__(256) void ec1_kernel(
    const float* __restrict__ feat, const int* __restrict__ idx,
    const float* __restrict__ w1, const float* __restrict__ b1,
    const float* __restrict__ w2, const float* __restrict__ b2,
    float* __restrict__ out) {
  __shared__ __align__(16) float fs[NPT][6];
  __shared__ __align__(16) float w1s[10][32];
  __shared__ __align__(16) float w2s[32][68];
  __shared__ float hs[256][33];
  __shared__ float b1s[32], b2s[64];
  const int z = blockIdx.x, t = threadIdx.x;
  const int b = z >> 1, hh = z & 1;
  const float* fb = feat + (size_t)b * NPT * 5;
  for (int e = t; e < NPT * 5; e += 256) fs[e / 5][e % 5] = fb[e];
  for (int e = t; e < 320; e += 256) w1s[e / 32][e % 32] = w1[e];
  for (int e = t; e < 2048; e += 256) w2s[e >> 6][e & 63] = w2[e];
  if (t < 32) b1s[t] = b1[t];
  if (t >= 192) b2s[t - 192] = b2[t - 192];
  __syncthreads();
  {
    const int p = hh * 64 + (t >> 2);
    const int j = idx[(size_t)b * 512 + p * 4 + (t & 3)];
    float h[32];
#pragma unroll
    for (int o = 0; o < 32; ++o) h[o] = b1s[o];
#pragma unroll
    for (int c = 0; c < 10; ++c) {
      float in_c = (c < 5) ? fs[p][c] : (fs[j][c - 5] - fs[p][c - 5]);
      const float4* wr = reinterpret_cast<const float4*>(&w1s[c][0]);
#pragma unroll
      for (int o4 = 0; o4 < 8; ++o4) {
        float4 w = wr[o4];
        h[4 * o4 + 0] += in_c * w.x; h[4 * o4 + 1] += in_c * w.y;
        h[4 * o4 + 2] += in_c * w.z; h[4 * o4 + 3] += in_c * w.w;
      }
    }
#pragma unroll
    for (int o = 0; o < 32; ++o) hs[t][o] = elu_f(h[o]);
  }
  __syncthreads();
  {
    const int g = t >> 2, q = t & 3;
    const int o0 = q * 16;
    float acc[4][16];
#pragma unroll
    for (int m = 0; m < 16; ++m) {
      float bv = b2s[o0 + m];
#pragma unroll
      for (int i = 0; i < 4; ++i) acc[i][m] = bv;
    }
    for (int k = 0; k < 32; ++k) {
      float hk0 = hs[g * 4 + 0][k];
      float hk1 = hs[g * 4 + 1][k];
      float hk2 = hs[g * 4 + 2][k];
      float hk3 = hs[g * 4 + 3][k];
      const float4* wr = reinterpret_cast<const float4*>(&w2s[k][o0]);
#pragma unroll
      for (int m4 = 0; m4 < 4; ++m4) {
        float4 w = wr[m4];
        acc[0][4 * m4 + 0] += hk0 * w.x; acc[0][4 * m4 + 1] += hk0 * w.y;
        acc[0][4 * m4 + 2] += hk0 * w.z; acc[0][4 * m4 + 3] += hk0 * w.w;
        acc[1][4 * m4 + 0] += hk1 * w.x; acc[1][4 * m4 + 1] += hk1 * w.y;
        acc[1][4 * m4 + 2] += hk1 * w.z; acc[1][4 * m4 + 3] += hk1 * w.w;
        acc[2][4 * m4 + 0] += hk2 * w.x; acc[2][4 * m4 + 1] += hk2 * w.y;
        acc[2][4 * m4 + 2] += hk2 * w.z; acc[2][4 * m4 + 3] += hk2 * w.w;
        acc[3][4 * m4 + 0] += hk3 * w.x; acc[3][4 * m4 + 1] += hk3 * w.y;
        acc[3][4 * m4 + 2] += hk3 * w.z; acc[3][4 * m4 + 3] += hk3 * w.w;
      }
    }
    float* ob = out + ((size_t)b * NPT + hh * 64 + g) * 64 + o0;
#pragma unroll
    for (int m4 = 0; m4 < 4; ++m4) {
      float4 v;
      float* vp = &v.x;
#pragma unroll
      for (int s = 0; s < 4; ++s) {
        int m = 4 * m4 + s;
        vp[s] = 0.25f * (elu_f(acc[0][m]) + elu_f(acc[1][m]) +
                         elu_f(acc[2][m]) + elu_f(acc[3][m]));
      }
      *reinterpret_cast<float4*>(&ob[4 * m4]) = v;
    }
  }
}

// ---------------------------------------------------------------- ec2a ----
__global__ __launch_bounds__(512, 2) void ec2a_kernel(
    const float* __restrict__ x, const int* __restrict__ idx,
    const float* __restrict__ w1, const float* __restrict__ b1,
    float* __restrict__ H) {
  __shared__ __align__(16) float xs[NPT][68];
  __shared__ __align__(16) float w1s[128][100];
  __shared__ float b1s[96];
  const int b = blockIdx.x, t = threadIdx.x;
  const float* xb = x + (size_t)b * NPT * 64;
  for (int e = t; e < NPT * 64; e += 512) xs[e >> 6][e & 63] = xb[e];
  for (int e = t; e < 128 * 96; e += 512) w1s[e / 96][e % 96] = w1[e];
  if (t < 96) b1s[t] = b1[t];
  __syncthreads();
  const int pb = t >> 2, part = t & 3;
  const int n0 = part * 24;
  int jn[4];
#pragma unroll
  for (int i = 0; i < 4; ++i) jn[i] = idx[(size_t)b * 512 + pb * 4 + i];
  float acc[4][24];
#pragma unroll
  for (int m = 0; m < 24; ++m) {
    float bv = b1s[n0 + m];
#pragma unroll
    for (int i = 0; i < 4; ++i) acc[i][m] = bv;
  }
  for (int c = 0; c < 64; ++c) {
    float in_c = xs[pb][c];
    const float4* wr = reinterpret_cast<const float4*>(&w1s[c][n0]);
#pragma unroll
    for (int q4 = 0; q4 < 6; ++q4) {
      float4 wv = wr[q4];
#pragma unroll
      for (int i = 0; i < 4; ++i) {
        acc[i][4 * q4 + 0] += in_c * wv.x;
        acc[i][4 * q4 + 1] += in_c * wv.y;
        acc[i][4 * q4 + 2] += in_c * wv.z;
        acc[i][4 * q4 + 3] += in_c * wv.w;
      }
    }
  }
  for (int c = 0; c < 64; ++c) {
    float xic = xs[pb][c];
    float in0 = xs[jn[0]][c] - xic;
    float in1 = xs[jn[1]][c] - xic;
    float in2 = xs[jn[2]][c] - xic;
    float in3 = xs[jn[3]][c] - xic;
    const float4* wr = reinterpret_cast<const float4*>(&w1s[64 + c][n0]);
#pragma unroll
    for (int q4 = 0; q4 < 6; ++q4) {
      float4 wv = wr[q4];
      acc[0][4 * q4 + 0] += in0 * wv.x; acc[0][4 * q4 + 1] += in0 * wv.y;
      acc[0][4 * q4 + 2] += in0 * wv.z; acc[0][4 * q4 + 3] += in0 * wv.w;
      acc[1][4 * q4 + 0] += in1 * wv.x; acc[1][4 * q4 + 1] += in1 * wv.y;
      acc[1][4 * q4 + 2] += in1 * wv.z; acc[1][4 * q4 + 3] += in1 * wv.w;
      acc[2][4 * q4 + 0] += in2 * wv.x; acc[2][4 * q4 + 1] += in2 * wv.y;
      acc[2][4 * q4 + 2] += in2 * wv.z; acc[2][4 * q4 + 3] += in2 * wv.w;
      acc[3][4 * q4 + 0] += in3 * wv.x; acc[3][4 * q4 + 1] += in3 * wv.y;
      acc[3][4 * q4 + 2] += in3 * wv.z; acc[3][4 * q4 + 3] += in3 * wv.w;
    }
  }
#pragma unroll
  for (int i = 0; i < 4; ++i) {
    float* hrow = H + ((size_t)b * 512 + pb * 4 + i) * 96 + n0;
#pragma unroll
    for (int q4 = 0; q4 < 6; ++q4) {
      float4 v = {elu_f(acc[i][4 * q4 + 0]), elu_f(acc[i][4 * q4 + 1]),
                  elu_f(acc[i][4 * q4 + 2]), elu_f(acc[i][4 * q4 + 3])};
      *reinterpret_cast<float4*>(&hrow[4 * q4]) = v;
    }
  }
}

// ---------------------------------------------------------------- ec2b ----
__global__ __launch_bounds__(512, 2) void ec2b_kernel(
    const float* __restrict__ H, const float* __restrict__ w2,
    const float* __restrict__ b2, float* __restrict__ out) {
  __shared__ __align__(16) float hsT[96][260];
  __shared__ float w2s[96][132];
  __shared__ float b2s[128];
  const int z = blockIdx.x, t = threadIdx.x;
  const int bc = z >> 1, hh = z & 1;
  const float* Hb = H + ((size_t)bc * 512 + hh * 256) * 96;
  for (int i = t; i < 256 * 96; i += 512) hsT[i % 96][i / 96] = Hb[i];
  for (int i = t; i < 96 * 128; i += 512) w2s[i >> 7][i & 127] = w2[i];
  if (t < 128) b2s[t] = b2[t];
  __syncthreads();
  const int g = t >> 3, oq = t & 7;
  float acc[4][16];
#pragma unroll
  for (int m = 0; m < 16; ++m) {
    float bv = b2s[oq + 8 * m];
#pragma unroll
    for (int i = 0; i < 4; ++i) acc[i][m] = bv;
  }
  for (int k = 0; k < 96; ++k) {
    float4 hv = *reinterpret_cast<const float4*>(&hsT[k][4 * g]);
#pragma unroll
    for (int m = 0; m < 16; ++m) {
      float wv = w2s[k][oq + 8 * m];
      acc[0][m] += hv.x * wv;
      acc[1][m] += hv.y * wv;
      acc[2][m] += hv.z * wv;
      acc[3][m] += hv.w * wv;
    }
  }
  float* orow = out + ((size_t)bc * NPT + hh * 64 + g) * 128;
#pragma unroll
  for (int m = 0; m < 16; ++m) {
    float s = elu_f(acc[0][m]) + elu_f(acc[1][m]) +
              elu_f(acc[2][m]) + elu_f(acc[3][m]);
    orow[oq + 8 * m] = 0.25f * s;
  }
}

// ---------------------------------------------------------------- ec3a ----
__global__ __launch_bounds__(512, 2) void ec3a_kernel(
    const float* __restrict__ x, const int* __restrict__ idx,
    const float* __restrict__ w1, const float* __restrict__ b1,
    unsigned short* __restrict__ h1) {
  __shared__ unsigned short Xb[128][136];
  __shared__ unsigned short W1t[192][264];
  __shared__ float b1s[192];
  __shared__ unsigned short stg[8][16][40];
  const int b = blockIdx.x, t = threadIdx.x;
  const float* xb = x + (size_t)b * NPT * 128;
  for (int e = t; e < NPT * 128; e += 512) Xb[e >> 7][e & 127] = f2bf(xb[e]);
  for (int e = t; e < 256 * 192; e += 512) {
    int k = e / 192, n = e % 192;
    W1t[n][k] = f2bf(w1[e]);
  }
  if (t < 192) b1s[t] = b1[t];
  __syncthreads();
  const int w = t >> 6, l = t & 63;
  const int lr = l & 15, lq = l >> 4;
  for (int mt = 0; mt < 4; ++mt) {
    const int m = (w * 4 + mt) * 16;
    const int e = m + lr;
    const int p = e >> 2;
    const int jp = idx[(size_t)b * 512 + e];
    short8 A[8];
#pragma unroll
    for (int kk = 0; kk < 4; ++kk) {
      int k0 = kk * 32 + lq * 8;
      A[kk] = *reinterpret_cast<const short8*>(&Xb[p][k0]);
    }
#pragma unroll
    for (int kk = 0; kk < 4; ++kk) {
      int k0 = kk * 32 + lq * 8;
      short8 aj = *reinterpret_cast<const short8*>(&Xb[jp][k0]);
      short8 ai = *reinterpret_cast<const short8*>(&Xb[p][k0]);
      short8 d;
#pragma unroll
      for (int q = 0; q < 8; ++q)
        d[q] = (short)f2bf(bf2f((unsigned short)aj[q]) - bf2f((unsigned short)ai[q]));
      A[4 + kk] = d;
    }
    floatx4 acc[12];
#pragma unroll
    for (int n = 0; n < 12; ++n) acc[n] = (floatx4){0.f, 0.f, 0.f, 0.f};
#pragma unroll
    for (int n = 0; n < 12; ++n) {
#pragma unroll
      for (int kk = 0; kk < 8; ++kk) {
        short8 Bf = *reinterpret_cast<const short8*>(&W1t[n * 16 + lr][kk * 32 + lq * 8]);
        acc[n] = __builtin_amdgcn_mfma_f32_16x16x32_bf16(A[kk], Bf, acc[n], 0, 0, 0);
      }
    }
#pragma unroll
    for (int pr = 0; pr < 6; ++pr) {
      float bv0 = b1s[pr * 32 + lr];
      float bv1 = b1s[pr * 32 + 16 + lr];
#pragma unroll
      for (int i = 0; i < 4; ++i) {
        stg[w][lq * 4 + i][lr]      = f2bf(elu_f(acc[2 * pr][i] + bv0));
        stg[w][lq * 4 + i][16 + lr] = f2bf(elu_f(acc[2 * pr + 1][i] + bv1));
      }
      asm volatile("s_waitcnt lgkmcnt(0)" ::: "memory");
      const unsigned short* src = &stg[w][l >> 2][(l & 3) * 8];
      uint4v vv = *reinterpret_cast<const uint4v*>(src);
      size_t dst = ((size_t)b * 512 + m + (l >> 2)) * 192 + pr * 32 + (l & 3) * 8;
      *reinterpret_cast<uint4v*>(&h1[dst]) = vv;
      asm volatile("s_waitcnt lgkmcnt(0)" ::: "memory");
    }
  }
}

// ---------------------------------------------------------------- ec3b ----
__global__ __launch_bounds__(512, 2) void ec3b_kernel(
    const unsigned short* __restrict__ h1,
    const float* __restrict__ w2, const float* __restrict__ b2,
    unsigned short* __restrict__ out3) {
  __shared__ unsigned short W2t[256][200];
  __shared__ float b2s[256];
  const int b = blockIdx.x, t = threadIdx.x;
  for (int e = t; e < 192 * 256; e += 512) {
    int k = e >> 8, n = e & 255;
    W2t[n][k] = f2bf(w2[e]);
  }
  if (t < 256) b2s[t] = b2[t];
  __syncthreads();
  const int w = t >> 6, l = t & 63;
  const int lr = l & 15, lq = l >> 4;
  for (int mt = 0; mt < 4; ++mt) {
    const int m = (w * 4 + mt) * 16;
    floatx4 acc[16];
#pragma unroll
    for (int n = 0; n < 16; ++n) acc[n] = (floatx4){0.f, 0.f, 0.f, 0.f};
    const unsigned short* arow = h1 + ((size_t)b * 512 + m + lr) * 192;
#pragma unroll
    for (int kk = 0; kk < 6; ++kk) {
      short8 Af = *reinterpret_cast<const short8*>(&arow[kk * 32 + lq * 8]);
#pragma unroll
      for (int n = 0; n < 16; ++n) {
        short8 Bf = *reinterpret_cast<const short8*>(&W2t[n * 16 + lr][kk * 32 + lq * 8]);
        acc[n] = __builtin_amdgcn_mfma_f32_16x16x32_bf16(Af, Bf, acc[n], 0, 0, 0);
      }
    }
    unsigned short* orow = out3 + ((size_t)b * NPT + (m >> 2) + lq) * 256;
#pragma unroll
    for (int n = 0; n < 16; ++n) {
      float bv = b2s[n * 16 + lr];
      float s = 0.f;
#pragma unroll
      for (int i = 0; i < 4; ++i) s += elu_f(acc[n][i] + bv);
      orow[n * 16 + lr] = f2bf(0.25f * s);
    }
  }
}

// ------------------------------------------------------------ head prep ----
__global__ __launch_bounds__(256) void head_prep_kernel(
    const float* __restrict__ w1, const float* __restrict__ w2,
    unsigned short* __restrict__ w1p, unsigned short* __restrict__ w2p) {
  int i = blockIdx.x * 256 + threadIdx.x;
  if (i < 512 * 480) {
    int n = i / 480, kp = i % 480;
    int ko = (kp < 5) ? kp : kp - 3;
    bool ok = ((kp < 5) || (kp >= 8 && kp < 456)) && (n < 453);
    w1p[i] = ok ? f2bf(w1[(size_t)ko * 453 + n]) : (unsigned short)0;
  } else {
    int j = i - 512 * 480;
    if (j < 256 * 480) {
      int n = j / 480, kp = j % 480;
      bool ok = (kp < 453) && (n < 226);
      w2p[j] = ok ? f2bf(w2[(size_t)kp * 226 + n]) : (unsigned short)0;
    }
  }
}

// ----------------------------------------------------------- head MFMA ----
#define HSTR 488
__global__ __launch_bounds__(256) void head_mfma_kernel(
    const float* __restrict__ feat, const float* __restrict__ o1,
    const float* __restrict__ o2, const unsigned short* __restrict__ o3,
    const unsigned short* __restrict__ w1p, const float* __restrict__ b1,
    const unsigned short* __restrict__ w2p, const float* __restrict__ b2,
    const float* __restrict__ w3, const float* __restrict__ b3,
    float* __restrict__ out) {
  __shared__ unsigned short uA[64 * HSTR];
  __shared__ unsigned short uH[64 * HSTR];
  __shared__ float b1s[512], b2s[256], w3s[512];
  const int t = threadIdx.x;
  const size_t base = (size_t)blockIdx.x * 64;

  for (int e = t; e < 64 * 8; e += 256) {
    int r = e >> 3, c = e & 7;
    uA[r * HSTR + c] = (c < 5) ? f2bf(feat[(base + r) * 5 + c]) : 0;
  }
  for (int e = t; e < 64 * 64; e += 256) {
    int r = e >> 6, c = e & 63;
    uA[r * HSTR + 8 + c] = f2bf(o1[(base + r) * 64 + c]);
  }
  for (int e = t; e < 64 * 128; e += 256) {
    int r = e >> 7, c = e & 127;
    uA[r * HSTR + 72 + c] = f2bf(o2[(base + r) * 128 + c]);
  }
  for (int e = t; e < 64 * 256; e += 256) {
    int r = e >> 8, c = e & 255;
    uA[r * HSTR + 200 + c] = o3[(base + r) * 256 + c];
  }
  for (int e = t; e < 64 * 32; e += 256) {
    int r = e >> 5, c = e & 31;
    uA[r * HSTR + 456 + c] = 0;
  }
  for (int i = t; i < 512; i += 256) b1s[i] = (i < 453) ? b1[i] : 0.f;
  if (t < 256) b2s[t] = (t < 226) ? b2[t] : 0.f;
  for (int i = t; i < 512; i += 256) w3s[i] = (i < 452) ? w3[i] : 0.f;
  __syncthreads();

  const int w = t >> 6, l = t & 63;
  const int lr = l & 15, lq = l >> 4;
  const int tr = t >> 2, tc = t & 3;

  short8 Af[15];
#pragma unroll
  for (int kk = 0; kk < 15; ++kk)
    Af[kk] = *reinterpret_cast<const short8*>(
        &uA[(w * 16 + lr) * HSTR + kk * 32 + lq * 8]);
  __syncthreads();

  uint4v v[15];
#define WLOAD(SRC, CH)                                                   \
  {                                                                      \
    _Pragma("unroll")                                                    \
    for (int i = 0; i < 15; ++i)                                         \
      v[i] = *reinterpret_cast<const uint4v*>(                           \
          &SRC[((size_t)((CH) * 64 + tr)) * 480 + (tc + 4 * i) * 8]);    \
  }
#define WWRITE()                                                         \
  {                                                                      \
    _Pragma("unroll")                                                    \
    for (int i = 0; i < 15; ++i)                                         \
      *reinterpret_cast<uint4v*>(&uA[tr * HSTR + (tc + 4 * i) * 8]) = v[i]; \
  }

  WLOAD(w1p, 0)
  WWRITE()
  __syncthreads();

  for (int ch = 0; ch < 8; ++ch) {
    if (ch < 7) WLOAD(w1p, ch + 1)
    floatx4 a0 = {0.f, 0.f, 0.f, 0.f}, a1 = {0.f, 0.f, 0.f, 0.f};
    floatx4 a2 = {0.f, 0.f, 0.f, 0.f}, a3 = {0.f, 0.f, 0.f, 0.f};
#pragma unroll
    for (int kk = 0; kk < 15; ++kk) {
      int ko = kk * 32 + lq * 8;
      short8 B0 = *reinterpret_cast<const short8*>(&uA[(lr)*HSTR + ko]);
      short8 B1 = *reinterpret_cast<const short8*>(&uA[(16 + lr) * HSTR + ko]);
      short8 B2 = *reinterpret_cast<const short8*>(&uA[(32 + lr) * HSTR + ko]);
      short8 B3 = *reinterpret_cast<const short8*>(&uA[(48 + lr) * HSTR + ko]);
      a0 = __builtin_amdgcn_mfma_f32_16x16x32_bf16(Af[kk], B0, a0, 0, 0, 0);
      a1 = __builtin_amdgcn_mfma_f32_16x16x32_bf16(Af[kk], B1, a1, 0, 0, 0);
      a2 = __builtin_amdgcn_mfma_f32_16x16x32_bf16(Af[kk], B2, a2, 0, 0, 0);
      a3 = __builtin_amdgcn_mfma_f32_16x16x32_bf16(Af[kk], B3, a3, 0, 0, 0);
    }
    {
      floatx4 aj[4] = {a0, a1, a2, a3};
#pragma unroll
      for (int jx = 0; jx < 4; ++jx) {
        int c = ch * 64 + jx * 16 + lr;
        if (c < 480) {
          float bb = b1s[c];
#pragma unroll
          for (int i = 0; i < 4; ++i) {
            int row = w * 16 + lq * 4 + i;
            uH[row * HSTR + c] =
                (c < 453) ? f2bf(elu_f(aj[jx][i] + bb)) : (unsigned short)0;
          }
        }
      }
    }
    __syncthreads();
    if (ch < 7) WWRITE()
    __syncthreads();
  }

#pragma unroll
  for (int kk = 0; kk < 15; ++kk)
    Af[kk] = *reinterpret_cast<const short8*>(
        &uH[(w * 16 + lr) * HSTR + kk * 32 + lq * 8]);
  WLOAD(w2p, 0)
  WWRITE()
  __syncthreads();

  float p0[4] = {0.f, 0.f, 0.f, 0.f}, p1[4] = {0.f, 0.f, 0.f, 0.f};
  for (int ch = 0; ch < 4; ++ch) {
    if (ch < 3) WLOAD(w2p, ch + 1)
    floatx4 a0 = {0.f, 0.f, 0.f, 0.f}, a1 = {0.f, 0.f, 0.f, 0.f};
    floatx4 a2 = {0.f, 0.f, 0.f, 0.f}, a3 = {0.f, 0.f, 0.f, 0.f};
#pragma unroll
    for (int kk = 0; kk < 15; ++kk) {
      int ko = kk * 32 + lq * 8;
      short8 B0 = *reinterpret_cast<const short8*>(&uA[(lr)*HSTR + ko]);
      short8 B1 = *reinterpret_cast<const short8*>(&uA[(16 + lr) * HSTR + ko]);
      short8 B2 = *reinterpret_cast<const short8*>(&uA[(32 + lr) * HSTR + ko]);
      short8 B3 = *reinterpret_cast<const short8*>(&uA[(48 + lr) * HSTR + ko]);
      a0 = __builtin_amdgcn_mfma_f32_16x16x32_bf16(Af[kk], B0, a0, 0, 0, 0);
      a1 = __builtin_amdgcn_mfma_f32_16x16x32_bf16(Af[kk], B1, a1, 0, 0, 0);
      a2 = __builtin_amdgcn_mfma_f32_16x16x32_bf16(Af[kk], B2, a2, 0, 0, 0);
      a3 = __builtin_amdgcn_mfma_f32_16x16x32_bf16(Af[kk], B3, a3, 0, 0, 0);
    }
    {
      floatx4 aj[4] = {a0, a1, a2, a3};
#pragma unroll
      for (int jx = 0; jx < 4; ++jx) {
        int c = ch * 64 + jx * 16 + lr;
        float bb = b2s[c];
        float wa = w3s[2 * c], wb = w3s[2 * c + 1];
#pragma unroll
        for (int i = 0; i < 4; ++i) {
          float h = (c < 226) ? elu_f(aj[jx][i] + bb) : 0.f;
          p0[i] += h * wa;
          p1[i] += h * wb;
        }
      }
    }
    __syncthreads();
    if (ch < 3) WWRITE()
    __syncthreads();
  }

#pragma unroll
  for (int i = 0; i < 4; ++i) {
    float a = p0[i], bvv = p1[i];
#pragma unroll
    for (int m = 1; m < 16; m <<= 1) {
      a += __shfl_xor(a, m);
      bvv += __shfl_xor(bvv, m);
    }
    if (lr == 0) {
      size_t row = base + w * 16 + lq * 4 + i;
      float2 vv = {a + b3[0], bvv + b3[1]};
      *reinterpret_cast<float2*>(&out[row * 2]) = vv;
    }
  }
#undef WLOAD
#undef WWRITE
}

// ------------------------------------------------------------- launch ----
extern "C" void kernel_launch(void* const* d_in, const int* in_sizes, int n_in,
                              void* d_out, int out_size, void* d_ws, size_t ws_size,
                              hipStream_t stream) {
  const float* coords = (const float*)d_in[0];
  const float* feat   = (const float*)d_in[1];
  const float* c1w1 = (const float*)d_in[2];  const float* c1b1 = (const float*)d_in[3];
  const float* c1w2 = (const float*)d_in[4];  const float* c1b2 = (const float*)d_in[5];
  const float* c2w1 = (const float*)d_in[6];  const float* c2b1 = (const float*)d_in[7];
  const float* c2w2 = (const float*)d_in[8];  const float* c2b2 = (const float*)d_in[9];
  const float* c3w1 = (const float*)d_in[10]; const float* c3b1 = (const float*)d_in[11];
  const float* c3w2 = (const float*)d_in[12]; const float* c3b2 = (const float*)d_in[13];
  const float* ow1  = (const float*)d_in[14]; const float* ob1  = (const float*)d_in[15];
  const float* ow2  = (const float*)d_in[16]; const float* ob2  = (const float*)d_in[17];
  const float* ow3  = (const float*)d_in[18]; const float* ob3  = (const float*)d_in[19];
  float* out = (float*)d_out;

  char* ws = (char*)d_ws;
  float* out1 = (float*)(ws);
  float* out2 = (float*)(ws + (32ull << 20));
  unsigned short* out3b = (unsigned short*)(ws + (96ull << 20));
  int* idx = (int*)(ws + (160ull << 20));
  float* Hbuf = (float*)(ws + (162ull << 20));
  unsigned short* h1 = (unsigned short*)(ws + (162ull << 20));
  unsigned short* w1p = (unsigned short*)(ws + (212ull << 20));
  unsigned short* w2p = (unsigned short*)(ws + (213ull << 20));

  head_prep_kernel<<<1440, 256, 0, stream>>>(ow1, ow2, w1p, w2p);
  knn_kernel<2><<<NB, 128, 0, stream>>>(coords, idx);
  ec1_kernel<<<2 * NB, 256, 0, stream>>>(feat, idx, c1w1, c1b1, c1w2, c1b2, out1);
  knn512_kernel<64><<<NB, 512, 0, stream>>>(out1, idx);
  for (int c = 0; c < 4; ++c) {
    ec2a_kernel<<<256, 512, 0, stream>>>(out1 + (size_t)c * 256 * NPT * 64,
                                         idx + (size_t)c * 256 * 512,
                                         c2w1, c2b1, Hbuf);
    ec2b_kernel<<<512, 512, 0, stream>>>(Hbuf, c2w2, c2b2,
                                         out2 + (size_t)c * 256 * NPT * 128);
  }
  knn512_kernel<128><<<NB, 512, 0, stream>>>(out2, idx);
  for (int c = 0; c < 4; ++c) {
    ec3a_kernel<<<256, 512, 0, stream>>>(out2 + (size_t)c * 256 * NPT * 128,
                                         idx + (size_t)c * 256 * 512,
                                         c3w1, c3b1, h1);
    ec3b_kernel<<<256, 512, 0, stream>>>(h1, c3w2, c3b2,
                                         out3b + (size_t)c * 256 * NPT * 256);
  }
  head_mfma_kernel<<<2048, 256, 0, stream>>>(feat, out1, out2, out3b,
                                             w1p, ob1, w2p, ob2, ow3, ob3, out);
}

// Round 10
// 2001.781 us; speedup vs baseline: 20.5834x; 1.0684x over previous
//
#include <hip/hip_runtime.h>
#include <cstdint>
#include <cstddef>

// ParticleNet MI355X — Round 10.
// - kNN C=2 (r2) / C=64,128 quarter-split (r9): verified.
// - ec1/ec2/ec3: verified (r7/r4/r3).
// - head v3: uH eliminated via per-wave tps transpose scratch (Af2 built
//   incrementally in registers during GEMM1). LDS 130->77 KB => 2 blocks/CU
//   (r9 version ran at 1 wave/SIMD: MfmaUtil 8.4%, all latency exposed).

#define NB 1024
#define NPT 128

typedef __attribute__((ext_vector_type(8))) short short8;
typedef __attribute__((ext_vector_type(4))) float floatx4;
typedef __attribute__((ext_vector_type(4))) unsigned int uint4v;

__device__ __forceinline__ float elu_f(float x) { return x > 0.0f ? x : expm1f(x); }

__device__ __forceinline__ unsigned short f2bf(float f) {
  unsigned u = __builtin_bit_cast(unsigned, f);
  unsigned r = u + 0x7FFFu + ((u >> 16) & 1u);
  return (unsigned short)(r >> 16);
}
__device__ __forceinline__ float bf2f(unsigned short h) {
  unsigned u = ((unsigned)h) << 16;
  return __builtin_bit_cast(float, u);
}

// ------------------------------------------------------------- kNN C=2 ----
template<int C>
__global__ __launch_bounds__(128) void knn_kernel(const float* __restrict__ x,
                                                  int* __restrict__ idx) {
  __shared__ __align__(16) float xs[NPT][C + 4];
  __shared__ float x2s[NPT];
  __shared__ double x2d[NPT];
  const int b = blockIdx.x, t = threadIdx.x;
  const float* xb = x + (size_t)b * NPT * C;
  for (int e = t; e < NPT * C; e += 128) xs[e / C][e % C] = xb[e];
  __syncthreads();
  float xi[C];
  float s2 = 0.0f;
  double s2d = 0.0;
#pragma unroll
  for (int c = 0; c < C; ++c) {
    xi[c] = xs[t][c];
    s2 += xi[c] * xi[c];
    s2d += (double)xi[c] * (double)xi[c];
  }
  x2s[t] = s2;
  x2d[t] = s2d;
  __syncthreads();
  float bd0 = 1e30f, bd1 = 1e30f, bd2 = 1e30f, bd3 = 1e30f, bd4 = 1e30f, bd5 = 1e30f;
  int bi0 = 0, bi1 = 0, bi2 = 0, bi3 = 0, bi4 = 0, bi5 = 0;
  for (int j = 0; j < NPT; ++j) {
    if (j == t) continue;
    float dot = 0.0f;
#pragma unroll
    for (int c = 0; c < C; ++c) dot += xi[c] * xs[j][c];
    float d = s2 + x2s[j] - 2.0f * dot;
    if (d < bd5) {
      bd5 = d; bi5 = j;
      if (bd5 < bd4) {
        float td = bd4; bd4 = bd5; bd5 = td; int ti = bi4; bi4 = bi5; bi5 = ti;
        if (bd4 < bd3) {
          td = bd3; bd3 = bd4; bd4 = td; ti = bi3; bi3 = bi4; bi4 = ti;
          if (bd3 < bd2) {
            td = bd2; bd2 = bd3; bd3 = td; ti = bi2; bi2 = bi3; bi3 = ti;
            if (bd2 < bd1) {
              td = bd1; bd1 = bd2; bd2 = td; ti = bi1; bi1 = bi2; bi2 = ti;
              if (bd1 < bd0) {
                td = bd0; bd0 = bd1; bd1 = td; ti = bi0; bi0 = bi1; bi1 = ti;
              }
            }
          }
        }
      }
    }
  }
  auto refine = [&](int j) -> double {
    double dot = 0.0;
#pragma unroll
    for (int c = 0; c < C; ++c) dot += (double)xi[c] * (double)xs[j][c];
    return s2d + x2d[j] - 2.0 * dot;
  };
  double e0 = refine(bi0), e1 = refine(bi1), e2 = refine(bi2);
  double e3 = refine(bi3), e4 = refine(bi4), e5 = refine(bi5);
#define CSWP(da, ia, db, ib)                                            \
  if ((da > db) || (da == db && ia > ib)) {                             \
    double _td = da; da = db; db = _td; int _ti = ia; ia = ib; ib = _ti; }
  CSWP(e0, bi0, e1, bi1) CSWP(e1, bi1, e2, bi2) CSWP(e2, bi2, e3, bi3)
  CSWP(e3, bi3, e4, bi4) CSWP(e4, bi4, e5, bi5)
  CSWP(e0, bi0, e1, bi1) CSWP(e1, bi1, e2, bi2) CSWP(e2, bi2, e3, bi3)
  CSWP(e3, bi3, e4, bi4)
  CSWP(e0, bi0, e1, bi1) CSWP(e1, bi1, e2, bi2) CSWP(e2, bi2, e3, bi3)
  CSWP(e0, bi0, e1, bi1) CSWP(e1, bi1, e2, bi2)
  CSWP(e0, bi0, e1, bi1)
#undef CSWP
  int* ib = idx + ((size_t)b * NPT + t) * 4;
  ib[0] = bi0; ib[1] = bi1; ib[2] = bi2; ib[3] = bi3;
}

// ------------------------------------------------------- kNN C=64/128 ----
template<int C>
__global__ __launch_bounds__(512) void knn512_kernel(const float* __restrict__ x,
                                                     int* __restrict__ idx) {
  constexpr int CQ = C / 4;
  constexpr int QS = CQ + 4;
  __shared__ __align__(16) float xs[NPT][4 * QS];
  __shared__ float x2s[NPT];
  __shared__ double x2d[NPT];
  const int b = blockIdx.x, t = threadIdx.x;
  const float* xb = x + (size_t)b * NPT * C;
  for (int e = t; e < NPT * C; e += 512) {
    int r = e / C, c = e % C;
    xs[r][(c / CQ) * QS + (c % CQ)] = xb[e];
  }
  __syncthreads();
  const int p = t >> 2, q = t & 3;
  float xi[CQ];
  float s2 = 0.f;
  double s2d = 0.0;
#pragma unroll
  for (int c = 0; c < CQ; ++c) {
    xi[c] = xs[p][q * QS + c];
    s2 += xi[c] * xi[c];
    s2d += (double)xi[c] * (double)xi[c];
  }
  s2 += __shfl_xor(s2, 1);  s2 += __shfl_xor(s2, 2);
  s2d += __shfl_xor(s2d, 1); s2d += __shfl_xor(s2d, 2);
  if (q == 0) { x2s[p] = s2; x2d[p] = s2d; }
  __syncthreads();
  float bd0 = 1e30f, bd1 = 1e30f, bd2 = 1e30f, bd3 = 1e30f, bd4 = 1e30f, bd5 = 1e30f;
  int bi0 = 0, bi1 = 0, bi2 = 0, bi3 = 0, bi4 = 0, bi5 = 0;
  for (int j = 0; j < NPT; ++j) {
    if (j == p) continue;
    const float4* xr = reinterpret_cast<const float4*>(&xs[j][q * QS]);
    float part0 = 0.f, part1 = 0.f, part2 = 0.f, part3 = 0.f;
#pragma unroll
    for (int c4 = 0; c4 < CQ / 4; ++c4) {
      float4 v = xr[c4];
      float s = xi[4 * c4 + 0] * v.x + xi[4 * c4 + 1] * v.y +
                xi[4 * c4 + 2] * v.z + xi[4 * c4 + 3] * v.w;
      if ((c4 & 3) == 0) part0 += s;
      else if ((c4 & 3) == 1) part1 += s;
      else if ((c4 & 3) == 2) part2 += s;
      else part3 += s;
    }
    float dot = (part0 + part1) + (part2 + part3);
    dot += __shfl_xor(dot, 1);
    dot += __shfl_xor(dot, 2);
    float d = s2 + x2s[j] - 2.0f * dot;
    if (d < bd5) {
      bd5 = d; bi5 = j;
      if (bd5 < bd4) {
        float td = bd4; bd4 = bd5; bd5 = td; int ti = bi4; bi4 = bi5; bi5 = ti;
        if (bd4 < bd3) {
          td = bd3; bd3 = bd4; bd4 = td; ti = bi3; bi3 = bi4; bi4 = ti;
          if (bd3 < bd2) {
            td = bd2; bd2 = bd3; bd3 = td; ti = bi2; bi2 = bi3; bi3 = ti;
            if (bd2 < bd1) {
              td = bd1; bd1 = bd2; bd2 = td; ti = bi1; bi1 = bi2; bi2 = ti;
              if (bd1 < bd0) {
                td = bd0; bd0 = bd1; bd1 = td; ti = bi0; bi0 = bi1; bi1 = ti;
              }
            }
          }
        }
      }
    }
  }
  auto refine = [&](int j) -> double {
    double dot = 0.0;
#pragma unroll
    for (int c = 0; c < CQ; ++c) dot += (double)xi[c] * (double)xs[j][q * QS + c];
    dot += __shfl_xor(dot, 1);
    dot += __shfl_xor(dot, 2);
    return s2d + x2d[j] - 2.0 * dot;
  };
  double e0 = refine(bi0), e1 = refine(bi1), e2 = refine(bi2);
  double e3 = refine(bi3), e4 = refine(bi4), e5 = refine(bi5);
#define CSWP(da, ia, db, ib)                                            \
  if ((da > db) || (da == db && ia > ib)) {                             \
    double _td = da; da = db; db = _td; int _ti = ia; ia = ib; ib = _ti; }
  CSWP(e0, bi0, e1, bi1) CSWP(e1, bi1, e2, bi2) CSWP(e2, bi2, e3, bi3)
  CSWP(e3, bi3, e4, bi4) CSWP(e4, bi4, e5, bi5)
  CSWP(e0, bi0, e1, bi1) CSWP(e1, bi1, e2, bi2) CSWP(e2, bi2, e3, bi3)
  CSWP(e3, bi3, e4, bi4)
  CSWP(e0, bi0, e1, bi1) CSWP(e1, bi1, e2, bi2) CSWP(e2, bi2, e3, bi3)
  CSWP(e0, bi0, e1, bi1) CSWP(e1, bi1, e2, bi2)
  CSWP(e0, bi0, e1, bi1)
#undef CSWP
  if (q == 0) {
    int* ib = idx + ((size_t)b * NPT + p) * 4;
    ib[0] = bi0; ib[1] = bi1; ib[2] = bi2; ib[3] = bi3;
  }
}

// ---------------------------------------------------------------- ec1 ----
__global__ __launch_bounds__(256) void ec1_kernel(
    const float* __restrict__ feat, const int* __restrict__ idx,
    const float* __restrict__ w1, const float* __restrict__ b1,
    const float* __restrict__ w2, const float* __restrict__ b2,
    float* __restrict__ out) {
  __shared__ __align__(16) float fs[NPT][6];
  __shared__ __align__(16) float w1s[10][32];
  __shared__ __align__(16) float w2s[32][68];
  __shared__ float hs[256][33];
  __shared__ float b1s[32], b2s[64];
  const int z = blockIdx.x, t = threadIdx.x;
  const int b = z >> 1, hh = z & 1;
  const float* fb = feat + (size_t)b * NPT * 5;
  for (int e = t; e < NPT * 5; e += 256) fs[e / 5][e % 5] = fb[e];
  for (int e = t; e < 320; e += 256) w1s[e / 32][e % 32] = w1[e];
  for (int e = t; e < 2048; e += 256) w2s[e >> 6][e & 63] = w2[e];
  if (t < 32) b1s[t] = b1[t];
  if (t >= 192) b2s[t - 192] = b2[t - 192];
  __syncthreads();
  {
    const int p = hh * 64 + (t >> 2);
    const int j = idx[(size_t)b * 512 + p * 4 + (t & 3)];
    float h[32];
#pragma unroll
    for (int o = 0; o < 32; ++o) h[o] = b1s[o];
#pragma unroll
    for (int c = 0; c < 10; ++c) {
      float in_c = (c < 5) ? fs[p][c] : (fs[j][c - 5] - fs[p][c - 5]);
      const float4* wr = reinterpret_cast<const float4*>(&w1s[c][0]);
#pragma unroll
      for (int o4 = 0; o4 < 8; ++o4) {
        float4 w = wr[o4];
        h[4 * o4 + 0] += in_c * w.x; h[4 * o4 + 1] += in_c * w.y;
        h[4 * o4 + 2] += in_c * w.z; h[4 * o4 + 3] += in_c * w.w;
      }
    }
#pragma unroll
    for (int o = 0; o < 32; ++o) hs[t][o] = elu_f(h[o]);
  }
  __syncthreads();
  {
    const int g = t >> 2, q = t & 3;
    const int o0 = q * 16;
    float acc[4][16];
#pragma unroll
    for (int m = 0; m < 16; ++m) {
      float bv = b2s[o0 + m];
#pragma unroll
      for (int i = 0; i < 4; ++i) acc[i][m] = bv;
    }
    for (int k = 0; k < 32; ++k) {
      float hk0 = hs[g * 4 + 0][k];
      float hk1 = hs[g * 4 + 1][k];
      float hk2 = hs[g * 4 + 2][k];
      float hk3 = hs[g * 4 + 3][k];
      const float4* wr = reinterpret_cast<const float4*>(&w2s[k][o0]);
#pragma unroll
      for (int m4 = 0; m4 < 4; ++m4) {
        float4 w = wr[m4];
        acc[0][4 * m4 + 0] += hk0 * w.x; acc[0][4 * m4 + 1] += hk0 * w.y;
        acc[0][4 * m4 + 2] += hk0 * w.z; acc[0][4 * m4 + 3] += hk0 * w.w;
        acc[1][4 * m4 + 0] += hk1 * w.x; acc[1][4 * m4 + 1] += hk1 * w.y;
        acc[1][4 * m4 + 2] += hk1 * w.z; acc[1][4 * m4 + 3] += hk1 * w.w;
        acc[2][4 * m4 + 0] += hk2 * w.x; acc[2][4 * m4 + 1] += hk2 * w.y;
        acc[2][4 * m4 + 2] += hk2 * w.z; acc[2][4 * m4 + 3] += hk2 * w.w;
        acc[3][4 * m4 + 0] += hk3 * w.x; acc[3][4 * m4 + 1] += hk3 * w.y;
        acc[3][4 * m4 + 2] += hk3 * w.z; acc[3][4 * m4 + 3] += hk3 * w.w;
      }
    }
    float* ob = out + ((size_t)b * NPT + hh * 64 + g) * 64 + o0;
#pragma unroll
    for (int m4 = 0; m4 < 4; ++m4) {
      float4 v;
      float* vp = &v.x;
#pragma unroll
      for (int s = 0; s < 4; ++s) {
        int m = 4 * m4 + s;
        vp[s] = 0.25f * (elu_f(acc[0][m]) + elu_f(acc[1][m]) +
                         elu_f(acc[2][m]) + elu_f(acc[3][m]));
      }
      *reinterpret_cast<float4*>(&ob[4 * m4]) = v;
    }
  }
}

// ---------------------------------------------------------------- ec2a ----
__global__ __launch_bounds__(512, 2) void ec2a_kernel(
    const float* __restrict__ x, const int* __restrict__ idx,
    const float* __restrict__ w1, const float* __restrict__ b1,
    float* __restrict__ H) {
  __shared__ __align__(16) float xs[NPT][68];
  __shared__ __align__(16) float w1s[128][100];
  __shared__ float b1s[96];
  const int b = blockIdx.x, t = threadIdx.x;
  const float* xb = x + (size_t)b * NPT * 64;
  for (int e = t; e < NPT * 64; e += 512) xs[e >> 6][e & 63] = xb[e];
  for (int e = t; e < 128 * 96; e += 512) w1s[e / 96][e % 96] = w1[e];
  if (t < 96) b1s[t] = b1[t];
  __syncthreads();
  const int pb = t >> 2, part = t & 3;
  const int n0 = part * 24;
  int jn[4];
#pragma unroll
  for (int i = 0; i < 4; ++i) jn[i] = idx[(size_t)b * 512 + pb * 4 + i];
  float acc[4][24];
#pragma unroll
  for (int m = 0; m < 24; ++m) {
    float bv = b1s[n0 + m];
#pragma unroll
    for (int i = 0; i < 4; ++i) acc[i][m] = bv;
  }
  for (int c = 0; c < 64; ++c) {
    float in_c = xs[pb][c];
    const float4* wr = reinterpret_cast<const float4*>(&w1s[c][n0]);
#pragma unroll
    for (int q4 = 0; q4 < 6; ++q4) {
      float4 wv = wr[q4];
#pragma unroll
      for (int i = 0; i < 4; ++i) {
        acc[i][4 * q4 + 0] += in_c * wv.x;
        acc[i][4 * q4 + 1] += in_c * wv.y;
        acc[i][4 * q4 + 2] += in_c * wv.z;
        acc[i][4 * q4 + 3] += in_c * wv.w;
      }
    }
  }
  for (int c = 0; c < 64; ++c) {
    float xic = xs[pb][c];
    float in0 = xs[jn[0]][c] - xic;
    float in1 = xs[jn[1]][c] - xic;
    float in2 = xs[jn[2]][c] - xic;
    float in3 = xs[jn[3]][c] - xic;
    const float4* wr = reinterpret_cast<const float4*>(&w1s[64 + c][n0]);
#pragma unroll
    for (int q4 = 0; q4 < 6; ++q4) {
      float4 wv = wr[q4];
      acc[0][4 * q4 + 0] += in0 * wv.x; acc[0][4 * q4 + 1] += in0 * wv.y;
      acc[0][4 * q4 + 2] += in0 * wv.z; acc[0][4 * q4 + 3] += in0 * wv.w;
      acc[1][4 * q4 + 0] += in1 * wv.x; acc[1][4 * q4 + 1] += in1 * wv.y;
      acc[1][4 * q4 + 2] += in1 * wv.z; acc[1][4 * q4 + 3] += in1 * wv.w;
      acc[2][4 * q4 + 0] += in2 * wv.x; acc[2][4 * q4 + 1] += in2 * wv.y;
      acc[2][4 * q4 + 2] += in2 * wv.z; acc[2][4 * q4 + 3] += in2 * wv.w;
      acc[3][4 * q4 + 0] += in3 * wv.x; acc[3][4 * q4 + 1] += in3 * wv.y;
      acc[3][4 * q4 + 2] += in3 * wv.z; acc[3][4 * q4 + 3] += in3 * wv.w;
    }
  }
#pragma unroll
  for (int i = 0; i < 4; ++i) {
    float* hrow = H + ((size_t)b * 512 + pb * 4 + i) * 96 + n0;
#pragma unroll
    for (int q4 = 0; q4 < 6; ++q4) {
      float4 v = {elu_f(acc[i][4 * q4 + 0]), elu_f(acc[i][4 * q4 + 1]),
                  elu_f(acc[i][4 * q4 + 2]), elu_f(acc[i][4 * q4 + 3])};
      *reinterpret_cast<float4*>(&hrow[4 * q4]) = v;
    }
  }
}

// ---------------------------------------------------------------- ec2b ----
__global__ __launch_bounds__(512, 2) void ec2b_kernel(
    const float* __restrict__ H, const float* __restrict__ w2,
    const float* __restrict__ b2, float* __restrict__ out) {
  __shared__ __align__(16) float hsT[96][260];
  __shared__ float w2s[96][132];
  __shared__ float b2s[128];
  const int z = blockIdx.x, t = threadIdx.x;
  const int bc = z >> 1, hh = z & 1;
  const float* Hb = H + ((size_t)bc * 512 + hh * 256) * 96;
  for (int i = t; i < 256 * 96; i += 512) hsT[i % 96][i / 96] = Hb[i];
  for (int i = t; i < 96 * 128; i += 512) w2s[i >> 7][i & 127] = w2[i];
  if (t < 128) b2s[t] = b2[t];
  __syncthreads();
  const int g = t >> 3, oq = t & 7;
  float acc[4][16];
#pragma unroll
  for (int m = 0; m < 16; ++m) {
    float bv = b2s[oq + 8 * m];
#pragma unroll
    for (int i = 0; i < 4; ++i) acc[i][m] = bv;
  }
  for (int k = 0; k < 96; ++k) {
    float4 hv = *reinterpret_cast<const float4*>(&hsT[k][4 * g]);
#pragma unroll
    for (int m = 0; m < 16; ++m) {
      float wv = w2s[k][oq + 8 * m];
      acc[0][m] += hv.x * wv;
      acc[1][m] += hv.y * wv;
      acc[2][m] += hv.z * wv;
      acc[3][m] += hv.w * wv;
    }
  }
  float* orow = out + ((size_t)bc * NPT + hh * 64 + g) * 128;
#pragma unroll
  for (int m = 0; m < 16; ++m) {
    float s = elu_f(acc[0][m]) + elu_f(acc[1][m]) +
              elu_f(acc[2][m]) + elu_f(acc[3][m]);
    orow[oq + 8 * m] = 0.25f * s;
  }
}

// ---------------------------------------------------------------- ec3a ----
__global__ __launch_bounds__(512, 2) void ec3a_kernel(
    const float* __restrict__ x, const int* __restrict__ idx,
    const float* __restrict__ w1, const float* __restrict__ b1,
    unsigned short* __restrict__ h1) {
  __shared__ unsigned short Xb[128][136];
  __shared__ unsigned short W1t[192][264];
  __shared__ float b1s[192];
  __shared__ unsigned short stg[8][16][40];
  const int b = blockIdx.x, t = threadIdx.x;
  const float* xb = x + (size_t)b * NPT * 128;
  for (int e = t; e < NPT * 128; e += 512) Xb[e >> 7][e & 127] = f2bf(xb[e]);
  for (int e = t; e < 256 * 192; e += 512) {
    int k = e / 192, n = e % 192;
    W1t[n][k] = f2bf(w1[e]);
  }
  if (t < 192) b1s[t] = b1[t];
  __syncthreads();
  const int w = t >> 6, l = t & 63;
  const int lr = l & 15, lq = l >> 4;
  for (int mt = 0; mt < 4; ++mt) {
    const int m = (w * 4 + mt) * 16;
    const int e = m + lr;
    const int p = e >> 2;
    const int jp = idx[(size_t)b * 512 + e];
    short8 A[8];
#pragma unroll
    for (int kk = 0; kk < 4; ++kk) {
      int k0 = kk * 32 + lq * 8;
      A[kk] = *reinterpret_cast<const short8*>(&Xb[p][k0]);
    }
#pragma unroll
    for (int kk = 0; kk < 4; ++kk) {
      int k0 = kk * 32 + lq * 8;
      short8 aj = *reinterpret_cast<const short8*>(&Xb[jp][k0]);
      short8 ai = *reinterpret_cast<const short8*>(&Xb[p][k0]);
      short8 d;
#pragma unroll
      for (int q = 0; q < 8; ++q)
        d[q] = (short)f2bf(bf2f((unsigned short)aj[q]) - bf2f((unsigned short)ai[q]));
      A[4 + kk] = d;
    }
    floatx4 acc[12];
#pragma unroll
    for (int n = 0; n < 12; ++n) acc[n] = (floatx4){0.f, 0.f, 0.f, 0.f};
#pragma unroll
    for (int n = 0; n < 12; ++n) {
#pragma unroll
      for (int kk = 0; kk < 8; ++kk) {
        short8 Bf = *reinterpret_cast<const short8*>(&W1t[n * 16 + lr][kk * 32 + lq * 8]);
        acc[n] = __builtin_amdgcn_mfma_f32_16x16x32_bf16(A[kk], Bf, acc[n], 0, 0, 0);
      }
    }
#pragma unroll
    for (int pr = 0; pr < 6; ++pr) {
      float bv0 = b1s[pr * 32 + lr];
      float bv1 = b1s[pr * 32 + 16 + lr];
#pragma unroll
      for (int i = 0; i < 4; ++i) {
        stg[w][lq * 4 + i][lr]      = f2bf(elu_f(acc[2 * pr][i] + bv0));
        stg[w][lq * 4 + i][16 + lr] = f2bf(elu_f(acc[2 * pr + 1][i] + bv1));
      }
      asm volatile("s_waitcnt lgkmcnt(0)" ::: "memory");
      const unsigned short* src = &stg[w][l >> 2][(l & 3) * 8];
      uint4v vv = *reinterpret_cast<const uint4v*>(src);
      size_t dst = ((size_t)b * 512 + m + (l >> 2)) * 192 + pr * 32 + (l & 3) * 8;
      *reinterpret_cast<uint4v*>(&h1[dst]) = vv;
      asm volatile("s_waitcnt lgkmcnt(0)" ::: "memory");
    }
  }
}

// ---------------------------------------------------------------- ec3b ----
__global__ __launch_bounds__(512, 2) void ec3b_kernel(
    const unsigned short* __restrict__ h1,
    const float* __restrict__ w2, const float* __restrict__ b2,
    unsigned short* __restrict__ out3) {
  __shared__ unsigned short W2t[256][200];
  __shared__ float b2s[256];
  const int b = blockIdx.x, t = threadIdx.x;
  for (int e = t; e < 192 * 256; e += 512) {
    int k = e >> 8, n = e & 255;
    W2t[n][k] = f2bf(w2[e]);
  }
  if (t < 256) b2s[t] = b2[t];
  __syncthreads();
  const int w = t >> 6, l = t & 63;
  const int lr = l & 15, lq = l >> 4;
  for (int mt = 0; mt < 4; ++mt) {
    const int m = (w * 4 + mt) * 16;
    floatx4 acc[16];
#pragma unroll
    for (int n = 0; n < 16; ++n) acc[n] = (floatx4){0.f, 0.f, 0.f, 0.f};
    const unsigned short* arow = h1 + ((size_t)b * 512 + m + lr) * 192;
#pragma unroll
    for (int kk = 0; kk < 6; ++kk) {
      short8 Af = *reinterpret_cast<const short8*>(&arow[kk * 32 + lq * 8]);
#pragma unroll
      for (int n = 0; n < 16; ++n) {
        short8 Bf = *reinterpret_cast<const short8*>(&W2t[n * 16 + lr][kk * 32 + lq * 8]);
        acc[n] = __builtin_amdgcn_mfma_f32_16x16x32_bf16(Af, Bf, acc[n], 0, 0, 0);
      }
    }
    unsigned short* orow = out3 + ((size_t)b * NPT + (m >> 2) + lq) * 256;
#pragma unroll
    for (int n = 0; n < 16; ++n) {
      float bv = b2s[n * 16 + lr];
      float s = 0.f;
#pragma unroll
      for (int i = 0; i < 4; ++i) s += elu_f(acc[n][i] + bv);
      orow[n * 16 + lr] = f2bf(0.25f * s);
    }
  }
}

// ------------------------------------------------------------ head prep ----
__global__ __launch_bounds__(256) void head_prep_kernel(
    const float* __restrict__ w1, const float* __restrict__ w2,
    unsigned short* __restrict__ w1p, unsigned short* __restrict__ w2p) {
  int i = blockIdx.x * 256 + threadIdx.x;
  if (i < 512 * 480) {
    int n = i / 480, kp = i % 480;
    int ko = (kp < 5) ? kp : kp - 3;
    bool ok = ((kp < 5) || (kp >= 8 && kp < 456)) && (n < 453);
    w1p[i] = ok ? f2bf(w1[(size_t)ko * 453 + n]) : (unsigned short)0;
  } else {
    int j = i - 512 * 480;
    if (j < 256 * 480) {
      int n = j / 480, kp = j % 480;
      bool ok = (kp < 453) && (n < 226);
      w2p[j] = ok ? f2bf(w2[(size_t)kp * 226 + n]) : (unsigned short)0;
    }
  }
}

// ----------------------------------------------------------- head MFMA ----
// v3: 64 rows/block, 256 thr, 4 waves. X staged in uA -> A1 regs; uA becomes
// W chunk buffer. H1 never block-wide: per-wave tps transpose builds Af2[15]
// in registers during GEMM1. LDS ~77 KB -> 2 blocks/CU.
#define HSTR 488
#define TPSS 72
__global__ __launch_bounds__(256, 2) void head_mfma_kernel(
    const float* __restrict__ feat, const float* __restrict__ o1,
    const float* __restrict__ o2, const unsigned short* __restrict__ o3,
    const unsigned short* __restrict__ w1p, const float* __restrict__ b1,
    const unsigned short* __restrict__ w2p, const float* __restrict__ b2,
    const float* __restrict__ w3, const float* __restrict__ b3,
    float* __restrict__ out) {
  __shared__ unsigned short uA[64 * HSTR];           // X, then W chunk buffer
  __shared__ __align__(16) unsigned short tps[4][16][TPSS];  // per-wave D->A
  __shared__ float b1s[512], b2s[256], w3s[512];
  const int t = threadIdx.x;
  const size_t base = (size_t)blockIdx.x * 64;

  // ---- stage concat X -> uA (bf16, padded k layout), coalesced ----
  for (int e = t; e < 64 * 8; e += 256) {
    int r = e >> 3, c = e & 7;
    uA[r * HSTR + c] = (c < 5) ? f2bf(feat[(base + r) * 5 + c]) : 0;
  }
  for (int e = t; e < 64 * 64; e += 256) {
    int r = e >> 6, c = e & 63;
    uA[r * HSTR + 8 + c] = f2bf(o1[(base + r) * 64 + c]);
  }
  for (int e = t; e < 64 * 128; e += 256) {
    int r = e >> 7, c = e & 127;
    uA[r * HSTR + 72 + c] = f2bf(o2[(base + r) * 128 + c]);
  }
  for (int e = t; e < 64 * 256; e += 256) {
    int r = e >> 8, c = e & 255;
    uA[r * HSTR + 200 + c] = o3[(base + r) * 256 + c];
  }
  for (int e = t; e < 64 * 32; e += 256) {
    int r = e >> 5, c = e & 31;
    uA[r * HSTR + 456 + c] = 0;
  }
  for (int i = t; i < 512; i += 256) b1s[i] = (i < 453) ? b1[i] : 0.f;
  if (t < 256) b2s[t] = (t < 226) ? b2[t] : 0.f;
  for (int i = t; i < 512; i += 256) w3s[i] = (i < 452) ? w3[i] : 0.f;
  __syncthreads();

  const int w = t >> 6, l = t & 63;
  const int lr = l & 15, lq = l >> 4;
  const int tr = t >> 2, tc = t & 3;

  short8 Af[15];
#pragma unroll
  for (int kk = 0; kk < 15; ++kk)
    Af[kk] = *reinterpret_cast<const short8*>(
        &uA[(w * 16 + lr) * HSTR + kk * 32 + lq * 8]);
  __syncthreads();  // X dead -> uA is the W chunk buffer

  uint4v v[15];
#define WLOAD(SRC, CH)                                                   \
  {                                                                      \
    _Pragma("unroll")                                                    \
    for (int i = 0; i < 15; ++i)                                         \
      v[i] = *reinterpret_cast<const uint4v*>(                           \
          &SRC[((size_t)((CH) * 64 + tr)) * 480 + (tc + 4 * i) * 8]);    \
  }
#define WWRITE()                                                         \
  {                                                                      \
    _Pragma("unroll")                                                    \
    for (int i = 0; i < 15; ++i)                                         \
      *reinterpret_cast<uint4v*>(&uA[tr * HSTR + (tc + 4 * i) * 8]) = v[i]; \
  }

  WLOAD(w1p, 0)
  WWRITE()
  __syncthreads();

  short8 Af2[15];
  // ---- GEMM1: 8 chunks of 64 cols; Af2 built incrementally via tps ----
#pragma unroll
  for (int ch = 0; ch < 8; ++ch) {
    if (ch < 7) WLOAD(w1p, ch + 1)
    else       WLOAD(w2p, 0)
    floatx4 a0 = {0.f, 0.f, 0.f, 0.f}, a1 = {0.f, 0.f, 0.f, 0.f};
    floatx4 a2 = {0.f, 0.f, 0.f, 0.f}, a3 = {0.f, 0.f, 0.f, 0.f};
#pragma unroll
    for (int kk = 0; kk < 15; ++kk) {
      int ko = kk * 32 + lq * 8;
      short8 B0 = *reinterpret_cast<const short8*>(&uA[(lr)*HSTR + ko]);
      short8 B1 = *reinterpret_cast<const short8*>(&uA[(16 + lr) * HSTR + ko]);
      short8 B2 = *reinterpret_cast<const short8*>(&uA[(32 + lr) * HSTR + ko]);
      short8 B3 = *reinterpret_cast<const short8*>(&uA[(48 + lr) * HSTR + ko]);
      a0 = __builtin_amdgcn_mfma_f32_16x16x32_bf16(Af[kk], B0, a0, 0, 0, 0);
      a1 = __builtin_amdgcn_mfma_f32_16x16x32_bf16(Af[kk], B1, a1, 0, 0, 0);
      a2 = __builtin_amdgcn_mfma_f32_16x16x32_bf16(Af[kk], B2, a2, 0, 0, 0);
      a3 = __builtin_amdgcn_mfma_f32_16x16x32_bf16(Af[kk], B3, a3, 0, 0, 0);
    }
    // epilogue -> per-wave tps (cols c>=453 are exactly 0: zero W rows+bias)
    {
      floatx4 aj[4] = {a0, a1, a2, a3};
#pragma unroll
      for (int jx = 0; jx < 4; ++jx) {
        int c = ch * 64 + jx * 16 + lr;
        float bb = b1s[c];
#pragma unroll
        for (int i = 0; i < 4; ++i)
          tps[w][lq * 4 + i][jx * 16 + lr] = f2bf(elu_f(aj[jx][i] + bb));
      }
    }
    asm volatile("s_waitcnt lgkmcnt(0)" ::: "memory");
    Af2[2 * ch] = *reinterpret_cast<const short8*>(&tps[w][lr][lq * 8]);
    if (ch < 7)
      Af2[2 * ch + 1] = *reinterpret_cast<const short8*>(&tps[w][lr][32 + lq * 8]);
    asm volatile("s_waitcnt lgkmcnt(0)" ::: "memory");
    __syncthreads();   // all waves done reading uA chunk
    WWRITE()
    __syncthreads();   // next chunk staged
  }

  // ---- GEMM2: 4 chunks of 64 cols + fp32 GEMM3 partials ----
  float p0[4] = {0.f, 0.f, 0.f, 0.f}, p1[4] = {0.f, 0.f, 0.f, 0.f};
#pragma unroll
  for (int ch = 0; ch < 4; ++ch) {
    if (ch < 3) WLOAD(w2p, ch + 1)
    floatx4 a0 = {0.f, 0.f, 0.f, 0.f}, a1 = {0.f, 0.f, 0.f, 0.f};
    floatx4 a2 = {0.f, 0.f, 0.f, 0.f}, a3 = {0.f, 0.f, 0.f, 0.f};
#pragma unroll
    for (int kk = 0; kk < 15; ++kk) {
      int ko = kk * 32 + lq * 8;
      short8 B0 = *reinterpret_cast<const short8*>(&uA[(lr)*HSTR + ko]);
      short8 B1 = *reinterpret_cast<const short8*>(&uA[(16 + lr) * HSTR + ko]);
      short8 B2 = *reinterpret_cast<const short8*>(&uA[(32 + lr) * HSTR + ko]);
      short8 B3 = *reinterpret_cast<const short8*>(&uA[(48 + lr) * HSTR + ko]);
      a0 = __builtin_amdgcn_mfma_f32_16x16x32_bf16(Af2[kk], B0, a0, 0, 0, 0);
      a1 = __builtin_amdgcn_mfma_f32_16x16x32_bf16(Af2[kk], B1, a1, 0, 0, 0);
      a2 = __builtin_amdgcn_mfma_f32_16x16x32_bf16(Af2[kk], B2, a2, 0, 0, 0);
      a3 = __builtin_amdgcn_mfma_f32_16x16x32_bf16(Af2[kk], B3, a3, 0, 0, 0);
    }
    {
      floatx4 aj[4] = {a0, a1, a2, a3};
#pragma unroll
      for (int jx = 0; jx < 4; ++jx) {
        int c = ch * 64 + jx * 16 + lr;
        float bb = b2s[c];
        float wa = w3s[2 * c], wb = w3s[2 * c + 1];
#pragma unroll
        for (int i = 0; i < 4; ++i) {
          float h = (c < 226) ? elu_f(aj[jx][i] + bb) : 0.f;
          p0[i] += h * wa;
          p1[i] += h * wb;
        }
      }
    }
    if (ch < 3) {
      __syncthreads();
      WWRITE()
      __syncthreads();
    }
  }

  // ---- reduce GEMM3 partials over the 16 lr lanes and store ----
#pragma unroll
  for (int i = 0; i < 4; ++i) {
    float a = p0[i], bvv = p1[i];
#pragma unroll
    for (int m = 1; m < 16; m <<= 1) {
      a += __shfl_xor(a, m);
      bvv += __shfl_xor(bvv, m);
    }
    if (lr == 0) {
      size_t row = base + w * 16 + lq * 4 + i;
      float2 vv = {a + b3[0], bvv + b3[1]};
      *reinterpret_cast<float2*>(&out[row * 2]) = vv;
    }
  }
#undef WLOAD
#undef WWRITE
}

// ------------------------------------------------------------- launch ----
extern "C" void kernel_launch(void* const* d_in, const int* in_sizes, int n_in,
                              void* d_out, int out_size, void* d_ws, size_t ws_size,
                              hipStream_t stream) {
  const float* coords = (const float*)d_in[0];
  const float* feat   = (const float*)d_in[1];
  const float* c1w1 = (const float*)d_in[2];  const float* c1b1 = (const float*)d_in[3];
  const float* c1w2 = (const float*)d_in[4];  const float* c1b2 = (const float*)d_in[5];
  const float* c2w1 = (const float*)d_in[6];  const float* c2b1 = (const float*)d_in[7];
  const float* c2w2 = (const float*)d_in[8];  const float* c2b2 = (const float*)d_in[9];
  const float* c3w1 = (const float*)d_in[10]; const float* c3b1 = (const float*)d_in[11];
  const float* c3w2 = (const float*)d_in[12]; const float* c3b2 = (const float*)d_in[13];
  const float* ow1  = (const float*)d_in[14]; const float* ob1  = (const float*)d_in[15];
  const float* ow2  = (const float*)d_in[16]; const float* ob2  = (const float*)d_in[17];
  const float* ow3  = (const float*)d_in[18]; const float* ob3  = (const float*)d_in[19];
  float* out = (float*)d_out;

  char* ws = (char*)d_ws;
  float* out1 = (float*)(ws);
  float* out2 = (float*)(ws + (32ull << 20));
  unsigned short* out3b = (unsigned short*)(ws + (96ull << 20));
  int* idx = (int*)(ws + (160ull << 20));
  float* Hbuf = (float*)(ws + (162ull << 20));
  unsigned short* h1 = (unsigned short*)(ws + (162ull << 20));
  unsigned short* w1p = (unsigned short*)(ws + (212ull << 20));
  unsigned short* w2p = (unsigned short*)(ws + (213ull << 20));

  head_prep_kernel<<<1440, 256, 0, stream>>>(ow1, ow2, w1p, w2p);
  knn_kernel<2><<<NB, 128, 0, stream>>>(coords, idx);
  ec1_kernel<<<2 * NB, 256, 0, stream>>>(feat, idx, c1w1, c1b1, c1w2, c1b2, out1);
  knn512_kernel<64><<<NB, 512, 0, stream>>>(out1, idx);
  for (int c = 0; c < 4; ++c) {
    ec2a_kernel<<<256, 512, 0, stream>>>(out1 + (size_t)c * 256 * NPT * 64,
                                         idx + (size_t)c * 256 * 512,
                                         c2w1, c2b1, Hbuf);
    ec2b_kernel<<<512, 512, 0, stream>>>(Hbuf, c2w2, c2b2,
                                         out2 + (size_t)c * 256 * NPT * 128);
  }
  knn512_kernel<128><<<NB, 512, 0, stream>>>(out2, idx);
  for (int c = 0; c < 4; ++c) {
    ec3a_kernel<<<256, 512, 0, stream>>>(out2 + (size_t)c * 256 * NPT * 128,
                                         idx + (size_t)c * 256 * 512,
                                         c3w1, c3b1, h1);
    ec3b_kernel<<<256, 512, 0, stream>>>(h1, c3w2, c3b2,
                                         out3b + (size_t)c * 256 * NPT * 256);
  }
  head_mfma_kernel<<<2048, 256, 0, stream>>>(feat, out1, out2, out3b,
                                             w1p, ob1, w2p, ob2, ow3, ob3, out);
}

// Round 11
// 1980.865 us; speedup vs baseline: 20.8008x; 1.0106x over previous
//
#include <hip/hip_runtime.h>
#include <cstdint>
#include <cstddef>

// ParticleNet MI355X — Round 11.
// - kNN C=2 (r2) / C=64,128 quarter-split (r9): verified.
// - ec1 (r7), ec2a/ec2b (r4, now 2 chunks of 512 events), ec3 (r3): verified.
// - ec3a/ec3b: W staged via prep-converted bf16 LDS images (linear uint4 copy;
//   r10 did 49K scalar f2bf + conflicted strided writes per block).
// - head v3.1: A-fragments built directly from global (X-staging phase and a
//   barrier pair removed); W-chunk machinery unchanged (r10-verified).
// ws layout (MiB): out1[0,32) out2[32,96) out3b[96,160) | ec2-Hbuf [96,192)
// (temporal reuse, dead before out3b written) | h1 [162,212) (ec3 temp) |
// w1p@212 w2p@212.5 w1t3g@213 w2t3g@213.25 | idx@[214,216).

#define NB 1024
#define NPT 128

typedef __attribute__((ext_vector_type(8))) short short8;
typedef __attribute__((ext_vector_type(4))) float floatx4;
typedef __attribute__((ext_vector_type(4))) unsigned int uint4v;

__device__ __forceinline__ float elu_f(float x) { return x > 0.0f ? x : expm1f(x); }

__device__ __forceinline__ unsigned short f2bf(float f) {
  unsigned u = __builtin_bit_cast(unsigned, f);
  unsigned r = u + 0x7FFFu + ((u >> 16) & 1u);
  return (unsigned short)(r >> 16);
}
__device__ __forceinline__ float bf2f(unsigned short h) {
  unsigned u = ((unsigned)h) << 16;
  return __builtin_bit_cast(float, u);
}

// ------------------------------------------------------------- kNN C=2 ----
template<int C>
__global__ __launch_bounds__(128) void knn_kernel(const float* __restrict__ x,
                                                  int* __restrict__ idx) {
  __shared__ __align__(16) float xs[NPT][C + 4];
  __shared__ float x2s[NPT];
  __shared__ double x2d[NPT];
  const int b = blockIdx.x, t = threadIdx.x;
  const float* xb = x + (size_t)b * NPT * C;
  for (int e = t; e < NPT * C; e += 128) xs[e / C][e % C] = xb[e];
  __syncthreads();
  float xi[C];
  float s2 = 0.0f;
  double s2d = 0.0;
#pragma unroll
  for (int c = 0; c < C; ++c) {
    xi[c] = xs[t][c];
    s2 += xi[c] * xi[c];
    s2d += (double)xi[c] * (double)xi[c];
  }
  x2s[t] = s2;
  x2d[t] = s2d;
  __syncthreads();
  float bd0 = 1e30f, bd1 = 1e30f, bd2 = 1e30f, bd3 = 1e30f, bd4 = 1e30f, bd5 = 1e30f;
  int bi0 = 0, bi1 = 0, bi2 = 0, bi3 = 0, bi4 = 0, bi5 = 0;
  for (int j = 0; j < NPT; ++j) {
    if (j == t) continue;
    float dot = 0.0f;
#pragma unroll
    for (int c = 0; c < C; ++c) dot += xi[c] * xs[j][c];
    float d = s2 + x2s[j] - 2.0f * dot;
    if (d < bd5) {
      bd5 = d; bi5 = j;
      if (bd5 < bd4) {
        float td = bd4; bd4 = bd5; bd5 = td; int ti = bi4; bi4 = bi5; bi5 = ti;
        if (bd4 < bd3) {
          td = bd3; bd3 = bd4; bd4 = td; ti = bi3; bi3 = bi4; bi4 = ti;
          if (bd3 < bd2) {
            td = bd2; bd2 = bd3; bd3 = td; ti = bi2; bi2 = bi3; bi3 = ti;
            if (bd2 < bd1) {
              td = bd1; bd1 = bd2; bd2 = td; ti = bi1; bi1 = bi2; bi2 = ti;
              if (bd1 < bd0) {
                td = bd0; bd0 = bd1; bd1 = td; ti = bi0; bi0 = bi1; bi1 = ti;
              }
            }
          }
        }
      }
    }
  }
  auto refine = [&](int j) -> double {
    double dot = 0.0;
#pragma unroll
    for (int c = 0; c < C; ++c) dot += (double)xi[c] * (double)xs[j][c];
    return s2d + x2d[j] - 2.0 * dot;
  };
  double e0 = refine(bi0), e1 = refine(bi1), e2 = refine(bi2);
  double e3 = refine(bi3), e4 = refine(bi4), e5 = refine(bi5);
#define CSWP(da, ia, db, ib)                                            \
  if ((da > db) || (da == db && ia > ib)) {                             \
    double _td = da; da = db; db = _td; int _ti = ia; ia = ib; ib = _ti; }
  CSWP(e0, bi0, e1, bi1) CSWP(e1, bi1, e2, bi2) CSWP(e2, bi2, e3, bi3)
  CSWP(e3, bi3, e4, bi4) CSWP(e4, bi4, e5, bi5)
  CSWP(e0, bi0, e1, bi1) CSWP(e1, bi1, e2, bi2) CSWP(e2, bi2, e3, bi3)
  CSWP(e3, bi3, e4, bi4)
  CSWP(e0, bi0, e1, bi1) CSWP(e1, bi1, e2, bi2) CSWP(e2, bi2, e3, bi3)
  CSWP(e0, bi0, e1, bi1) CSWP(e1, bi1, e2, bi2)
  CSWP(e0, bi0, e1, bi1)
#undef CSWP
  int* ib = idx + ((size_t)b * NPT + t) * 4;
  ib[0] = bi0; ib[1] = bi1; ib[2] = bi2; ib[3] = bi3;
}

// ------------------------------------------------------- kNN C=64/128 ----
template<int C>
__global__ __launch_bounds__(512) void knn512_kernel(const float* __restrict__ x,
                                                     int* __restrict__ idx) {
  constexpr int CQ = C / 4;
  constexpr int QS = CQ + 4;
  __shared__ __align__(16) float xs[NPT][4 * QS];
  __shared__ float x2s[NPT];
  __shared__ double x2d[NPT];
  const int b = blockIdx.x, t = threadIdx.x;
  const float* xb = x + (size_t)b * NPT * C;
  for (int e = t; e < NPT * C; e += 512) {
    int r = e / C, c = e % C;
    xs[r][(c / CQ) * QS + (c % CQ)] = xb[e];
  }
  __syncthreads();
  const int p = t >> 2, q = t & 3;
  float xi[CQ];
  float s2 = 0.f;
  double s2d = 0.0;
#pragma unroll
  for (int c = 0; c < CQ; ++c) {
    xi[c] = xs[p][q * QS + c];
    s2 += xi[c] * xi[c];
    s2d += (double)xi[c] * (double)xi[c];
  }
  s2 += __shfl_xor(s2, 1);  s2 += __shfl_xor(s2, 2);
  s2d += __shfl_xor(s2d, 1); s2d += __shfl_xor(s2d, 2);
  if (q == 0) { x2s[p] = s2; x2d[p] = s2d; }
  __syncthreads();
  float bd0 = 1e30f, bd1 = 1e30f, bd2 = 1e30f, bd3 = 1e30f, bd4 = 1e30f, bd5 = 1e30f;
  int bi0 = 0, bi1 = 0, bi2 = 0, bi3 = 0, bi4 = 0, bi5 = 0;
  for (int j = 0; j < NPT; ++j) {
    if (j == p) continue;
    const float4* xr = reinterpret_cast<const float4*>(&xs[j][q * QS]);
    float part0 = 0.f, part1 = 0.f, part2 = 0.f, part3 = 0.f;
#pragma unroll
    for (int c4 = 0; c4 < CQ / 4; ++c4) {
      float4 v = xr[c4];
      float s = xi[4 * c4 + 0] * v.x + xi[4 * c4 + 1] * v.y +
                xi[4 * c4 + 2] * v.z + xi[4 * c4 + 3] * v.w;
      if ((c4 & 3) == 0) part0 += s;
      else if ((c4 & 3) == 1) part1 += s;
      else if ((c4 & 3) == 2) part2 += s;
      else part3 += s;
    }
    float dot = (part0 + part1) + (part2 + part3);
    dot += __shfl_xor(dot, 1);
    dot += __shfl_xor(dot, 2);
    float d = s2 + x2s[j] - 2.0f * dot;
    if (d < bd5) {
      bd5 = d; bi5 = j;
      if (bd5 < bd4) {
        float td = bd4; bd4 = bd5; bd5 = td; int ti = bi4; bi4 = bi5; bi5 = ti;
        if (bd4 < bd3) {
          td = bd3; bd3 = bd4; bd4 = td; ti = bi3; bi3 = bi4; bi4 = ti;
          if (bd3 < bd2) {
            td = bd2; bd2 = bd3; bd3 = td; ti = bi2; bi2 = bi3; bi3 = ti;
            if (bd2 < bd1) {
              td = bd1; bd1 = bd2; bd2 = td; ti = bi1; bi1 = bi2; bi2 = ti;
              if (bd1 < bd0) {
                td = bd0; bd0 = bd1; bd1 = td; ti = bi0; bi0 = bi1; bi1 = ti;
              }
            }
          }
        }
      }
    }
  }
  auto refine = [&](int j) -> double {
    double dot = 0.0;
#pragma unroll
    for (int c = 0; c < CQ; ++c) dot += (double)xi[c] * (double)xs[j][q * QS + c];
    dot += __shfl_xor(dot, 1);
    dot += __shfl_xor(dot, 2);
    return s2d + x2d[j] - 2.0 * dot;
  };
  double e0 = refine(bi0), e1 = refine(bi1), e2 = refine(bi2);
  double e3 = refine(bi3), e4 = refine(bi4), e5 = refine(bi5);
#define CSWP(da, ia, db, ib)                                            \
  if ((da > db) || (da == db && ia > ib)) {                             \
    double _td = da; da = db; db = _td; int _ti = ia; ia = ib; ib = _ti; }
  CSWP(e0, bi0, e1, bi1) CSWP(e1, bi1, e2, bi2) CSWP(e2, bi2, e3, bi3)
  CSWP(e3, bi3, e4, bi4) CSWP(e4, bi4, e5, bi5)
  CSWP(e0, bi0, e1, bi1) CSWP(e1, bi1, e2, bi2) CSWP(e2, bi2, e3, bi3)
  CSWP(e3, bi3, e4, bi4)
  CSWP(e0, bi0, e1, bi1) CSWP(e1, bi1, e2, bi2) CSWP(e2, bi2, e3, bi3)
  CSWP(e0, bi0, e1, bi1) CSWP(e1, bi1, e2, bi2)
  CSWP(e0, bi0, e1, bi1)
#undef CSWP
  if (q == 0) {
    int* ib = idx + ((size_t)b * NPT + p) * 4;
    ib[0] = bi0; ib[1] = bi1; ib[2] = bi2; ib[3] = bi3;
  }
}

// ---------------------------------------------------------------- ec1 ----
__global__ __launch_bounds__(256) void ec1_kernel(
    const float* __restrict__ feat, const int* __restrict__ idx,
    const float* __restrict__ w1, const float* __restrict__ b1,
    const float* __restrict__ w2, const float* __restrict__ b2,
    float* __restrict__ out) {
  __shared__ __align__(16) float fs[NPT][6];
  __shared__ __align__(16) float w1s[10][32];
  __shared__ __align__(16) float w2s[32][68];
  __shared__ float hs[256][33];
  __shared__ float b1s[32], b2s[64];
  const int z = blockIdx.x, t = threadIdx.x;
  const int b = z >> 1, hh = z & 1;
  const float* fb = feat + (size_t)b * NPT * 5;
  for (int e = t; e < NPT * 5; e += 256) fs[e / 5][e % 5] = fb[e];
  for (int e = t; e < 320; e += 256) w1s[e / 32][e % 32] = w1[e];
  for (int e = t; e < 2048; e += 256) w2s[e >> 6][e & 63] = w2[e];
  if (t < 32) b1s[t] = b1[t];
  if (t >= 192) b2s[t - 192] = b2[t - 192];
  __syncthreads();
  {
    const int p = hh * 64 + (t >> 2);
    const int j = idx[(size_t)b * 512 + p * 4 + (t & 3)];
    float h[32];
#pragma unroll
    for (int o = 0; o < 32; ++o) h[o] = b1s[o];
#pragma unroll
    for (int c = 0; c < 10; ++c) {
      float in_c = (c < 5) ? fs[p][c] : (fs[j][c - 5] - fs[p][c - 5]);
      const float4* wr = reinterpret_cast<const float4*>(&w1s[c][0]);
#pragma unroll
      for (int o4 = 0; o4 < 8; ++o4) {
        float4 w = wr[o4];
        h[4 * o4 + 0] += in_c * w.x; h[4 * o4 + 1] += in_c * w.y;
        h[4 * o4 + 2] += in_c * w.z; h[4 * o4 + 3] += in_c * w.w;
      }
    }
#pragma unroll
    for (int o = 0; o < 32; ++o) hs[t][o] = elu_f(h[o]);
  }
  __syncthreads();
  {
    const int g = t >> 2, q = t & 3;
    const int o0 = q * 16;
    float acc[4][16];
#pragma unroll
    for (int m = 0; m < 16; ++m) {
      float bv = b2s[o0 + m];
#pragma unroll
      for (int i = 0; i < 4; ++i) acc[i][m] = bv;
    }
    for (int k = 0; k < 32; ++k) {
      float hk0 = hs[g * 4 + 0][k];
      float hk1 = hs[g * 4 + 1][k];
      float hk2 = hs[g * 4 + 2][k];
      float hk3 = hs[g * 4 + 3][k];
      const float4* wr = reinterpret_cast<const float4*>(&w2s[k][o0]);
#pragma unroll
      for (int m4 = 0; m4 < 4; ++m4) {
        float4 w = wr[m4];
        acc[0][4 * m4 + 0] += hk0 * w.x; acc[0][4 * m4 + 1] += hk0 * w.y;
        acc[0][4 * m4 + 2] += hk0 * w.z; acc[0][4 * m4 + 3] += hk0 * w.w;
        acc[1][4 * m4 + 0] += hk1 * w.x; acc[1][4 * m4 + 1] += hk1 * w.y;
        acc[1][4 * m4 + 2] += hk1 * w.z; acc[1][4 * m4 + 3] += hk1 * w.w;
        acc[2][4 * m4 + 0] += hk2 * w.x; acc[2][4 * m4 + 1] += hk2 * w.y;
        acc[2][4 * m4 + 2] += hk2 * w.z; acc[2][4 * m4 + 3] += hk2 * w.w;
        acc[3][4 * m4 + 0] += hk3 * w.x; acc[3][4 * m4 + 1] += hk3 * w.y;
        acc[3][4 * m4 + 2] += hk3 * w.z; acc[3][4 * m4 + 3] += hk3 * w.w;
      }
    }
    float* ob = out + ((size_t)b * NPT + hh * 64 + g) * 64 + o0;
#pragma unroll
    for (int m4 = 0; m4 < 4; ++m4) {
      float4 v;
      float* vp = &v.x;
#pragma unroll
      for (int s = 0; s < 4; ++s) {
        int m = 4 * m4 + s;
        vp[s] = 0.25f * (elu_f(acc[0][m]) + elu_f(acc[1][m]) +
                         elu_f(acc[2][m]) + elu_f(acc[3][m]));
      }
      *reinterpret_cast<float4*>(&ob[4 * m4]) = v;
    }
  }
}

// ---------------------------------------------------------------- ec2a ----
__global__ __launch_bounds__(512, 2) void ec2a_kernel(
    const float* __restrict__ x, const int* __restrict__ idx,
    const float* __restrict__ w1, const float* __restrict__ b1,
    float* __restrict__ H) {
  __shared__ __align__(16) float xs[NPT][68];
  __shared__ __align__(16) float w1s[128][100];
  __shared__ float b1s[96];
  const int b = blockIdx.x, t = threadIdx.x;
  const float* xb = x + (size_t)b * NPT * 64;
  for (int e = t; e < NPT * 64; e += 512) xs[e >> 6][e & 63] = xb[e];
  for (int e = t; e < 128 * 96; e += 512) w1s[e / 96][e % 96] = w1[e];
  if (t < 96) b1s[t] = b1[t];
  __syncthreads();
  const int pb = t >> 2, part = t & 3;
  const int n0 = part * 24;
  int jn[4];
#pragma unroll
  for (int i = 0; i < 4; ++i) jn[i] = idx[(size_t)b * 512 + pb * 4 + i];
  float acc[4][24];
#pragma unroll
  for (int m = 0; m < 24; ++m) {
    float bv = b1s[n0 + m];
#pragma unroll
    for (int i = 0; i < 4; ++i) acc[i][m] = bv;
  }
  for (int c = 0; c < 64; ++c) {
    float in_c = xs[pb][c];
    const float4* wr = reinterpret_cast<const float4*>(&w1s[c][n0]);
#pragma unroll
    for (int q4 = 0; q4 < 6; ++q4) {
      float4 wv = wr[q4];
#pragma unroll
      for (int i = 0; i < 4; ++i) {
        acc[i][4 * q4 + 0] += in_c * wv.x;
        acc[i][4 * q4 + 1] += in_c * wv.y;
        acc[i][4 * q4 + 2] += in_c * wv.z;
        acc[i][4 * q4 + 3] += in_c * wv.w;
      }
    }
  }
  for (int c = 0; c < 64; ++c) {
    float xic = xs[pb][c];
    float in0 = xs[jn[0]][c] - xic;
    float in1 = xs[jn[1]][c] - xic;
    float in2 = xs[jn[2]][c] - xic;
    float in3 = xs[jn[3]][c] - xic;
    const float4* wr = reinterpret_cast<const float4*>(&w1s[64 + c][n0]);
#pragma unroll
    for (int q4 = 0; q4 < 6; ++q4) {
      float4 wv = wr[q4];
      acc[0][4 * q4 + 0] += in0 * wv.x; acc[0][4 * q4 + 1] += in0 * wv.y;
      acc[0][4 * q4 + 2] += in0 * wv.z; acc[0][4 * q4 + 3] += in0 * wv.w;
      acc[1][4 * q4 + 0] += in1 * wv.x; acc[1][4 * q4 + 1] += in1 * wv.y;
      acc[1][4 * q4 + 2] += in1 * wv.z; acc[1][4 * q4 + 3] += in1 * wv.w;
      acc[2][4 * q4 + 0] += in2 * wv.x; acc[2][4 * q4 + 1] += in2 * wv.y;
      acc[2][4 * q4 + 2] += in2 * wv.z; acc[2][4 * q4 + 3] += in2 * wv.w;
      acc[3][4 * q4 + 0] += in3 * wv.x; acc[3][4 * q4 + 1] += in3 * wv.y;
      acc[3][4 * q4 + 2] += in3 * wv.z; acc[3][4 * q4 + 3] += in3 * wv.w;
    }
  }
#pragma unroll
  for (int i = 0; i < 4; ++i) {
    float* hrow = H + ((size_t)b * 512 + pb * 4 + i) * 96 + n0;
#pragma unroll
    for (int q4 = 0; q4 < 6; ++q4) {
      float4 v = {elu_f(acc[i][4 * q4 + 0]), elu_f(acc[i][4 * q4 + 1]),
                  elu_f(acc[i][4 * q4 + 2]), elu_f(acc[i][4 * q4 + 3])};
      *reinterpret_cast<float4*>(&hrow[4 * q4]) = v;
    }
  }
}

// ---------------------------------------------------------------- ec2b ----
__global__ __launch_bounds__(512, 2) void ec2b_kernel(
    const float* __restrict__ H, const float* __restrict__ w2,
    const float* __restrict__ b2, float* __restrict__ out) {
  __shared__ __align__(16) float hsT[96][260];
  __shared__ float w2s[96][132];
  __shared__ float b2s[128];
  const int z = blockIdx.x, t = threadIdx.x;
  const int bc = z >> 1, hh = z & 1;
  const float* Hb = H + ((size_t)bc * 512 + hh * 256) * 96;
  for (int i = t; i < 256 * 96; i += 512) hsT[i % 96][i / 96] = Hb[i];
  for (int i = t; i < 96 * 128; i += 512) w2s[i >> 7][i & 127] = w2[i];
  if (t < 128) b2s[t] = b2[t];
  __syncthreads();
  const int g = t >> 3, oq = t & 7;
  float acc[4][16];
#pragma unroll
  for (int m = 0; m < 16; ++m) {
    float bv = b2s[oq + 8 * m];
#pragma unroll
    for (int i = 0; i < 4; ++i) acc[i][m] = bv;
  }
  for (int k = 0; k < 96; ++k) {
    float4 hv = *reinterpret_cast<const float4*>(&hsT[k][4 * g]);
#pragma unroll
    for (int m = 0; m < 16; ++m) {
      float wv = w2s[k][oq + 8 * m];
      acc[0][m] += hv.x * wv;
      acc[1][m] += hv.y * wv;
      acc[2][m] += hv.z * wv;
      acc[3][m] += hv.w * wv;
    }
  }
  float* orow = out + ((size_t)bc * NPT + hh * 64 + g) * 128;
#pragma unroll
  for (int m = 0; m < 16; ++m) {
    float s = elu_f(acc[0][m]) + elu_f(acc[1][m]) +
              elu_f(acc[2][m]) + elu_f(acc[3][m]);
    orow[oq + 8 * m] = 0.25f * s;
  }
}

// ---------------------------------------------------------------- ec3a ----
// W1t staged via linear uint4 copy from the prep-converted image.
__global__ __launch_bounds__(512, 2) void ec3a_kernel(
    const float* __restrict__ x, const int* __restrict__ idx,
    const unsigned short* __restrict__ w1t3g, const float* __restrict__ b1,
    unsigned short* __restrict__ h1) {
  __shared__ unsigned short Xb[128][136];
  __shared__ __align__(16) unsigned short W1t[192][264];
  __shared__ float b1s[192];
  __shared__ unsigned short stg[8][16][40];
  const int b = blockIdx.x, t = threadIdx.x;
  const float* xb = x + (size_t)b * NPT * 128;
  for (int e = t; e < NPT * 128; e += 512) Xb[e >> 7][e & 127] = f2bf(xb[e]);
  {
    const uint4v* src = reinterpret_cast<const uint4v*>(w1t3g);
    uint4v* dst = reinterpret_cast<uint4v*>(&W1t[0][0]);
    for (int i = t; i < 192 * 264 / 8; i += 512) dst[i] = src[i];
  }
  if (t < 192) b1s[t] = b1[t];
  __syncthreads();
  const int w = t >> 6, l = t & 63;
  const int lr = l & 15, lq = l >> 4;
  for (int mt = 0; mt < 4; ++mt) {
    const int m = (w * 4 + mt) * 16;
    const int e = m + lr;
    const int p = e >> 2;
    const int jp = idx[(size_t)b * 512 + e];
    short8 A[8];
#pragma unroll
    for (int kk = 0; kk < 4; ++kk) {
      int k0 = kk * 32 + lq * 8;
      A[kk] = *reinterpret_cast<const short8*>(&Xb[p][k0]);
    }
#pragma unroll
    for (int kk = 0; kk < 4; ++kk) {
      int k0 = kk * 32 + lq * 8;
      short8 aj = *reinterpret_cast<const short8*>(&Xb[jp][k0]);
      short8 ai = *reinterpret_cast<const short8*>(&Xb[p][k0]);
      short8 d;
#pragma unroll
      for (int q = 0; q < 8; ++q)
        d[q] = (short)f2bf(bf2f((unsigned short)aj[q]) - bf2f((unsigned short)ai[q]));
      A[4 + kk] = d;
    }
    floatx4 acc[12];
#pragma unroll
    for (int n = 0; n < 12; ++n) acc[n] = (floatx4){0.f, 0.f, 0.f, 0.f};
#pragma unroll
    for (int n = 0; n < 12; ++n) {
#pragma unroll
      for (int kk = 0; kk < 8; ++kk) {
        short8 Bf = *reinterpret_cast<const short8*>(&W1t[n * 16 + lr][kk * 32 + lq * 8]);
        acc[n] = __builtin_amdgcn_mfma_f32_16x16x32_bf16(A[kk], Bf, acc[n], 0, 0, 0);
      }
    }
#pragma unroll
    for (int pr = 0; pr < 6; ++pr) {
      float bv0 = b1s[pr * 32 + lr];
      float bv1 = b1s[pr * 32 + 16 + lr];
#pragma unroll
      for (int i = 0; i < 4; ++i) {
        stg[w][lq * 4 + i][lr]      = f2bf(elu_f(acc[2 * pr][i] + bv0));
        stg[w][lq * 4 + i][16 + lr] = f2bf(elu_f(acc[2 * pr + 1][i] + bv1));
      }
      asm volatile("s_waitcnt lgkmcnt(0)" ::: "memory");
      const unsigned short* src = &stg[w][l >> 2][(l & 3) * 8];
      uint4v vv = *reinterpret_cast<const uint4v*>(src);
      size_t dst = ((size_t)b * 512 + m + (l >> 2)) * 192 + pr * 32 + (l & 3) * 8;
      *reinterpret_cast<uint4v*>(&h1[dst]) = vv;
      asm volatile("s_waitcnt lgkmcnt(0)" ::: "memory");
    }
  }
}

// ---------------------------------------------------------------- ec3b ----
// W2t staged via linear uint4 copy from the prep-converted image.
__global__ __launch_bounds__(512, 2) void ec3b_kernel(
    const unsigned short* __restrict__ h1,
    const unsigned short* __restrict__ w2t3g, const float* __restrict__ b2,
    unsigned short* __restrict__ out3) {
  __shared__ __align__(16) unsigned short W2t[256][200];
  __shared__ float b2s[256];
  const int b = blockIdx.x, t = threadIdx.x;
  {
    const uint4v* src = reinterpret_cast<const uint4v*>(w2t3g);
    uint4v* dst = reinterpret_cast<uint4v*>(&W2t[0][0]);
    for (int i = t; i < 256 * 200 / 8; i += 512) dst[i] = src[i];
  }
  if (t < 256) b2s[t] = b2[t];
  __syncthreads();
  const int w = t >> 6, l = t & 63;
  const int lr = l & 15, lq = l >> 4;
  for (int mt = 0; mt < 4; ++mt) {
    const int m = (w * 4 + mt) * 16;
    floatx4 acc[16];
#pragma unroll
    for (int n = 0; n < 16; ++n) acc[n] = (floatx4){0.f, 0.f, 0.f, 0.f};
    const unsigned short* arow = h1 + ((size_t)b * 512 + m + lr) * 192;
#pragma unroll
    for (int kk = 0; kk < 6; ++kk) {
      short8 Af = *reinterpret_cast<const short8*>(&arow[kk * 32 + lq * 8]);
#pragma unroll
      for (int n = 0; n < 16; ++n) {
        short8 Bf = *reinterpret_cast<const short8*>(&W2t[n * 16 + lr][kk * 32 + lq * 8]);
        acc[n] = __builtin_amdgcn_mfma_f32_16x16x32_bf16(Af, Bf, acc[n], 0, 0, 0);
      }
    }
    unsigned short* orow = out3 + ((size_t)b * NPT + (m >> 2) + lq) * 256;
#pragma unroll
    for (int n = 0; n < 16; ++n) {
      float bv = b2s[n * 16 + lr];
      float s = 0.f;
#pragma unroll
      for (int i = 0; i < 4; ++i) s += elu_f(acc[n][i] + bv);
      orow[n * 16 + lr] = f2bf(0.25f * s);
    }
  }
}

// ------------------------------------------------------------ prep -------
// Converts head weights (w1p/w2p) and ec3 weight LDS images (w1t3g/w2t3g).
__global__ __launch_bounds__(256) void prep_kernel(
    const float* __restrict__ hw1, const float* __restrict__ hw2,
    const float* __restrict__ c3w1, const float* __restrict__ c3w2,
    unsigned short* __restrict__ w1p, unsigned short* __restrict__ w2p,
    unsigned short* __restrict__ w1t3g, unsigned short* __restrict__ w2t3g) {
  int i = blockIdx.x * 256 + threadIdx.x;
  if (i < 512 * 480) {
    int n = i / 480, kp = i % 480;
    int ko = (kp < 5) ? kp : kp - 3;
    bool ok = ((kp < 5) || (kp >= 8 && kp < 456)) && (n < 453);
    w1p[i] = ok ? f2bf(hw1[(size_t)ko * 453 + n]) : (unsigned short)0;
  } else if (i < 512 * 480 + 256 * 480) {
    int j = i - 512 * 480;
    int n = j / 480, kp = j % 480;
    bool ok = (kp < 453) && (n < 226);
    w2p[j] = ok ? f2bf(hw2[(size_t)kp * 226 + n]) : (unsigned short)0;
  } else if (i < 512 * 480 + 256 * 480 + 192 * 264) {
    int m = i - (512 * 480 + 256 * 480);
    int n = m / 264, k = m % 264;
    w1t3g[m] = (k < 256) ? f2bf(c3w1[(size_t)k * 192 + n]) : (unsigned short)0;
  } else {
    int m = i - (512 * 480 + 256 * 480 + 192 * 264);
    if (m < 256 * 200) {
      int n = m / 200, k = m % 200;
      w2t3g[m] = (k < 192) ? f2bf(c3w2[(size_t)k * 256 + n]) : (unsigned short)0;
    }
  }
}

// ----------------------------------------------------------- head MFMA ----
// v3.1: A-fragments built directly from global (padded-concat 8-blocks never
// straddle sources); uA is W-chunk buffer only. tps per-wave transpose (r10).
#define HSTR 488
#define TPSS 72
__global__ __launch_bounds__(256, 2) void head_mfma_kernel(
    const float* __restrict__ feat, const float* __restrict__ o1,
    const float* __restrict__ o2, const unsigned short* __restrict__ o3,
    const unsigned short* __restrict__ w1p, const float* __restrict__ b1,
    const unsigned short* __restrict__ w2p, const float* __restrict__ b2,
    const float* __restrict__ w3, const float* __restrict__ b3,
    float* __restrict__ out) {
  __shared__ unsigned short uA[64 * HSTR];                   // W chunk buffer
  __shared__ __align__(16) unsigned short tps[4][16][TPSS];  // per-wave D->A
  __shared__ float b1s[512], b2s[256], w3s[512];
  const int t = threadIdx.x;
  const size_t base = (size_t)blockIdx.x * 64;

  for (int i = t; i < 512; i += 256) b1s[i] = (i < 453) ? b1[i] : 0.f;
  if (t < 256) b2s[t] = (t < 226) ? b2[t] : 0.f;
  for (int i = t; i < 512; i += 256) w3s[i] = (i < 452) ? w3[i] : 0.f;

  const int w = t >> 6, l = t & 63;
  const int lr = l & 15, lq = l >> 4;
  const int tr = t >> 2, tc = t & 3;
  const size_t grow = base + w * 16 + lr;   // this thread's X row

  // ---- A1 fragments straight from global (bit-identical to staged path) ----
  short8 Af[15];
#pragma unroll
  for (int kk = 0; kk < 15; ++kk) {
    const int kbase = kk * 32 + lq * 8;
    short8 r;
    if (kbase >= 456) {
#pragma unroll
      for (int q = 0; q < 8; ++q) r[q] = 0;
    } else if (kbase >= 200) {
      r = *reinterpret_cast<const short8*>(&o3[grow * 256 + (kbase - 200)]);
    } else if (kbase >= 72) {
      const float* s = &o2[grow * 128 + (kbase - 72)];
#pragma unroll
      for (int q = 0; q < 8; ++q) r[q] = (short)f2bf(s[q]);
    } else if (kbase >= 8) {
      const float* s = &o1[grow * 64 + (kbase - 8)];
#pragma unroll
      for (int q = 0; q < 8; ++q) r[q] = (short)f2bf(s[q]);
    } else {
      const float* s = &feat[grow * 5];
#pragma unroll
      for (int q = 0; q < 8; ++q) r[q] = (q < 5) ? (short)f2bf(s[q]) : (short)0;
    }
    Af[kk] = r;
  }

  uint4v v[15];
#define WLOAD(SRC, CH)                                                   \
  {                                                                      \
    _Pragma("unroll")                                                    \
    for (int i = 0; i < 15; ++i)                                         \
      v[i] = *reinterpret_cast<const uint4v*>(                           \
          &SRC[((size_t)((CH) * 64 + tr)) * 480 + (tc + 4 * i) * 8]);    \
  }
#define WWRITE()                                                         \
  {                                                                      \
    _Pragma("unroll")                                                    \
    for (int i = 0; i < 15; ++i)                                         \
      *reinterpret_cast<uint4v*>(&uA[tr * HSTR + (tc + 4 * i) * 8]) = v[i]; \
  }

  WLOAD(w1p, 0)
  WWRITE()
  __syncthreads();

  short8 Af2[15];
  // ---- GEMM1: 8 chunks of 64 cols; Af2 built incrementally via tps ----
#pragma unroll
  for (int ch = 0; ch < 8; ++ch) {
    if (ch < 7) WLOAD(w1p, ch + 1)
    else       WLOAD(w2p, 0)
    floatx4 a0 = {0.f, 0.f, 0.f, 0.f}, a1 = {0.f, 0.f, 0.f, 0.f};
    floatx4 a2 = {0.f, 0.f, 0.f, 0.f}, a3 = {0.f, 0.f, 0.f, 0.f};
#pragma unroll
    for (int kk = 0; kk < 15; ++kk) {
      int ko = kk * 32 + lq * 8;
      short8 B0 = *reinterpret_cast<const short8*>(&uA[(lr)*HSTR + ko]);
      short8 B1 = *reinterpret_cast<const short8*>(&uA[(16 + lr) * HSTR + ko]);
      short8 B2 = *reinterpret_cast<const short8*>(&uA[(32 + lr) * HSTR + ko]);
      short8 B3 = *reinterpret_cast<const short8*>(&uA[(48 + lr) * HSTR + ko]);
      a0 = __builtin_amdgcn_mfma_f32_16x16x32_bf16(Af[kk], B0, a0, 0, 0, 0);
      a1 = __builtin_amdgcn_mfma_f32_16x16x32_bf16(Af[kk], B1, a1, 0, 0, 0);
      a2 = __builtin_amdgcn_mfma_f32_16x16x32_bf16(Af[kk], B2, a2, 0, 0, 0);
      a3 = __builtin_amdgcn_mfma_f32_16x16x32_bf16(Af[kk], B3, a3, 0, 0, 0);
    }
    {
      floatx4 aj[4] = {a0, a1, a2, a3};
#pragma unroll
      for (int jx = 0; jx < 4; ++jx) {
        int c = ch * 64 + jx * 16 + lr;
        float bb = b1s[c];
#pragma unroll
        for (int i = 0; i < 4; ++i)
          tps[w][lq * 4 + i][jx * 16 + lr] = f2bf(elu_f(aj[jx][i] + bb));
      }
    }
    asm volatile("s_waitcnt lgkmcnt(0)" ::: "memory");
    Af2[2 * ch] = *reinterpret_cast<const short8*>(&tps[w][lr][lq * 8]);
    if (ch < 7)
      Af2[2 * ch + 1] = *reinterpret_cast<const short8*>(&tps[w][lr][32 + lq * 8]);
    asm volatile("s_waitcnt lgkmcnt(0)" ::: "memory");
    __syncthreads();
    WWRITE()
    __syncthreads();
  }

  // ---- GEMM2: 4 chunks of 64 cols + fp32 GEMM3 partials ----
  float p0[4] = {0.f, 0.f, 0.f, 0.f}, p1[4] = {0.f, 0.f, 0.f, 0.f};
#pragma unroll
  for (int ch = 0; ch < 4; ++ch) {
    if (ch < 3) WLOAD(w2p, ch + 1)
    floatx4 a0 = {0.f, 0.f, 0.f, 0.f}, a1 = {0.f, 0.f, 0.f, 0.f};
    floatx4 a2 = {0.f, 0.f, 0.f, 0.f}, a3 = {0.f, 0.f, 0.f, 0.f};
#pragma unroll
    for (int kk = 0; kk < 15; ++kk) {
      int ko = kk * 32 + lq * 8;
      short8 B0 = *reinterpret_cast<const short8*>(&uA[(lr)*HSTR + ko]);
      short8 B1 = *reinterpret_cast<const short8*>(&uA[(16 + lr) * HSTR + ko]);
      short8 B2 = *reinterpret_cast<const short8*>(&uA[(32 + lr) * HSTR + ko]);
      short8 B3 = *reinterpret_cast<const short8*>(&uA[(48 + lr) * HSTR + ko]);
      a0 = __builtin_amdgcn_mfma_f32_16x16x32_bf16(Af2[kk], B0, a0, 0, 0, 0);
      a1 = __builtin_amdgcn_mfma_f32_16x16x32_bf16(Af2[kk], B1, a1, 0, 0, 0);
      a2 = __builtin_amdgcn_mfma_f32_16x16x32_bf16(Af2[kk], B2, a2, 0, 0, 0);
      a3 = __builtin_amdgcn_mfma_f32_16x16x32_bf16(Af2[kk], B3, a3, 0, 0, 0);
    }
    {
      floatx4 aj[4] = {a0, a1, a2, a3};
#pragma unroll
      for (int jx = 0; jx < 4; ++jx) {
        int c = ch * 64 + jx * 16 + lr;
        float bb = b2s[c];
        float wa = w3s[2 * c], wb = w3s[2 * c + 1];
#pragma unroll
        for (int i = 0; i < 4; ++i) {
          float h = (c < 226) ? elu_f(aj[jx][i] + bb) : 0.f;
          p0[i] += h * wa;
          p1[i] += h * wb;
        }
      }
    }
    if (ch < 3) {
      __syncthreads();
      WWRITE()
      __syncthreads();
    }
  }

#pragma unroll
  for (int i = 0; i < 4; ++i) {
    float a = p0[i], bvv = p1[i];
#pragma unroll
    for (int m = 1; m < 16; m <<= 1) {
      a += __shfl_xor(a, m);
      bvv += __shfl_xor(bvv, m);
    }
    if (lr == 0) {
      size_t row = base + w * 16 + lq * 4 + i;
      float2 vv = {a + b3[0], bvv + b3[1]};
      *reinterpret_cast<float2*>(&out[row * 2]) = vv;
    }
  }
#undef WLOAD
#undef WWRITE
}

// ------------------------------------------------------------- launch ----
extern "C" void kernel_launch(void* const* d_in, const int* in_sizes, int n_in,
                              void* d_out, int out_size, void* d_ws, size_t ws_size,
                              hipStream_t stream) {
  const float* coords = (const float*)d_in[0];
  const float* feat   = (const float*)d_in[1];
  const float* c1w1 = (const float*)d_in[2];  const float* c1b1 = (const float*)d_in[3];
  const float* c1w2 = (const float*)d_in[4];  const float* c1b2 = (const float*)d_in[5];
  const float* c2w1 = (const float*)d_in[6];  const float* c2b1 = (const float*)d_in[7];
  const float* c2w2 = (const float*)d_in[8];  const float* c2b2 = (const float*)d_in[9];
  const float* c3w1 = (const float*)d_in[10]; const float* c3b1 = (const float*)d_in[11];
  const float* c3w2 = (const float*)d_in[12]; const float* c3b2 = (const float*)d_in[13];
  const float* ow1  = (const float*)d_in[14]; const float* ob1  = (const float*)d_in[15];
  const float* ow2  = (const float*)d_in[16]; const float* ob2  = (const float*)d_in[17];
  const float* ow3  = (const float*)d_in[18]; const float* ob3  = (const float*)d_in[19];
  float* out = (float*)d_out;

  char* ws = (char*)d_ws;
  float* out1 = (float*)(ws);                                  // [0,32) MiB
  float* out2 = (float*)(ws + (32ull << 20));                  // [32,96)
  unsigned short* out3b = (unsigned short*)(ws + (96ull << 20)); // [96,160)
  float* Hbuf2 = (float*)(ws + (96ull << 20));                 // [96,192) ec2 temp
  unsigned short* h1 = (unsigned short*)(ws + (162ull << 20)); // [162,212) ec3 temp
  unsigned short* w1p = (unsigned short*)(ws + (212ull << 20));
  unsigned short* w2p = (unsigned short*)(ws + (212ull << 20) + (512ull << 10));
  unsigned short* w1t3g = (unsigned short*)(ws + (213ull << 20));
  unsigned short* w2t3g = (unsigned short*)(ws + (213ull << 20) + (256ull << 10));
  int* idx = (int*)(ws + (214ull << 20));                      // [214,216)

  prep_kernel<<<1838, 256, 0, stream>>>(ow1, ow2, c3w1, c3w2,
                                        w1p, w2p, w1t3g, w2t3g);
  knn_kernel<2><<<NB, 128, 0, stream>>>(coords, idx);
  ec1_kernel<<<2 * NB, 256, 0, stream>>>(feat, idx, c1w1, c1b1, c1w2, c1b2, out1);
  knn512_kernel<64><<<NB, 512, 0, stream>>>(out1, idx);
  for (int c = 0; c < 2; ++c) {
    ec2a_kernel<<<512, 512, 0, stream>>>(out1 + (size_t)c * 512 * NPT * 64,
                                         idx + (size_t)c * 512 * 512,
                                         c2w1, c2b1, Hbuf2);
    ec2b_kernel<<<1024, 512, 0, stream>>>(Hbuf2, c2w2, c2b2,
                                          out2 + (size_t)c * 512 * NPT * 128);
  }
  knn512_kernel<128><<<NB, 512, 0, stream>>>(out2, idx);
  for (int c = 0; c < 4; ++c) {
    ec3a_kernel<<<256, 512, 0, stream>>>(out2 + (size_t)c * 256 * NPT * 128,
                                         idx + (size_t)c * 256 * 512,
                                         w1t3g, c3b1, h1);
    ec3b_kernel<<<256, 512, 0, stream>>>(h1, w2t3g, c3b2,
                                         out3b + (size_t)c * 256 * NPT * 256);
  }
  head_mfma_kernel<<<2048, 256, 0, stream>>>(feat, out1, out2, out3b,
                                             w1p, ob1, w2p, ob2, ow3, ob3, out);
}

// Round 12
// 1733.613 us; speedup vs baseline: 23.7674x; 1.1426x over previous
//
#include <hip/hip_runtime.h>
#include <cstdint>
#include <cstddef>

// ParticleNet MI355X — Round 12.
// - kNN C=2: r2 (verified). kNN C=64/128: NEW MFMA Gram-matrix kernel with
//   bf16 hi/lo split (err ~1e-4 abs) + reg-local top-6 + fp64 rescore
//   (r11 quarter-split version was VALU-bound at 256 us each).
// - ec1 (r7), ec2 (r11 2-chunk), ec3 (r11 prep-image), head (r11 v3.1),
//   prep (r11): verified, unchanged.

#define NB 1024
#define NPT 128

typedef __attribute__((ext_vector_type(8))) short short8;
typedef __attribute__((ext_vector_type(4))) float floatx4;
typedef __attribute__((ext_vector_type(4))) unsigned int uint4v;

__device__ __forceinline__ float elu_f(float x) { return x > 0.0f ? x : expm1f(x); }

__device__ __forceinline__ unsigned short f2bf(float f) {
  unsigned u = __builtin_bit_cast(unsigned, f);
  unsigned r = u + 0x7FFFu + ((u >> 16) & 1u);
  return (unsigned short)(r >> 16);
}
__device__ __forceinline__ float bf2f(unsigned short h) {
  unsigned u = ((unsigned)h) << 16;
  return __builtin_bit_cast(float, u);
}

// top-6 insertion cascade (strict <): shared by all kNN kernels
#define INS6(dv, jv)                                                    \
  if ((dv) < bd5) {                                                     \
    bd5 = (dv); bi5 = (jv);                                             \
    if (bd5 < bd4) {                                                    \
      float _t = bd4; bd4 = bd5; bd5 = _t; int _i = bi4; bi4 = bi5; bi5 = _i; \
      if (bd4 < bd3) {                                                  \
        _t = bd3; bd3 = bd4; bd4 = _t; _i = bi3; bi3 = bi4; bi4 = _i;   \
        if (bd3 < bd2) {                                                \
          _t = bd2; bd2 = bd3; bd3 = _t; _i = bi2; bi2 = bi3; bi3 = _i; \
          if (bd2 < bd1) {                                              \
            _t = bd1; bd1 = bd2; bd2 = _t; _i = bi1; bi1 = bi2; bi2 = _i; \
            if (bd1 < bd0) {                                            \
              _t = bd0; bd0 = bd1; bd1 = _t; _i = bi0; bi0 = bi1; bi1 = _i; \
            } } } } } }

// ------------------------------------------------------------- kNN C=2 ----
template<int C>
__global__ __launch_bounds__(128) void knn_kernel(const float* __restrict__ x,
                                                  int* __restrict__ idx) {
  __shared__ __align__(16) float xs[NPT][C + 4];
  __shared__ float x2s[NPT];
  __shared__ double x2d[NPT];
  const int b = blockIdx.x, t = threadIdx.x;
  const float* xb = x + (size_t)b * NPT * C;
  for (int e = t; e < NPT * C; e += 128) xs[e / C][e % C] = xb[e];
  __syncthreads();
  float xi[C];
  float s2 = 0.0f;
  double s2d = 0.0;
#pragma unroll
  for (int c = 0; c < C; ++c) {
    xi[c] = xs[t][c];
    s2 += xi[c] * xi[c];
    s2d += (double)xi[c] * (double)xi[c];
  }
  x2s[t] = s2;
  x2d[t] = s2d;
  __syncthreads();
  float bd0 = 1e30f, bd1 = 1e30f, bd2 = 1e30f, bd3 = 1e30f, bd4 = 1e30f, bd5 = 1e30f;
  int bi0 = 0, bi1 = 0, bi2 = 0, bi3 = 0, bi4 = 0, bi5 = 0;
  for (int j = 0; j < NPT; ++j) {
    if (j == t) continue;
    float dot = 0.0f;
#pragma unroll
    for (int c = 0; c < C; ++c) dot += xi[c] * xs[j][c];
    float d = s2 + x2s[j] - 2.0f * dot;
    INS6(d, j)
  }
  auto refine = [&](int j) -> double {
    double dot = 0.0;
#pragma unroll
    for (int c = 0; c < C; ++c) dot += (double)xi[c] * (double)xs[j][c];
    return s2d + x2d[j] - 2.0 * dot;
  };
  double e0 = refine(bi0), e1 = refine(bi1), e2 = refine(bi2);
  double e3 = refine(bi3), e4 = refine(bi4), e5 = refine(bi5);
#define CSWP(da, ia, db, ib)                                            \
  if ((da > db) || (da == db && ia > ib)) {                             \
    double _td = da; da = db; db = _td; int _ti = ia; ia = ib; ib = _ti; }
  CSWP(e0, bi0, e1, bi1) CSWP(e1, bi1, e2, bi2) CSWP(e2, bi2, e3, bi3)
  CSWP(e3, bi3, e4, bi4) CSWP(e4, bi4, e5, bi5)
  CSWP(e0, bi0, e1, bi1) CSWP(e1, bi1, e2, bi2) CSWP(e2, bi2, e3, bi3)
  CSWP(e3, bi3, e4, bi4)
  CSWP(e0, bi0, e1, bi1) CSWP(e1, bi1, e2, bi2) CSWP(e2, bi2, e3, bi3)
  CSWP(e0, bi0, e1, bi1) CSWP(e1, bi1, e2, bi2)
  CSWP(e0, bi0, e1, bi1)
#undef CSWP
  int* ib = idx + ((size_t)b * NPT + t) * 4;
  ib[0] = bi0; ib[1] = bi1; ib[2] = bi2; ib[3] = bi3;
}

// ------------------------------------------------- kNN C=64/128 (MFMA) ----
// Gram matrix via bf16 hi/lo split (3 MFMA/term-pair, fp32 accum, abs err
// ~1e-4 << neighbor gaps) -> per-lane top-6 over 32 reg-local distances ->
// 2-round shfl merge -> fp64 rescore from fp32 X (LDS re-staged) = exact
// ordering among shortlist (same guarantee as all passing rounds).
// Block = 1 event, 512 thr, 8 waves; wave w owns queries i = 16w+lr.
template<int C>
__global__ __launch_bounds__(512) void knn_mfma_kernel(const float* __restrict__ x,
                                                       int* __restrict__ idx) {
  constexpr int KC = C / 32;      // MFMA k-chunks
  constexpr int HS = C + 8;       // hi/lo row stride (shorts)
  constexpr int FS = C + 4;       // fp32 row stride (floats)
  constexpr int CQ = C / 4;       // rescore quarter
  __shared__ __align__(16) unsigned short lbuf[2 * NPT * HS];
  __shared__ float x2s[NPT];
  __shared__ double x2d[NPT];
  unsigned short* Xhi = lbuf;
  unsigned short* Xlo = lbuf + NPT * HS;
  float* Xs = reinterpret_cast<float*>(lbuf);
  const int b = blockIdx.x, t = threadIdx.x;
  const float* xb = x + (size_t)b * NPT * C;
  // phase A: stage bf16 hi/lo (v-hi is exact in fp32; lo rounds to bf16)
  for (int e = t; e < NPT * C; e += 512) {
    int r = e / C, c = e % C;
    float v = xb[e];
    unsigned short h = f2bf(v);
    Xhi[r * HS + c] = h;
    Xlo[r * HS + c] = f2bf(v - bf2f(h));
  }
  // phase A2: x2 fp32 + fp64 (quarter-split per point)
  {
    const int p = t >> 2, q = t & 3;
    const float4* r4 = reinterpret_cast<const float4*>(xb + p * C + q * CQ);
    float s2 = 0.f;
    double s2d = 0.0;
#pragma unroll
    for (int c4 = 0; c4 < CQ / 4; ++c4) {
      float4 v = r4[c4];
      s2 += v.x * v.x + v.y * v.y + v.z * v.z + v.w * v.w;
      s2d += (double)v.x * v.x + (double)v.y * v.y +
             (double)v.z * v.z + (double)v.w * v.w;
    }
    s2 += __shfl_xor(s2, 1);  s2 += __shfl_xor(s2, 2);
    s2d += __shfl_xor(s2d, 1); s2d += __shfl_xor(s2d, 2);
    if (q == 0) { x2s[p] = s2; x2d[p] = s2d; }
  }
  __syncthreads();
  const int w = t >> 6, l = t & 63;
  const int lr = l & 15, lq = l >> 4;
  const int iq = w * 16 + lr;          // this lane's query point
  // B fragments: query rows (hi & lo)
  short8 Bhi[KC], Blo[KC];
#pragma unroll
  for (int kk = 0; kk < KC; ++kk) {
    Bhi[kk] = *reinterpret_cast<const short8*>(&Xhi[iq * HS + kk * 32 + lq * 8]);
    Blo[kk] = *reinterpret_cast<const short8*>(&Xlo[iq * HS + kk * 32 + lq * 8]);
  }
  const float x2i = x2s[iq];
  float bd0 = 1e30f, bd1 = 1e30f, bd2 = 1e30f, bd3 = 1e30f, bd4 = 1e30f, bd5 = 1e30f;
  int bi0 = 0, bi1 = 0, bi2 = 0, bi3 = 0, bi4 = 0, bi5 = 0;
#pragma unroll
  for (int jt = 0; jt < 8; ++jt) {
    short8 Ahi[KC], Alo[KC];
#pragma unroll
    for (int kk = 0; kk < KC; ++kk) {
      Ahi[kk] = *reinterpret_cast<const short8*>(
          &Xhi[(jt * 16 + lr) * HS + kk * 32 + lq * 8]);
      Alo[kk] = *reinterpret_cast<const short8*>(
          &Xlo[(jt * 16 + lr) * HS + kk * 32 + lq * 8]);
    }
    floatx4 g = {0.f, 0.f, 0.f, 0.f};
#pragma unroll
    for (int kk = 0; kk < KC; ++kk) {
      g = __builtin_amdgcn_mfma_f32_16x16x32_bf16(Ahi[kk], Bhi[kk], g, 0, 0, 0);
      g = __builtin_amdgcn_mfma_f32_16x16x32_bf16(Ahi[kk], Blo[kk], g, 0, 0, 0);
      g = __builtin_amdgcn_mfma_f32_16x16x32_bf16(Alo[kk], Bhi[kk], g, 0, 0, 0);
    }
#pragma unroll
    for (int r = 0; r < 4; ++r) {
      int j = jt * 16 + lq * 4 + r;     // D row = (lane>>4)*4+reg, col = lr
      float d = (j == iq) ? 1e30f : (x2i + x2s[j] - 2.0f * g[r]);
      INS6(d, j)
    }
  }
  // merge the 4 lanes (lq=0..3) holding query iq: xor 16, then xor 32
#pragma unroll
  for (int rnd = 0; rnd < 2; ++rnd) {
    const int m = 16 << rnd;
    float od0 = __shfl_xor(bd0, m), od1 = __shfl_xor(bd1, m), od2 = __shfl_xor(bd2, m);
    float od3 = __shfl_xor(bd3, m), od4 = __shfl_xor(bd4, m), od5 = __shfl_xor(bd5, m);
    int oi0 = __shfl_xor(bi0, m), oi1 = __shfl_xor(bi1, m), oi2 = __shfl_xor(bi2, m);
    int oi3 = __shfl_xor(bi3, m), oi4 = __shfl_xor(bi4, m), oi5 = __shfl_xor(bi5, m);
    INS6(od0, oi0) INS6(od1, oi1) INS6(od2, oi2)
    INS6(od3, oi3) INS6(od4, oi4) INS6(od5, oi5)
  }
  // broadcast lq=0's list so all 4 lanes agree bit-exactly
  bi0 = __shfl(bi0, lr); bi1 = __shfl(bi1, lr); bi2 = __shfl(bi2, lr);
  bi3 = __shfl(bi3, lr); bi4 = __shfl(bi4, lr); bi5 = __shfl(bi5, lr);
  __syncthreads();
  // phase C: overwrite LDS with fp32 X for exact rescore
  for (int e = t; e < NPT * C; e += 512) {
    int r = e / C, c = e % C;
    Xs[r * FS + c] = xb[e];
  }
  __syncthreads();
  const double x2di = x2d[iq];
  auto refine = [&](int j) -> double {
    double dot = 0.0;
    const float* ri = &Xs[iq * FS + lq * CQ];
    const float* rj = &Xs[j * FS + lq * CQ];
#pragma unroll
    for (int c = 0; c < CQ; ++c) dot += (double)ri[c] * (double)rj[c];
    dot += __shfl_xor(dot, 16);
    dot += __shfl_xor(dot, 32);
    return x2di + x2d[j] - 2.0 * dot;
  };
  double e0 = refine(bi0), e1 = refine(bi1), e2 = refine(bi2);
  double e3 = refine(bi3), e4 = refine(bi4), e5 = refine(bi5);
#define CSWP(da, ia, db, ib)                                            \
  if ((da > db) || (da == db && ia > ib)) {                             \
    double _td = da; da = db; db = _td; int _ti = ia; ia = ib; ib = _ti; }
  CSWP(e0, bi0, e1, bi1) CSWP(e1, bi1, e2, bi2) CSWP(e2, bi2, e3, bi3)
  CSWP(e3, bi3, e4, bi4) CSWP(e4, bi4, e5, bi5)
  CSWP(e0, bi0, e1, bi1) CSWP(e1, bi1, e2, bi2) CSWP(e2, bi2, e3, bi3)
  CSWP(e3, bi3, e4, bi4)
  CSWP(e0, bi0, e1, bi1) CSWP(e1, bi1, e2, bi2) CSWP(e2, bi2, e3, bi3)
  CSWP(e0, bi0, e1, bi1) CSWP(e1, bi1, e2, bi2)
  CSWP(e0, bi0, e1, bi1)
#undef CSWP
  if (lq == 0) {
    int* ib = idx + ((size_t)b * NPT + iq) * 4;
    ib[0] = bi0; ib[1] = bi1; ib[2] = bi2; ib[3] = bi3;
  }
}

// ---------------------------------------------------------------- ec1 ----
__global__ __launch_bounds__(256) void ec1_kernel(
    const float* __restrict__ feat, const int* __restrict__ idx,
    const float* __restrict__ w1, const float* __restrict__ b1,
    const float* __restrict__ w2, const float* __restrict__ b2,
    float* __restrict__ out) {
  __shared__ __align__(16) float fs[NPT][6];
  __shared__ __align__(16) float w1s[10][32];
  __shared__ __align__(16) float w2s[32][68];
  __shared__ float hs[256][33];
  __shared__ float b1s[32], b2s[64];
  const int z = blockIdx.x, t = threadIdx.x;
  const int b = z >> 1, hh = z & 1;
  const float* fb = feat + (size_t)b * NPT * 5;
  for (int e = t; e < NPT * 5; e += 256) fs[e / 5][e % 5] = fb[e];
  for (int e = t; e < 320; e += 256) w1s[e / 32][e % 32] = w1[e];
  for (int e = t; e < 2048; e += 256) w2s[e >> 6][e & 63] = w2[e];
  if (t < 32) b1s[t] = b1[t];
  if (t >= 192) b2s[t - 192] = b2[t - 192];
  __syncthreads();
  {
    const int p = hh * 64 + (t >> 2);
    const int j = idx[(size_t)b * 512 + p * 4 + (t & 3)];
    float h[32];
#pragma unroll
    for (int o = 0; o < 32; ++o) h[o] = b1s[o];
#pragma unroll
    for (int c = 0; c < 10; ++c) {
      float in_c = (c < 5) ? fs[p][c] : (fs[j][c - 5] - fs[p][c - 5]);
      const float4* wr = reinterpret_cast<const float4*>(&w1s[c][0]);
#pragma unroll
      for (int o4 = 0; o4 < 8; ++o4) {
        float4 w = wr[o4];
        h[4 * o4 + 0] += in_c * w.x; h[4 * o4 + 1] += in_c * w.y;
        h[4 * o4 + 2] += in_c * w.z; h[4 * o4 + 3] += in_c * w.w;
      }
    }
#pragma unroll
    for (int o = 0; o < 32; ++o) hs[t][o] = elu_f(h[o]);
  }
  __syncthreads();
  {
    const int g = t >> 2, q = t & 3;
    const int o0 = q * 16;
    float acc[4][16];
#pragma unroll
    for (int m = 0; m < 16; ++m) {
      float bv = b2s[o0 + m];
#pragma unroll
      for (int i = 0; i < 4; ++i) acc[i][m] = bv;
    }
    for (int k = 0; k < 32; ++k) {
      float hk0 = hs[g * 4 + 0][k];
      float hk1 = hs[g * 4 + 1][k];
      float hk2 = hs[g * 4 + 2][k];
      float hk3 = hs[g * 4 + 3][k];
      const float4* wr = reinterpret_cast<const float4*>(&w2s[k][o0]);
#pragma unroll
      for (int m4 = 0; m4 < 4; ++m4) {
        float4 w = wr[m4];
        acc[0][4 * m4 + 0] += hk0 * w.x; acc[0][4 * m4 + 1] += hk0 * w.y;
        acc[0][4 * m4 + 2] += hk0 * w.z; acc[0][4 * m4 + 3] += hk0 * w.w;
        acc[1][4 * m4 + 0] += hk1 * w.x; acc[1][4 * m4 + 1] += hk1 * w.y;
        acc[1][4 * m4 + 2] += hk1 * w.z; acc[1][4 * m4 + 3] += hk1 * w.w;
        acc[2][4 * m4 + 0] += hk2 * w.x; acc[2][4 * m4 + 1] += hk2 * w.y;
        acc[2][4 * m4 + 2] += hk2 * w.z; acc[2][4 * m4 + 3] += hk2 * w.w;
        acc[3][4 * m4 + 0] += hk3 * w.x; acc[3][4 * m4 + 1] += hk3 * w.y;
        acc[3][4 * m4 + 2] += hk3 * w.z; acc[3][4 * m4 + 3] += hk3 * w.w;
      }
    }
    float* ob = out + ((size_t)b * NPT + hh * 64 + g) * 64 + o0;
#pragma unroll
    for (int m4 = 0; m4 < 4; ++m4) {
      float4 v;
      float* vp = &v.x;
#pragma unroll
      for (int s = 0; s < 4; ++s) {
        int m = 4 * m4 + s;
        vp[s] = 0.25f * (elu_f(acc[0][m]) + elu_f(acc[1][m]) +
                         elu_f(acc[2][m]) + elu_f(acc[3][m]));
      }
      *reinterpret_cast<float4*>(&ob[4 * m4]) = v;
    }
  }
}

// ---------------------------------------------------------------- ec2a ----
__global__ __launch_bounds__(512, 2) void ec2a_kernel(
    const float* __restrict__ x, const int* __restrict__ idx,
    const float* __restrict__ w1, const float* __restrict__ b1,
    float* __restrict__ H) {
  __shared__ __align__(16) float xs[NPT][68];
  __shared__ __align__(16) float w1s[128][100];
  __shared__ float b1s[96];
  const int b = blockIdx.x, t = threadIdx.x;
  const float* xb = x + (size_t)b * NPT * 64;
  for (int e = t; e < NPT * 64; e += 512) xs[e >> 6][e & 63] = xb[e];
  for (int e = t; e < 128 * 96; e += 512) w1s[e / 96][e % 96] = w1[e];
  if (t < 96) b1s[t] = b1[t];
  __syncthreads();
  const int pb = t >> 2, part = t & 3;
  const int n0 = part * 24;
  int jn[4];
#pragma unroll
  for (int i = 0; i < 4; ++i) jn[i] = idx[(size_t)b * 512 + pb * 4 + i];
  float acc[4][24];
#pragma unroll
  for (int m = 0; m < 24; ++m) {
    float bv = b1s[n0 + m];
#pragma unroll
    for (int i = 0; i < 4; ++i) acc[i][m] = bv;
  }
  for (int c = 0; c < 64; ++c) {
    float in_c = xs[pb][c];
    const float4* wr = reinterpret_cast<const float4*>(&w1s[c][n0]);
#pragma unroll
    for (int q4 = 0; q4 < 6; ++q4) {
      float4 wv = wr[q4];
#pragma unroll
      for (int i = 0; i < 4; ++i) {
        acc[i][4 * q4 + 0] += in_c * wv.x;
        acc[i][4 * q4 + 1] += in_c * wv.y;
        acc[i][4 * q4 + 2] += in_c * wv.z;
        acc[i][4 * q4 + 3] += in_c * wv.w;
      }
    }
  }
  for (int c = 0; c < 64; ++c) {
    float xic = xs[pb][c];
    float in0 = xs[jn[0]][c] - xic;
    float in1 = xs[jn[1]][c] - xic;
    float in2 = xs[jn[2]][c] - xic;
    float in3 = xs[jn[3]][c] - xic;
    const float4* wr = reinterpret_cast<const float4*>(&w1s[64 + c][n0]);
#pragma unroll
    for (int q4 = 0; q4 < 6; ++q4) {
      float4 wv = wr[q4];
      acc[0][4 * q4 + 0] += in0 * wv.x; acc[0][4 * q4 + 1] += in0 * wv.y;
      acc[0][4 * q4 + 2] += in0 * wv.z; acc[0][4 * q4 + 3] += in0 * wv.w;
      acc[1][4 * q4 + 0] += in1 * wv.x; acc[1][4 * q4 + 1] += in1 * wv.y;
      acc[1][4 * q4 + 2] += in1 * wv.z; acc[1][4 * q4 + 3] += in1 * wv.w;
      acc[2][4 * q4 + 0] += in2 * wv.x; acc[2][4 * q4 + 1] += in2 * wv.y;
      acc[2][4 * q4 + 2] += in2 * wv.z; acc[2][4 * q4 + 3] += in2 * wv.w;
      acc[3][4 * q4 + 0] += in3 * wv.x; acc[3][4 * q4 + 1] += in3 * wv.y;
      acc[3][4 * q4 + 2] += in3 * wv.z; acc[3][4 * q4 + 3] += in3 * wv.w;
    }
  }
#pragma unroll
  for (int i = 0; i < 4; ++i) {
    float* hrow = H + ((size_t)b * 512 + pb * 4 + i) * 96 + n0;
#pragma unroll
    for (int q4 = 0; q4 < 6; ++q4) {
      float4 v = {elu_f(acc[i][4 * q4 + 0]), elu_f(acc[i][4 * q4 + 1]),
                  elu_f(acc[i][4 * q4 + 2]), elu_f(acc[i][4 * q4 + 3])};
      *reinterpret_cast<float4*>(&hrow[4 * q4]) = v;
    }
  }
}

// ---------------------------------------------------------------- ec2b ----
__global__ __launch_bounds__(512, 2) void ec2b_kernel(
    const float* __restrict__ H, const float* __restrict__ w2,
    const float* __restrict__ b2, float* __restrict__ out) {
  __shared__ __align__(16) float hsT[96][260];
  __shared__ float w2s[96][132];
  __shared__ float b2s[128];
  const int z = blockIdx.x, t = threadIdx.x;
  const int bc = z >> 1, hh = z & 1;
  const float* Hb = H + ((size_t)bc * 512 + hh * 256) * 96;
  for (int i = t; i < 256 * 96; i += 512) hsT[i % 96][i / 96] = Hb[i];
  for (int i = t; i < 96 * 128; i += 512) w2s[i >> 7][i & 127] = w2[i];
  if (t < 128) b2s[t] = b2[t];
  __syncthreads();
  const int g = t >> 3, oq = t & 7;
  float acc[4][16];
#pragma unroll
  for (int m = 0; m < 16; ++m) {
    float bv = b2s[oq + 8 * m];
#pragma unroll
    for (int i = 0; i < 4; ++i) acc[i][m] = bv;
  }
  for (int k = 0; k < 96; ++k) {
    float4 hv = *reinterpret_cast<const float4*>(&hsT[k][4 * g]);
#pragma unroll
    for (int m = 0; m < 16; ++m) {
      float wv = w2s[k][oq + 8 * m];
      acc[0][m] += hv.x * wv;
      acc[1][m] += hv.y * wv;
      acc[2][m] += hv.z * wv;
      acc[3][m] += hv.w * wv;
    }
  }
  float* orow = out + ((size_t)bc * NPT + hh * 64 + g) * 128;
#pragma unroll
  for (int m = 0; m < 16; ++m) {
    float s = elu_f(acc[0][m]) + elu_f(acc[1][m]) +
              elu_f(acc[2][m]) + elu_f(acc[3][m]);
    orow[oq + 8 * m] = 0.25f * s;
  }
}

// ---------------------------------------------------------------- ec3a ----
__global__ __launch_bounds__(512, 2) void ec3a_kernel(
    const float* __restrict__ x, const int* __restrict__ idx,
    const unsigned short* __restrict__ w1t3g, const float* __restrict__ b1,
    unsigned short* __restrict__ h1) {
  __shared__ unsigned short Xb[128][136];
  __shared__ __align__(16) unsigned short W1t[192][264];
  __shared__ float b1s[192];
  __shared__ unsigned short stg[8][16][40];
  const int b = blockIdx.x, t = threadIdx.x;
  const float* xb = x + (size_t)b * NPT * 128;
  for (int e = t; e < NPT * 128; e += 512) Xb[e >> 7][e & 127] = f2bf(xb[e]);
  {
    const uint4v* src = reinterpret_cast<const uint4v*>(w1t3g);
    uint4v* dst = reinterpret_cast<uint4v*>(&W1t[0][0]);
    for (int i = t; i < 192 * 264 / 8; i += 512) dst[i] = src[i];
  }
  if (t < 192) b1s[t] = b1[t];
  __syncthreads();
  const int w = t >> 6, l = t & 63;
  const int lr = l & 15, lq = l >> 4;
  for (int mt = 0; mt < 4; ++mt) {
    const int m = (w * 4 + mt) * 16;
    const int e = m + lr;
    const int p = e >> 2;
    const int jp = idx[(size_t)b * 512 + e];
    short8 A[8];
#pragma unroll
    for (int kk = 0; kk < 4; ++kk) {
      int k0 = kk * 32 + lq * 8;
      A[kk] = *reinterpret_cast<const short8*>(&Xb[p][k0]);
    }
#pragma unroll
    for (int kk = 0; kk < 4; ++kk) {
      int k0 = kk * 32 + lq * 8;
      short8 aj = *reinterpret_cast<const short8*>(&Xb[jp][k0]);
      short8 ai = *reinterpret_cast<const short8*>(&Xb[p][k0]);
      short8 d;
#pragma unroll
      for (int q = 0; q < 8; ++q)
        d[q] = (short)f2bf(bf2f((unsigned short)aj[q]) - bf2f((unsigned short)ai[q]));
      A[4 + kk] = d;
    }
    floatx4 acc[12];
#pragma unroll
    for (int n = 0; n < 12; ++n) acc[n] = (floatx4){0.f, 0.f, 0.f, 0.f};
#pragma unroll
    for (int n = 0; n < 12; ++n) {
#pragma unroll
      for (int kk = 0; kk < 8; ++kk) {
        short8 Bf = *reinterpret_cast<const short8*>(&W1t[n * 16 + lr][kk * 32 + lq * 8]);
        acc[n] = __builtin_amdgcn_mfma_f32_16x16x32_bf16(A[kk], Bf, acc[n], 0, 0, 0);
      }
    }
#pragma unroll
    for (int pr = 0; pr < 6; ++pr) {
      float bv0 = b1s[pr * 32 + lr];
      float bv1 = b1s[pr * 32 + 16 + lr];
#pragma unroll
      for (int i = 0; i < 4; ++i) {
        stg[w][lq * 4 + i][lr]      = f2bf(elu_f(acc[2 * pr][i] + bv0));
        stg[w][lq * 4 + i][16 + lr] = f2bf(elu_f(acc[2 * pr + 1][i] + bv1));
      }
      asm volatile("s_waitcnt lgkmcnt(0)" ::: "memory");
      const unsigned short* src = &stg[w][l >> 2][(l & 3) * 8];
      uint4v vv = *reinterpret_cast<const uint4v*>(src);
      size_t dst = ((size_t)b * 512 + m + (l >> 2)) * 192 + pr * 32 + (l & 3) * 8;
      *reinterpret_cast<uint4v*>(&h1[dst]) = vv;
      asm volatile("s_waitcnt lgkmcnt(0)" ::: "memory");
    }
  }
}

// ---------------------------------------------------------------- ec3b ----
__global__ __launch_bounds__(512, 2) void ec3b_kernel(
    const unsigned short* __restrict__ h1,
    const unsigned short* __restrict__ w2t3g, const float* __restrict__ b2,
    unsigned short* __restrict__ out3) {
  __shared__ __align__(16) unsigned short W2t[256][200];
  __shared__ float b2s[256];
  const int b = blockIdx.x, t = threadIdx.x;
  {
    const uint4v* src = reinterpret_cast<const uint4v*>(w2t3g);
    uint4v* dst = reinterpret_cast<uint4v*>(&W2t[0][0]);
    for (int i = t; i < 256 * 200 / 8; i += 512) dst[i] = src[i];
  }
  if (t < 256) b2s[t] = b2[t];
  __syncthreads();
  const int w = t >> 6, l = t & 63;
  const int lr = l & 15, lq = l >> 4;
  for (int mt = 0; mt < 4; ++mt) {
    const int m = (w * 4 + mt) * 16;
    floatx4 acc[16];
#pragma unroll
    for (int n = 0; n < 16; ++n) acc[n] = (floatx4){0.f, 0.f, 0.f, 0.f};
    const unsigned short* arow = h1 + ((size_t)b * 512 + m + lr) * 192;
#pragma unroll
    for (int kk = 0; kk < 6; ++kk) {
      short8 Af = *reinterpret_cast<const short8*>(&arow[kk * 32 + lq * 8]);
#pragma unroll
      for (int n = 0; n < 16; ++n) {
        short8 Bf = *reinterpret_cast<const short8*>(&W2t[n * 16 + lr][kk * 32 + lq * 8]);
        acc[n] = __builtin_amdgcn_mfma_f32_16x16x32_bf16(Af, Bf, acc[n], 0, 0, 0);
      }
    }
    unsigned short* orow = out3 + ((size_t)b * NPT + (m >> 2) + lq) * 256;
#pragma unroll
    for (int n = 0; n < 16; ++n) {
      float bv = b2s[n * 16 + lr];
      float s = 0.f;
#pragma unroll
      for (int i = 0; i < 4; ++i) s += elu_f(acc[n][i] + bv);
      orow[n * 16 + lr] = f2bf(0.25f * s);
    }
  }
}

// ------------------------------------------------------------ prep -------
__global__ __launch_bounds__(256) void prep_kernel(
    const float* __restrict__ hw1, const float* __restrict__ hw2,
    const float* __restrict__ c3w1, const float* __restrict__ c3w2,
    unsigned short* __restrict__ w1p, unsigned short* __restrict__ w2p,
    unsigned short* __restrict__ w1t3g, unsigned short* __restrict__ w2t3g) {
  int i = blockIdx.x * 256 + threadIdx.x;
  if (i < 512 * 480) {
    int n = i / 480, kp = i % 480;
    int ko = (kp < 5) ? kp : kp - 3;
    bool ok = ((kp < 5) || (kp >= 8 && kp < 456)) && (n < 453);
    w1p[i] = ok ? f2bf(hw1[(size_t)ko * 453 + n]) : (unsigned short)0;
  } else if (i < 512 * 480 + 256 * 480) {
    int j = i - 512 * 480;
    int n = j / 480, kp = j % 480;
    bool ok = (kp < 453) && (n < 226);
    w2p[j] = ok ? f2bf(hw2[(size_t)kp * 226 + n]) : (unsigned short)0;
  } else if (i < 512 * 480 + 256 * 480 + 192 * 264) {
    int m = i - (512 * 480 + 256 * 480);
    int n = m / 264, k = m % 264;
    w1t3g[m] = (k < 256) ? f2bf(c3w1[(size_t)k * 192 + n]) : (unsigned short)0;
  } else {
    int m = i - (512 * 480 + 256 * 480 + 192 * 264);
    if (m < 256 * 200) {
      int n = m / 200, k = m % 200;
      w2t3g[m] = (k < 192) ? f2bf(c3w2[(size_t)k * 256 + n]) : (unsigned short)0;
    }
  }
}

// ----------------------------------------------------------- head MFMA ----
#define HSTR 488
#define TPSS 72
__global__ __launch_bounds__(256, 2) void head_mfma_kernel(
    const float* __restrict__ feat, const float* __restrict__ o1,
    const float* __restrict__ o2, const unsigned short* __restrict__ o3,
    const unsigned short* __restrict__ w1p, const float* __restrict__ b1,
    const unsigned short* __restrict__ w2p, const float* __restrict__ b2,
    const float* __restrict__ w3, const float* __restrict__ b3,
    float* __restrict__ out) {
  __shared__ unsigned short uA[64 * HSTR];
  __shared__ __align__(16) unsigned short tps[4][16][TPSS];
  __shared__ float b1s[512], b2s[256], w3s[512];
  const int t = threadIdx.x;
  const size_t base = (size_t)blockIdx.x * 64;

  for (int i = t; i < 512; i += 256) b1s[i] = (i < 453) ? b1[i] : 0.f;
  if (t < 256) b2s[t] = (t < 226) ? b2[t] : 0.f;
  for (int i = t; i < 512; i += 256) w3s[i] = (i < 452) ? w3[i] : 0.f;

  const int w = t >> 6, l = t & 63;
  const int lr = l & 15, lq = l >> 4;
  const int tr = t >> 2, tc = t & 3;
  const size_t grow = base + w * 16 + lr;

  short8 Af[15];
#pragma unroll
  for (int kk = 0; kk < 15; ++kk) {
    const int kbase = kk * 32 + lq * 8;
    short8 r;
    if (kbase >= 456) {
#pragma unroll
      for (int q = 0; q < 8; ++q) r[q] = 0;
    } else if (kbase >= 200) {
      r = *reinterpret_cast<const short8*>(&o3[grow * 256 + (kbase - 200)]);
    } else if (kbase >= 72) {
      const float* s = &o2[grow * 128 + (kbase - 72)];
#pragma unroll
      for (int q = 0; q < 8; ++q) r[q] = (short)f2bf(s[q]);
    } else if (kbase >= 8) {
      const float* s = &o1[grow * 64 + (kbase - 8)];
#pragma unroll
      for (int q = 0; q < 8; ++q) r[q] = (short)f2bf(s[q]);
    } else {
      const float* s = &feat[grow * 5];
#pragma unroll
      for (int q = 0; q < 8; ++q) r[q] = (q < 5) ? (short)f2bf(s[q]) : (short)0;
    }
    Af[kk] = r;
  }

  uint4v v[15];
#define WLOAD(SRC, CH)                                                   \
  {                                                                      \
    _Pragma("unroll")                                                    \
    for (int i = 0; i < 15; ++i)                                         \
      v[i] = *reinterpret_cast<const uint4v*>(                           \
          &SRC[((size_t)((CH) * 64 + tr)) * 480 + (tc + 4 * i) * 8]);    \
  }
#define WWRITE()                                                         \
  {                                                                      \
    _Pragma("unroll")                                                    \
    for (int i = 0; i < 15; ++i)                                         \
      *reinterpret_cast<uint4v*>(&uA[tr * HSTR + (tc + 4 * i) * 8]) = v[i]; \
  }

  WLOAD(w1p, 0)
  WWRITE()
  __syncthreads();

  short8 Af2[15];
#pragma unroll
  for (int ch = 0; ch < 8; ++ch) {
    if (ch < 7) WLOAD(w1p, ch + 1)
    else       WLOAD(w2p, 0)
    floatx4 a0 = {0.f, 0.f, 0.f, 0.f}, a1 = {0.f, 0.f, 0.f, 0.f};
    floatx4 a2 = {0.f, 0.f, 0.f, 0.f}, a3 = {0.f, 0.f, 0.f, 0.f};
#pragma unroll
    for (int kk = 0; kk < 15; ++kk) {
      int ko = kk * 32 + lq * 8;
      short8 B0 = *reinterpret_cast<const short8*>(&uA[(lr)*HSTR + ko]);
      short8 B1 = *reinterpret_cast<const short8*>(&uA[(16 + lr) * HSTR + ko]);
      short8 B2 = *reinterpret_cast<const short8*>(&uA[(32 + lr) * HSTR + ko]);
      short8 B3 = *reinterpret_cast<const short8*>(&uA[(48 + lr) * HSTR + ko]);
      a0 = __builtin_amdgcn_mfma_f32_16x16x32_bf16(Af[kk], B0, a0, 0, 0, 0);
      a1 = __builtin_amdgcn_mfma_f32_16x16x32_bf16(Af[kk], B1, a1, 0, 0, 0);
      a2 = __builtin_amdgcn_mfma_f32_16x16x32_bf16(Af[kk], B2, a2, 0, 0, 0);
      a3 = __builtin_amdgcn_mfma_f32_16x16x32_bf16(Af[kk], B3, a3, 0, 0, 0);
    }
    {
      floatx4 aj[4] = {a0, a1, a2, a3};
#pragma unroll
      for (int jx = 0; jx < 4; ++jx) {
        int c = ch * 64 + jx * 16 + lr;
        float bb = b1s[c];
#pragma unroll
        for (int i = 0; i < 4; ++i)
          tps[w][lq * 4 + i][jx * 16 + lr] = f2bf(elu_f(aj[jx][i] + bb));
      }
    }
    asm volatile("s_waitcnt lgkmcnt(0)" ::: "memory");
    Af2[2 * ch] = *reinterpret_cast<const short8*>(&tps[w][lr][lq * 8]);
    if (ch < 7)
      Af2[2 * ch + 1] = *reinterpret_cast<const short8*>(&tps[w][lr][32 + lq * 8]);
    asm volatile("s_waitcnt lgkmcnt(0)" ::: "memory");
    __syncthreads();
    WWRITE()
    __syncthreads();
  }

  float p0[4] = {0.f, 0.f, 0.f, 0.f}, p1[4] = {0.f, 0.f, 0.f, 0.f};
#pragma unroll
  for (int ch = 0; ch < 4; ++ch) {
    if (ch < 3) WLOAD(w2p, ch + 1)
    floatx4 a0 = {0.f, 0.f, 0.f, 0.f}, a1 = {0.f, 0.f, 0.f, 0.f};
    floatx4 a2 = {0.f, 0.f, 0.f, 0.f}, a3 = {0.f, 0.f, 0.f, 0.f};
#pragma unroll
    for (int kk = 0; kk < 15; ++kk) {
      int ko = kk * 32 + lq * 8;
      short8 B0 = *reinterpret_cast<const short8*>(&uA[(lr)*HSTR + ko]);
      short8 B1 = *reinterpret_cast<const short8*>(&uA[(16 + lr) * HSTR + ko]);
      short8 B2 = *reinterpret_cast<const short8*>(&uA[(32 + lr) * HSTR + ko]);
      short8 B3 = *reinterpret_cast<const short8*>(&uA[(48 + lr) * HSTR + ko]);
      a0 = __builtin_amdgcn_mfma_f32_16x16x32_bf16(Af2[kk], B0, a0, 0, 0, 0);
      a1 = __builtin_amdgcn_mfma_f32_16x16x32_bf16(Af2[kk], B1, a1, 0, 0, 0);
      a2 = __builtin_amdgcn_mfma_f32_16x16x32_bf16(Af2[kk], B2, a2, 0, 0, 0);
      a3 = __builtin_amdgcn_mfma_f32_16x16x32_bf16(Af2[kk], B3, a3, 0, 0, 0);
    }
    {
      floatx4 aj[4] = {a0, a1, a2, a3};
#pragma unroll
      for (int jx = 0; jx < 4; ++jx) {
        int c = ch * 64 + jx * 16 + lr;
        float bb = b2s[c];
        float wa = w3s[2 * c], wb = w3s[2 * c + 1];
#pragma unroll
        for (int i = 0; i < 4; ++i) {
          float h = (c < 226) ? elu_f(aj[jx][i] + bb) : 0.f;
          p0[i] += h * wa;
          p1[i] += h * wb;
        }
      }
    }
    if (ch < 3) {
      __syncthreads();
      WWRITE()
      __syncthreads();
    }
  }

#pragma unroll
  for (int i = 0; i < 4; ++i) {
    float a = p0[i], bvv = p1[i];
#pragma unroll
    for (int m = 1; m < 16; m <<= 1) {
      a += __shfl_xor(a, m);
      bvv += __shfl_xor(bvv, m);
    }
    if (lr == 0) {
      size_t row = base + w * 16 + lq * 4 + i;
      float2 vv = {a + b3[0], bvv + b3[1]};
      *reinterpret_cast<float2*>(&out[row * 2]) = vv;
    }
  }
#undef WLOAD
#undef WWRITE
}

// ------------------------------------------------------------- launch ----
extern "C" void kernel_launch(void* const* d_in, const int* in_sizes, int n_in,
                              void* d_out, int out_size, void* d_ws, size_t ws_size,
                              hipStream_t stream) {
  const float* coords = (const float*)d_in[0];
  const float* feat   = (const float*)d_in[1];
  const float* c1w1 = (const float*)d_in[2];  const float* c1b1 = (const float*)d_in[3];
  const float* c1w2 = (const float*)d_in[4];  const float* c1b2 = (const float*)d_in[5];
  const float* c2w1 = (const float*)d_in[6];  const float* c2b1 = (const float*)d_in[7];
  const float* c2w2 = (const float*)d_in[8];  const float* c2b2 = (const float*)d_in[9];
  const float* c3w1 = (const float*)d_in[10]; const float* c3b1 = (const float*)d_in[11];
  const float* c3w2 = (const float*)d_in[12]; const float* c3b2 = (const float*)d_in[13];
  const float* ow1  = (const float*)d_in[14]; const float* ob1  = (const float*)d_in[15];
  const float* ow2  = (const float*)d_in[16]; const float* ob2  = (const float*)d_in[17];
  const float* ow3  = (const float*)d_in[18]; const float* ob3  = (const float*)d_in[19];
  float* out = (float*)d_out;

  char* ws = (char*)d_ws;
  float* out1 = (float*)(ws);                                    // [0,32) MiB
  float* out2 = (float*)(ws + (32ull << 20));                    // [32,96)
  unsigned short* out3b = (unsigned short*)(ws + (96ull << 20)); // [96,160)
  float* Hbuf2 = (float*)(ws + (96ull << 20));                   // [96,192) ec2 temp
  unsigned short* h1 = (unsigned short*)(ws + (162ull << 20));   // [162,212) ec3 temp
  unsigned short* w1p = (unsigned short*)(ws + (212ull << 20));
  unsigned short* w2p = (unsigned short*)(ws + (212ull << 20) + (512ull << 10));
  unsigned short* w1t3g = (unsigned short*)(ws + (213ull << 20));
  unsigned short* w2t3g = (unsigned short*)(ws + (213ull << 20) + (256ull << 10));
  int* idx = (int*)(ws + (214ull << 20));                        // [214,216)

  prep_kernel<<<1838, 256, 0, stream>>>(ow1, ow2, c3w1, c3w2,
                                        w1p, w2p, w1t3g, w2t3g);
  knn_kernel<2><<<NB, 128, 0, stream>>>(coords, idx);
  ec1_kernel<<<2 * NB, 256, 0, stream>>>(feat, idx, c1w1, c1b1, c1w2, c1b2, out1);
  knn_mfma_kernel<64><<<NB, 512, 0, stream>>>(out1, idx);
  for (int c = 0; c < 2; ++c) {
    ec2a_kernel<<<512, 512, 0, stream>>>(out1 + (size_t)c * 512 * NPT * 64,
                                         idx + (size_t)c * 512 * 512,
                                         c2w1, c2b1, Hbuf2);
    ec2b_kernel<<<1024, 512, 0, stream>>>(Hbuf2, c2w2, c2b2,
                                          out2 + (size_t)c * 512 * NPT * 128);
  }
  knn_mfma_kernel<128><<<NB, 512, 0, stream>>>(out2, idx);
  for (int c = 0; c < 4; ++c) {
    ec3a_kernel<<<256, 512, 0, stream>>>(out2 + (size_t)c * 256 * NPT * 128,
                                         idx + (size_t)c * 256 * 512,
                                         w1t3g, c3b1, h1);
    ec3b_kernel<<<256, 512, 0, stream>>>(h1, w2t3g, c3b2,
                                         out3b + (size_t)c * 256 * NPT * 256);
  }
  head_mfma_kernel<<<2048, 256, 0, stream>>>(feat, out1, out2, out3b,
                                             w1p, ob1, w2p, ob2, ow3, ob3, out);
}

// Round 14
// 1653.632 us; speedup vs baseline: 24.9170x; 1.0484x over previous
//
#include <hip/hip_runtime.h>
#include <cstdint>
#include <cstddef>

// ParticleNet MI355X — Round 14 (= verified Round 12 source).
// r13's ec2-MFMA pair caused POST-TIMING divergence (first call passed,
// replays diverged to absmax 1.256) — state-dependence my audit could not
// localize. Reverted ec2 to the r12-verified VALU kernels; everything else
// identical to the r12 run that passed at 1733 us. Next round bisects
// (ec2b-only MFMA).

#define NB 1024
#define NPT 128

typedef __attribute__((ext_vector_type(8))) short short8;
typedef __attribute__((ext_vector_type(4))) float floatx4;
typedef __attribute__((ext_vector_type(4))) unsigned int uint4v;

__device__ __forceinline__ float elu_f(float x) { return x > 0.0f ? x : expm1f(x); }

__device__ __forceinline__ unsigned short f2bf(float f) {
  unsigned u = __builtin_bit_cast(unsigned, f);
  unsigned r = u + 0x7FFFu + ((u >> 16) & 1u);
  return (unsigned short)(r >> 16);
}
__device__ __forceinline__ float bf2f(unsigned short h) {
  unsigned u = ((unsigned)h) << 16;
  return __builtin_bit_cast(float, u);
}

// top-6 insertion cascade (strict <): shared by all kNN kernels
#define INS6(dv, jv)                                                    \
  if ((dv) < bd5) {                                                     \
    bd5 = (dv); bi5 = (jv);                                             \
    if (bd5 < bd4) {                                                    \
      float _t = bd4; bd4 = bd5; bd5 = _t; int _i = bi4; bi4 = bi5; bi5 = _i; \
      if (bd4 < bd3) {                                                  \
        _t = bd3; bd3 = bd4; bd4 = _t; _i = bi3; bi3 = bi4; bi4 = _i;   \
        if (bd3 < bd2) {                                                \
          _t = bd2; bd2 = bd3; bd3 = _t; _i = bi2; bi2 = bi3; bi3 = _i; \
          if (bd2 < bd1) {                                              \
            _t = bd1; bd1 = bd2; bd2 = _t; _i = bi1; bi1 = bi2; bi2 = _i; \
            if (bd1 < bd0) {                                            \
              _t = bd0; bd0 = bd1; bd1 = _t; _i = bi0; bi0 = bi1; bi1 = _i; \
            } } } } } }

// ------------------------------------------------------------- kNN C=2 ----
template<int C>
__global__ __launch_bounds__(128) void knn_kernel(const float* __restrict__ x,
                                                  int* __restrict__ idx) {
  __shared__ __align__(16) float xs[NPT][C + 4];
  __shared__ float x2s[NPT];
  __shared__ double x2d[NPT];
  const int b = blockIdx.x, t = threadIdx.x;
  const float* xb = x + (size_t)b * NPT * C;
  for (int e = t; e < NPT * C; e += 128) xs[e / C][e % C] = xb[e];
  __syncthreads();
  float xi[C];
  float s2 = 0.0f;
  double s2d = 0.0;
#pragma unroll
  for (int c = 0; c < C; ++c) {
    xi[c] = xs[t][c];
    s2 += xi[c] * xi[c];
    s2d += (double)xi[c] * (double)xi[c];
  }
  x2s[t] = s2;
  x2d[t] = s2d;
  __syncthreads();
  float bd0 = 1e30f, bd1 = 1e30f, bd2 = 1e30f, bd3 = 1e30f, bd4 = 1e30f, bd5 = 1e30f;
  int bi0 = 0, bi1 = 0, bi2 = 0, bi3 = 0, bi4 = 0, bi5 = 0;
  for (int j = 0; j < NPT; ++j) {
    if (j == t) continue;
    float dot = 0.0f;
#pragma unroll
    for (int c = 0; c < C; ++c) dot += xi[c] * xs[j][c];
    float d = s2 + x2s[j] - 2.0f * dot;
    INS6(d, j)
  }
  auto refine = [&](int j) -> double {
    double dot = 0.0;
#pragma unroll
    for (int c = 0; c < C; ++c) dot += (double)xi[c] * (double)xs[j][c];
    return s2d + x2d[j] - 2.0 * dot;
  };
  double e0 = refine(bi0), e1 = refine(bi1), e2 = refine(bi2);
  double e3 = refine(bi3), e4 = refine(bi4), e5 = refine(bi5);
#define CSWP(da, ia, db, ib)                                            \
  if ((da > db) || (da == db && ia > ib)) {                             \
    double _td = da; da = db; db = _td; int _ti = ia; ia = ib; ib = _ti; }
  CSWP(e0, bi0, e1, bi1) CSWP(e1, bi1, e2, bi2) CSWP(e2, bi2, e3, bi3)
  CSWP(e3, bi3, e4, bi4) CSWP(e4, bi4, e5, bi5)
  CSWP(e0, bi0, e1, bi1) CSWP(e1, bi1, e2, bi2) CSWP(e2, bi2, e3, bi3)
  CSWP(e3, bi3, e4, bi4)
  CSWP(e0, bi0, e1, bi1) CSWP(e1, bi1, e2, bi2) CSWP(e2, bi2, e3, bi3)
  CSWP(e0, bi0, e1, bi1) CSWP(e1, bi1, e2, bi2)
  CSWP(e0, bi0, e1, bi1)
#undef CSWP
  int* ib = idx + ((size_t)b * NPT + t) * 4;
  ib[0] = bi0; ib[1] = bi1; ib[2] = bi2; ib[3] = bi3;
}

// ------------------------------------------------- kNN C=64/128 (MFMA) ----
template<int C>
__global__ __launch_bounds__(512) void knn_mfma_kernel(const float* __restrict__ x,
                                                       int* __restrict__ idx) {
  constexpr int KC = C / 32;
  constexpr int HS = C + 8;
  constexpr int FS = C + 4;
  constexpr int CQ = C / 4;
  __shared__ __align__(16) unsigned short lbuf[2 * NPT * HS];
  __shared__ float x2s[NPT];
  __shared__ double x2d[NPT];
  unsigned short* Xhi = lbuf;
  unsigned short* Xlo = lbuf + NPT * HS;
  float* Xs = reinterpret_cast<float*>(lbuf);
  const int b = blockIdx.x, t = threadIdx.x;
  const float* xb = x + (size_t)b * NPT * C;
  for (int e = t; e < NPT * C; e += 512) {
    int r = e / C, c = e % C;
    float v = xb[e];
    unsigned short h = f2bf(v);
    Xhi[r * HS + c] = h;
    Xlo[r * HS + c] = f2bf(v - bf2f(h));
  }
  {
    const int p = t >> 2, q = t & 3;
    const float4* r4 = reinterpret_cast<const float4*>(xb + p * C + q * CQ);
    float s2 = 0.f;
    double s2d = 0.0;
#pragma unroll
    for (int c4 = 0; c4 < CQ / 4; ++c4) {
      float4 v = r4[c4];
      s2 += v.x * v.x + v.y * v.y + v.z * v.z + v.w * v.w;
      s2d += (double)v.x * v.x + (double)v.y * v.y +
             (double)v.z * v.z + (double)v.w * v.w;
    }
    s2 += __shfl_xor(s2, 1);  s2 += __shfl_xor(s2, 2);
    s2d += __shfl_xor(s2d, 1); s2d += __shfl_xor(s2d, 2);
    if (q == 0) { x2s[p] = s2; x2d[p] = s2d; }
  }
  __syncthreads();
  const int w = t >> 6, l = t & 63;
  const int lr = l & 15, lq = l >> 4;
  const int iq = w * 16 + lr;
  short8 Bhi[KC], Blo[KC];
#pragma unroll
  for (int kk = 0; kk < KC; ++kk) {
    Bhi[kk] = *reinterpret_cast<const short8*>(&Xhi[iq * HS + kk * 32 + lq * 8]);
    Blo[kk] = *reinterpret_cast<const short8*>(&Xlo[iq * HS + kk * 32 + lq * 8]);
  }
  const float x2i = x2s[iq];
  float bd0 = 1e30f, bd1 = 1e30f, bd2 = 1e30f, bd3 = 1e30f, bd4 = 1e30f, bd5 = 1e30f;
  int bi0 = 0, bi1 = 0, bi2 = 0, bi3 = 0, bi4 = 0, bi5 = 0;
#pragma unroll
  for (int jt = 0; jt < 8; ++jt) {
    short8 Ahi[KC], Alo[KC];
#pragma unroll
    for (int kk = 0; kk < KC; ++kk) {
      Ahi[kk] = *reinterpret_cast<const short8*>(
          &Xhi[(jt * 16 + lr) * HS + kk * 32 + lq * 8]);
      Alo[kk] = *reinterpret_cast<const short8*>(
          &Xlo[(jt * 16 + lr) * HS + kk * 32 + lq * 8]);
    }
    floatx4 g = {0.f, 0.f, 0.f, 0.f};
#pragma unroll
    for (int kk = 0; kk < KC; ++kk) {
      g = __builtin_amdgcn_mfma_f32_16x16x32_bf16(Ahi[kk], Bhi[kk], g, 0, 0, 0);
      g = __builtin_amdgcn_mfma_f32_16x16x32_bf16(Ahi[kk], Blo[kk], g, 0, 0, 0);
      g = __builtin_amdgcn_mfma_f32_16x16x32_bf16(Alo[kk], Bhi[kk], g, 0, 0, 0);
    }
#pragma unroll
    for (int r = 0; r < 4; ++r) {
      int j = jt * 16 + lq * 4 + r;
      float d = (j == iq) ? 1e30f : (x2i + x2s[j] - 2.0f * g[r]);
      INS6(d, j)
    }
  }
#pragma unroll
  for (int rnd = 0; rnd < 2; ++rnd) {
    const int m = 16 << rnd;
    float od0 = __shfl_xor(bd0, m), od1 = __shfl_xor(bd1, m), od2 = __shfl_xor(bd2, m);
    float od3 = __shfl_xor(bd3, m), od4 = __shfl_xor(bd4, m), od5 = __shfl_xor(bd5, m);
    int oi0 = __shfl_xor(bi0, m), oi1 = __shfl_xor(bi1, m), oi2 = __shfl_xor(bi2, m);
    int oi3 = __shfl_xor(bi3, m), oi4 = __shfl_xor(bi4, m), oi5 = __shfl_xor(bi5, m);
    INS6(od0, oi0) INS6(od1, oi1) INS6(od2, oi2)
    INS6(od3, oi3) INS6(od4, oi4) INS6(od5, oi5)
  }
  bi0 = __shfl(bi0, lr); bi1 = __shfl(bi1, lr); bi2 = __shfl(bi2, lr);
  bi3 = __shfl(bi3, lr); bi4 = __shfl(bi4, lr); bi5 = __shfl(bi5, lr);
  __syncthreads();
  for (int e = t; e < NPT * C; e += 512) {
    int r = e / C, c = e % C;
    Xs[r * FS + c] = xb[e];
  }
  __syncthreads();
  const double x2di = x2d[iq];
  auto refine = [&](int j) -> double {
    double dot = 0.0;
    const float* ri = &Xs[iq * FS + lq * CQ];
    const float* rj = &Xs[j * FS + lq * CQ];
#pragma unroll
    for (int c = 0; c < CQ; ++c) dot += (double)ri[c] * (double)rj[c];
    dot += __shfl_xor(dot, 16);
    dot += __shfl_xor(dot, 32);
    return x2di + x2d[j] - 2.0 * dot;
  };
  double e0 = refine(bi0), e1 = refine(bi1), e2 = refine(bi2);
  double e3 = refine(bi3), e4 = refine(bi4), e5 = refine(bi5);
#define CSWP(da, ia, db, ib)                                            \
  if ((da > db) || (da == db && ia > ib)) {                             \
    double _td = da; da = db; db = _td; int _ti = ia; ia = ib; ib = _ti; }
  CSWP(e0, bi0, e1, bi1) CSWP(e1, bi1, e2, bi2) CSWP(e2, bi2, e3, bi3)
  CSWP(e3, bi3, e4, bi4) CSWP(e4, bi4, e5, bi5)
  CSWP(e0, bi0, e1, bi1) CSWP(e1, bi1, e2, bi2) CSWP(e2, bi2, e3, bi3)
  CSWP(e3, bi3, e4, bi4)
  CSWP(e0, bi0, e1, bi1) CSWP(e1, bi1, e2, bi2) CSWP(e2, bi2, e3, bi3)
  CSWP(e0, bi0, e1, bi1) CSWP(e1, bi1, e2, bi2)
  CSWP(e0, bi0, e1, bi1)
#undef CSWP
  if (lq == 0) {
    int* ib = idx + ((size_t)b * NPT + iq) * 4;
    ib[0] = bi0; ib[1] = bi1; ib[2] = bi2; ib[3] = bi3;
  }
}

// ---------------------------------------------------------------- ec1 ----
__global__ __launch_bounds__(256) void ec1_kernel(
    const float* __restrict__ feat, const int* __restrict__ idx,
    const float* __restrict__ w1, const float* __restrict__ b1,
    const float* __restrict__ w2, const float* __restrict__ b2,
    float* __restrict__ out) {
  __shared__ __align__(16) float fs[NPT][6];
  __shared__ __align__(16) float w1s[10][32];
  __shared__ __align__(16) float w2s[32][68];
  __shared__ float hs[256][33];
  __shared__ float b1s[32], b2s[64];
  const int z = blockIdx.x, t = threadIdx.x;
  const int b = z >> 1, hh = z & 1;
  const float* fb = feat + (size_t)b * NPT * 5;
  for (int e = t; e < NPT * 5; e += 256) fs[e / 5][e % 5] = fb[e];
  for (int e = t; e < 320; e += 256) w1s[e / 32][e % 32] = w1[e];
  for (int e = t; e < 2048; e += 256) w2s[e >> 6][e & 63] = w2[e];
  if (t < 32) b1s[t] = b1[t];
  if (t >= 192) b2s[t - 192] = b2[t - 192];
  __syncthreads();
  {
    const int p = hh * 64 + (t >> 2);
    const int j = idx[(size_t)b * 512 + p * 4 + (t & 3)];
    float h[32];
#pragma unroll
    for (int o = 0; o < 32; ++o) h[o] = b1s[o];
#pragma unroll
    for (int c = 0; c < 10; ++c) {
      float in_c = (c < 5) ? fs[p][c] : (fs[j][c - 5] - fs[p][c - 5]);
      const float4* wr = reinterpret_cast<const float4*>(&w1s[c][0]);
#pragma unroll
      for (int o4 = 0; o4 < 8; ++o4) {
        float4 w = wr[o4];
        h[4 * o4 + 0] += in_c * w.x; h[4 * o4 + 1] += in_c * w.y;
        h[4 * o4 + 2] += in_c * w.z; h[4 * o4 + 3] += in_c * w.w;
      }
    }
#pragma unroll
    for (int o = 0; o < 32; ++o) hs[t][o] = elu_f(h[o]);
  }
  __syncthreads();
  {
    const int g = t >> 2, q = t & 3;
    const int o0 = q * 16;
    float acc[4][16];
#pragma unroll
    for (int m = 0; m < 16; ++m) {
      float bv = b2s[o0 + m];
#pragma unroll
      for (int i = 0; i < 4; ++i) acc[i][m] = bv;
    }
    for (int k = 0; k < 32; ++k) {
      float hk0 = hs[g * 4 + 0][k];
      float hk1 = hs[g * 4 + 1][k];
      float hk2 = hs[g * 4 + 2][k];
      float hk3 = hs[g * 4 + 3][k];
      const float4* wr = reinterpret_cast<const float4*>(&w2s[k][o0]);
#pragma unroll
      for (int m4 = 0; m4 < 4; ++m4) {
        float4 w = wr[m4];
        acc[0][4 * m4 + 0] += hk0 * w.x; acc[0][4 * m4 + 1] += hk0 * w.y;
        acc[0][4 * m4 + 2] += hk0 * w.z; acc[0][4 * m4 + 3] += hk0 * w.w;
        acc[1][4 * m4 + 0] += hk1 * w.x; acc[1][4 * m4 + 1] += hk1 * w.y;
        acc[1][4 * m4 + 2] += hk1 * w.z; acc[1][4 * m4 + 3] += hk1 * w.w;
        acc[2][4 * m4 + 0] += hk2 * w.x; acc[2][4 * m4 + 1] += hk2 * w.y;
        acc[2][4 * m4 + 2] += hk2 * w.z; acc[2][4 * m4 + 3] += hk2 * w.w;
        acc[3][4 * m4 + 0] += hk3 * w.x; acc[3][4 * m4 + 1] += hk3 * w.y;
        acc[3][4 * m4 + 2] += hk3 * w.z; acc[3][4 * m4 + 3] += hk3 * w.w;
      }
    }
    float* ob = out + ((size_t)b * NPT + hh * 64 + g) * 64 + o0;
#pragma unroll
    for (int m4 = 0; m4 < 4; ++m4) {
      float4 v;
      float* vp = &v.x;
#pragma unroll
      for (int s = 0; s < 4; ++s) {
        int m = 4 * m4 + s;
        vp[s] = 0.25f * (elu_f(acc[0][m]) + elu_f(acc[1][m]) +
                         elu_f(acc[2][m]) + elu_f(acc[3][m]));
      }
      *reinterpret_cast<float4*>(&ob[4 * m4]) = v;
    }
  }
}

// ---------------------------------------------------------------- ec2a ----
__global__ __launch_bounds__(512, 2) void ec2a_kernel(
    const float* __restrict__ x, const int* __restrict__ idx,
    const float* __restrict__ w1, const float* __restrict__ b1,
    float* __restrict__ H) {
  __shared__ __align__(16) float xs[NPT][68];
  __shared__ __align__(16) float w1s[128][100];
  __shared__ float b1s[96];
  const int b = blockIdx.x, t = threadIdx.x;
  const float* xb = x + (size_t)b * NPT * 64;
  for (int e = t; e < NPT * 64; e += 512) xs[e >> 6][e & 63] = xb[e];
  for (int e = t; e < 128 * 96; e += 512) w1s[e / 96][e % 96] = w1[e];
  if (t < 96) b1s[t] = b1[t];
  __syncthreads();
  const int pb = t >> 2, part = t & 3;
  const int n0 = part * 24;
  int jn[4];
#pragma unroll
  for (int i = 0; i < 4; ++i) jn[i] = idx[(size_t)b * 512 + pb * 4 + i];
  float acc[4][24];
#pragma unroll
  for (int m = 0; m < 24; ++m) {
    float bv = b1s[n0 + m];
#pragma unroll
    for (int i = 0; i < 4; ++i) acc[i][m] = bv;
  }
  for (int c = 0; c < 64; ++c) {
    float in_c = xs[pb][c];
    const float4* wr = reinterpret_cast<const float4*>(&w1s[c][n0]);
#pragma unroll
    for (int q4 = 0; q4 < 6; ++q4) {
      float4 wv = wr[q4];
#pragma unroll
      for (int i = 0; i < 4; ++i) {
        acc[i][4 * q4 + 0] += in_c * wv.x;
        acc[i][4 * q4 + 1] += in_c * wv.y;
        acc[i][4 * q4 + 2] += in_c * wv.z;
        acc[i][4 * q4 + 3] += in_c * wv.w;
      }
    }
  }
  for (int c = 0; c < 64; ++c) {
    float xic = xs[pb][c];
    float in0 = xs[jn[0]][c] - xic;
    float in1 = xs[jn[1]][c] - xic;
    float in2 = xs[jn[2]][c] - xic;
    float in3 = xs[jn[3]][c] - xic;
    const float4* wr = reinterpret_cast<const float4*>(&w1s[64 + c][n0]);
#pragma unroll
    for (int q4 = 0; q4 < 6; ++q4) {
      float4 wv = wr[q4];
      acc[0][4 * q4 + 0] += in0 * wv.x; acc[0][4 * q4 + 1] += in0 * wv.y;
      acc[0][4 * q4 + 2] += in0 * wv.z; acc[0][4 * q4 + 3] += in0 * wv.w;
      acc[1][4 * q4 + 0] += in1 * wv.x; acc[1][4 * q4 + 1] += in1 * wv.y;
      acc[1][4 * q4 + 2] += in1 * wv.z; acc[1][4 * q4 + 3] += in1 * wv.w;
      acc[2][4 * q4 + 0] += in2 * wv.x; acc[2][4 * q4 + 1] += in2 * wv.y;
      acc[2][4 * q4 + 2] += in2 * wv.z; acc[2][4 * q4 + 3] += in2 * wv.w;
      acc[3][4 * q4 + 0] += in3 * wv.x; acc[3][4 * q4 + 1] += in3 * wv.y;
      acc[3][4 * q4 + 2] += in3 * wv.z; acc[3][4 * q4 + 3] += in3 * wv.w;
    }
  }
#pragma unroll
  for (int i = 0; i < 4; ++i) {
    float* hrow = H + ((size_t)b * 512 + pb * 4 + i) * 96 + n0;
#pragma unroll
    for (int q4 = 0; q4 < 6; ++q4) {
      float4 v = {elu_f(acc[i][4 * q4 + 0]), elu_f(acc[i][4 * q4 + 1]),
                  elu_f(acc[i][4 * q4 + 2]), elu_f(acc[i][4 * q4 + 3])};
      *reinterpret_cast<float4*>(&hrow[4 * q4]) = v;
    }
  }
}

// ---------------------------------------------------------------- ec2b ----
__global__ __launch_bounds__(512, 2) void ec2b_kernel(
    const float* __restrict__ H, const float* __restrict__ w2,
    const float* __restrict__ b2, float* __restrict__ out) {
  __shared__ __align__(16) float hsT[96][260];
  __shared__ float w2s[96][132];
  __shared__ float b2s[128];
  const int z = blockIdx.x, t = threadIdx.x;
  const int bc = z >> 1, hh = z & 1;
  const float* Hb = H + ((size_t)bc * 512 + hh * 256) * 96;
  for (int i = t; i < 256 * 96; i += 512) hsT[i % 96][i / 96] = Hb[i];
  for (int i = t; i < 96 * 128; i += 512) w2s[i >> 7][i & 127] = w2[i];
  if (t < 128) b2s[t] = b2[t];
  __syncthreads();
  const int g = t >> 3, oq = t & 7;
  float acc[4][16];
#pragma unroll
  for (int m = 0; m < 16; ++m) {
    float bv = b2s[oq + 8 * m];
#pragma unroll
    for (int i = 0; i < 4; ++i) acc[i][m] = bv;
  }
  for (int k = 0; k < 96; ++k) {
    float4 hv = *reinterpret_cast<const float4*>(&hsT[k][4 * g]);
#pragma unroll
    for (int m = 0; m < 16; ++m) {
      float wv = w2s[k][oq + 8 * m];
      acc[0][m] += hv.x * wv;
      acc[1][m] += hv.y * wv;
      acc[2][m] += hv.z * wv;
      acc[3][m] += hv.w * wv;
    }
  }
  float* orow = out + ((size_t)bc * NPT + hh * 64 + g) * 128;
#pragma unroll
  for (int m = 0; m < 16; ++m) {
    float s = elu_f(acc[0][m]) + elu_f(acc[1][m]) +
              elu_f(acc[2][m]) + elu_f(acc[3][m]);
    orow[oq + 8 * m] = 0.25f * s;
  }
}

// ---------------------------------------------------------------- ec3a ----
__global__ __launch_bounds__(512, 2) void ec3a_kernel(
    const float* __restrict__ x, const int* __restrict__ idx,
    const unsigned short* __restrict__ w1t3g, const float* __restrict__ b1,
    unsigned short* __restrict__ h1) {
  __shared__ unsigned short Xb[128][136];
  __shared__ __align__(16) unsigned short W1t[192][264];
  __shared__ float b1s[192];
  __shared__ unsigned short stg[8][16][40];
  const int b = blockIdx.x, t = threadIdx.x;
  const float* xb = x + (size_t)b * NPT * 128;
  for (int e = t; e < NPT * 128; e += 512) Xb[e >> 7][e & 127] = f2bf(xb[e]);
  {
    const uint4v* src = reinterpret_cast<const uint4v*>(w1t3g);
    uint4v* dst = reinterpret_cast<uint4v*>(&W1t[0][0]);
    for (int i = t; i < 192 * 264 / 8; i += 512) dst[i] = src[i];
  }
  if (t < 192) b1s[t] = b1[t];
  __syncthreads();
  const int w = t >> 6, l = t & 63;
  const int lr = l & 15, lq = l >> 4;
  for (int mt = 0; mt < 4; ++mt) {
    const int m = (w * 4 + mt) * 16;
    const int e = m + lr;
    const int p = e >> 2;
    const int jp = idx[(size_t)b * 512 + e];
    short8 A[8];
#pragma unroll
    for (int kk = 0; kk < 4; ++kk) {
      int k0 = kk * 32 + lq * 8;
      A[kk] = *reinterpret_cast<const short8*>(&Xb[p][k0]);
    }
#pragma unroll
    for (int kk = 0; kk < 4; ++kk) {
      int k0 = kk * 32 + lq * 8;
      short8 aj = *reinterpret_cast<const short8*>(&Xb[jp][k0]);
      short8 ai = *reinterpret_cast<const short8*>(&Xb[p][k0]);
      short8 d;
#pragma unroll
      for (int q = 0; q < 8; ++q)
        d[q] = (short)f2bf(bf2f((unsigned short)aj[q]) - bf2f((unsigned short)ai[q]));
      A[4 + kk] = d;
    }
    floatx4 acc[12];
#pragma unroll
    for (int n = 0; n < 12; ++n) acc[n] = (floatx4){0.f, 0.f, 0.f, 0.f};
#pragma unroll
    for (int n = 0; n < 12; ++n) {
#pragma unroll
      for (int kk = 0; kk < 8; ++kk) {
        short8 Bf = *reinterpret_cast<const short8*>(&W1t[n * 16 + lr][kk * 32 + lq * 8]);
        acc[n] = __builtin_amdgcn_mfma_f32_16x16x32_bf16(A[kk], Bf, acc[n], 0, 0, 0);
      }
    }
#pragma unroll
    for (int pr = 0; pr < 6; ++pr) {
      float bv0 = b1s[pr * 32 + lr];
      float bv1 = b1s[pr * 32 + 16 + lr];
#pragma unroll
      for (int i = 0; i < 4; ++i) {
        stg[w][lq * 4 + i][lr]      = f2bf(elu_f(acc[2 * pr][i] + bv0));
        stg[w][lq * 4 + i][16 + lr] = f2bf(elu_f(acc[2 * pr + 1][i] + bv1));
      }
      asm volatile("s_waitcnt lgkmcnt(0)" ::: "memory");
      const unsigned short* src = &stg[w][l >> 2][(l & 3) * 8];
      uint4v vv = *reinterpret_cast<const uint4v*>(src);
      size_t dst = ((size_t)b * 512 + m + (l >> 2)) * 192 + pr * 32 + (l & 3) * 8;
      *reinterpret_cast<uint4v*>(&h1[dst]) = vv;
      asm volatile("s_waitcnt lgkmcnt(0)" ::: "memory");
    }
  }
}

// ---------------------------------------------------------------- ec3b ----
__global__ __launch_bounds__(512, 2) void ec3b_kernel(
    const unsigned short* __restrict__ h1,
    const unsigned short* __restrict__ w2t3g, const float* __restrict__ b2,
    unsigned short* __restrict__ out3) {
  __shared__ __align__(16) unsigned short W2t[256][200];
  __shared__ float b2s[256];
  const int b = blockIdx.x, t = threadIdx.x;
  {
    const uint4v* src = reinterpret_cast<const uint4v*>(w2t3g);
    uint4v* dst = reinterpret_cast<uint4v*>(&W2t[0][0]);
    for (int i = t; i < 256 * 200 / 8; i += 512) dst[i] = src[i];
  }
  if (t < 256) b2s[t] = b2[t];
  __syncthreads();
  const int w = t >> 6, l = t & 63;
  const int lr = l & 15, lq = l >> 4;
  for (int mt = 0; mt < 4; ++mt) {
    const int m = (w * 4 + mt) * 16;
    floatx4 acc[16];
#pragma unroll
    for (int n = 0; n < 16; ++n) acc[n] = (floatx4){0.f, 0.f, 0.f, 0.f};
    const unsigned short* arow = h1 + ((size_t)b * 512 + m + lr) * 192;
#pragma unroll
    for (int kk = 0; kk < 6; ++kk) {
      short8 Af = *reinterpret_cast<const short8*>(&arow[kk * 32 + lq * 8]);
#pragma unroll
      for (int n = 0; n < 16; ++n) {
        short8 Bf = *reinterpret_cast<const short8*>(&W2t[n * 16 + lr][kk * 32 + lq * 8]);
        acc[n] = __builtin_amdgcn_mfma_f32_16x16x32_bf16(Af, Bf, acc[n], 0, 0, 0);
      }
    }
    unsigned short* orow = out3 + ((size_t)b * NPT + (m >> 2) + lq) * 256;
#pragma unroll
    for (int n = 0; n < 16; ++n) {
      float bv = b2s[n * 16 + lr];
      float s = 0.f;
#pragma unroll
      for (int i = 0; i < 4; ++i) s += elu_f(acc[n][i] + bv);
      orow[n * 16 + lr] = f2bf(0.25f * s);
    }
  }
}

// ------------------------------------------------------------ prep -------
__global__ __launch_bounds__(256) void prep_kernel(
    const float* __restrict__ hw1, const float* __restrict__ hw2,
    const float* __restrict__ c3w1, const float* __restrict__ c3w2,
    unsigned short* __restrict__ w1p, unsigned short* __restrict__ w2p,
    unsigned short* __restrict__ w1t3g, unsigned short* __restrict__ w2t3g) {
  int i = blockIdx.x * 256 + threadIdx.x;
  if (i < 512 * 480) {
    int n = i / 480, kp = i % 480;
    int ko = (kp < 5) ? kp : kp - 3;
    bool ok = ((kp < 5) || (kp >= 8 && kp < 456)) && (n < 453);
    w1p[i] = ok ? f2bf(hw1[(size_t)ko * 453 + n]) : (unsigned short)0;
  } else if (i < 512 * 480 + 256 * 480) {
    int j = i - 512 * 480;
    int n = j / 480, kp = j % 480;
    bool ok = (kp < 453) && (n < 226);
    w2p[j] = ok ? f2bf(hw2[(size_t)kp * 226 + n]) : (unsigned short)0;
  } else if (i < 512 * 480 + 256 * 480 + 192 * 264) {
    int m = i - (512 * 480 + 256 * 480);
    int n = m / 264, k = m % 264;
    w1t3g[m] = (k < 256) ? f2bf(c3w1[(size_t)k * 192 + n]) : (unsigned short)0;
  } else {
    int m = i - (512 * 480 + 256 * 480 + 192 * 264);
    if (m < 256 * 200) {
      int n = m / 200, k = m % 200;
      w2t3g[m] = (k < 192) ? f2bf(c3w2[(size_t)k * 256 + n]) : (unsigned short)0;
    }
  }
}

// ----------------------------------------------------------- head MFMA ----
#define HSTR 488
#define TPSS 72
__global__ __launch_bounds__(256, 2) void head_mfma_kernel(
    const float* __restrict__ feat, const float* __restrict__ o1,
    const float* __restrict__ o2, const unsigned short* __restrict__ o3,
    const unsigned short* __restrict__ w1p, const float* __restrict__ b1,
    const unsigned short* __restrict__ w2p, const float* __restrict__ b2,
    const float* __restrict__ w3, const float* __restrict__ b3,
    float* __restrict__ out) {
  __shared__ unsigned short uA[64 * HSTR];
  __shared__ __align__(16) unsigned short tps[4][16][TPSS];
  __shared__ float b1s[512], b2s[256], w3s[512];
  const int t = threadIdx.x;
  const size_t base = (size_t)blockIdx.x * 64;

  for (int i = t; i < 512; i += 256) b1s[i] = (i < 453) ? b1[i] : 0.f;
  if (t < 256) b2s[t] = (t < 226) ? b2[t] : 0.f;
  for (int i = t; i < 512; i += 256) w3s[i] = (i < 452) ? w3[i] : 0.f;

  const int w = t >> 6, l = t & 63;
  const int lr = l & 15, lq = l >> 4;
  const int tr = t >> 2, tc = t & 3;
  const size_t grow = base + w * 16 + lr;

  short8 Af[15];
#pragma unroll
  for (int kk = 0; kk < 15; ++kk) {
    const int kbase = kk * 32 + lq * 8;
    short8 r;
    if (kbase >= 456) {
#pragma unroll
      for (int q = 0; q < 8; ++q) r[q] = 0;
    } else if (kbase >= 200) {
      r = *reinterpret_cast<const short8*>(&o3[grow * 256 + (kbase - 200)]);
    } else if (kbase >= 72) {
      const float* s = &o2[grow * 128 + (kbase - 72)];
#pragma unroll
      for (int q = 0; q < 8; ++q) r[q] = (short)f2bf(s[q]);
    } else if (kbase >= 8) {
      const float* s = &o1[grow * 64 + (kbase - 8)];
#pragma unroll
      for (int q = 0; q < 8; ++q) r[q] = (short)f2bf(s[q]);
    } else {
      const float* s = &feat[grow * 5];
#pragma unroll
      for (int q = 0; q < 8; ++q) r[q] = (q < 5) ? (short)f2bf(s[q]) : (short)0;
    }
    Af[kk] = r;
  }

  uint4v v[15];
#define WLOAD(SRC, CH)                                                   \
  {                                                                      \
    _Pragma("unroll")                                                    \
    for (int i = 0; i < 15; ++i)                                         \
      v[i] = *reinterpret_cast<const uint4v*>(                           \
          &SRC[((size_t)((CH) * 64 + tr)) * 480 + (tc + 4 * i) * 8]);    \
  }
#define WWRITE()                                                         \
  {                                                                      \
    _Pragma("unroll")                                                    \
    for (int i = 0; i < 15; ++i)                                         \
      *reinterpret_cast<uint4v*>(&uA[tr * HSTR + (tc + 4 * i) * 8]) = v[i]; \
  }

  WLOAD(w1p, 0)
  WWRITE()
  __syncthreads();

  short8 Af2[15];
#pragma unroll
  for (int ch = 0; ch < 8; ++ch) {
    if (ch < 7) WLOAD(w1p, ch + 1)
    else       WLOAD(w2p, 0)
    floatx4 a0 = {0.f, 0.f, 0.f, 0.f}, a1 = {0.f, 0.f, 0.f, 0.f};
    floatx4 a2 = {0.f, 0.f, 0.f, 0.f}, a3 = {0.f, 0.f, 0.f, 0.f};
#pragma unroll
    for (int kk = 0; kk < 15; ++kk) {
      int ko = kk * 32 + lq * 8;
      short8 B0 = *reinterpret_cast<const short8*>(&uA[(lr)*HSTR + ko]);
      short8 B1 = *reinterpret_cast<const short8*>(&uA[(16 + lr) * HSTR + ko]);
      short8 B2 = *reinterpret_cast<const short8*>(&uA[(32 + lr) * HSTR + ko]);
      short8 B3 = *reinterpret_cast<const short8*>(&uA[(48 + lr) * HSTR + ko]);
      a0 = __builtin_amdgcn_mfma_f32_16x16x32_bf16(Af[kk], B0, a0, 0, 0, 0);
      a1 = __builtin_amdgcn_mfma_f32_16x16x32_bf16(Af[kk], B1, a1, 0, 0, 0);
      a2 = __builtin_amdgcn_mfma_f32_16x16x32_bf16(Af[kk], B2, a2, 0, 0, 0);
      a3 = __builtin_amdgcn_mfma_f32_16x16x32_bf16(Af[kk], B3, a3, 0, 0, 0);
    }
    {
      floatx4 aj[4] = {a0, a1, a2, a3};
#pragma unroll
      for (int jx = 0; jx < 4; ++jx) {
        int c = ch * 64 + jx * 16 + lr;
        float bb = b1s[c];
#pragma unroll
        for (int i = 0; i < 4; ++i)
          tps[w][lq * 4 + i][jx * 16 + lr] = f2bf(elu_f(aj[jx][i] + bb));
      }
    }
    asm volatile("s_waitcnt lgkmcnt(0)" ::: "memory");
    Af2[2 * ch] = *reinterpret_cast<const short8*>(&tps[w][lr][lq * 8]);
    if (ch < 7)
      Af2[2 * ch + 1] = *reinterpret_cast<const short8*>(&tps[w][lr][32 + lq * 8]);
    asm volatile("s_waitcnt lgkmcnt(0)" ::: "memory");
    __syncthreads();
    WWRITE()
    __syncthreads();
  }

  float p0[4] = {0.f, 0.f, 0.f, 0.f}, p1[4] = {0.f, 0.f, 0.f, 0.f};
#pragma unroll
  for (int ch = 0; ch < 4; ++ch) {
    if (ch < 3) WLOAD(w2p, ch + 1)
    floatx4 a0 = {0.f, 0.f, 0.f, 0.f}, a1 = {0.f, 0.f, 0.f, 0.f};
    floatx4 a2 = {0.f, 0.f, 0.f, 0.f}, a3 = {0.f, 0.f, 0.f, 0.f};
#pragma unroll
    for (int kk = 0; kk < 15; ++kk) {
      int ko = kk * 32 + lq * 8;
      short8 B0 = *reinterpret_cast<const short8*>(&uA[(lr)*HSTR + ko]);
      short8 B1 = *reinterpret_cast<const short8*>(&uA[(16 + lr) * HSTR + ko]);
      short8 B2 = *reinterpret_cast<const short8*>(&uA[(32 + lr) * HSTR + ko]);
      short8 B3 = *reinterpret_cast<const short8*>(&uA[(48 + lr) * HSTR + ko]);
      a0 = __builtin_amdgcn_mfma_f32_16x16x32_bf16(Af2[kk], B0, a0, 0, 0, 0);
      a1 = __builtin_amdgcn_mfma_f32_16x16x32_bf16(Af2[kk], B1, a1, 0, 0, 0);
      a2 = __builtin_amdgcn_mfma_f32_16x16x32_bf16(Af2[kk], B2, a2, 0, 0, 0);
      a3 = __builtin_amdgcn_mfma_f32_16x16x32_bf16(Af2[kk], B3, a3, 0, 0, 0);
    }
    {
      floatx4 aj[4] = {a0, a1, a2, a3};
#pragma unroll
      for (int jx = 0; jx < 4; ++jx) {
        int c = ch * 64 + jx * 16 + lr;
        float bb = b2s[c];
        float wa = w3s[2 * c], wb = w3s[2 * c + 1];
#pragma unroll
        for (int i = 0; i < 4; ++i) {
          float h = (c < 226) ? elu_f(aj[jx][i] + bb) : 0.f;
          p0[i] += h * wa;
          p1[i] += h * wb;
        }
      }
    }
    if (ch < 3) {
      __syncthreads();
      WWRITE()
      __syncthreads();
    }
  }

#pragma unroll
  for (int i = 0; i < 4; ++i) {
    float a = p0[i], bvv = p1[i];
#pragma unroll
    for (int m = 1; m < 16; m <<= 1) {
      a += __shfl_xor(a, m);
      bvv += __shfl_xor(bvv, m);
    }
    if (lr == 0) {
      size_t row = base + w * 16 + lq * 4 + i;
      float2 vv = {a + b3[0], bvv + b3[1]};
      *reinterpret_cast<float2*>(&out[row * 2]) = vv;
    }
  }
#undef WLOAD
#undef WWRITE
}

// ------------------------------------------------------------- launch ----
extern "C" void kernel_launch(void* const* d_in, const int* in_sizes, int n_in,
                              void* d_out, int out_size, void* d_ws, size_t ws_size,
                              hipStream_t stream) {
  const float* coords = (const float*)d_in[0];
  const float* feat   = (const float*)d_in[1];
  const float* c1w1 = (const float*)d_in[2];  const float* c1b1 = (const float*)d_in[3];
  const float* c1w2 = (const float*)d_in[4];  const float* c1b2 = (const float*)d_in[5];
  const float* c2w1 = (const float*)d_in[6];  const float* c2b1 = (const float*)d_in[7];
  const float* c2w2 = (const float*)d_in[8];  const float* c2b2 = (const float*)d_in[9];
  const float* c3w1 = (const float*)d_in[10]; const float* c3b1 = (const float*)d_in[11];
  const float* c3w2 = (const float*)d_in[12]; const float* c3b2 = (const float*)d_in[13];
  const float* ow1  = (const float*)d_in[14]; const float* ob1  = (const float*)d_in[15];
  const float* ow2  = (const float*)d_in[16]; const float* ob2  = (const float*)d_in[17];
  const float* ow3  = (const float*)d_in[18]; const float* ob3  = (const float*)d_in[19];
  float* out = (float*)d_out;

  char* ws = (char*)d_ws;
  float* out1 = (float*)(ws);                                    // [0,32) MiB
  float* out2 = (float*)(ws + (32ull << 20));                    // [32,96)
  unsigned short* out3b = (unsigned short*)(ws + (96ull << 20)); // [96,160)
  float* Hbuf2 = (float*)(ws + (96ull << 20));                   // [96,192) ec2 temp
  unsigned short* h1 = (unsigned short*)(ws + (162ull << 20));   // [162,212) ec3 temp
  unsigned short* w1p = (unsigned short*)(ws + (212ull << 20));
  unsigned short* w2p = (unsigned short*)(ws + (212ull << 20) + (512ull << 10));
  unsigned short* w1t3g = (unsigned short*)(ws + (213ull << 20));
  unsigned short* w2t3g = (unsigned short*)(ws + (213ull << 20) + (256ull << 10));
  int* idx = (int*)(ws + (214ull << 20));                        // [214,216)

  prep_kernel<<<1838, 256, 0, stream>>>(ow1, ow2, c3w1, c3w2,
                                        w1p, w2p, w1t3g, w2t3g);
  knn_kernel<2><<<NB, 128, 0, stream>>>(coords, idx);
  ec1_kernel<<<2 * NB, 256, 0, stream>>>(feat, idx, c1w1, c1b1, c1w2, c1b2, out1);
  knn_mfma_kernel<64><<<NB, 512, 0, stream>>>(out1, idx);
  for (int c = 0; c < 2; ++c) {
    ec2a_kernel<<<512, 512, 0, stream>>>(out1 + (size_t)c * 512 * NPT * 64,
                                         idx + (size_t)c * 512 * 512,
                                         c2w1, c2b1, Hbuf2);
    ec2b_kernel<<<1024, 512, 0, stream>>>(Hbuf2, c2w2, c2b2,
                                          out2 + (size_t)c * 512 * NPT * 128);
  }
  knn_mfma_kernel<128><<<NB, 512, 0, stream>>>(out2, idx);
  for (int c = 0; c < 4; ++c) {
    ec3a_kernel<<<256, 512, 0, stream>>>(out2 + (size_t)c * 256 * NPT * 128,
                                         idx + (size_t)c * 256 * 512,
                                         w1t3g, c3b1, h1);
    ec3b_kernel<<<256, 512, 0, stream>>>(h1, w2t3g, c3b2,
                                         out3b + (size_t)c * 256 * NPT * 256);
  }
  head_mfma_kernel<<<2048, 256, 0, stream>>>(feat, out1, out2, out3b,
                                             w1p, ob1, w2p, ob2, ow3, ob3, out);
}